// Round 1
// baseline (1257.472 us; speedup 1.0000x reference)
//
#include <hip/hip_runtime.h>
#include <math.h>

#define ROWS   16384L
#define LSEQ   1024
#define NB     16
#define DM     256
#define DPROJ  1288
#define XBCW   768
#define DIN    512
#define DSTATE 128
#define NH     8
#define HD     64
#define QLEN   256
#define NCHUNK 4
#define NCLS   17

// workspace offsets (in floats); total 54,919,168 floats = 219.7 MB
constexpr long O_U   = 0;                       // 16384*256 (reused as G after in_proj)
constexpr long O_ZX  = O_U   + ROWS*DM;         // 16384*1288
constexpr long O_XBC = O_ZX  + ROWS*DPROJ;      // 16384*768
constexpr long O_DT  = O_XBC + ROWS*XBCW;       // 16384*8
constexpr long O_ACS = O_DT  + ROWS*NH;         // 16*8*4*256
constexpr long O_Y   = O_ACS + 131072;          // 16384*512
constexpr long O_ST  = O_Y   + ROWS*DIN;        // 16*4*8*64*128 (scan converts to prev in place)
constexpr long O_Y2  = O_ST  + 4194304;         // 16384*256

// ---------------- generic f32 GEMM: C[M,N] = A[M,K] @ W[K,N] (+bias) ----------------
__global__ __launch_bounds__(256) void gemm_f32(
    const float* __restrict__ A, const float* __restrict__ W,
    const float* __restrict__ bias, float* __restrict__ C,
    int M, int N, int K)
{
  __shared__ float As[16][68];
  __shared__ float Ws[16][68];
  const int m0 = blockIdx.y * 64, n0 = blockIdx.x * 64;
  const int tid = threadIdx.x;
  const int tm = (tid >> 4) << 2, tn = (tid & 15) << 2;
  float acc[4][4] = {};
  for (int k0 = 0; k0 < K; k0 += 16) {
#pragma unroll
    for (int i = 0; i < 4; ++i) {                 // A tile 64x16
      int e = tid + i * 256;
      int m = e >> 4, k = e & 15;
      As[k][m] = (k0 + k < K) ? A[(long)(m0 + m) * K + k0 + k] : 0.f;
    }
#pragma unroll
    for (int i = 0; i < 4; ++i) {                 // W tile 16x64
      int e = tid + i * 256;
      int k = e >> 6, n = e & 63;
      Ws[k][n] = (k0 + k < K && n0 + n < N) ? W[(long)(k0 + k) * N + n0 + n] : 0.f;
    }
    __syncthreads();
#pragma unroll
    for (int k = 0; k < 16; ++k) {
      float a[4], w[4];
#pragma unroll
      for (int i = 0; i < 4; ++i) a[i] = As[k][tm + i];
#pragma unroll
      for (int j = 0; j < 4; ++j) w[j] = Ws[k][tn + j];
#pragma unroll
      for (int i = 0; i < 4; ++i)
#pragma unroll
        for (int j = 0; j < 4; ++j) acc[i][j] = fmaf(a[i], w[j], acc[i][j]);
    }
    __syncthreads();
  }
#pragma unroll
  for (int i = 0; i < 4; ++i) {
    long m = m0 + tm + i;
#pragma unroll
    for (int j = 0; j < 4; ++j) {
      int n = n0 + tn + j;
      if (n < N) C[m * (long)N + n] = acc[i][j] + (bias ? bias[n] : 0.f);
    }
  }
}

// ---------------- causal depthwise conv1d (k=4) + SiLU ----------------
__global__ __launch_bounds__(256) void conv_silu(
    const float* __restrict__ zx, const float* __restrict__ cw,
    const float* __restrict__ cb, float* __restrict__ out)
{
  long idx = (long)blockIdx.x * 256 + threadIdx.x;   // (b*l) * 768
  if (idx >= ROWS * XBCW) return;
  int ch = (int)(idx % XBCW);
  long row = idx / XBCW;
  int t = (int)(row % LSEQ);
  float acc = cb[ch];
#pragma unroll
  for (int w = 0; w < 4; ++w) {
    int tt = t - 3 + w;
    if (tt >= 0) acc += zx[(row + tt - t) * DPROJ + 512 + ch] * cw[w * XBCW + ch];
  }
  out[idx] = acc / (1.f + __expf(-acc));
}

// ---------------- dt = softplus(dt+bias); Acs = cumsum(dt*A) per (b,h,chunk) ----------------
__global__ void dt_cumsum(const float* __restrict__ zx, const float* __restrict__ dtb,
                          const float* __restrict__ alog,
                          float* __restrict__ dtsp, float* __restrict__ acs)
{
  int idx = blockIdx.x * blockDim.x + threadIdx.x;   // (b,h,c)
  if (idx >= NB * NH * NCHUNK) return;
  int c = idx & 3, h = (idx >> 2) & 7, b = idx >> 5;
  float Ah = -expf(alog[h]);
  float bias = dtb[h];
  float run = 0.f;
  long rowbase = (long)b * LSEQ + c * QLEN;
  long abase = (((long)b * NH + h) * NCHUNK + c) * QLEN;
  for (int q = 0; q < QLEN; ++q) {
    float xv = zx[(rowbase + q) * DPROJ + 1280 + h] + bias;
    float sp = (xv > 20.f) ? xv : log1pf(expf(xv));
    dtsp[(rowbase + q) * NH + h] = sp;
    run += sp * Ah;
    acs[abase + q] = run;
  }
}

// ---------------- G[q,k] = C(q)·B(k) per (b,c)  (NT GEMM, lower-triangle blocks only) ----------------
__global__ __launch_bounds__(256) void g_gemm(const float* __restrict__ xbc, float* __restrict__ G)
{
  if (blockIdx.x > blockIdx.y) return;               // upper-triangle tiles never read
  int bc = blockIdx.z;
  int q0 = blockIdx.y * 64, k0 = blockIdx.x * 64;
  long rowbase = (long)(bc >> 2) * LSEQ + (bc & 3) * QLEN;
  __shared__ float Cs[64][33], Bs[64][33];
  int tid = threadIdx.x;
  float acc[4][4] = {};
  for (int n0 = 0; n0 < DSTATE; n0 += 32) {
    for (int i = tid; i < 64 * 32; i += 256) {
      int r = i >> 5, nn = i & 31;
      Cs[r][nn] = xbc[(rowbase + q0 + r) * XBCW + 640 + n0 + nn];
      Bs[r][nn] = xbc[(rowbase + k0 + r) * XBCW + 512 + n0 + nn];
    }
    __syncthreads();
    int tq = (tid >> 4) << 2, tk = (tid & 15) << 2;
#pragma unroll
    for (int nn = 0; nn < 32; ++nn) {
      float cv[4], bv[4];
#pragma unroll
      for (int i = 0; i < 4; ++i) cv[i] = Cs[tq + i][nn];
#pragma unroll
      for (int j = 0; j < 4; ++j) bv[j] = Bs[tk + j][nn];
#pragma unroll
      for (int i = 0; i < 4; ++i)
#pragma unroll
        for (int j = 0; j < 4; ++j) acc[i][j] = fmaf(cv[i], bv[j], acc[i][j]);
    }
    __syncthreads();
  }
  long gb = (long)bc * 65536;
  int tq = (tid >> 4) << 2, tk = (tid & 15) << 2;
#pragma unroll
  for (int i = 0; i < 4; ++i)
#pragma unroll
    for (int j = 0; j < 4; ++j)
      G[gb + (long)(q0 + tq + i) * 256 + k0 + tk + j] = acc[i][j];
}

// ---------------- per (b,c,h): Yd (masked decay GEMM) + chunk states ----------------
__global__ __launch_bounds__(256) void yd_states(
    const float* __restrict__ xbc, const float* __restrict__ dtsp,
    const float* __restrict__ acs, const float* __restrict__ G,
    float* __restrict__ y, float* __restrict__ st)
{
  int bch = blockIdx.x;                      // ((b*4+c)*8+h)
  int h = bch & 7, bc = bch >> 3;
  int c = bc & 3, b = bc >> 2;
  __shared__ float Xd_s[QLEN][HD];           // 64 KB
  __shared__ float Acs_s[QLEN];
  long rowbase = (long)b * LSEQ + c * QLEN;
  for (int i = threadIdx.x; i < QLEN * HD; i += 256) {
    int q = i >> 6, p = i & 63;
    long row = rowbase + q;
    Xd_s[q][p] = xbc[row * XBCW + h * HD + p] * dtsp[row * NH + h];
  }
  if (threadIdx.x < QLEN)
    Acs_s[threadIdx.x] = acs[(((long)b * NH + h) * NCHUNK + c) * QLEN + threadIdx.x];
  __syncthreads();

  // Yd: wave-uniform q, lanes over p
  int p = threadIdx.x & 63, qg = threadIdx.x >> 6;
  long gbase = (long)bc * 65536;
  for (int qi = 0; qi < 64; ++qi) {
    int q = qi * 4 + qg;
    float aq = Acs_s[q];
    float acc = 0.f;
    const float* Grow = &G[gbase + (long)q * 256];
    for (int k = 0; k <= q; ++k)
      acc = fmaf(Grow[k] * __expf(aq - Acs_s[k]), Xd_s[k][p], acc);
    y[(rowbase + q) * DIN + h * HD + p] = acc;
  }

  // states[p,n] = sum_q B[q,n] * exp(AcsLast - Acs[q]) * Xd[q,p]
  int n = threadIdx.x & 127, ph = threadIdx.x >> 7;
  float AL = Acs_s[QLEN - 1];
  float accs[32];
#pragma unroll
  for (int i = 0; i < 32; ++i) accs[i] = 0.f;
  for (int q = 0; q < QLEN; ++q) {
    float w = __expf(AL - Acs_s[q]);
    float bv = xbc[(rowbase + q) * XBCW + 512 + n];
    float wb = w * bv;
#pragma unroll
    for (int pp = 0; pp < 32; ++pp)
      accs[pp] = fmaf(wb, Xd_s[q][ph * 32 + pp], accs[pp]);
  }
  long sbase = (long)bch * (HD * DSTATE);
  for (int pp = 0; pp < 32; ++pp)
    st[sbase + (ph * 32 + pp) * DSTATE + n] = accs[pp];
}

// ---------------- inter-chunk scan (in place: states -> prev) ----------------
__global__ void scan_states(float* __restrict__ st, const float* __restrict__ acs)
{
  long idx = (long)blockIdx.x * 256 + threadIdx.x;   // (b,h,p,n)
  if (idx >= (long)NB * NH * HD * DSTATE) return;
  int n = (int)(idx & 127);
  int p = (int)((idx >> 7) & 63);
  int h = (int)((idx >> 13) & 7);
  int b = (int)(idx >> 16);
  float carry = 0.f;
  for (int c = 0; c < NCHUNK; ++c) {
    float dc = __expf(acs[(((long)b * NH + h) * NCHUNK + c) * QLEN + (QLEN - 1)]);
    long si = ((((long)b * NCHUNK + c) * NH + h) * HD + p) * DSTATE + n;
    float s = st[si];
    st[si] = carry;
    carry = carry * dc + s;
  }
}

// ---------------- Yo = exp(Acs[q]) * C(q)·prev  ; y = Yd + Yo + xh*D ----------------
__global__ __launch_bounds__(256) void yo_combine(
    const float* __restrict__ xbc, const float* __restrict__ prev,
    const float* __restrict__ acs, const float* __restrict__ Dp,
    float* __restrict__ y)
{
  int bch = blockIdx.x;
  int h = bch & 7, bc = bch >> 3;
  int c = bc & 3, b = bc >> 2;
  __shared__ float Ps[HD][DSTATE + 1];     // pad kills bank conflicts
  __shared__ float As_[QLEN];
  for (int i = threadIdx.x; i < HD * DSTATE; i += 256)
    Ps[i >> 7][i & 127] = prev[(long)bch * (HD * DSTATE) + i];
  if (threadIdx.x < QLEN)
    As_[threadIdx.x] = acs[(((long)b * NH + h) * NCHUNK + c) * QLEN + threadIdx.x];
  __syncthreads();
  int p = threadIdx.x & 63, qg = threadIdx.x >> 6;
  float Dh = Dp[h];
  long rowbase = (long)b * LSEQ + c * QLEN;
  for (int qi = 0; qi < 64; ++qi) {
    int q = qi * 4 + qg;
    long row = rowbase + q;
    const float* Crow = &xbc[row * XBCW + 640];
    float acc = 0.f;
#pragma unroll 8
    for (int n = 0; n < DSTATE; ++n) acc = fmaf(Crow[n], Ps[p][n], acc);
    float xh = xbc[row * XBCW + h * HD + p];
    long yi = row * DIN + h * HD + p;
    y[yi] += acc * __expf(As_[q]) + xh * Dh;
  }
}

// ---------------- gated RMSNorm in place: y = rmsnorm(y*silu(z)) * rms_w ----------------
__global__ __launch_bounds__(256) void gated_rms(
    float* __restrict__ y, const float* __restrict__ zx, const float* __restrict__ rmsw)
{
  long row = blockIdx.x;
  int t = threadIdx.x;
  float z0 = zx[row * DPROJ + t], z1 = zx[row * DPROJ + t + 256];
  float v0 = y[row * DIN + t] * (z0 / (1.f + __expf(-z0)));
  float v1 = y[row * DIN + t + 256] * (z1 / (1.f + __expf(-z1)));
  float ss = v0 * v0 + v1 * v1;
#pragma unroll
  for (int off = 32; off; off >>= 1) ss += __shfl_down(ss, off);
  __shared__ float red[4];
  if ((t & 63) == 0) red[t >> 6] = ss;
  __syncthreads();
  float tot = red[0] + red[1] + red[2] + red[3];
  float scale = rsqrtf(tot * (1.f / DIN) + 1e-5f);
  y[row * DIN + t]       = v0 * scale * rmsw[t];
  y[row * DIN + t + 256] = v1 * scale * rmsw[t + 256];
}

// ---------------- LayerNorm in place over 256 ----------------
__global__ __launch_bounds__(256) void layernorm(
    float* __restrict__ y2, const float* __restrict__ g, const float* __restrict__ bb)
{
  long row = blockIdx.x;
  int t = threadIdx.x;
  float v = y2[row * DM + t];
  float s = v, q = v * v;
#pragma unroll
  for (int off = 32; off; off >>= 1) { s += __shfl_down(s, off); q += __shfl_down(q, off); }
  __shared__ float sA[4], sB[4];
  if ((t & 63) == 0) { sA[t >> 6] = s; sB[t >> 6] = q; }
  __syncthreads();
  float S = sA[0] + sA[1] + sA[2] + sA[3];
  float Qs = sB[0] + sB[1] + sB[2] + sB[3];
  float mu = S * (1.f / DM);
  float var = Qs * (1.f / DM) - mu * mu;
  y2[row * DM + t] = (v - mu) * rsqrtf(var + 1e-5f) * g[t] + bb[t];
}

// ---------------- classifier: out = yn @ w_cls + b_cls ----------------
__global__ void cls(const float* __restrict__ yn, const float* __restrict__ w,
                    const float* __restrict__ bias, float* __restrict__ out)
{
  long idx = (long)blockIdx.x * 256 + threadIdx.x;
  if (idx >= ROWS * NCLS) return;
  int j = (int)(idx % NCLS);
  long row = idx / NCLS;
  float acc = bias[j];
  for (int i = 0; i < DM; ++i) acc = fmaf(yn[row * DM + i], w[i * NCLS + j], acc);
  out[idx] = acc;
}

extern "C" void kernel_launch(void* const* d_in, const int* in_sizes, int n_in,
                              void* d_out, int out_size, void* d_ws, size_t ws_size,
                              hipStream_t stream)
{
  const float* x     = (const float*)d_in[0];
  const float* w_inp = (const float*)d_in[1];
  const float* b_inp = (const float*)d_in[2];
  const float* w_in  = (const float*)d_in[3];
  const float* convw = (const float*)d_in[4];
  const float* convb = (const float*)d_in[5];
  const float* dtb   = (const float*)d_in[6];
  const float* alog  = (const float*)d_in[7];
  const float* Dp    = (const float*)d_in[8];
  const float* rmsw  = (const float*)d_in[9];
  const float* wout  = (const float*)d_in[10];
  const float* lng   = (const float*)d_in[11];
  const float* lnb   = (const float*)d_in[12];
  const float* wcls  = (const float*)d_in[13];
  const float* bcls  = (const float*)d_in[14];
  float* out = (float*)d_out;
  float* ws  = (float*)d_ws;

  float* u    = ws + O_U;
  float* zx   = ws + O_ZX;
  float* xbc  = ws + O_XBC;
  float* dtsp = ws + O_DT;
  float* acs  = ws + O_ACS;
  float* G    = ws + O_U;    // reuse u
  float* y    = ws + O_Y;
  float* st   = ws + O_ST;
  float* y2   = ws + O_Y2;

  gemm_f32<<<dim3(4, 256), 256, 0, stream>>>(x, w_inp, b_inp, u, 16384, 256, 200);
  gemm_f32<<<dim3(21, 256), 256, 0, stream>>>(u, w_in, nullptr, zx, 16384, 1288, 256);
  conv_silu<<<(int)((ROWS * XBCW) / 256), 256, 0, stream>>>(zx, convw, convb, xbc);
  dt_cumsum<<<2, 256, 0, stream>>>(zx, dtb, alog, dtsp, acs);
  g_gemm<<<dim3(4, 4, 64), 256, 0, stream>>>(xbc, G);
  yd_states<<<512, 256, 0, stream>>>(xbc, dtsp, acs, G, y, st);
  scan_states<<<(int)((NB * NH * HD * DSTATE) / 256), 256, 0, stream>>>(st, acs);
  yo_combine<<<512, 256, 0, stream>>>(xbc, st, acs, Dp, y);
  gated_rms<<<16384, 256, 0, stream>>>(y, zx, rmsw);
  gemm_f32<<<dim3(4, 256), 256, 0, stream>>>(y, wout, nullptr, y2, 16384, 256, 512);
  layernorm<<<16384, 256, 0, stream>>>(y2, lng, lnb);
  cls<<<(int)((ROWS * NCLS + 255) / 256), 256, 0, stream>>>(y2, wcls, bcls, out);
}

// Round 2
// 749.897 us; speedup vs baseline: 1.6769x; 1.6769x over previous
//
#include <hip/hip_runtime.h>
#include <math.h>

#define ROWS   16384L
#define LSEQ   1024
#define NB     16
#define DM     256
#define DPROJ  1288
#define XBCW   768
#define DIN    512
#define DSTATE 128
#define NH     8
#define HD     64
#define QLEN   256
#define NCHUNK 4
#define NCLS   17

typedef __attribute__((ext_vector_type(8))) short s16x8;
typedef __attribute__((ext_vector_type(4))) float f32x4;

// workspace offsets (in floats)
constexpr long O_U    = 0;                       // 16384*256 f32 (reused as G after dt_cumsum2)
constexpr long O_ZX   = O_U   + ROWS*DM;         // 16384*1288 f32
constexpr long O_XBC  = O_ZX  + ROWS*DPROJ;      // 16384*768 f32
constexpr long O_DT   = O_XBC + ROWS*XBCW;       // 16384*8
constexpr long O_ACS  = O_DT  + ROWS*NH;         // 16*8*4*256
constexpr long O_Y    = O_ACS + 131072;          // 16384*512 f32
constexpr long O_ST   = O_Y   + ROWS*DIN;        // 16*4*8*64*128
constexpr long O_Y2   = O_ST  + 4194304;         // 16384*256
// overlapped bf16 buffers (element counts are bf16; offsets in float slots)
constexpr long O_UBF  = O_Y;                     // u_bf: 4.19M bf16 (2.10M float slots) — dead before y written
constexpr long O_WINT = O_Y + 2200000;           // w_inT: 1288x256 bf16
constexpr long O_YBF  = O_ZX;                    // y_bf: 8.39M bf16 — written after gated_rms (zx dead)
constexpr long O_WOUTT= O_ZX + 4300000;          // woutT: 256x512 bf16

__device__ inline unsigned short f2bf(float f) {
  union { float f; unsigned u; } v; v.f = f;
  unsigned r = v.u + 0x7FFFu + ((v.u >> 16) & 1u);
  return (unsigned short)(r >> 16);
}

// ---------------- f32 GEMM (input_proj only): C[M,N]=A[M,K]@W[K,N]+bias ----------------
__global__ __launch_bounds__(256) void gemm_f32(
    const float* __restrict__ A, const float* __restrict__ W,
    const float* __restrict__ bias, float* __restrict__ C,
    int M, int N, int K)
{
  __shared__ float As[16][68];
  __shared__ float Ws[16][68];
  const int m0 = blockIdx.y * 64, n0 = blockIdx.x * 64;
  const int tid = threadIdx.x;
  const int tm = (tid >> 4) << 2, tn = (tid & 15) << 2;
  float acc[4][4] = {};
  for (int k0 = 0; k0 < K; k0 += 16) {
#pragma unroll
    for (int i = 0; i < 4; ++i) {
      int e = tid + i * 256;
      int m = e >> 4, k = e & 15;
      As[k][m] = (k0 + k < K) ? A[(long)(m0 + m) * K + k0 + k] : 0.f;
    }
#pragma unroll
    for (int i = 0; i < 4; ++i) {
      int e = tid + i * 256;
      int k = e >> 6, n = e & 63;
      Ws[k][n] = (k0 + k < K && n0 + n < N) ? W[(long)(k0 + k) * N + n0 + n] : 0.f;
    }
    __syncthreads();
#pragma unroll
    for (int k = 0; k < 16; ++k) {
      float a[4], w[4];
#pragma unroll
      for (int i = 0; i < 4; ++i) a[i] = As[k][tm + i];
#pragma unroll
      for (int j = 0; j < 4; ++j) w[j] = Ws[k][tn + j];
#pragma unroll
      for (int i = 0; i < 4; ++i)
#pragma unroll
        for (int j = 0; j < 4; ++j) acc[i][j] = fmaf(a[i], w[j], acc[i][j]);
    }
    __syncthreads();
  }
#pragma unroll
  for (int i = 0; i < 4; ++i) {
    long m = m0 + tm + i;
#pragma unroll
    for (int j = 0; j < 4; ++j) {
      int n = n0 + tn + j;
      if (n < N) C[m * (long)N + n] = acc[i][j] + (bias ? bias[n] : 0.f);
    }
  }
}

// ---------------- cast f32 -> bf16 ----------------
__global__ __launch_bounds__(256) void cast_bf16(const float* __restrict__ src,
                                                 unsigned short* __restrict__ dst, long n)
{
  long i = ((long)blockIdx.x * 256 + threadIdx.x) * 4;
  if (i >= n) return;
  float4 v = *(const float4*)&src[i];
  ushort4 o;
  o.x = f2bf(v.x); o.y = f2bf(v.y); o.z = f2bf(v.z); o.w = f2bf(v.w);
  *(ushort4*)&dst[i] = o;
}

// ---------------- transpose+cast: w[K,N] f32 -> wt[N,K] bf16 (K = 1<<kbits) --------------
__global__ __launch_bounds__(256) void tcast(const float* __restrict__ w,
                                             unsigned short* __restrict__ wt,
                                             int kbits, int N)
{
  long i = (long)blockIdx.x * 256 + threadIdx.x;
  int K = 1 << kbits;
  if (i >= (long)K * N) return;
  int k = (int)(i & (K - 1));
  long n = i >> kbits;
  wt[i] = f2bf(w[(long)k * N + n]);
}

// ---------------- bf16 MFMA GEMM: C[M,N] = A[M,K] @ BT[N,K]^T ----------------
// 128x128 tile, BK=32, 4 waves; 16x16x32 bf16 MFMA.
__global__ __launch_bounds__(256) void gemm_bf16(
    const unsigned short* __restrict__ A,   // M x K bf16 row-major
    const unsigned short* __restrict__ BT,  // N x K bf16 row-major
    float* __restrict__ C, int M, int N, int K)
{
  __shared__ __align__(16) unsigned short As[128 * 32];
  __shared__ __align__(16) unsigned short Bs[128 * 32];
  const int tid = threadIdx.x;
  const int m0 = blockIdx.y * 128, n0 = blockIdx.x * 128;
  const int lane = tid & 63, wv = tid >> 6;
  const int wr = (wv >> 1) * 64, wc = (wv & 1) * 64;
  f32x4 acc[4][4];
#pragma unroll
  for (int i = 0; i < 4; ++i)
#pragma unroll
    for (int j = 0; j < 4; ++j) acc[i][j] = (f32x4){0.f, 0.f, 0.f, 0.f};

  for (int k0 = 0; k0 < K; k0 += 32) {
    __syncthreads();
#pragma unroll
    for (int s = 0; s < 2; ++s) {              // A tile: 128x32 bf16
      int idx = (tid + 256 * s) * 8;
      int r = idx >> 5, kk = idx & 31;
      *(s16x8*)&As[idx] = *(const s16x8*)&A[(long)(m0 + r) * K + k0 + kk];
    }
#pragma unroll
    for (int s = 0; s < 2; ++s) {              // B tile (transposed layout [n][k])
      int idx = (tid + 256 * s) * 8;
      int n = idx >> 5, kk = idx & 31;
      s16x8 vv = {};
      if (n0 + n < N) vv = *(const s16x8*)&BT[(long)(n0 + n) * K + k0 + kk];
      *(s16x8*)&Bs[idx] = vv;
    }
    __syncthreads();
    s16x8 af[4], bf[4];
#pragma unroll
    for (int i = 0; i < 4; ++i)
      af[i] = *(const s16x8*)&As[(wr + i * 16 + (lane & 15)) * 32 + (lane >> 4) * 8];
#pragma unroll
    for (int j = 0; j < 4; ++j)
      bf[j] = *(const s16x8*)&Bs[(wc + j * 16 + (lane & 15)) * 32 + (lane >> 4) * 8];
#pragma unroll
    for (int i = 0; i < 4; ++i)
#pragma unroll
      for (int j = 0; j < 4; ++j)
        acc[i][j] = __builtin_amdgcn_mfma_f32_16x16x32_bf16(af[i], bf[j], acc[i][j], 0, 0, 0);
  }
  const int cr = (lane >> 4) * 4, cc = lane & 15;
#pragma unroll
  for (int i = 0; i < 4; ++i)
#pragma unroll
    for (int j = 0; j < 4; ++j) {
      int col = n0 + wc + j * 16 + cc;
      if (col < N) {
        long rowb = (long)(m0 + wr + i * 16 + cr);
#pragma unroll
        for (int r = 0; r < 4; ++r)
          C[(rowb + r) * N + col] = acc[i][j][r];
      }
    }
}

// ---------------- causal depthwise conv1d (k=4) + SiLU ----------------
__global__ __launch_bounds__(256) void conv_silu(
    const float* __restrict__ zx, const float* __restrict__ cw,
    const float* __restrict__ cb, float* __restrict__ out)
{
  long idx = (long)blockIdx.x * 256 + threadIdx.x;
  if (idx >= ROWS * XBCW) return;
  int ch = (int)(idx % XBCW);
  long row = idx / XBCW;
  int t = (int)(row % LSEQ);
  float acc = cb[ch];
#pragma unroll
  for (int w = 0; w < 4; ++w) {
    int tt = t - 3 + w;
    if (tt >= 0) acc += zx[(row + tt - t) * DPROJ + 512 + ch] * cw[w * XBCW + ch];
  }
  out[idx] = acc / (1.f + __expf(-acc));
}

// ---------------- dt (f32 recompute) + softplus + wave-parallel cumsum ----------------
// one wave per (b,h,c); lane handles 4 consecutive q
__global__ __launch_bounds__(256) void dt_cumsum2(
    const float* __restrict__ u, const float* __restrict__ w_in,
    const float* __restrict__ dtb, const float* __restrict__ alog,
    float* __restrict__ dtsp, float* __restrict__ acs)
{
  int g = ((int)blockIdx.x * 256 + (int)threadIdx.x) >> 6;   // (b,h,c) group
  int lane = threadIdx.x & 63;
  int c = g & 3, h = (g >> 2) & 7, b = g >> 5;
  float Ah = -__expf(alog[h]);
  float bias = dtb[h];
  long rowbase = (long)b * LSEQ + c * QLEN;
  long abase = (((long)b * NH + h) * NCHUNK + c) * QLEN;
  float v[4];
#pragma unroll
  for (int j = 0; j < 4; ++j) {
    long row = rowbase + lane * 4 + j;
    const float4* u4 = (const float4*)&u[row * DM];
    float acc = bias;
    for (int i = 0; i < 64; ++i) {
      float4 uv = u4[i];
      acc += uv.x * w_in[(long)(i * 4 + 0) * DPROJ + 1280 + h]
           + uv.y * w_in[(long)(i * 4 + 1) * DPROJ + 1280 + h]
           + uv.z * w_in[(long)(i * 4 + 2) * DPROJ + 1280 + h]
           + uv.w * w_in[(long)(i * 4 + 3) * DPROJ + 1280 + h];
    }
    float sp = (acc > 20.f) ? acc : log1pf(__expf(acc));
    dtsp[row * NH + h] = sp;
    v[j] = sp * Ah;
  }
  v[1] += v[0]; v[2] += v[1]; v[3] += v[2];
  float tot = v[3];
  float run = tot;
#pragma unroll
  for (int d = 1; d < 64; d <<= 1) {
    float t = __shfl_up(run, d);
    if (lane >= d) run += t;
  }
  float excl = run - tot;
#pragma unroll
  for (int j = 0; j < 4; ++j) acs[abase + lane * 4 + j] = excl + v[j];
}

// ---------------- G[q,k] = C(q)·B(k) per (b,c) ----------------
__global__ __launch_bounds__(256) void g_gemm(const float* __restrict__ xbc, float* __restrict__ G)
{
  if (blockIdx.x > blockIdx.y) return;
  int bc = blockIdx.z;
  int q0 = blockIdx.y * 64, k0 = blockIdx.x * 64;
  long rowbase = (long)(bc >> 2) * LSEQ + (bc & 3) * QLEN;
  __shared__ float Cs[64][33], Bs2[64][33];
  int tid = threadIdx.x;
  float acc[4][4] = {};
  for (int n0 = 0; n0 < DSTATE; n0 += 32) {
    for (int i = tid; i < 64 * 32; i += 256) {
      int r = i >> 5, nn = i & 31;
      Cs[r][nn]  = xbc[(rowbase + q0 + r) * XBCW + 640 + n0 + nn];
      Bs2[r][nn] = xbc[(rowbase + k0 + r) * XBCW + 512 + n0 + nn];
    }
    __syncthreads();
    int tq = (tid >> 4) << 2, tk = (tid & 15) << 2;
#pragma unroll
    for (int nn = 0; nn < 32; ++nn) {
      float cv[4], bv[4];
#pragma unroll
      for (int i = 0; i < 4; ++i) cv[i] = Cs[tq + i][nn];
#pragma unroll
      for (int j = 0; j < 4; ++j) bv[j] = Bs2[tk + j][nn];
#pragma unroll
      for (int i = 0; i < 4; ++i)
#pragma unroll
        for (int j = 0; j < 4; ++j) acc[i][j] = fmaf(cv[i], bv[j], acc[i][j]);
    }
    __syncthreads();
  }
  long gb = (long)bc * 65536;
  int tq = (tid >> 4) << 2, tk = (tid & 15) << 2;
#pragma unroll
  for (int i = 0; i < 4; ++i)
#pragma unroll
    for (int j = 0; j < 4; ++j)
      G[gb + (long)(q0 + tq + i) * 256 + k0 + tk + j] = acc[i][j];
}

// ---------------- tiled yd + states; exp hoisted to cooperative LDS precompute ----------
__global__ __launch_bounds__(256) void yd_states2(
    const float* __restrict__ xbc, const float* __restrict__ dtsp,
    const float* __restrict__ acs, const float* __restrict__ G,
    float* __restrict__ y, float* __restrict__ st)
{
  int bch = blockIdx.x;                      // ((b*4+c)*8+h)
  int h = bch & 7, bc = bch >> 3;
  int c = bc & 3, b = bc >> 2;
  __shared__ __align__(16) float Xdt[64][68];
  __shared__ __align__(16) float Wt[64][68];
  __shared__ float AcsS[256];
  __shared__ float Eq[256];
  long rowbase = (long)b * LSEQ + c * QLEN;
  int tid = threadIdx.x;
  AcsS[tid] = acs[(((long)b * NH + h) * NCHUNK + c) * QLEN + tid];
  __syncthreads();
  float AL = AcsS[255];
  Eq[tid] = __expf(AL - AcsS[tid]);

  int p = tid & 63, qq = tid >> 6;
  long gbase = (long)bc * 65536;

  // ---- Phase A: Yd = (G o L) @ Xd, 64x64 tiles ----
  for (int qt = 0; qt < 4; ++qt) {
    float acc[16];
#pragma unroll
    for (int i = 0; i < 16; ++i) acc[i] = 0.f;
    for (int kt = 0; kt <= qt; ++kt) {
      __syncthreads();
#pragma unroll 4
      for (int s = 0; s < 16; ++s) {          // stage Xd tile (k rows)
        int e = tid + 256 * s;
        int r = e >> 6, pp = e & 63;
        long row = rowbase + kt * 64 + r;
        Xdt[r][pp] = xbc[row * XBCW + h * HD + pp] * dtsp[row * NH + h];
      }
#pragma unroll 4
      for (int s = 0; s < 16; ++s) {          // stage decay-weight tile
        int e = tid + 256 * s;
        int wq = e >> 6, wk = e & 63;
        int gq = qt * 64 + wq, gk = kt * 64 + wk;
        float wv = 0.f;
        if (gk <= gq) wv = G[gbase + (long)gq * 256 + gk] * __expf(AcsS[gq] - AcsS[gk]);
        Wt[wq][wk] = wv;
      }
      __syncthreads();
      for (int k = 0; k < 64; k += 4) {
        float x0 = Xdt[k][p], x1 = Xdt[k + 1][p], x2 = Xdt[k + 2][p], x3 = Xdt[k + 3][p];
#pragma unroll
        for (int i = 0; i < 16; ++i) {
          float4 w4 = *(const float4*)&Wt[qq * 16 + i][k];
          acc[i] += w4.x * x0 + w4.y * x1 + w4.z * x2 + w4.w * x3;
        }
      }
    }
#pragma unroll
    for (int i = 0; i < 16; ++i) {
      long row = rowbase + qt * 64 + qq * 16 + i;
      y[row * DIN + h * HD + p] = acc[i];
    }
  }

  // ---- Phase B: states[p][n] = sum_q B[q,n] * Eq[q] * Xd[q,p] ----
  int n = tid & 127, ph = tid >> 7;
  float acc2[32];
#pragma unroll
  for (int j = 0; j < 32; ++j) acc2[j] = 0.f;
  for (int kt = 0; kt < 4; ++kt) {
    __syncthreads();
#pragma unroll 4
    for (int s = 0; s < 16; ++s) {
      int e = tid + 256 * s;
      int r = e >> 6, pp = e & 63;
      long row = rowbase + kt * 64 + r;
      Xdt[r][pp] = xbc[row * XBCW + h * HD + pp] * dtsp[row * NH + h];
    }
    __syncthreads();
    for (int qk = 0; qk < 64; ++qk) {
      float w = Eq[kt * 64 + qk];
      float bv = xbc[(rowbase + kt * 64 + qk) * XBCW + 512 + n];
      float wb = w * bv;
#pragma unroll
      for (int j = 0; j < 32; j += 4) {
        float4 x4 = *(const float4*)&Xdt[qk][ph * 32 + j];
        acc2[j]     += wb * x4.x;
        acc2[j + 1] += wb * x4.y;
        acc2[j + 2] += wb * x4.z;
        acc2[j + 3] += wb * x4.w;
      }
    }
  }
  long sbase = (long)bch * (HD * DSTATE);
#pragma unroll
  for (int j = 0; j < 32; ++j)
    st[sbase + (long)(ph * 32 + j) * DSTATE + n] = acc2[j];
}

// ---------------- inter-chunk scan (in place: states -> prev) ----------------
__global__ void scan_states(float* __restrict__ st, const float* __restrict__ acs)
{
  long idx = (long)blockIdx.x * 256 + threadIdx.x;
  if (idx >= (long)NB * NH * HD * DSTATE) return;
  int n = (int)(idx & 127);
  int p = (int)((idx >> 7) & 63);
  int h = (int)((idx >> 13) & 7);
  int b = (int)(idx >> 16);
  float carry = 0.f;
  for (int c = 0; c < NCHUNK; ++c) {
    float dc = __expf(acs[(((long)b * NH + h) * NCHUNK + c) * QLEN + (QLEN - 1)]);
    long si = ((((long)b * NCHUNK + c) * NH + h) * HD + p) * DSTATE + n;
    float s = st[si];
    st[si] = carry;
    carry = carry * dc + s;
  }
}

// ---------------- Yo = exp(Acs[q]) * C(q)·prev ; y += Yo + xh*D ----------------
__global__ __launch_bounds__(256) void yo_combine2(
    const float* __restrict__ xbc, const float* __restrict__ prev,
    const float* __restrict__ acs, const float* __restrict__ Dp,
    float* __restrict__ y)
{
  int bch = blockIdx.x;
  int h = bch & 7, bc = bch >> 3;
  int c = bc & 3, b = bc >> 2;
  __shared__ __align__(16) float Ps[HD][132];
  __shared__ float EqA[QLEN];
  int tid = threadIdx.x;
  for (int i = tid; i < HD * DSTATE; i += 256)
    Ps[i >> 7][i & 127] = prev[(long)bch * (HD * DSTATE) + i];
  EqA[tid] = __expf(acs[(((long)b * NH + h) * NCHUNK + c) * QLEN + tid]);
  __syncthreads();
  int p = tid & 63, qg = tid >> 6;
  float Dh = Dp[h];
  long rowbase = (long)b * LSEQ + c * QLEN;
  for (int qi = 0; qi < 64; ++qi) {
    int q = qi * 4 + qg;
    long row = rowbase + q;
    const float4* C4 = (const float4*)&xbc[row * XBCW + 640];
    float acc = 0.f;
#pragma unroll
    for (int n4 = 0; n4 < 32; ++n4) {
      float4 cv = C4[n4];
      float4 pv = *(const float4*)&Ps[p][n4 * 4];
      acc += cv.x * pv.x + cv.y * pv.y + cv.z * pv.z + cv.w * pv.w;
    }
    float xh = xbc[row * XBCW + h * HD + p];
    long yi = row * DIN + h * HD + p;
    y[yi] += acc * EqA[q] + xh * Dh;
  }
}

// ---------------- gated RMSNorm in place ----------------
__global__ __launch_bounds__(256) void gated_rms(
    float* __restrict__ y, const float* __restrict__ zx, const float* __restrict__ rmsw)
{
  long row = blockIdx.x;
  int t = threadIdx.x;
  float z0 = zx[row * DPROJ + t], z1 = zx[row * DPROJ + t + 256];
  float v0 = y[row * DIN + t] * (z0 / (1.f + __expf(-z0)));
  float v1 = y[row * DIN + t + 256] * (z1 / (1.f + __expf(-z1)));
  float ss = v0 * v0 + v1 * v1;
#pragma unroll
  for (int off = 32; off; off >>= 1) ss += __shfl_down(ss, off);
  __shared__ float red[4];
  if ((t & 63) == 0) red[t >> 6] = ss;
  __syncthreads();
  float tot = red[0] + red[1] + red[2] + red[3];
  float scale = rsqrtf(tot * (1.f / DIN) + 1e-5f);
  y[row * DIN + t]       = v0 * scale * rmsw[t];
  y[row * DIN + t + 256] = v1 * scale * rmsw[t + 256];
}

// ---------------- LayerNorm in place over 256 ----------------
__global__ __launch_bounds__(256) void layernorm(
    float* __restrict__ y2, const float* __restrict__ g, const float* __restrict__ bb)
{
  long row = blockIdx.x;
  int t = threadIdx.x;
  float v = y2[row * DM + t];
  float s = v, q = v * v;
#pragma unroll
  for (int off = 32; off; off >>= 1) { s += __shfl_down(s, off); q += __shfl_down(q, off); }
  __shared__ float sA[4], sB[4];
  if ((t & 63) == 0) { sA[t >> 6] = s; sB[t >> 6] = q; }
  __syncthreads();
  float S = sA[0] + sA[1] + sA[2] + sA[3];
  float Qs = sB[0] + sB[1] + sB[2] + sB[3];
  float mu = S * (1.f / DM);
  float var = Qs * (1.f / DM) - mu * mu;
  y2[row * DM + t] = (v - mu) * rsqrtf(var + 1e-5f) * g[t] + bb[t];
}

// ---------------- classifier ----------------
__global__ void cls(const float* __restrict__ yn, const float* __restrict__ w,
                    const float* __restrict__ bias, float* __restrict__ out)
{
  long idx = (long)blockIdx.x * 256 + threadIdx.x;
  if (idx >= ROWS * NCLS) return;
  int j = (int)(idx % NCLS);
  long row = idx / NCLS;
  float acc = bias[j];
  for (int i = 0; i < DM; ++i) acc = fmaf(yn[row * DM + i], w[i * NCLS + j], acc);
  out[idx] = acc;
}

extern "C" void kernel_launch(void* const* d_in, const int* in_sizes, int n_in,
                              void* d_out, int out_size, void* d_ws, size_t ws_size,
                              hipStream_t stream)
{
  const float* x     = (const float*)d_in[0];
  const float* w_inp = (const float*)d_in[1];
  const float* b_inp = (const float*)d_in[2];
  const float* w_in  = (const float*)d_in[3];
  const float* convw = (const float*)d_in[4];
  const float* convb = (const float*)d_in[5];
  const float* dtb   = (const float*)d_in[6];
  const float* alog  = (const float*)d_in[7];
  const float* Dp    = (const float*)d_in[8];
  const float* rmsw  = (const float*)d_in[9];
  const float* wout  = (const float*)d_in[10];
  const float* lng   = (const float*)d_in[11];
  const float* lnb   = (const float*)d_in[12];
  const float* wcls  = (const float*)d_in[13];
  const float* bcls  = (const float*)d_in[14];
  float* out = (float*)d_out;
  float* ws  = (float*)d_ws;

  float* u    = ws + O_U;
  float* zx   = ws + O_ZX;
  float* xbc  = ws + O_XBC;
  float* dtsp = ws + O_DT;
  float* acs  = ws + O_ACS;
  float* G    = ws + O_U;    // reuse u (after dt_cumsum2)
  float* y    = ws + O_Y;
  float* st   = ws + O_ST;
  float* y2   = ws + O_Y2;
  unsigned short* u_bf  = (unsigned short*)(ws + O_UBF);
  unsigned short* w_inT = (unsigned short*)(ws + O_WINT);
  unsigned short* y_bf  = (unsigned short*)(ws + O_YBF);
  unsigned short* woutT = (unsigned short*)(ws + O_WOUTT);

  // input_proj (f32): u = x @ w_inp + b_inp
  gemm_f32<<<dim3(4, 256), 256, 0, stream>>>(x, w_inp, b_inp, u, 16384, 256, 200);
  // in_proj via bf16 MFMA
  cast_bf16<<<4096, 256, 0, stream>>>(u, u_bf, ROWS * DM);
  tcast<<<1288, 256, 0, stream>>>(w_in, w_inT, 8, DPROJ);
  gemm_bf16<<<dim3(11, 128), 256, 0, stream>>>(u_bf, w_inT, zx, 16384, DPROJ, DM);
  // conv + SiLU
  conv_silu<<<(int)((ROWS * XBCW) / 256), 256, 0, stream>>>(zx, convw, convb, xbc);
  // dt in f32 (recomputed from u) + wave-parallel cumsum
  dt_cumsum2<<<128, 256, 0, stream>>>(u, w_in, dtb, alog, dtsp, acs);
  // SSD
  g_gemm<<<dim3(4, 4, 64), 256, 0, stream>>>(xbc, G);
  yd_states2<<<512, 256, 0, stream>>>(xbc, dtsp, acs, G, y, st);
  scan_states<<<4096, 256, 0, stream>>>(st, acs);
  yo_combine2<<<512, 256, 0, stream>>>(xbc, st, acs, Dp, y);
  // gated RMSNorm
  gated_rms<<<16384, 256, 0, stream>>>(y, zx, rmsw);
  // out_proj via bf16 MFMA
  cast_bf16<<<8192, 256, 0, stream>>>(y, y_bf, ROWS * DIN);
  tcast<<<512, 256, 0, stream>>>(wout, woutT, 9, DM);
  gemm_bf16<<<dim3(2, 128), 256, 0, stream>>>(y_bf, woutT, y2, 16384, DM, DIN);
  // classifier head
  layernorm<<<16384, 256, 0, stream>>>(y2, lng, lnb);
  cls<<<(int)((ROWS * NCLS + 255) / 256), 256, 0, stream>>>(y2, wcls, bcls, out);
}

// Round 3
// 562.670 us; speedup vs baseline: 2.2348x; 1.3327x over previous
//
#include <hip/hip_runtime.h>
#include <math.h>

#define ROWS   16384L
#define LSEQ   1024
#define NB     16
#define DM     256
#define DPROJ  1288
#define XBCW   768
#define DIN    512
#define DSTATE 128
#define NH     8
#define HD     64
#define QLEN   256
#define NCHUNK 4
#define NCLS   17

typedef __attribute__((ext_vector_type(8))) short s16x8;
typedef __attribute__((ext_vector_type(4))) float f32x4;

// workspace offsets (in floats)
constexpr long O_U    = 0;                       // 16384*256 f32 (reused as G after dt_cumsum2)
constexpr long O_ZX   = O_U   + ROWS*DM;         // 16384*1288 f32
constexpr long O_XBC  = O_ZX  + ROWS*DPROJ;      // 16384*768 f32
constexpr long O_DT   = O_XBC + ROWS*XBCW;       // 16384*8
constexpr long O_ACS  = O_DT  + ROWS*NH;         // 16*8*4*256
constexpr long O_Y    = O_ACS + 131072;          // 16384*512 f32
constexpr long O_ST   = O_Y   + ROWS*DIN;        // 16*4*8*64*128
constexpr long O_Y2   = O_ST  + 4194304;         // 16384*256
// overlays (bf16 counts; offsets in float slots)
constexpr long O_UBF  = O_Y;                     // u_bf: dead before y written
constexpr long O_WINT = O_Y + 2200000;           // w_inT: 1288x256 bf16
constexpr long O_YBF  = O_ZX;                    // y_bf: zx dead after gated_rms
constexpr long O_WOUTT= O_ZX + 4300000;          // woutT
constexpr long O_BBF  = O_Y2;                    // B bf16 [ROWS][128] (y2 written much later)
constexpr long O_CBF  = O_Y2 + 1048576;          // C bf16 [ROWS][128]

__device__ inline unsigned short f2bf(float f) {
  union { float f; unsigned u; } v; v.f = f;
  unsigned r = v.u + 0x7FFFu + ((v.u >> 16) & 1u);
  return (unsigned short)(r >> 16);
}

// ---------------- f32 GEMM (input_proj only) ----------------
__global__ __launch_bounds__(256) void gemm_f32(
    const float* __restrict__ A, const float* __restrict__ W,
    const float* __restrict__ bias, float* __restrict__ C,
    int M, int N, int K)
{
  __shared__ float As[16][68];
  __shared__ float Ws[16][68];
  const int m0 = blockIdx.y * 64, n0 = blockIdx.x * 64;
  const int tid = threadIdx.x;
  const int tm = (tid >> 4) << 2, tn = (tid & 15) << 2;
  float acc[4][4] = {};
  for (int k0 = 0; k0 < K; k0 += 16) {
#pragma unroll
    for (int i = 0; i < 4; ++i) {
      int e = tid + i * 256;
      int m = e >> 4, k = e & 15;
      As[k][m] = (k0 + k < K) ? A[(long)(m0 + m) * K + k0 + k] : 0.f;
    }
#pragma unroll
    for (int i = 0; i < 4; ++i) {
      int e = tid + i * 256;
      int k = e >> 6, n = e & 63;
      Ws[k][n] = (k0 + k < K && n0 + n < N) ? W[(long)(k0 + k) * N + n0 + n] : 0.f;
    }
    __syncthreads();
#pragma unroll
    for (int k = 0; k < 16; ++k) {
      float a[4], w[4];
#pragma unroll
      for (int i = 0; i < 4; ++i) a[i] = As[k][tm + i];
#pragma unroll
      for (int j = 0; j < 4; ++j) w[j] = Ws[k][tn + j];
#pragma unroll
      for (int i = 0; i < 4; ++i)
#pragma unroll
        for (int j = 0; j < 4; ++j) acc[i][j] = fmaf(a[i], w[j], acc[i][j]);
    }
    __syncthreads();
  }
#pragma unroll
  for (int i = 0; i < 4; ++i) {
    long m = m0 + tm + i;
#pragma unroll
    for (int j = 0; j < 4; ++j) {
      int n = n0 + tn + j;
      if (n < N) C[m * (long)N + n] = acc[i][j] + (bias ? bias[n] : 0.f);
    }
  }
}

// ---------------- cast f32 -> bf16 ----------------
__global__ __launch_bounds__(256) void cast_bf16(const float* __restrict__ src,
                                                 unsigned short* __restrict__ dst, long n)
{
  long i = ((long)blockIdx.x * 256 + threadIdx.x) * 4;
  if (i >= n) return;
  float4 v = *(const float4*)&src[i];
  ushort4 o;
  o.x = f2bf(v.x); o.y = f2bf(v.y); o.z = f2bf(v.z); o.w = f2bf(v.w);
  *(ushort4*)&dst[i] = o;
}

// ---------------- transpose+cast: w[K,N] f32 -> wt[N,K] bf16 ----------------
__global__ __launch_bounds__(256) void tcast(const float* __restrict__ w,
                                             unsigned short* __restrict__ wt,
                                             int kbits, int N)
{
  long i = (long)blockIdx.x * 256 + threadIdx.x;
  int K = 1 << kbits;
  if (i >= (long)K * N) return;
  int k = (int)(i & (K - 1));
  long n = i >> kbits;
  wt[i] = f2bf(w[(long)k * N + n]);
}

// ---------------- bf16 MFMA GEMM: C[M,N] = A[M,K] @ BT[N,K]^T ----------------
__global__ __launch_bounds__(256) void gemm_bf16(
    const unsigned short* __restrict__ A, const unsigned short* __restrict__ BT,
    float* __restrict__ C, int M, int N, int K)
{
  __shared__ __align__(16) unsigned short As[128 * 32];
  __shared__ __align__(16) unsigned short Bs[128 * 32];
  const int tid = threadIdx.x;
  const int m0 = blockIdx.y * 128, n0 = blockIdx.x * 128;
  const int lane = tid & 63, wv = tid >> 6;
  const int wr = (wv >> 1) * 64, wc = (wv & 1) * 64;
  f32x4 acc[4][4];
#pragma unroll
  for (int i = 0; i < 4; ++i)
#pragma unroll
    for (int j = 0; j < 4; ++j) acc[i][j] = (f32x4){0.f, 0.f, 0.f, 0.f};

  for (int k0 = 0; k0 < K; k0 += 32) {
    __syncthreads();
#pragma unroll
    for (int s = 0; s < 2; ++s) {
      int idx = (tid + 256 * s) * 8;
      int r = idx >> 5, kk = idx & 31;
      *(s16x8*)&As[idx] = *(const s16x8*)&A[(long)(m0 + r) * K + k0 + kk];
    }
#pragma unroll
    for (int s = 0; s < 2; ++s) {
      int idx = (tid + 256 * s) * 8;
      int n = idx >> 5, kk = idx & 31;
      s16x8 vv = {};
      if (n0 + n < N) vv = *(const s16x8*)&BT[(long)(n0 + n) * K + k0 + kk];
      *(s16x8*)&Bs[idx] = vv;
    }
    __syncthreads();
    s16x8 af[4], bf[4];
#pragma unroll
    for (int i = 0; i < 4; ++i)
      af[i] = *(const s16x8*)&As[(wr + i * 16 + (lane & 15)) * 32 + (lane >> 4) * 8];
#pragma unroll
    for (int j = 0; j < 4; ++j)
      bf[j] = *(const s16x8*)&Bs[(wc + j * 16 + (lane & 15)) * 32 + (lane >> 4) * 8];
#pragma unroll
    for (int i = 0; i < 4; ++i)
#pragma unroll
      for (int j = 0; j < 4; ++j)
        acc[i][j] = __builtin_amdgcn_mfma_f32_16x16x32_bf16(af[i], bf[j], acc[i][j], 0, 0, 0);
  }
  const int cr = (lane >> 4) * 4, cc = lane & 15;
#pragma unroll
  for (int i = 0; i < 4; ++i)
#pragma unroll
    for (int j = 0; j < 4; ++j) {
      int col = n0 + wc + j * 16 + cc;
      if (col < N) {
        long rowb = (long)(m0 + wr + i * 16 + cr);
#pragma unroll
        for (int r = 0; r < 4; ++r)
          C[(rowb + r) * N + col] = acc[i][j][r];
      }
    }
}

// ---------------- G = C·B^T per (b,c) via MFMA (lower-tri blocks) ----------------
__global__ __launch_bounds__(256) void g_gemm_bf16(
    const unsigned short* __restrict__ Cbf, const unsigned short* __restrict__ Bbf,
    float* __restrict__ G)
{
  if (blockIdx.x > blockIdx.y) return;            // (1,0) of 2x2 never read
  int bc = blockIdx.z;
  long rowbase = (long)(bc >> 2) * LSEQ + (bc & 3) * QLEN;
  const unsigned short* A  = Cbf + rowbase * 128;
  const unsigned short* BT = Bbf + rowbase * 128;
  float* Gout = G + (long)bc * 65536;
  __shared__ __align__(16) unsigned short As[128 * 32];
  __shared__ __align__(16) unsigned short Bs[128 * 32];
  const int tid = threadIdx.x;
  const int m0 = blockIdx.y * 128, n0 = blockIdx.x * 128;
  const int lane = tid & 63, wv = tid >> 6;
  const int wr = (wv >> 1) * 64, wc = (wv & 1) * 64;
  f32x4 acc[4][4];
#pragma unroll
  for (int i = 0; i < 4; ++i)
#pragma unroll
    for (int j = 0; j < 4; ++j) acc[i][j] = (f32x4){0.f, 0.f, 0.f, 0.f};
  for (int k0 = 0; k0 < 128; k0 += 32) {
    __syncthreads();
#pragma unroll
    for (int s = 0; s < 2; ++s) {
      int idx = (tid + 256 * s) * 8;
      int r = idx >> 5, kk = idx & 31;
      *(s16x8*)&As[idx] = *(const s16x8*)&A[(long)(m0 + r) * 128 + k0 + kk];
      *(s16x8*)&Bs[idx] = *(const s16x8*)&BT[(long)(n0 + r) * 128 + k0 + kk];
    }
    __syncthreads();
    s16x8 af[4], bf[4];
#pragma unroll
    for (int i = 0; i < 4; ++i)
      af[i] = *(const s16x8*)&As[(wr + i * 16 + (lane & 15)) * 32 + (lane >> 4) * 8];
#pragma unroll
    for (int j = 0; j < 4; ++j)
      bf[j] = *(const s16x8*)&Bs[(wc + j * 16 + (lane & 15)) * 32 + (lane >> 4) * 8];
#pragma unroll
    for (int i = 0; i < 4; ++i)
#pragma unroll
      for (int j = 0; j < 4; ++j)
        acc[i][j] = __builtin_amdgcn_mfma_f32_16x16x32_bf16(af[i], bf[j], acc[i][j], 0, 0, 0);
  }
  const int cr = (lane >> 4) * 4, cc = lane & 15;
#pragma unroll
  for (int i = 0; i < 4; ++i)
#pragma unroll
    for (int j = 0; j < 4; ++j) {
      int col = n0 + wc + j * 16 + cc;
      long rowb = (long)(m0 + wr + i * 16 + cr);
#pragma unroll
      for (int r = 0; r < 4; ++r)
        Gout[(rowb + r) * 256 + col] = acc[i][j][r];
    }
}

// ---------------- causal depthwise conv1d (k=4) + SiLU; emits bf16 B,C copies --------
__global__ __launch_bounds__(256) void conv_silu(
    const float* __restrict__ zx, const float* __restrict__ cw,
    const float* __restrict__ cb, float* __restrict__ out,
    unsigned short* __restrict__ Bbf, unsigned short* __restrict__ Cbf)
{
  long idx = (long)blockIdx.x * 256 + threadIdx.x;
  if (idx >= ROWS * XBCW) return;
  int ch = (int)(idx % XBCW);
  long row = idx / XBCW;
  int t = (int)(row % LSEQ);
  float acc = cb[ch];
#pragma unroll
  for (int w = 0; w < 4; ++w) {
    int tt = t - 3 + w;
    if (tt >= 0) acc += zx[(row + tt - t) * DPROJ + 512 + ch] * cw[w * XBCW + ch];
  }
  float r = acc / (1.f + __expf(-acc));
  out[idx] = r;
  if (ch >= 512) {
    unsigned short bv = f2bf(r);
    if (ch < 640) Bbf[row * 128 + ch - 512] = bv;
    else          Cbf[row * 128 + ch - 640] = bv;
  }
}

// ---------------- dt (f32 recompute) + softplus + wave-parallel cumsum ----------------
__global__ __launch_bounds__(256) void dt_cumsum2(
    const float* __restrict__ u, const float* __restrict__ w_in,
    const float* __restrict__ dtb, const float* __restrict__ alog,
    float* __restrict__ dtsp, float* __restrict__ acs)
{
  int g = ((int)blockIdx.x * 256 + (int)threadIdx.x) >> 6;
  int lane = threadIdx.x & 63;
  int c = g & 3, h = (g >> 2) & 7, b = g >> 5;
  float Ah = -__expf(alog[h]);
  float bias = dtb[h];
  long rowbase = (long)b * LSEQ + c * QLEN;
  long abase = (((long)b * NH + h) * NCHUNK + c) * QLEN;
  float v[4];
#pragma unroll
  for (int j = 0; j < 4; ++j) {
    long row = rowbase + lane * 4 + j;
    const float4* u4 = (const float4*)&u[row * DM];
    float acc = bias;
    for (int i = 0; i < 64; ++i) {
      float4 uv = u4[i];
      acc += uv.x * w_in[(long)(i * 4 + 0) * DPROJ + 1280 + h]
           + uv.y * w_in[(long)(i * 4 + 1) * DPROJ + 1280 + h]
           + uv.z * w_in[(long)(i * 4 + 2) * DPROJ + 1280 + h]
           + uv.w * w_in[(long)(i * 4 + 3) * DPROJ + 1280 + h];
    }
    float sp = (acc > 20.f) ? acc : log1pf(__expf(acc));
    dtsp[row * NH + h] = sp;
    v[j] = sp * Ah;
  }
  v[1] += v[0]; v[2] += v[1]; v[3] += v[2];
  float tot = v[3];
  float run = tot;
#pragma unroll
  for (int d = 1; d < 64; d <<= 1) {
    float t = __shfl_up(run, d);
    if (lane >= d) run += t;
  }
  float excl = run - tot;
#pragma unroll
  for (int j = 0; j < 4; ++j) acs[abase + lane * 4 + j] = excl + v[j];
}

// ---------------- tiled yd + states ----------------
__global__ __launch_bounds__(256) void yd_states2(
    const float* __restrict__ xbc, const float* __restrict__ dtsp,
    const float* __restrict__ acs, const float* __restrict__ G,
    float* __restrict__ y, float* __restrict__ st)
{
  int bch = blockIdx.x;
  int h = bch & 7, bc = bch >> 3;
  int c = bc & 3, b = bc >> 2;
  __shared__ __align__(16) float Xdt[64][68];
  __shared__ __align__(16) float Wt[64][68];
  __shared__ float AcsS[256];
  __shared__ float Eq[256];
  long rowbase = (long)b * LSEQ + c * QLEN;
  int tid = threadIdx.x;
  AcsS[tid] = acs[(((long)b * NH + h) * NCHUNK + c) * QLEN + tid];
  __syncthreads();
  float AL = AcsS[255];
  Eq[tid] = __expf(AL - AcsS[tid]);

  int p = tid & 63, qq = tid >> 6;
  long gbase = (long)bc * 65536;

  for (int qt = 0; qt < 4; ++qt) {
    float acc[16];
#pragma unroll
    for (int i = 0; i < 16; ++i) acc[i] = 0.f;
    for (int kt = 0; kt <= qt; ++kt) {
      __syncthreads();
#pragma unroll 4
      for (int s = 0; s < 16; ++s) {
        int e = tid + 256 * s;
        int r = e >> 6, pp = e & 63;
        long row = rowbase + kt * 64 + r;
        Xdt[r][pp] = xbc[row * XBCW + h * HD + pp] * dtsp[row * NH + h];
      }
#pragma unroll 4
      for (int s = 0; s < 16; ++s) {
        int e = tid + 256 * s;
        int wq = e >> 6, wk = e & 63;
        int gq = qt * 64 + wq, gk = kt * 64 + wk;
        float wv = 0.f;
        if (gk <= gq) wv = G[gbase + (long)gq * 256 + gk] * __expf(AcsS[gq] - AcsS[gk]);
        Wt[wq][wk] = wv;
      }
      __syncthreads();
      for (int k = 0; k < 64; k += 4) {
        float x0 = Xdt[k][p], x1 = Xdt[k + 1][p], x2 = Xdt[k + 2][p], x3 = Xdt[k + 3][p];
#pragma unroll
        for (int i = 0; i < 16; ++i) {
          float4 w4 = *(const float4*)&Wt[qq * 16 + i][k];
          acc[i] += w4.x * x0 + w4.y * x1 + w4.z * x2 + w4.w * x3;
        }
      }
    }
#pragma unroll
    for (int i = 0; i < 16; ++i) {
      long row = rowbase + qt * 64 + qq * 16 + i;
      y[row * DIN + h * HD + p] = acc[i];
    }
  }

  int n = tid & 127, ph = tid >> 7;
  float acc2[32];
#pragma unroll
  for (int j = 0; j < 32; ++j) acc2[j] = 0.f;
  for (int kt = 0; kt < 4; ++kt) {
    __syncthreads();
#pragma unroll 4
    for (int s = 0; s < 16; ++s) {
      int e = tid + 256 * s;
      int r = e >> 6, pp = e & 63;
      long row = rowbase + kt * 64 + r;
      Xdt[r][pp] = xbc[row * XBCW + h * HD + pp] * dtsp[row * NH + h];
    }
    __syncthreads();
    for (int qk = 0; qk < 64; ++qk) {
      float w = Eq[kt * 64 + qk];
      float bv = xbc[(rowbase + kt * 64 + qk) * XBCW + 512 + n];
      float wb = w * bv;
#pragma unroll
      for (int j = 0; j < 32; j += 4) {
        float4 x4 = *(const float4*)&Xdt[qk][ph * 32 + j];
        acc2[j]     += wb * x4.x;
        acc2[j + 1] += wb * x4.y;
        acc2[j + 2] += wb * x4.z;
        acc2[j + 3] += wb * x4.w;
      }
    }
  }
  long sbase = (long)bch * (HD * DSTATE);
#pragma unroll
  for (int j = 0; j < 32; ++j)
    st[sbase + (long)(ph * 32 + j) * DSTATE + n] = acc2[j];
}

// ---------------- inter-chunk scan ----------------
__global__ void scan_states(float* __restrict__ st, const float* __restrict__ acs)
{
  long idx = (long)blockIdx.x * 256 + threadIdx.x;
  if (idx >= (long)NB * NH * HD * DSTATE) return;
  int n = (int)(idx & 127);
  int p = (int)((idx >> 7) & 63);
  int h = (int)((idx >> 13) & 7);
  int b = (int)(idx >> 16);
  float carry = 0.f;
  for (int c = 0; c < NCHUNK; ++c) {
    float dc = __expf(acs[(((long)b * NH + h) * NCHUNK + c) * QLEN + (QLEN - 1)]);
    long si = ((((long)b * NCHUNK + c) * NH + h) * HD + p) * DSTATE + n;
    float s = st[si];
    st[si] = carry;
    carry = carry * dc + s;
  }
}

// ---------------- Yo as tiled f32 GEMM: y += exp(Acs[q]) * C·prev^T + xh*D -----------
__global__ __launch_bounds__(256) void yo_combine3(
    const float* __restrict__ xbc, const float* __restrict__ prev,
    const float* __restrict__ acs, const float* __restrict__ Dp,
    float* __restrict__ y)
{
  int bch = blockIdx.x;
  int h = bch & 7, bc = bch >> 3;
  int c = bc & 3, b = bc >> 2;
  __shared__ __align__(16) float Pn[128][68];   // Pn[n][p] = prev[p][n]
  __shared__ __align__(16) float Cs[128][68];   // Cs[n][q-sub]
  __shared__ float EqA[QLEN];
  int tid = threadIdx.x;
  for (int e = tid; e < HD * DSTATE; e += 256) {
    int p = e >> 7, n = e & 127;
    Pn[n][p] = prev[(long)bch * (HD * DSTATE) + e];
  }
  EqA[tid] = __expf(acs[(((long)b * NH + h) * NCHUNK + c) * QLEN + tid]);
  long rowbase = (long)b * LSEQ + c * QLEN;
  float Dh = Dp[h];
  int tq = tid >> 4, tp = tid & 15;
  for (int qt = 0; qt < 4; ++qt) {
    __syncthreads();
    for (int e = tid; e < 64 * 128; e += 256) {
      int q = e >> 7, n = e & 127;
      Cs[n][q] = xbc[(rowbase + qt * 64 + q) * XBCW + 640 + n];
    }
    __syncthreads();
    float acc[4][4] = {};
    for (int k = 0; k < 128; ++k) {
      float4 av = *(const float4*)&Cs[k][tq * 4];
      float4 bv = *(const float4*)&Pn[k][tp * 4];
      float a_[4] = {av.x, av.y, av.z, av.w};
      float b_[4] = {bv.x, bv.y, bv.z, bv.w};
#pragma unroll
      for (int i = 0; i < 4; ++i)
#pragma unroll
        for (int j = 0; j < 4; ++j) acc[i][j] = fmaf(a_[i], b_[j], acc[i][j]);
    }
#pragma unroll
    for (int i = 0; i < 4; ++i) {
      int q = qt * 64 + tq * 4 + i;
      long row = rowbase + q;
      float eq = EqA[q];
#pragma unroll
      for (int j = 0; j < 4; ++j) {
        int p = tp * 4 + j;
        float xh = xbc[row * XBCW + h * HD + p];
        y[row * DIN + h * HD + p] += acc[i][j] * eq + xh * Dh;
      }
    }
  }
}

// ---------------- gated RMSNorm in place ----------------
__global__ __launch_bounds__(256) void gated_rms(
    float* __restrict__ y, const float* __restrict__ zx, const float* __restrict__ rmsw)
{
  long row = blockIdx.x;
  int t = threadIdx.x;
  float z0 = zx[row * DPROJ + t], z1 = zx[row * DPROJ + t + 256];
  float v0 = y[row * DIN + t] * (z0 / (1.f + __expf(-z0)));
  float v1 = y[row * DIN + t + 256] * (z1 / (1.f + __expf(-z1)));
  float ss = v0 * v0 + v1 * v1;
#pragma unroll
  for (int off = 32; off; off >>= 1) ss += __shfl_down(ss, off);
  __shared__ float red[4];
  if ((t & 63) == 0) red[t >> 6] = ss;
  __syncthreads();
  float tot = red[0] + red[1] + red[2] + red[3];
  float scale = rsqrtf(tot * (1.f / DIN) + 1e-5f);
  y[row * DIN + t]       = v0 * scale * rmsw[t];
  y[row * DIN + t + 256] = v1 * scale * rmsw[t + 256];
}

// ---------------- LayerNorm in place over 256 ----------------
__global__ __launch_bounds__(256) void layernorm(
    float* __restrict__ y2, const float* __restrict__ g, const float* __restrict__ bb)
{
  long row = blockIdx.x;
  int t = threadIdx.x;
  float v = y2[row * DM + t];
  float s = v, q = v * v;
#pragma unroll
  for (int off = 32; off; off >>= 1) { s += __shfl_down(s, off); q += __shfl_down(q, off); }
  __shared__ float sA[4], sB[4];
  if ((t & 63) == 0) { sA[t >> 6] = s; sB[t >> 6] = q; }
  __syncthreads();
  float S = sA[0] + sA[1] + sA[2] + sA[3];
  float Qs = sB[0] + sB[1] + sB[2] + sB[3];
  float mu = S * (1.f / DM);
  float var = Qs * (1.f / DM) - mu * mu;
  y2[row * DM + t] = (v - mu) * rsqrtf(var + 1e-5f) * g[t] + bb[t];
}

// ---------------- classifier ----------------
__global__ void cls(const float* __restrict__ yn, const float* __restrict__ w,
                    const float* __restrict__ bias, float* __restrict__ out)
{
  long idx = (long)blockIdx.x * 256 + threadIdx.x;
  if (idx >= ROWS * NCLS) return;
  int j = (int)(idx % NCLS);
  long row = idx / NCLS;
  float acc = bias[j];
  for (int i = 0; i < DM; ++i) acc = fmaf(yn[row * DM + i], w[i * NCLS + j], acc);
  out[idx] = acc;
}

extern "C" void kernel_launch(void* const* d_in, const int* in_sizes, int n_in,
                              void* d_out, int out_size, void* d_ws, size_t ws_size,
                              hipStream_t stream)
{
  const float* x     = (const float*)d_in[0];
  const float* w_inp = (const float*)d_in[1];
  const float* b_inp = (const float*)d_in[2];
  const float* w_in  = (const float*)d_in[3];
  const float* convw = (const float*)d_in[4];
  const float* convb = (const float*)d_in[5];
  const float* dtb   = (const float*)d_in[6];
  const float* alog  = (const float*)d_in[7];
  const float* Dp    = (const float*)d_in[8];
  const float* rmsw  = (const float*)d_in[9];
  const float* wout  = (const float*)d_in[10];
  const float* lng   = (const float*)d_in[11];
  const float* lnb   = (const float*)d_in[12];
  const float* wcls  = (const float*)d_in[13];
  const float* bcls  = (const float*)d_in[14];
  float* out = (float*)d_out;
  float* ws  = (float*)d_ws;

  float* u    = ws + O_U;
  float* zx   = ws + O_ZX;
  float* xbc  = ws + O_XBC;
  float* dtsp = ws + O_DT;
  float* acs  = ws + O_ACS;
  float* G    = ws + O_U;
  float* y    = ws + O_Y;
  float* st   = ws + O_ST;
  float* y2   = ws + O_Y2;
  unsigned short* u_bf  = (unsigned short*)(ws + O_UBF);
  unsigned short* w_inT = (unsigned short*)(ws + O_WINT);
  unsigned short* y_bf  = (unsigned short*)(ws + O_YBF);
  unsigned short* woutT = (unsigned short*)(ws + O_WOUTT);
  unsigned short* Bbf   = (unsigned short*)(ws + O_BBF);
  unsigned short* Cbf   = (unsigned short*)(ws + O_CBF);

  gemm_f32<<<dim3(4, 256), 256, 0, stream>>>(x, w_inp, b_inp, u, 16384, 256, 200);
  cast_bf16<<<4096, 256, 0, stream>>>(u, u_bf, ROWS * DM);
  tcast<<<1288, 256, 0, stream>>>(w_in, w_inT, 8, DPROJ);
  gemm_bf16<<<dim3(11, 128), 256, 0, stream>>>(u_bf, w_inT, zx, 16384, DPROJ, DM);
  conv_silu<<<(int)((ROWS * XBCW) / 256), 256, 0, stream>>>(zx, convw, convb, xbc, Bbf, Cbf);
  dt_cumsum2<<<128, 256, 0, stream>>>(u, w_in, dtb, alog, dtsp, acs);
  g_gemm_bf16<<<dim3(2, 2, 64), 256, 0, stream>>>(Cbf, Bbf, G);
  yd_states2<<<512, 256, 0, stream>>>(xbc, dtsp, acs, G, y, st);
  scan_states<<<4096, 256, 0, stream>>>(st, acs);
  yo_combine3<<<512, 256, 0, stream>>>(xbc, st, acs, Dp, y);
  gated_rms<<<16384, 256, 0, stream>>>(y, zx, rmsw);
  cast_bf16<<<8192, 256, 0, stream>>>(y, y_bf, ROWS * DIN);
  tcast<<<512, 256, 0, stream>>>(wout, woutT, 9, DM);
  gemm_bf16<<<dim3(2, 128), 256, 0, stream>>>(y_bf, woutT, y2, 16384, DM, DIN);
  layernorm<<<16384, 256, 0, stream>>>(y2, lng, lnb);
  cls<<<(int)((ROWS * NCLS + 255) / 256), 256, 0, stream>>>(y2, wcls, bcls, out);
}

// Round 4
// 435.092 us; speedup vs baseline: 2.8901x; 1.2932x over previous
//
#include <hip/hip_runtime.h>
#include <math.h>

#define ROWS   16384L
#define LSEQ   1024
#define NB     16
#define DM     256
#define DPROJ  1288
#define XBCW   768
#define DIN    512
#define DSTATE 128
#define NH     8
#define HD     64
#define QLEN   256
#define NCHUNK 4
#define NCLS   17

typedef __attribute__((ext_vector_type(8))) short s16x8;
typedef __attribute__((ext_vector_type(4))) float f32x4;

// workspace offsets (in floats)
constexpr long O_U    = 0;                       // 16384*256 f32 (reused as G)
constexpr long O_ZX   = O_U   + ROWS*DM;
constexpr long O_XBC  = O_ZX  + ROWS*DPROJ;
constexpr long O_DT   = O_XBC + ROWS*XBCW;
constexpr long O_ACS  = O_DT  + ROWS*NH;
constexpr long O_Y    = O_ACS + 131072;
constexpr long O_ST   = O_Y   + ROWS*DIN;
constexpr long O_Y2   = O_ST  + 4194304;
// overlays
constexpr long O_UBF  = O_Y;
constexpr long O_WINT = O_Y + 2200000;
constexpr long O_YBF  = O_ZX;
constexpr long O_WOUTT= O_ZX + 4300000;
constexpr long O_BBF  = O_Y2;
constexpr long O_CBF  = O_Y2 + 1048576;

__device__ inline unsigned short f2bf(float f) {
  union { float f; unsigned u; } v; v.f = f;
  unsigned r = v.u + 0x7FFFu + ((v.u >> 16) & 1u);
  return (unsigned short)(r >> 16);
}

// ---------------- f32 GEMM (input_proj only) ----------------
__global__ __launch_bounds__(256) void gemm_f32(
    const float* __restrict__ A, const float* __restrict__ W,
    const float* __restrict__ bias, float* __restrict__ C,
    int M, int N, int K)
{
  __shared__ float As[16][68];
  __shared__ float Ws[16][68];
  const int m0 = blockIdx.y * 64, n0 = blockIdx.x * 64;
  const int tid = threadIdx.x;
  const int tm = (tid >> 4) << 2, tn = (tid & 15) << 2;
  float acc[4][4] = {};
  for (int k0 = 0; k0 < K; k0 += 16) {
#pragma unroll
    for (int i = 0; i < 4; ++i) {
      int e = tid + i * 256;
      int m = e >> 4, k = e & 15;
      As[k][m] = (k0 + k < K) ? A[(long)(m0 + m) * K + k0 + k] : 0.f;
    }
#pragma unroll
    for (int i = 0; i < 4; ++i) {
      int e = tid + i * 256;
      int k = e >> 6, n = e & 63;
      Ws[k][n] = (k0 + k < K && n0 + n < N) ? W[(long)(k0 + k) * N + n0 + n] : 0.f;
    }
    __syncthreads();
#pragma unroll
    for (int k = 0; k < 16; ++k) {
      float a[4], w[4];
#pragma unroll
      for (int i = 0; i < 4; ++i) a[i] = As[k][tm + i];
#pragma unroll
      for (int j = 0; j < 4; ++j) w[j] = Ws[k][tn + j];
#pragma unroll
      for (int i = 0; i < 4; ++i)
#pragma unroll
        for (int j = 0; j < 4; ++j) acc[i][j] = fmaf(a[i], w[j], acc[i][j]);
    }
    __syncthreads();
  }
#pragma unroll
  for (int i = 0; i < 4; ++i) {
    long m = m0 + tm + i;
#pragma unroll
    for (int j = 0; j < 4; ++j) {
      int n = n0 + tn + j;
      if (n < N) C[m * (long)N + n] = acc[i][j] + (bias ? bias[n] : 0.f);
    }
  }
}

// ---------------- cast f32 -> bf16 ----------------
__global__ __launch_bounds__(256) void cast_bf16(const float* __restrict__ src,
                                                 unsigned short* __restrict__ dst, long n)
{
  long i = ((long)blockIdx.x * 256 + threadIdx.x) * 4;
  if (i >= n) return;
  float4 v = *(const float4*)&src[i];
  ushort4 o;
  o.x = f2bf(v.x); o.y = f2bf(v.y); o.z = f2bf(v.z); o.w = f2bf(v.w);
  *(ushort4*)&dst[i] = o;
}

// ---------------- transpose+cast: w[K,N] f32 -> wt[N,K] bf16 ----------------
__global__ __launch_bounds__(256) void tcast(const float* __restrict__ w,
                                             unsigned short* __restrict__ wt,
                                             int kbits, int N)
{
  long i = (long)blockIdx.x * 256 + threadIdx.x;
  int K = 1 << kbits;
  if (i >= (long)K * N) return;
  int k = (int)(i & (K - 1));
  long n = i >> kbits;
  wt[i] = f2bf(w[(long)k * N + n]);
}

// ---------------- bf16 MFMA GEMM: C[M,N] = A[M,K] @ BT[N,K]^T ----------------
__global__ __launch_bounds__(256) void gemm_bf16(
    const unsigned short* __restrict__ A, const unsigned short* __restrict__ BT,
    float* __restrict__ C, int M, int N, int K)
{
  __shared__ __align__(16) unsigned short As[128 * 32];
  __shared__ __align__(16) unsigned short Bs[128 * 32];
  const int tid = threadIdx.x;
  const int m0 = blockIdx.y * 128, n0 = blockIdx.x * 128;
  const int lane = tid & 63, wv = tid >> 6;
  const int wr = (wv >> 1) * 64, wc = (wv & 1) * 64;
  f32x4 acc[4][4];
#pragma unroll
  for (int i = 0; i < 4; ++i)
#pragma unroll
    for (int j = 0; j < 4; ++j) acc[i][j] = (f32x4){0.f, 0.f, 0.f, 0.f};

  for (int k0 = 0; k0 < K; k0 += 32) {
    __syncthreads();
#pragma unroll
    for (int s = 0; s < 2; ++s) {
      int idx = (tid + 256 * s) * 8;
      int r = idx >> 5, kk = idx & 31;
      *(s16x8*)&As[idx] = *(const s16x8*)&A[(long)(m0 + r) * K + k0 + kk];
    }
#pragma unroll
    for (int s = 0; s < 2; ++s) {
      int idx = (tid + 256 * s) * 8;
      int n = idx >> 5, kk = idx & 31;
      s16x8 vv = {};
      if (n0 + n < N) vv = *(const s16x8*)&BT[(long)(n0 + n) * K + k0 + kk];
      *(s16x8*)&Bs[idx] = vv;
    }
    __syncthreads();
    s16x8 af[4], bf[4];
#pragma unroll
    for (int i = 0; i < 4; ++i)
      af[i] = *(const s16x8*)&As[(wr + i * 16 + (lane & 15)) * 32 + (lane >> 4) * 8];
#pragma unroll
    for (int j = 0; j < 4; ++j)
      bf[j] = *(const s16x8*)&Bs[(wc + j * 16 + (lane & 15)) * 32 + (lane >> 4) * 8];
#pragma unroll
    for (int i = 0; i < 4; ++i)
#pragma unroll
      for (int j = 0; j < 4; ++j)
        acc[i][j] = __builtin_amdgcn_mfma_f32_16x16x32_bf16(af[i], bf[j], acc[i][j], 0, 0, 0);
  }
  const int cr = (lane >> 4) * 4, cc = lane & 15;
#pragma unroll
  for (int i = 0; i < 4; ++i)
#pragma unroll
    for (int j = 0; j < 4; ++j) {
      int col = n0 + wc + j * 16 + cc;
      if (col < N) {
        long rowb = (long)(m0 + wr + i * 16 + cr);
#pragma unroll
        for (int r = 0; r < 4; ++r)
          C[(rowb + r) * N + col] = acc[i][j][r];
      }
    }
}

// ---------------- G = C·B^T per (b,c) via MFMA (lower-tri blocks) ----------------
__global__ __launch_bounds__(256) void g_gemm_bf16(
    const unsigned short* __restrict__ Cbf, const unsigned short* __restrict__ Bbf,
    float* __restrict__ G)
{
  if (blockIdx.x > blockIdx.y) return;
  int bc = blockIdx.z;
  long rowbase = (long)(bc >> 2) * LSEQ + (bc & 3) * QLEN;
  const unsigned short* A  = Cbf + rowbase * 128;
  const unsigned short* BT = Bbf + rowbase * 128;
  float* Gout = G + (long)bc * 65536;
  __shared__ __align__(16) unsigned short As[128 * 32];
  __shared__ __align__(16) unsigned short Bs[128 * 32];
  const int tid = threadIdx.x;
  const int m0 = blockIdx.y * 128, n0 = blockIdx.x * 128;
  const int lane = tid & 63, wv = tid >> 6;
  const int wr = (wv >> 1) * 64, wc = (wv & 1) * 64;
  f32x4 acc[4][4];
#pragma unroll
  for (int i = 0; i < 4; ++i)
#pragma unroll
    for (int j = 0; j < 4; ++j) acc[i][j] = (f32x4){0.f, 0.f, 0.f, 0.f};
  for (int k0 = 0; k0 < 128; k0 += 32) {
    __syncthreads();
#pragma unroll
    for (int s = 0; s < 2; ++s) {
      int idx = (tid + 256 * s) * 8;
      int r = idx >> 5, kk = idx & 31;
      *(s16x8*)&As[idx] = *(const s16x8*)&A[(long)(m0 + r) * 128 + k0 + kk];
      *(s16x8*)&Bs[idx] = *(const s16x8*)&BT[(long)(n0 + r) * 128 + k0 + kk];
    }
    __syncthreads();
    s16x8 af[4], bf[4];
#pragma unroll
    for (int i = 0; i < 4; ++i)
      af[i] = *(const s16x8*)&As[(wr + i * 16 + (lane & 15)) * 32 + (lane >> 4) * 8];
#pragma unroll
    for (int j = 0; j < 4; ++j)
      bf[j] = *(const s16x8*)&Bs[(wc + j * 16 + (lane & 15)) * 32 + (lane >> 4) * 8];
#pragma unroll
    for (int i = 0; i < 4; ++i)
#pragma unroll
      for (int j = 0; j < 4; ++j)
        acc[i][j] = __builtin_amdgcn_mfma_f32_16x16x32_bf16(af[i], bf[j], acc[i][j], 0, 0, 0);
  }
  const int cr = (lane >> 4) * 4, cc = lane & 15;
#pragma unroll
  for (int i = 0; i < 4; ++i)
#pragma unroll
    for (int j = 0; j < 4; ++j) {
      int col = n0 + wc + j * 16 + cc;
      long rowb = (long)(m0 + wr + i * 16 + cr);
#pragma unroll
      for (int r = 0; r < 4; ++r)
        Gout[(rowb + r) * 256 + col] = acc[i][j][r];
    }
}

// ---------------- causal depthwise conv1d (k=4) + SiLU; emits bf16 B,C copies --------
__global__ __launch_bounds__(256) void conv_silu(
    const float* __restrict__ zx, const float* __restrict__ cw,
    const float* __restrict__ cb, float* __restrict__ out,
    unsigned short* __restrict__ Bbf, unsigned short* __restrict__ Cbf)
{
  long idx = (long)blockIdx.x * 256 + threadIdx.x;
  if (idx >= ROWS * XBCW) return;
  int ch = (int)(idx % XBCW);
  long row = idx / XBCW;
  int t = (int)(row % LSEQ);
  float acc = cb[ch];
#pragma unroll
  for (int w = 0; w < 4; ++w) {
    int tt = t - 3 + w;
    if (tt >= 0) acc += zx[(row + tt - t) * DPROJ + 512 + ch] * cw[w * XBCW + ch];
  }
  float r = acc / (1.f + __expf(-acc));
  out[idx] = r;
  if (ch >= 512) {
    unsigned short bv = f2bf(r);
    if (ch < 640) Bbf[row * 128 + ch - 512] = bv;
    else          Cbf[row * 128 + ch - 640] = bv;
  }
}

// ---------------- dt (f32 recompute) + softplus + wave-parallel cumsum ----------------
__global__ __launch_bounds__(256) void dt_cumsum2(
    const float* __restrict__ u, const float* __restrict__ w_in,
    const float* __restrict__ dtb, const float* __restrict__ alog,
    float* __restrict__ dtsp, float* __restrict__ acs)
{
  int g = ((int)blockIdx.x * 256 + (int)threadIdx.x) >> 6;
  int lane = threadIdx.x & 63;
  int c = g & 3, h = (g >> 2) & 7, b = g >> 5;
  float Ah = -__expf(alog[h]);
  float bias = dtb[h];
  long rowbase = (long)b * LSEQ + c * QLEN;
  long abase = (((long)b * NH + h) * NCHUNK + c) * QLEN;
  float v[4];
#pragma unroll
  for (int j = 0; j < 4; ++j) {
    long row = rowbase + lane * 4 + j;
    const float4* u4 = (const float4*)&u[row * DM];
    float acc = bias;
    for (int i = 0; i < 64; ++i) {
      float4 uv = u4[i];
      acc += uv.x * w_in[(long)(i * 4 + 0) * DPROJ + 1280 + h]
           + uv.y * w_in[(long)(i * 4 + 1) * DPROJ + 1280 + h]
           + uv.z * w_in[(long)(i * 4 + 2) * DPROJ + 1280 + h]
           + uv.w * w_in[(long)(i * 4 + 3) * DPROJ + 1280 + h];
    }
    float sp = (acc > 20.f) ? acc : log1pf(__expf(acc));
    dtsp[row * NH + h] = sp;
    v[j] = sp * Ah;
  }
  v[1] += v[0]; v[2] += v[1]; v[3] += v[2];
  float tot = v[3];
  float run = tot;
#pragma unroll
  for (int d = 1; d < 64; d <<= 1) {
    float t = __shfl_up(run, d);
    if (lane >= d) run += t;
  }
  float excl = run - tot;
#pragma unroll
  for (int j = 0; j < 4; ++j) acs[abase + lane * 4 + j] = excl + v[j];
}

// ---------------- MFMA yd + states: per (b,c,h) block -------------------------------
// Yd[256q][64p] = W @ Xd,  statesT[128n][64p] = (Eq*B)^T @ Xd, chunked K=64.
__global__ __launch_bounds__(256) void yd_states3(
    const float* __restrict__ xbc, const float* __restrict__ dtsp,
    const float* __restrict__ acs, const float* __restrict__ G,
    float* __restrict__ y, float* __restrict__ st)
{
  // XCD-chunked swizzle: 8 blocks sharing one (b,c) G-slab land on same XCD
  int bid = blockIdx.x;
  int xcd = bid & 7, i0 = bid >> 3;
  int bc = xcd * 8 + (i0 >> 3), h = i0 & 7;
  int c = bc & 3, b = bc >> 2;
  int bch = bc * 8 + h;

  __shared__ __align__(16) unsigned short Ws_[256][72];
  __shared__ __align__(16) unsigned short EqBT[128][72];
  __shared__ __align__(16) unsigned short XdT[64][72];
  __shared__ float AcsS[256];
  __shared__ float E1[256];
  __shared__ float E2[64], EqS[64];

  const int tid = threadIdx.x;
  const int lane = tid & 63, wv = tid >> 6;
  long rowbase = (long)b * LSEQ + c * QLEN;
  long gbase = (long)bc * 65536;

  AcsS[tid] = acs[(((long)b * NH + h) * NCHUNK + c) * QLEN + tid];
  __syncthreads();
  float AL = AcsS[255];

  f32x4 accY[4][4], accS[2][4];
#pragma unroll
  for (int i = 0; i < 4; ++i)
#pragma unroll
    for (int j = 0; j < 4; ++j) accY[i][j] = (f32x4){0.f, 0.f, 0.f, 0.f};
#pragma unroll
  for (int i = 0; i < 2; ++i)
#pragma unroll
    for (int j = 0; j < 4; ++j) accS[i][j] = (f32x4){0.f, 0.f, 0.f, 0.f};

  for (int kt = 0; kt < 4; ++kt) {
    __syncthreads();
    float ref = AcsS[kt * 64 + 63];
    E1[tid] = __expf(AcsS[tid] - ref);          // only rows q>=kt*64 consumed
    if (tid < 64) {
      E2[tid]  = __expf(ref - AcsS[kt * 64 + tid]);
      EqS[tid] = __expf(AL  - AcsS[kt * 64 + tid]);
    }
    __syncthreads();
    // XdT[p][k] = xh * dt (transposed)
#pragma unroll 4
    for (int s = 0; s < 16; ++s) {
      int k = s * 4 + wv;
      long row = rowbase + kt * 64 + k;
      float v = xbc[row * XBCW + h * HD + lane] * dtsp[row * NH + h];
      XdT[lane][k] = f2bf(v);
    }
    // EqBT[n][k] = exp(AL-Acs[k]) * B[k][n] (transposed)
#pragma unroll 4
    for (int s = 0; s < 32; ++s) {
      int e = s * 256 + tid;
      int k = e >> 7, n = e & 127;
      float v = xbc[(rowbase + kt * 64 + k) * XBCW + 512 + n] * EqS[k];
      EqBT[n][k] = f2bf(v);
    }
    // Ws_[q][kk] = G[q][kt*64+kk] * E1[q] * E2[kk]  (k<=q), rows q<kt*64 never read
    {
      int qlo = kt * 64;
#pragma unroll 4
      for (int s = 0; s < 64; ++s) {
        int q = s * 4 + wv;
        if (q >= qlo) {
          float g = (qlo + lane <= q) ? G[gbase + (long)q * 256 + qlo + lane] : 0.f;
          Ws_[q][lane] = f2bf(g * E1[q] * E2[lane]);
        }
      }
    }
    __syncthreads();
#pragma unroll
    for (int ks = 0; ks < 2; ++ks) {
      s16x8 bfr[4];
#pragma unroll
      for (int j = 0; j < 4; ++j)
        bfr[j] = *(const s16x8*)&XdT[j * 16 + (lane & 15)][ks * 32 + (lane >> 4) * 8];
      if (wv >= kt) {
#pragma unroll
        for (int i = 0; i < 4; ++i) {
          s16x8 a = *(const s16x8*)&Ws_[wv * 64 + i * 16 + (lane & 15)][ks * 32 + (lane >> 4) * 8];
#pragma unroll
          for (int j = 0; j < 4; ++j)
            accY[i][j] = __builtin_amdgcn_mfma_f32_16x16x32_bf16(a, bfr[j], accY[i][j], 0, 0, 0);
        }
      }
#pragma unroll
      for (int i2 = 0; i2 < 2; ++i2) {
        s16x8 a = *(const s16x8*)&EqBT[wv * 32 + i2 * 16 + (lane & 15)][ks * 32 + (lane >> 4) * 8];
#pragma unroll
        for (int j = 0; j < 4; ++j)
          accS[i2][j] = __builtin_amdgcn_mfma_f32_16x16x32_bf16(a, bfr[j], accS[i2][j], 0, 0, 0);
      }
    }
  }
  const int cr = (lane >> 4) * 4, cc = lane & 15;
#pragma unroll
  for (int i = 0; i < 4; ++i)
#pragma unroll
    for (int j = 0; j < 4; ++j) {
      int q = wv * 64 + i * 16 + cr;
      int p = j * 16 + cc;
#pragma unroll
      for (int r = 0; r < 4; ++r)
        y[(rowbase + q + r) * DIN + h * HD + p] = accY[i][j][r];
    }
#pragma unroll
  for (int i2 = 0; i2 < 2; ++i2)
#pragma unroll
    for (int j = 0; j < 4; ++j) {
      int n = wv * 32 + i2 * 16 + cr;
      int p = j * 16 + cc;
#pragma unroll
      for (int r = 0; r < 4; ++r)
        st[(long)bch * 8192 + (long)(n + r) * 64 + p] = accS[i2][j][r];
    }
}

// ---------------- inter-chunk scan (in place; statesT layout [n*64+p]) ---------------
__global__ void scan_states(float* __restrict__ st, const float* __restrict__ acs)
{
  long idx = (long)blockIdx.x * 256 + threadIdx.x;   // (b,h,inner)
  if (idx >= (long)NB * NH * 8192) return;
  long inner = idx & 8191;
  int h = (int)((idx >> 13) & 7);
  int b = (int)(idx >> 16);
  float carry = 0.f;
  for (int c = 0; c < NCHUNK; ++c) {
    float dc = __expf(acs[(((long)b * NH + h) * NCHUNK + c) * QLEN + (QLEN - 1)]);
    long si = (((long)(b * NCHUNK + c) * NH + h) << 13) + inner;
    float s = st[si];
    st[si] = carry;
    carry = carry * dc + s;
  }
}

// ---------------- Yo as tiled f32 GEMM: y += exp(Acs[q]) * C·prev^T + xh*D -----------
__global__ __launch_bounds__(256) void yo_combine3(
    const float* __restrict__ xbc, const float* __restrict__ prev,
    const float* __restrict__ acs, const float* __restrict__ Dp,
    float* __restrict__ y)
{
  int bch = blockIdx.x;
  int h = bch & 7, bc = bch >> 3;
  int c = bc & 3, b = bc >> 2;
  __shared__ __align__(16) float Pn[128][68];   // Pn[n][p] (prev stored as [n][p])
  __shared__ __align__(16) float Cs[128][68];   // Cs[n][q-sub]
  __shared__ float EqA[QLEN];
  int tid = threadIdx.x;
  for (int e = tid; e < HD * DSTATE; e += 256)
    Pn[e >> 6][e & 63] = prev[((long)bch << 13) + e];
  EqA[tid] = __expf(acs[(((long)b * NH + h) * NCHUNK + c) * QLEN + tid]);
  long rowbase = (long)b * LSEQ + c * QLEN;
  float Dh = Dp[h];
  int tq = tid >> 4, tp = tid & 15;
  for (int qt = 0; qt < 4; ++qt) {
    __syncthreads();
    for (int e = tid; e < 64 * 128; e += 256) {
      int q = e >> 7, n = e & 127;
      Cs[n][q] = xbc[(rowbase + qt * 64 + q) * XBCW + 640 + n];
    }
    __syncthreads();
    float acc[4][4] = {};
    for (int k = 0; k < 128; ++k) {
      float4 av = *(const float4*)&Cs[k][tq * 4];
      float4 bv = *(const float4*)&Pn[k][tp * 4];
      float a_[4] = {av.x, av.y, av.z, av.w};
      float b_[4] = {bv.x, bv.y, bv.z, bv.w};
#pragma unroll
      for (int i = 0; i < 4; ++i)
#pragma unroll
        for (int j = 0; j < 4; ++j) acc[i][j] = fmaf(a_[i], b_[j], acc[i][j]);
    }
#pragma unroll
    for (int i = 0; i < 4; ++i) {
      int q = qt * 64 + tq * 4 + i;
      long row = rowbase + q;
      float eq = EqA[q];
#pragma unroll
      for (int j = 0; j < 4; ++j) {
        int p = tp * 4 + j;
        float xh = xbc[row * XBCW + h * HD + p];
        y[row * DIN + h * HD + p] += acc[i][j] * eq + xh * Dh;
      }
    }
  }
}

// ---------------- gated RMSNorm in place ----------------
__global__ __launch_bounds__(256) void gated_rms(
    float* __restrict__ y, const float* __restrict__ zx, const float* __restrict__ rmsw)
{
  long row = blockIdx.x;
  int t = threadIdx.x;
  float z0 = zx[row * DPROJ + t], z1 = zx[row * DPROJ + t + 256];
  float v0 = y[row * DIN + t] * (z0 / (1.f + __expf(-z0)));
  float v1 = y[row * DIN + t + 256] * (z1 / (1.f + __expf(-z1)));
  float ss = v0 * v0 + v1 * v1;
#pragma unroll
  for (int off = 32; off; off >>= 1) ss += __shfl_down(ss, off);
  __shared__ float red[4];
  if ((t & 63) == 0) red[t >> 6] = ss;
  __syncthreads();
  float tot = red[0] + red[1] + red[2] + red[3];
  float scale = rsqrtf(tot * (1.f / DIN) + 1e-5f);
  y[row * DIN + t]       = v0 * scale * rmsw[t];
  y[row * DIN + t + 256] = v1 * scale * rmsw[t + 256];
}

// ---------------- LayerNorm in place over 256 ----------------
__global__ __launch_bounds__(256) void layernorm(
    float* __restrict__ y2, const float* __restrict__ g, const float* __restrict__ bb)
{
  long row = blockIdx.x;
  int t = threadIdx.x;
  float v = y2[row * DM + t];
  float s = v, q = v * v;
#pragma unroll
  for (int off = 32; off; off >>= 1) { s += __shfl_down(s, off); q += __shfl_down(q, off); }
  __shared__ float sA[4], sB[4];
  if ((t & 63) == 0) { sA[t >> 6] = s; sB[t >> 6] = q; }
  __syncthreads();
  float S = sA[0] + sA[1] + sA[2] + sA[3];
  float Qs = sB[0] + sB[1] + sB[2] + sB[3];
  float mu = S * (1.f / DM);
  float var = Qs * (1.f / DM) - mu * mu;
  y2[row * DM + t] = (v - mu) * rsqrtf(var + 1e-5f) * g[t] + bb[t];
}

// ---------------- classifier ----------------
__global__ void cls(const float* __restrict__ yn, const float* __restrict__ w,
                    const float* __restrict__ bias, float* __restrict__ out)
{
  long idx = (long)blockIdx.x * 256 + threadIdx.x;
  if (idx >= ROWS * NCLS) return;
  int j = (int)(idx % NCLS);
  long row = idx / NCLS;
  float acc = bias[j];
  for (int i = 0; i < DM; ++i) acc = fmaf(yn[row * DM + i], w[i * NCLS + j], acc);
  out[idx] = acc;
}

extern "C" void kernel_launch(void* const* d_in, const int* in_sizes, int n_in,
                              void* d_out, int out_size, void* d_ws, size_t ws_size,
                              hipStream_t stream)
{
  const float* x     = (const float*)d_in[0];
  const float* w_inp = (const float*)d_in[1];
  const float* b_inp = (const float*)d_in[2];
  const float* w_in  = (const float*)d_in[3];
  const float* convw = (const float*)d_in[4];
  const float* convb = (const float*)d_in[5];
  const float* dtb   = (const float*)d_in[6];
  const float* alog  = (const float*)d_in[7];
  const float* Dp    = (const float*)d_in[8];
  const float* rmsw  = (const float*)d_in[9];
  const float* wout  = (const float*)d_in[10];
  const float* lng   = (const float*)d_in[11];
  const float* lnb   = (const float*)d_in[12];
  const float* wcls  = (const float*)d_in[13];
  const float* bcls  = (const float*)d_in[14];
  float* out = (float*)d_out;
  float* ws  = (float*)d_ws;

  float* u    = ws + O_U;
  float* zx   = ws + O_ZX;
  float* xbc  = ws + O_XBC;
  float* dtsp = ws + O_DT;
  float* acs  = ws + O_ACS;
  float* G    = ws + O_U;
  float* y    = ws + O_Y;
  float* st   = ws + O_ST;
  float* y2   = ws + O_Y2;
  unsigned short* u_bf  = (unsigned short*)(ws + O_UBF);
  unsigned short* w_inT = (unsigned short*)(ws + O_WINT);
  unsigned short* y_bf  = (unsigned short*)(ws + O_YBF);
  unsigned short* woutT = (unsigned short*)(ws + O_WOUTT);
  unsigned short* Bbf   = (unsigned short*)(ws + O_BBF);
  unsigned short* Cbf   = (unsigned short*)(ws + O_CBF);

  gemm_f32<<<dim3(4, 256), 256, 0, stream>>>(x, w_inp, b_inp, u, 16384, 256, 200);
  cast_bf16<<<4096, 256, 0, stream>>>(u, u_bf, ROWS * DM);
  tcast<<<1288, 256, 0, stream>>>(w_in, w_inT, 8, DPROJ);
  gemm_bf16<<<dim3(11, 128), 256, 0, stream>>>(u_bf, w_inT, zx, 16384, DPROJ, DM);
  conv_silu<<<(int)((ROWS * XBCW) / 256), 256, 0, stream>>>(zx, convw, convb, xbc, Bbf, Cbf);
  dt_cumsum2<<<128, 256, 0, stream>>>(u, w_in, dtb, alog, dtsp, acs);
  g_gemm_bf16<<<dim3(2, 2, 64), 256, 0, stream>>>(Cbf, Bbf, G);
  yd_states3<<<512, 256, 0, stream>>>(xbc, dtsp, acs, G, y, st);
  scan_states<<<4096, 256, 0, stream>>>(st, acs);
  yo_combine3<<<512, 256, 0, stream>>>(xbc, st, acs, Dp, y);
  gated_rms<<<16384, 256, 0, stream>>>(y, zx, rmsw);
  cast_bf16<<<8192, 256, 0, stream>>>(y, y_bf, ROWS * DIN);
  tcast<<<512, 256, 0, stream>>>(wout, woutT, 9, DM);
  gemm_bf16<<<dim3(2, 128), 256, 0, stream>>>(y_bf, woutT, y2, 16384, DM, DIN);
  layernorm<<<16384, 256, 0, stream>>>(y2, lng, lnb);
  cls<<<(int)((ROWS * NCLS + 255) / 256), 256, 0, stream>>>(y2, wcls, bcls, out);
}

// Round 5
// 362.627 us; speedup vs baseline: 3.4677x; 1.1998x over previous
//
#include <hip/hip_runtime.h>
#include <math.h>

#define ROWS   16384L
#define LSEQ   1024
#define NB     16
#define DM     256
#define DPROJ  1288
#define XBCW   768
#define DIN    512
#define DSTATE 128
#define NH     8
#define HD     64
#define QLEN   256
#define NCHUNK 4
#define NCLS   17

typedef __attribute__((ext_vector_type(8))) short s16x8;
typedef __attribute__((ext_vector_type(4))) float f32x4;

// ---- workspace map (floats) ----
constexpr long O_U    = 0;                        // Gbf overlay (bf16, 2.1M slots)
constexpr long O_ZX   = O_U   + ROWS*DM;          // zxb bf16 [ROWS][1288]
constexpr long O_XBC  = O_ZX  + ROWS*DPROJ;       // xbc f32; later ybf+woutT overlay
constexpr long O_DT   = O_XBC + ROWS*XBCW;
constexpr long O_ACS  = O_DT  + ROWS*NH;
constexpr long O_Y    = O_ACS + 131072;           // y f32; overlays below (all dead before yd)
constexpr long O_ST   = O_Y   + ROWS*DIN;
constexpr long O_Y2   = O_ST  + 4194304;          // y2 f32; overlays Bbf/Cbf/BbfT
// overlays in O_Y region:
constexpr long O_UBF  = O_Y;                      // u_bf [ROWS][256] bf16
constexpr long O_WINT = O_Y + 2200000;            // w_inT [1288][256] bf16
constexpr long O_XPBF = O_Y + 2500000;            // xp_bf [ROWS][224] bf16
constexpr long O_WINPT= O_Y + 4500000;            // w_inpT [256][224] bf16
constexpr long O_WDT  = O_Y + 8300000;            // Wdt[200][8] + bdt[8] f32
// overlays in O_XBC region:
constexpr long O_YBF  = O_XBC;                    // ybf [ROWS][512] bf16 (after yo done)
constexpr long O_WOUTT= O_XBC + 4300000;          // woutT [256][512] bf16
// overlays in O_Y2 region:
constexpr long O_BBF  = O_Y2;                     // Bbf [ROWS][128] bf16
constexpr long O_CBF  = O_Y2 + 1048576;           // Cbf [ROWS][128] bf16
constexpr long O_BT   = O_Y2 + 2097152;           // BbfT [64][128][256] bf16

__device__ inline unsigned short f2bf(float f) {
  union { float f; unsigned u; } v; v.f = f;
  unsigned r = v.u + 0x7FFFu + ((v.u >> 16) & 1u);
  return (unsigned short)(r >> 16);
}
__device__ inline float bf2f(unsigned short s) {
  union { unsigned u; float f; } v; v.u = ((unsigned)s) << 16; return v.f;
}

// ---------------- pad+cast x: [ROWS][200] f32 -> [ROWS][224] bf16 ----------------
__global__ __launch_bounds__(256) void cast_pad_x(const float* __restrict__ x,
                                                  unsigned short* __restrict__ xp)
{
  long idx = (long)blockIdx.x * 256 + threadIdx.x;     // ushort4 units
  if (idx >= ROWS * 56) return;
  int q = (int)(idx % 56);
  long row = idx / 56;
  ushort4 o = {0, 0, 0, 0};
  if (q < 50) {
    float4 v = *(const float4*)&x[row * 200 + q * 4];
    o.x = f2bf(v.x); o.y = f2bf(v.y); o.z = f2bf(v.z); o.w = f2bf(v.w);
  }
  *(ushort4*)&xp[row * 224 + q * 4] = o;
}

// ---------------- w_inp [200][256] -> w_inpT [256][224] bf16 (zero-pad K) ------------
__global__ __launch_bounds__(256) void tcast_pad_winp(const float* __restrict__ w,
                                                      unsigned short* __restrict__ wt)
{
  int i = blockIdx.x * 256 + threadIdx.x;             // 256*224
  if (i >= 256 * 224) return;
  int k = i % 224, n = i / 224;
  wt[i] = (k < 200) ? f2bf(w[(long)k * 256 + n]) : (unsigned short)0;
}

// ---------------- transpose+cast: w[K,N] f32 -> wt[N,K] bf16 (K=1<<kbits) ------------
__global__ __launch_bounds__(256) void tcast(const float* __restrict__ w,
                                             unsigned short* __restrict__ wt,
                                             int kbits, int N)
{
  long i = (long)blockIdx.x * 256 + threadIdx.x;
  int K = 1 << kbits;
  if (i >= (long)K * N) return;
  int k = (int)(i & (K - 1));
  long n = i >> kbits;
  wt[i] = f2bf(w[(long)k * N + n]);
}

// ---------------- Wdt[k][h] = sum_j w_inp[k][j]*w_in[j][1280+h]; bdt similarly -------
__global__ void combine_wdt(const float* __restrict__ w_inp, const float* __restrict__ w_in,
                            const float* __restrict__ b_inp,
                            float* __restrict__ Wdt, float* __restrict__ bdt)
{
  int e = blockIdx.x * 256 + threadIdx.x;
  if (e < 1600) {
    int k = e >> 3, h = e & 7;
    float a = 0.f;
    for (int j = 0; j < 256; ++j) a += w_inp[(long)k * 256 + j] * w_in[(long)j * DPROJ + 1280 + h];
    Wdt[e] = a;
  } else if (e < 1608) {
    int h = e - 1600;
    float a = 0.f;
    for (int j = 0; j < 256; ++j) a += b_inp[j] * w_in[(long)j * DPROJ + 1280 + h];
    bdt[h] = a;
  }
}

// ---------------- bf16 MFMA GEMM: out = A[M,K] @ BT[N,K]^T (+bias); f32 and/or bf16 out
__global__ __launch_bounds__(256) void gemm_bf16(
    const unsigned short* __restrict__ A, const unsigned short* __restrict__ BT,
    float* __restrict__ C, unsigned short* __restrict__ Cb,
    const float* __restrict__ bias, int M, int N, int K)
{
  __shared__ __align__(16) unsigned short As[128 * 32];
  __shared__ __align__(16) unsigned short Bs[128 * 32];
  const int tid = threadIdx.x;
  const int m0 = blockIdx.y * 128, n0 = blockIdx.x * 128;
  const int lane = tid & 63, wv = tid >> 6;
  const int wr = (wv >> 1) * 64, wc = (wv & 1) * 64;
  f32x4 acc[4][4];
#pragma unroll
  for (int i = 0; i < 4; ++i)
#pragma unroll
    for (int j = 0; j < 4; ++j) acc[i][j] = (f32x4){0.f, 0.f, 0.f, 0.f};

  for (int k0 = 0; k0 < K; k0 += 32) {
    __syncthreads();
#pragma unroll
    for (int s = 0; s < 2; ++s) {
      int idx = (tid + 256 * s) * 8;
      int r = idx >> 5, kk = idx & 31;
      *(s16x8*)&As[idx] = *(const s16x8*)&A[(long)(m0 + r) * K + k0 + kk];
    }
#pragma unroll
    for (int s = 0; s < 2; ++s) {
      int idx = (tid + 256 * s) * 8;
      int n = idx >> 5, kk = idx & 31;
      s16x8 vv = {};
      if (n0 + n < N) vv = *(const s16x8*)&BT[(long)(n0 + n) * K + k0 + kk];
      *(s16x8*)&Bs[idx] = vv;
    }
    __syncthreads();
    s16x8 af[4], bf[4];
#pragma unroll
    for (int i = 0; i < 4; ++i)
      af[i] = *(const s16x8*)&As[(wr + i * 16 + (lane & 15)) * 32 + (lane >> 4) * 8];
#pragma unroll
    for (int j = 0; j < 4; ++j)
      bf[j] = *(const s16x8*)&Bs[(wc + j * 16 + (lane & 15)) * 32 + (lane >> 4) * 8];
#pragma unroll
    for (int i = 0; i < 4; ++i)
#pragma unroll
      for (int j = 0; j < 4; ++j)
        acc[i][j] = __builtin_amdgcn_mfma_f32_16x16x32_bf16(af[i], bf[j], acc[i][j], 0, 0, 0);
  }
  const int cr = (lane >> 4) * 4, cc = lane & 15;
#pragma unroll
  for (int i = 0; i < 4; ++i)
#pragma unroll
    for (int j = 0; j < 4; ++j) {
      int col = n0 + wc + j * 16 + cc;
      if (col < N) {
        long rowb = (long)(m0 + wr + i * 16 + cr);
        float bv = bias ? bias[col] : 0.f;
#pragma unroll
        for (int r = 0; r < 4; ++r) {
          float v = acc[i][j][r] + bv;
          if (C)  C[(rowb + r) * N + col] = v;
          if (Cb) Cb[(rowb + r) * (long)N + col] = f2bf(v);
        }
      }
    }
}

// ---------------- G = C·B^T per (b,c) -> bf16, causal-masked, upper block zeroed ------
__global__ __launch_bounds__(256) void g_gemm_bf16(
    const unsigned short* __restrict__ Cbf, const unsigned short* __restrict__ Bbf,
    unsigned short* __restrict__ Gbf)
{
  int bc = blockIdx.z;
  unsigned short* Gout = Gbf + (long)bc * 65536;
  const int tid = threadIdx.x;
  const int m0 = blockIdx.y * 128, n0 = blockIdx.x * 128;
  if (blockIdx.x > blockIdx.y) {                    // strictly-upper tile: zeros
    s16x8 z = {};
    for (int e = tid; e < 128 * 16; e += 256) {
      int r = e >> 4, seg = e & 15;
      *(s16x8*)&Gout[(long)(m0 + r) * 256 + n0 + seg * 8] = z;
    }
    return;
  }
  long rowbase = (long)(bc >> 2) * LSEQ + (bc & 3) * QLEN;
  const unsigned short* A  = Cbf + rowbase * 128;
  const unsigned short* BT = Bbf + rowbase * 128;
  __shared__ __align__(16) unsigned short As[128 * 32];
  __shared__ __align__(16) unsigned short Bs[128 * 32];
  const int lane = tid & 63, wv = tid >> 6;
  const int wr = (wv >> 1) * 64, wc = (wv & 1) * 64;
  f32x4 acc[4][4];
#pragma unroll
  for (int i = 0; i < 4; ++i)
#pragma unroll
    for (int j = 0; j < 4; ++j) acc[i][j] = (f32x4){0.f, 0.f, 0.f, 0.f};
  for (int k0 = 0; k0 < 128; k0 += 32) {
    __syncthreads();
#pragma unroll
    for (int s = 0; s < 2; ++s) {
      int idx = (tid + 256 * s) * 8;
      int r = idx >> 5, kk = idx & 31;
      *(s16x8*)&As[idx] = *(const s16x8*)&A[(long)(m0 + r) * 128 + k0 + kk];
      *(s16x8*)&Bs[idx] = *(const s16x8*)&BT[(long)(n0 + r) * 128 + k0 + kk];
    }
    __syncthreads();
    s16x8 af[4], bf[4];
#pragma unroll
    for (int i = 0; i < 4; ++i)
      af[i] = *(const s16x8*)&As[(wr + i * 16 + (lane & 15)) * 32 + (lane >> 4) * 8];
#pragma unroll
    for (int j = 0; j < 4; ++j)
      bf[j] = *(const s16x8*)&Bs[(wc + j * 16 + (lane & 15)) * 32 + (lane >> 4) * 8];
#pragma unroll
    for (int i = 0; i < 4; ++i)
#pragma unroll
      for (int j = 0; j < 4; ++j)
        acc[i][j] = __builtin_amdgcn_mfma_f32_16x16x32_bf16(af[i], bf[j], acc[i][j], 0, 0, 0);
  }
  const int cr = (lane >> 4) * 4, cc = lane & 15;
#pragma unroll
  for (int i = 0; i < 4; ++i)
#pragma unroll
    for (int j = 0; j < 4; ++j) {
      int col = n0 + wc + j * 16 + cc;
      int qb = m0 + wr + i * 16 + cr;
#pragma unroll
      for (int r = 0; r < 4; ++r)
        Gout[(long)(qb + r) * 256 + col] = (col <= qb + r) ? f2bf(acc[i][j][r]) : (unsigned short)0;
    }
}

// ---------------- conv1d (k=4, causal) + SiLU, bf16 in, f32 out + bf16 B,C ------------
__global__ __launch_bounds__(256) void conv_silu2(
    const unsigned short* __restrict__ zxb, const float* __restrict__ cw,
    const float* __restrict__ cb, float* __restrict__ out,
    unsigned short* __restrict__ Bbf, unsigned short* __restrict__ Cbf)
{
  long idx = (long)blockIdx.x * 256 + threadIdx.x;     // (row, ch-quad)
  if (idx >= ROWS * 192) return;
  int cq = (int)(idx % 192);
  long row = idx / 192;
  int t = (int)(row & 1023);
  int ch = cq * 4;
  float4 cbv = *(const float4*)&cb[ch];
  float a0 = cbv.x, a1 = cbv.y, a2 = cbv.z, a3 = cbv.w;
#pragma unroll
  for (int w = 0; w < 4; ++w) {
    int d = w - 3;
    if (t + d >= 0) {
      ushort4 zv = *(const ushort4*)&zxb[(row + d) * DPROJ + 512 + ch];
      float4 cwv = *(const float4*)&cw[w * XBCW + ch];
      a0 = fmaf(bf2f(zv.x), cwv.x, a0);
      a1 = fmaf(bf2f(zv.y), cwv.y, a1);
      a2 = fmaf(bf2f(zv.z), cwv.z, a2);
      a3 = fmaf(bf2f(zv.w), cwv.w, a3);
    }
  }
  float r0 = a0 / (1.f + __expf(-a0));
  float r1 = a1 / (1.f + __expf(-a1));
  float r2 = a2 / (1.f + __expf(-a2));
  float r3 = a3 / (1.f + __expf(-a3));
  *(float4*)&out[row * XBCW + ch] = (float4){r0, r1, r2, r3};
  if (ch >= 512) {
    ushort4 o = {f2bf(r0), f2bf(r1), f2bf(r2), f2bf(r3)};
    if (ch < 640) *(ushort4*)&Bbf[row * 128 + ch - 512] = o;
    else          *(ushort4*)&Cbf[row * 128 + ch - 640] = o;
  }
}

// ---------------- dt from f32 x directly; softplus; wave-parallel cumsum --------------
__global__ __launch_bounds__(256) void dt_cumsum3(
    const float* __restrict__ x, const float* __restrict__ Wdt,
    const float* __restrict__ bdt, const float* __restrict__ dtb,
    const float* __restrict__ alog,
    float* __restrict__ dtsp, float* __restrict__ acs)
{
  int g = ((int)blockIdx.x * 256 + (int)threadIdx.x) >> 6;
  int lane = threadIdx.x & 63;
  int c = g & 3, h = (g >> 2) & 7, b = g >> 5;
  float Ah = -__expf(alog[h]);
  float bias = dtb[h] + bdt[h];
  long rowbase = (long)b * LSEQ + c * QLEN;
  long abase = (((long)b * NH + h) * NCHUNK + c) * QLEN;
  float v[4];
#pragma unroll
  for (int j = 0; j < 4; ++j) {
    long row = rowbase + lane * 4 + j;
    const float4* x4 = (const float4*)&x[row * 200];
    float acc = bias;
    for (int i = 0; i < 50; ++i) {
      float4 xv = x4[i];
      acc += xv.x * Wdt[(i * 4 + 0) * 8 + h]
           + xv.y * Wdt[(i * 4 + 1) * 8 + h]
           + xv.z * Wdt[(i * 4 + 2) * 8 + h]
           + xv.w * Wdt[(i * 4 + 3) * 8 + h];
    }
    float sp = (acc > 20.f) ? acc : log1pf(__expf(acc));
    dtsp[row * NH + h] = sp;
    v[j] = sp * Ah;
  }
  v[1] += v[0]; v[2] += v[1]; v[3] += v[2];
  float tot = v[3];
  float run = tot;
#pragma unroll
  for (int d = 1; d < 64; d <<= 1) {
    float t = __shfl_up(run, d);
    if (lane >= d) run += t;
  }
  float excl = run - tot;
#pragma unroll
  for (int j = 0; j < 4; ++j) acs[abase + lane * 4 + j] = excl + v[j];
}

// ---------------- Bbf [ROWS][128] -> BbfT [bc][128][256] ----------------
__global__ __launch_bounds__(256) void transB(const unsigned short* __restrict__ Bbf,
                                              unsigned short* __restrict__ BbfT)
{
  __shared__ unsigned short T[128][130];
  int bc = blockIdx.y, kh = blockIdx.x;
  int tid = threadIdx.x;
  long rowbase = (long)(bc >> 2) * LSEQ + (bc & 3) * QLEN + kh * 128;
  for (int e = tid; e < 128 * 128; e += 256) {
    int r = e >> 7, n = e & 127;
    T[r][n] = Bbf[(rowbase + r) * 128 + n];
  }
  __syncthreads();
  for (int e = tid; e < 128 * 128; e += 256) {
    int n = e >> 7, k = e & 127;
    BbfT[((long)bc * 128 + n) * 256 + kh * 128 + k] = T[k][n];
  }
}

// ---------------- MFMA yd + states, copy-staged operands + accumulator rescale --------
__global__ __launch_bounds__(256) void yd_states4(
    const float* __restrict__ xbc, const float* __restrict__ dtsp,
    const float* __restrict__ acs, const unsigned short* __restrict__ Gbf,
    const unsigned short* __restrict__ BbfT,
    float* __restrict__ y, float* __restrict__ st)
{
  int bid = blockIdx.x;
  int xcd = bid & 7, i0 = bid >> 3;
  int bc = xcd * 8 + (i0 >> 3), h = i0 & 7;
  int c = bc & 3, b = bc >> 2;
  int bch = bc * 8 + h;

  __shared__ __align__(16) unsigned short Ws[256][72];
  __shared__ __align__(16) unsigned short BT[128][72];
  __shared__ __align__(16) unsigned short XdT[64][72];
  __shared__ float AcsS[256], E1f[256];
  __shared__ float E2[64];

  const int tid = threadIdx.x;
  const int lane = tid & 63, wv = tid >> 6;
  long rowbase = (long)b * LSEQ + c * QLEN;
  const unsigned short* Gb  = Gbf + (long)bc * 65536;
  const unsigned short* BTg = BbfT + (long)bc * 32768;

  AcsS[tid] = acs[(((long)b * NH + h) * NCHUNK + c) * QLEN + tid];
  __syncthreads();
  E1f[tid] = __expf(AcsS[tid] - AcsS[tid | 63]);

  f32x4 accY[4][4], accS[2][4];
#pragma unroll
  for (int i = 0; i < 4; ++i)
#pragma unroll
    for (int j = 0; j < 4; ++j) accY[i][j] = (f32x4){0.f, 0.f, 0.f, 0.f};
#pragma unroll
  for (int i = 0; i < 2; ++i)
#pragma unroll
    for (int j = 0; j < 4; ++j) accS[i][j] = (f32x4){0.f, 0.f, 0.f, 0.f};

  for (int kt = 0; kt < 4; ++kt) {
    int qlo = kt * 64;
    float ref = AcsS[qlo + 63];
    __syncthreads();                                 // prior MFMA reads done
    if (tid < 64) E2[tid] = __expf(ref - AcsS[qlo + tid]);
    __syncthreads();
    // XdT[p][k] = bf16(xh * dt * E2[k]); b64 writes
#pragma unroll
    for (int s = 0; s < 4; ++s) {
      int kq = wv * 4 + s;
      ushort4 pk;
      unsigned short* pp = (unsigned short*)&pk;
#pragma unroll
      for (int j = 0; j < 4; ++j) {
        int k = kq * 4 + j;
        long row = rowbase + qlo + k;
        float v = xbc[row * XBCW + h * HD + lane] * dtsp[row * NH + h] * E2[k];
        pp[j] = f2bf(v);
      }
      *(ushort4*)&XdT[lane][kq * 4] = pk;
    }
    // BT rows (plain copy from BbfT)
#pragma unroll
    for (int s = 0; s < 4; ++s) {
      int e = s * 256 + tid;
      int n = e >> 3, seg = e & 7;
      *(s16x8*)&BT[n][seg * 8] = *(const s16x8*)&BTg[(long)n * 256 + qlo + seg * 8];
    }
    // Ws rows q in [qlo,256) (plain copy from masked bf16 G)
    int nunits = (256 - qlo) * 8;
    for (int e = tid; e < nunits; e += 256) {
      int q = qlo + (e >> 3), seg = e & 7;
      *(s16x8*)&Ws[q][seg * 8] = *(const s16x8*)&Gb[(long)q * 256 + qlo + seg * 8];
    }
    __syncthreads();
    // cross-chunk rescale
    if (kt) {
      float rs = __expf(ref - AcsS[qlo - 1]);
      if (wv >= kt)
#pragma unroll
        for (int i = 0; i < 4; ++i)
#pragma unroll
          for (int j = 0; j < 4; ++j) accY[i][j] *= rs;
#pragma unroll
      for (int i = 0; i < 2; ++i)
#pragma unroll
        for (int j = 0; j < 4; ++j) accS[i][j] *= rs;
    }
#pragma unroll
    for (int ks = 0; ks < 2; ++ks) {
      s16x8 bfr[4];
#pragma unroll
      for (int j = 0; j < 4; ++j)
        bfr[j] = *(const s16x8*)&XdT[j * 16 + (lane & 15)][ks * 32 + (lane >> 4) * 8];
      if (wv >= kt) {
#pragma unroll
        for (int i = 0; i < 4; ++i) {
          s16x8 a = *(const s16x8*)&Ws[wv * 64 + i * 16 + (lane & 15)][ks * 32 + (lane >> 4) * 8];
#pragma unroll
          for (int j = 0; j < 4; ++j)
            accY[i][j] = __builtin_amdgcn_mfma_f32_16x16x32_bf16(a, bfr[j], accY[i][j], 0, 0, 0);
        }
      }
#pragma unroll
      for (int i2 = 0; i2 < 2; ++i2) {
        s16x8 a = *(const s16x8*)&BT[wv * 32 + i2 * 16 + (lane & 15)][ks * 32 + (lane >> 4) * 8];
#pragma unroll
        for (int j = 0; j < 4; ++j)
          accS[i2][j] = __builtin_amdgcn_mfma_f32_16x16x32_bf16(a, bfr[j], accS[i2][j], 0, 0, 0);
      }
    }
  }
  const int cr = (lane >> 4) * 4, cc = lane & 15;
#pragma unroll
  for (int i = 0; i < 4; ++i)
#pragma unroll
    for (int j = 0; j < 4; ++j) {
      int q = wv * 64 + i * 16 + cr;
      int p = j * 16 + cc;
#pragma unroll
      for (int r = 0; r < 4; ++r)
        y[(rowbase + q + r) * DIN + h * HD + p] = accY[i][j][r] * E1f[q + r];
    }
#pragma unroll
  for (int i2 = 0; i2 < 2; ++i2)
#pragma unroll
    for (int j = 0; j < 4; ++j) {
      int n = wv * 32 + i2 * 16 + cr;
      int p = j * 16 + cc;
#pragma unroll
      for (int r = 0; r < 4; ++r)
        st[(long)bch * 8192 + (long)(n + r) * 64 + p] = accS[i2][j][r];
    }
}

// ---------------- inter-chunk scan (in place; layout [n*64+p]) ----------------
__global__ void scan_states(float* __restrict__ st, const float* __restrict__ acs)
{
  long idx = (long)blockIdx.x * 256 + threadIdx.x;
  if (idx >= (long)NB * NH * 8192) return;
  long inner = idx & 8191;
  int h = (int)((idx >> 13) & 7);
  int b = (int)(idx >> 16);
  float carry = 0.f;
  for (int c = 0; c < NCHUNK; ++c) {
    float dc = __expf(acs[(((long)b * NH + h) * NCHUNK + c) * QLEN + (QLEN - 1)]);
    long si = (((long)(b * NCHUNK + c) * NH + h) << 13) + inner;
    float s = st[si];
    st[si] = carry;
    carry = carry * dc + s;
  }
}

// ---------------- Yo tiled f32: y += exp(Acs[q]) * C·prev^T + xh*D ----------------
__global__ __launch_bounds__(256) void yo_combine3(
    const float* __restrict__ xbc, const float* __restrict__ prev,
    const float* __restrict__ acs, const float* __restrict__ Dp,
    float* __restrict__ y)
{
  int bch = blockIdx.x;
  int h = bch & 7, bc = bch >> 3;
  int c = bc & 3, b = bc >> 2;
  __shared__ __align__(16) float Pn[128][68];
  __shared__ __align__(16) float Cs[128][68];
  __shared__ float EqA[QLEN];
  int tid = threadIdx.x;
  for (int e = tid; e < HD * DSTATE; e += 256)
    Pn[e >> 6][e & 63] = prev[((long)bch << 13) + e];
  EqA[tid] = __expf(acs[(((long)b * NH + h) * NCHUNK + c) * QLEN + tid]);
  long rowbase = (long)b * LSEQ + c * QLEN;
  float Dh = Dp[h];
  int tq = tid >> 4, tp = tid & 15;
  for (int qt = 0; qt < 4; ++qt) {
    __syncthreads();
    for (int e = tid; e < 64 * 128; e += 256) {
      int q = e >> 7, n = e & 127;
      Cs[n][q] = xbc[(rowbase + qt * 64 + q) * XBCW + 640 + n];
    }
    __syncthreads();
    float acc[4][4] = {};
    for (int k = 0; k < 128; ++k) {
      float4 av = *(const float4*)&Cs[k][tq * 4];
      float4 bv = *(const float4*)&Pn[k][tp * 4];
      float a_[4] = {av.x, av.y, av.z, av.w};
      float b_[4] = {bv.x, bv.y, bv.z, bv.w};
#pragma unroll
      for (int i = 0; i < 4; ++i)
#pragma unroll
        for (int j = 0; j < 4; ++j) acc[i][j] = fmaf(a_[i], b_[j], acc[i][j]);
    }
#pragma unroll
    for (int i = 0; i < 4; ++i) {
      int q = qt * 64 + tq * 4 + i;
      long row = rowbase + q;
      float eq = EqA[q];
#pragma unroll
      for (int j = 0; j < 4; ++j) {
        int p = tp * 4 + j;
        float xh = xbc[row * XBCW + h * HD + p];
        y[row * DIN + h * HD + p] += acc[i][j] * eq + xh * Dh;
      }
    }
  }
}

// ---------------- gated RMSNorm: bf16 z in, bf16 y out ----------------
__global__ __launch_bounds__(256) void gated_rms2(
    const float* __restrict__ y, const unsigned short* __restrict__ zxb,
    const float* __restrict__ rmsw, unsigned short* __restrict__ ybf)
{
  long row = blockIdx.x;
  int t = threadIdx.x;
  float z0 = bf2f(zxb[row * DPROJ + t]), z1 = bf2f(zxb[row * DPROJ + t + 256]);
  float v0 = y[row * DIN + t] * (z0 / (1.f + __expf(-z0)));
  float v1 = y[row * DIN + t + 256] * (z1 / (1.f + __expf(-z1)));
  float ss = v0 * v0 + v1 * v1;
#pragma unroll
  for (int off = 32; off; off >>= 1) ss += __shfl_down(ss, off);
  __shared__ float red[4];
  if ((t & 63) == 0) red[t >> 6] = ss;
  __syncthreads();
  float tot = red[0] + red[1] + red[2] + red[3];
  float scale = rsqrtf(tot * (1.f / DIN) + 1e-5f);
  ybf[row * DIN + t]       = f2bf(v0 * scale * rmsw[t]);
  ybf[row * DIN + t + 256] = f2bf(v1 * scale * rmsw[t + 256]);
}

// ---------------- LayerNorm in place over 256 ----------------
__global__ __launch_bounds__(256) void layernorm(
    float* __restrict__ y2, const float* __restrict__ g, const float* __restrict__ bb)
{
  long row = blockIdx.x;
  int t = threadIdx.x;
  float v = y2[row * DM + t];
  float s = v, q = v * v;
#pragma unroll
  for (int off = 32; off; off >>= 1) { s += __shfl_down(s, off); q += __shfl_down(q, off); }
  __shared__ float sA[4], sB[4];
  if ((t & 63) == 0) { sA[t >> 6] = s; sB[t >> 6] = q; }
  __syncthreads();
  float S = sA[0] + sA[1] + sA[2] + sA[3];
  float Qs = sB[0] + sB[1] + sB[2] + sB[3];
  float mu = S * (1.f / DM);
  float var = Qs * (1.f / DM) - mu * mu;
  y2[row * DM + t] = (v - mu) * rsqrtf(var + 1e-5f) * g[t] + bb[t];
}

// ---------------- classifier ----------------
__global__ void cls(const float* __restrict__ yn, const float* __restrict__ w,
                    const float* __restrict__ bias, float* __restrict__ out)
{
  long idx = (long)blockIdx.x * 256 + threadIdx.x;
  if (idx >= ROWS * NCLS) return;
  int j = (int)(idx % NCLS);
  long row = idx / NCLS;
  float acc = bias[j];
  for (int i = 0; i < DM; ++i) acc = fmaf(yn[row * DM + i], w[i * NCLS + j], acc);
  out[idx] = acc;
}

extern "C" void kernel_launch(void* const* d_in, const int* in_sizes, int n_in,
                              void* d_out, int out_size, void* d_ws, size_t ws_size,
                              hipStream_t stream)
{
  const float* x     = (const float*)d_in[0];
  const float* w_inp = (const float*)d_in[1];
  const float* b_inp = (const float*)d_in[2];
  const float* w_in  = (const float*)d_in[3];
  const float* convw = (const float*)d_in[4];
  const float* convb = (const float*)d_in[5];
  const float* dtb   = (const float*)d_in[6];
  const float* alog  = (const float*)d_in[7];
  const float* Dp    = (const float*)d_in[8];
  const float* rmsw  = (const float*)d_in[9];
  const float* wout  = (const float*)d_in[10];
  const float* lng   = (const float*)d_in[11];
  const float* lnb   = (const float*)d_in[12];
  const float* wcls  = (const float*)d_in[13];
  const float* bcls  = (const float*)d_in[14];
  float* out = (float*)d_out;
  float* ws  = (float*)d_ws;

  float* xbc  = ws + O_XBC;
  float* dtsp = ws + O_DT;
  float* acs  = ws + O_ACS;
  float* y    = ws + O_Y;
  float* st   = ws + O_ST;
  float* y2   = ws + O_Y2;
  float* Wdt  = ws + O_WDT;
  float* bdt  = Wdt + 1600;
  unsigned short* Gbf   = (unsigned short*)(ws + O_U);
  unsigned short* zxb   = (unsigned short*)(ws + O_ZX);
  unsigned short* u_bf  = (unsigned short*)(ws + O_UBF);
  unsigned short* w_inT = (unsigned short*)(ws + O_WINT);
  unsigned short* xp_bf = (unsigned short*)(ws + O_XPBF);
  unsigned short* w_inpT= (unsigned short*)(ws + O_WINPT);
  unsigned short* y_bf  = (unsigned short*)(ws + O_YBF);
  unsigned short* woutT = (unsigned short*)(ws + O_WOUTT);
  unsigned short* Bbf   = (unsigned short*)(ws + O_BBF);
  unsigned short* Cbf   = (unsigned short*)(ws + O_CBF);
  unsigned short* BbfT  = (unsigned short*)(ws + O_BT);

  // input_proj via bf16 MFMA (K padded 200->224); dt path stays f32 via Wdt
  cast_pad_x<<<(int)((ROWS * 56 + 255) / 256), 256, 0, stream>>>(x, xp_bf);
  tcast_pad_winp<<<224, 256, 0, stream>>>(w_inp, w_inpT);
  combine_wdt<<<7, 256, 0, stream>>>(w_inp, w_in, b_inp, Wdt, bdt);
  gemm_bf16<<<dim3(2, 128), 256, 0, stream>>>(xp_bf, w_inpT, nullptr, u_bf, b_inp, 16384, 256, 224);
  // in_proj -> bf16 zx
  tcast<<<1288, 256, 0, stream>>>(w_in, w_inT, 8, DPROJ);
  gemm_bf16<<<dim3(11, 128), 256, 0, stream>>>(u_bf, w_inT, nullptr, zxb, nullptr, 16384, DPROJ, DM);
  // conv + SiLU
  conv_silu2<<<12288, 256, 0, stream>>>(zxb, convw, convb, xbc, Bbf, Cbf);
  // dt (f32 from x) + cumsum
  dt_cumsum3<<<128, 256, 0, stream>>>(x, Wdt, bdt, dtb, alog, dtsp, acs);
  // SSD
  transB<<<dim3(2, 64), 256, 0, stream>>>(Bbf, BbfT);
  g_gemm_bf16<<<dim3(2, 2, 64), 256, 0, stream>>>(Cbf, Bbf, Gbf);
  yd_states4<<<512, 256, 0, stream>>>(xbc, dtsp, acs, Gbf, BbfT, y, st);
  scan_states<<<4096, 256, 0, stream>>>(st, acs);
  yo_combine3<<<512, 256, 0, stream>>>(xbc, st, acs, Dp, y);
  // gated RMSNorm -> bf16
  gated_rms2<<<16384, 256, 0, stream>>>(y, zxb, rmsw, y_bf);
  // out_proj
  tcast<<<512, 256, 0, stream>>>(wout, woutT, 9, DM);
  gemm_bf16<<<dim3(2, 128), 256, 0, stream>>>(y_bf, woutT, y2, nullptr, nullptr, 16384, DM, DIN);
  // head
  layernorm<<<16384, 256, 0, stream>>>(y2, lng, lnb);
  cls<<<(int)((ROWS * NCLS + 255) / 256), 256, 0, stream>>>(y2, wcls, bcls, out);
}

// Round 6
// 346.661 us; speedup vs baseline: 3.6274x; 1.0461x over previous
//
#include <hip/hip_runtime.h>
#include <math.h>

#define ROWS   16384L
#define LSEQ   1024
#define NB     16
#define DM     256
#define DPROJ  1288
#define XBCW   768
#define DIN    512
#define DSTATE 128
#define NH     8
#define HD     64
#define QLEN   256
#define NCHUNK 4
#define NCLS   17

typedef __attribute__((ext_vector_type(8))) short s16x8;
typedef __attribute__((ext_vector_type(4))) float f32x4;

// ---- workspace map (floats) ----
constexpr long O_U    = 0;                        // Gbf overlay (bf16)
constexpr long O_ZX   = O_U   + ROWS*DM;          // zxb bf16 [ROWS][1288]
constexpr long O_XBC  = O_ZX  + ROWS*DPROJ;       // xbc f32; later ybf+woutT overlay
constexpr long O_DT   = O_XBC + ROWS*XBCW;
constexpr long O_ACS  = O_DT  + ROWS*NH;
constexpr long O_Y    = O_ACS + 131072;           // y f32; overlays below
constexpr long O_ST   = O_Y   + ROWS*DIN;         // st f32 [512][64p][128n]
constexpr long O_Y2   = O_ST  + 4194304;          // y2 f32; overlays Bbf/Cbf/BbfT
// overlays in O_Y region (dead before yd writes y):
constexpr long O_UBF  = O_Y;
constexpr long O_WINT = O_Y + 2200000;
constexpr long O_XPBF = O_Y + 2500000;
constexpr long O_WINPT= O_Y + 4500000;
constexpr long O_WDT  = O_Y + 8300000;
// overlays in O_XBC region:
constexpr long O_YBF  = O_XBC;
constexpr long O_WOUTT= O_XBC + 4300000;
// overlays in O_Y2 region:
constexpr long O_BBF  = O_Y2;
constexpr long O_CBF  = O_Y2 + 1048576;
constexpr long O_BT   = O_Y2 + 2097152;

__device__ inline unsigned short f2bf(float f) {
  union { float f; unsigned u; } v; v.f = f;
  unsigned r = v.u + 0x7FFFu + ((v.u >> 16) & 1u);
  return (unsigned short)(r >> 16);
}
__device__ inline float bf2f(unsigned short s) {
  union { unsigned u; float f; } v; v.u = ((unsigned)s) << 16; return v.f;
}

// ---------------- pad+cast x: [ROWS][200] f32 -> [ROWS][224] bf16 ----------------
__global__ __launch_bounds__(256) void cast_pad_x(const float* __restrict__ x,
                                                  unsigned short* __restrict__ xp)
{
  long idx = (long)blockIdx.x * 256 + threadIdx.x;
  if (idx >= ROWS * 56) return;
  int q = (int)(idx % 56);
  long row = idx / 56;
  ushort4 o = {0, 0, 0, 0};
  if (q < 50) {
    float4 v = *(const float4*)&x[row * 200 + q * 4];
    o.x = f2bf(v.x); o.y = f2bf(v.y); o.z = f2bf(v.z); o.w = f2bf(v.w);
  }
  *(ushort4*)&xp[row * 224 + q * 4] = o;
}

// ---------------- w_inp [200][256] -> w_inpT [256][224] bf16 ----------------
__global__ __launch_bounds__(256) void tcast_pad_winp(const float* __restrict__ w,
                                                      unsigned short* __restrict__ wt)
{
  int i = blockIdx.x * 256 + threadIdx.x;
  if (i >= 256 * 224) return;
  int k = i % 224, n = i / 224;
  wt[i] = (k < 200) ? f2bf(w[(long)k * 256 + n]) : (unsigned short)0;
}

// ---------------- transpose+cast: w[K,N] f32 -> wt[N,K] bf16 ----------------
__global__ __launch_bounds__(256) void tcast(const float* __restrict__ w,
                                             unsigned short* __restrict__ wt,
                                             int kbits, int N)
{
  long i = (long)blockIdx.x * 256 + threadIdx.x;
  int K = 1 << kbits;
  if (i >= (long)K * N) return;
  int k = (int)(i & (K - 1));
  long n = i >> kbits;
  wt[i] = f2bf(w[(long)k * N + n]);
}

// ---------------- Wdt = w_inp @ w_in[:,1280:1288]; bdt = b_inp @ same -------
__global__ void combine_wdt(const float* __restrict__ w_inp, const float* __restrict__ w_in,
                            const float* __restrict__ b_inp,
                            float* __restrict__ Wdt, float* __restrict__ bdt)
{
  int e = blockIdx.x * 256 + threadIdx.x;
  if (e < 1600) {
    int k = e >> 3, h = e & 7;
    float a = 0.f;
    for (int j = 0; j < 256; ++j) a += w_inp[(long)k * 256 + j] * w_in[(long)j * DPROJ + 1280 + h];
    Wdt[e] = a;
  } else if (e < 1608) {
    int h = e - 1600;
    float a = 0.f;
    for (int j = 0; j < 256; ++j) a += b_inp[j] * w_in[(long)j * DPROJ + 1280 + h];
    bdt[h] = a;
  }
}

// ---------------- bf16 MFMA GEMM: out = A[M,K] @ BT[N,K]^T (+bias) ----------------
__global__ __launch_bounds__(256) void gemm_bf16(
    const unsigned short* __restrict__ A, const unsigned short* __restrict__ BT,
    float* __restrict__ C, unsigned short* __restrict__ Cb,
    const float* __restrict__ bias, int M, int N, int K)
{
  __shared__ __align__(16) unsigned short As[128 * 32];
  __shared__ __align__(16) unsigned short Bs[128 * 32];
  const int tid = threadIdx.x;
  const int m0 = blockIdx.y * 128, n0 = blockIdx.x * 128;
  const int lane = tid & 63, wv = tid >> 6;
  const int wr = (wv >> 1) * 64, wc = (wv & 1) * 64;
  f32x4 acc[4][4];
#pragma unroll
  for (int i = 0; i < 4; ++i)
#pragma unroll
    for (int j = 0; j < 4; ++j) acc[i][j] = (f32x4){0.f, 0.f, 0.f, 0.f};

  for (int k0 = 0; k0 < K; k0 += 32) {
    __syncthreads();
#pragma unroll
    for (int s = 0; s < 2; ++s) {
      int idx = (tid + 256 * s) * 8;
      int r = idx >> 5, kk = idx & 31;
      *(s16x8*)&As[idx] = *(const s16x8*)&A[(long)(m0 + r) * K + k0 + kk];
    }
#pragma unroll
    for (int s = 0; s < 2; ++s) {
      int idx = (tid + 256 * s) * 8;
      int n = idx >> 5, kk = idx & 31;
      s16x8 vv = {};
      if (n0 + n < N) vv = *(const s16x8*)&BT[(long)(n0 + n) * K + k0 + kk];
      *(s16x8*)&Bs[idx] = vv;
    }
    __syncthreads();
    s16x8 af[4], bf[4];
#pragma unroll
    for (int i = 0; i < 4; ++i)
      af[i] = *(const s16x8*)&As[(wr + i * 16 + (lane & 15)) * 32 + (lane >> 4) * 8];
#pragma unroll
    for (int j = 0; j < 4; ++j)
      bf[j] = *(const s16x8*)&Bs[(wc + j * 16 + (lane & 15)) * 32 + (lane >> 4) * 8];
#pragma unroll
    for (int i = 0; i < 4; ++i)
#pragma unroll
      for (int j = 0; j < 4; ++j)
        acc[i][j] = __builtin_amdgcn_mfma_f32_16x16x32_bf16(af[i], bf[j], acc[i][j], 0, 0, 0);
  }
  const int cr = (lane >> 4) * 4, cc = lane & 15;
#pragma unroll
  for (int i = 0; i < 4; ++i)
#pragma unroll
    for (int j = 0; j < 4; ++j) {
      int col = n0 + wc + j * 16 + cc;
      if (col < N) {
        long rowb = (long)(m0 + wr + i * 16 + cr);
        float bv = bias ? bias[col] : 0.f;
#pragma unroll
        for (int r = 0; r < 4; ++r) {
          float v = acc[i][j][r] + bv;
          if (C)  C[(rowb + r) * N + col] = v;
          if (Cb) Cb[(rowb + r) * (long)N + col] = f2bf(v);
        }
      }
    }
}

// ---------------- G = C·B^T per (b,c) -> bf16 causal-masked ----------------
__global__ __launch_bounds__(256) void g_gemm_bf16(
    const unsigned short* __restrict__ Cbf, const unsigned short* __restrict__ Bbf,
    unsigned short* __restrict__ Gbf)
{
  int bc = blockIdx.z;
  unsigned short* Gout = Gbf + (long)bc * 65536;
  const int tid = threadIdx.x;
  const int m0 = blockIdx.y * 128, n0 = blockIdx.x * 128;
  if (blockIdx.x > blockIdx.y) {
    s16x8 z = {};
    for (int e = tid; e < 128 * 16; e += 256) {
      int r = e >> 4, seg = e & 15;
      *(s16x8*)&Gout[(long)(m0 + r) * 256 + n0 + seg * 8] = z;
    }
    return;
  }
  long rowbase = (long)(bc >> 2) * LSEQ + (bc & 3) * QLEN;
  const unsigned short* A  = Cbf + rowbase * 128;
  const unsigned short* BT = Bbf + rowbase * 128;
  __shared__ __align__(16) unsigned short As[128 * 32];
  __shared__ __align__(16) unsigned short Bs[128 * 32];
  const int lane = tid & 63, wv = tid >> 6;
  const int wr = (wv >> 1) * 64, wc = (wv & 1) * 64;
  f32x4 acc[4][4];
#pragma unroll
  for (int i = 0; i < 4; ++i)
#pragma unroll
    for (int j = 0; j < 4; ++j) acc[i][j] = (f32x4){0.f, 0.f, 0.f, 0.f};
  for (int k0 = 0; k0 < 128; k0 += 32) {
    __syncthreads();
#pragma unroll
    for (int s = 0; s < 2; ++s) {
      int idx = (tid + 256 * s) * 8;
      int r = idx >> 5, kk = idx & 31;
      *(s16x8*)&As[idx] = *(const s16x8*)&A[(long)(m0 + r) * 128 + k0 + kk];
      *(s16x8*)&Bs[idx] = *(const s16x8*)&BT[(long)(n0 + r) * 128 + k0 + kk];
    }
    __syncthreads();
    s16x8 af[4], bf[4];
#pragma unroll
    for (int i = 0; i < 4; ++i)
      af[i] = *(const s16x8*)&As[(wr + i * 16 + (lane & 15)) * 32 + (lane >> 4) * 8];
#pragma unroll
    for (int j = 0; j < 4; ++j)
      bf[j] = *(const s16x8*)&Bs[(wc + j * 16 + (lane & 15)) * 32 + (lane >> 4) * 8];
#pragma unroll
    for (int i = 0; i < 4; ++i)
#pragma unroll
      for (int j = 0; j < 4; ++j)
        acc[i][j] = __builtin_amdgcn_mfma_f32_16x16x32_bf16(af[i], bf[j], acc[i][j], 0, 0, 0);
  }
  const int cr = (lane >> 4) * 4, cc = lane & 15;
#pragma unroll
  for (int i = 0; i < 4; ++i)
#pragma unroll
    for (int j = 0; j < 4; ++j) {
      int col = n0 + wc + j * 16 + cc;
      int qb = m0 + wr + i * 16 + cr;
#pragma unroll
      for (int r = 0; r < 4; ++r)
        Gout[(long)(qb + r) * 256 + col] = (col <= qb + r) ? f2bf(acc[i][j][r]) : (unsigned short)0;
    }
}

// ---------------- conv1d (k=4, causal) + SiLU ----------------
__global__ __launch_bounds__(256) void conv_silu2(
    const unsigned short* __restrict__ zxb, const float* __restrict__ cw,
    const float* __restrict__ cb, float* __restrict__ out,
    unsigned short* __restrict__ Bbf, unsigned short* __restrict__ Cbf)
{
  long idx = (long)blockIdx.x * 256 + threadIdx.x;
  if (idx >= ROWS * 192) return;
  int cq = (int)(idx % 192);
  long row = idx / 192;
  int t = (int)(row & 1023);
  int ch = cq * 4;
  float4 cbv = *(const float4*)&cb[ch];
  float a0 = cbv.x, a1 = cbv.y, a2 = cbv.z, a3 = cbv.w;
#pragma unroll
  for (int w = 0; w < 4; ++w) {
    int d = w - 3;
    if (t + d >= 0) {
      ushort4 zv = *(const ushort4*)&zxb[(row + d) * DPROJ + 512 + ch];
      float4 cwv = *(const float4*)&cw[w * XBCW + ch];
      a0 = fmaf(bf2f(zv.x), cwv.x, a0);
      a1 = fmaf(bf2f(zv.y), cwv.y, a1);
      a2 = fmaf(bf2f(zv.z), cwv.z, a2);
      a3 = fmaf(bf2f(zv.w), cwv.w, a3);
    }
  }
  float r0 = a0 / (1.f + __expf(-a0));
  float r1 = a1 / (1.f + __expf(-a1));
  float r2 = a2 / (1.f + __expf(-a2));
  float r3 = a3 / (1.f + __expf(-a3));
  *(float4*)&out[row * XBCW + ch] = (float4){r0, r1, r2, r3};
  if (ch >= 512) {
    ushort4 o = {f2bf(r0), f2bf(r1), f2bf(r2), f2bf(r3)};
    if (ch < 640) *(ushort4*)&Bbf[row * 128 + ch - 512] = o;
    else          *(ushort4*)&Cbf[row * 128 + ch - 640] = o;
  }
}

// ---------------- dt from f32 x; softplus; wave-parallel cumsum ----------------
__global__ __launch_bounds__(256) void dt_cumsum3(
    const float* __restrict__ x, const float* __restrict__ Wdt,
    const float* __restrict__ bdt, const float* __restrict__ dtb,
    const float* __restrict__ alog,
    float* __restrict__ dtsp, float* __restrict__ acs)
{
  int g = ((int)blockIdx.x * 256 + (int)threadIdx.x) >> 6;
  int lane = threadIdx.x & 63;
  int c = g & 3, h = (g >> 2) & 7, b = g >> 5;
  float Ah = -__expf(alog[h]);
  float bias = dtb[h] + bdt[h];
  long rowbase = (long)b * LSEQ + c * QLEN;
  long abase = (((long)b * NH + h) * NCHUNK + c) * QLEN;
  float v[4];
#pragma unroll
  for (int j = 0; j < 4; ++j) {
    long row = rowbase + lane * 4 + j;
    const float4* x4 = (const float4*)&x[row * 200];
    float acc = bias;
    for (int i = 0; i < 50; ++i) {
      float4 xv = x4[i];
      acc += xv.x * Wdt[(i * 4 + 0) * 8 + h]
           + xv.y * Wdt[(i * 4 + 1) * 8 + h]
           + xv.z * Wdt[(i * 4 + 2) * 8 + h]
           + xv.w * Wdt[(i * 4 + 3) * 8 + h];
    }
    float sp = (acc > 20.f) ? acc : log1pf(__expf(acc));
    dtsp[row * NH + h] = sp;
    v[j] = sp * Ah;
  }
  v[1] += v[0]; v[2] += v[1]; v[3] += v[2];
  float tot = v[3];
  float run = tot;
#pragma unroll
  for (int d = 1; d < 64; d <<= 1) {
    float t = __shfl_up(run, d);
    if (lane >= d) run += t;
  }
  float excl = run - tot;
#pragma unroll
  for (int j = 0; j < 4; ++j) acs[abase + lane * 4 + j] = excl + v[j];
}

// ---------------- Bbf [ROWS][128] -> BbfT [bc][128][256] ----------------
__global__ __launch_bounds__(256) void transB(const unsigned short* __restrict__ Bbf,
                                              unsigned short* __restrict__ BbfT)
{
  __shared__ unsigned short T[128][130];
  int bc = blockIdx.y, kh = blockIdx.x;
  int tid = threadIdx.x;
  long rowbase = (long)(bc >> 2) * LSEQ + (bc & 3) * QLEN + kh * 128;
  for (int e = tid; e < 128 * 128; e += 256) {
    int r = e >> 7, n = e & 127;
    T[r][n] = Bbf[(rowbase + r) * 128 + n];
  }
  __syncthreads();
  for (int e = tid; e < 128 * 128; e += 256) {
    int n = e >> 7, k = e & 127;
    BbfT[((long)bc * 128 + n) * 256 + kh * 128 + k] = T[k][n];
  }
}

// ---------------- yd+states: role-split waves, operands direct from L2 ----------------
// grid 1024: (xcd, bc-local, h, half). Waves 0-1: Yd rows q in [half*128+wv*64, +64).
// Waves 2-3: statesT[p][n] for n in [half*64+(wv-2)*32, +32).
__global__ __launch_bounds__(256) void yd_states5(
    const float* __restrict__ xbc, const float* __restrict__ dtsp,
    const float* __restrict__ acs, const unsigned short* __restrict__ Gbf,
    const unsigned short* __restrict__ BbfT,
    float* __restrict__ y, float* __restrict__ st)
{
  int bid = blockIdx.x;
  int xcd = bid & 7, i0 = bid >> 3;
  int bc = xcd * 8 + (i0 >> 4);
  int rem = i0 & 15, h = rem >> 1, half = rem & 1;
  int c = bc & 3, b = bc >> 2;
  int bch = bc * 8 + h;

  __shared__ __align__(16) unsigned short XdT[64][72];
  __shared__ float AcsS[256], E1f[256], E2[64];

  const int tid = threadIdx.x;
  const int lane = tid & 63, wv = tid >> 6;
  const bool ydw = wv < 2;
  const int q0 = half * 128 + wv * 64;          // Yd waves
  const int myqt = half * 2 + wv;               // chunk of q0
  const int n0w = half * 64 + (wv - 2) * 32;    // states waves
  long rowbase = (long)b * LSEQ + c * QLEN;
  const unsigned short* Gb  = Gbf + (long)bc * 65536;
  const unsigned short* BTg = BbfT + (long)bc * 32768;

  AcsS[tid] = acs[(((long)b * NH + h) * NCHUNK + c) * QLEN + tid];
  __syncthreads();
  E1f[tid] = __expf(AcsS[tid] - AcsS[tid | 63]);

  f32x4 accY[4][4], accS[4][2];
#pragma unroll
  for (int i = 0; i < 4; ++i)
#pragma unroll
    for (int j = 0; j < 4; ++j) accY[i][j] = (f32x4){0.f, 0.f, 0.f, 0.f};
#pragma unroll
  for (int i = 0; i < 4; ++i)
#pragma unroll
    for (int j = 0; j < 2; ++j) accS[i][j] = (f32x4){0.f, 0.f, 0.f, 0.f};

  for (int kt = 0; kt < 4; ++kt) {
    int qlo = kt * 64;
    float ref = AcsS[qlo + 63];
    __syncthreads();
    if (tid < 64) E2[tid] = __expf(ref - AcsS[qlo + tid]);
    __syncthreads();
    // stage XdT[p][k] = bf16(xh * dt * E2[k])
#pragma unroll
    for (int s = 0; s < 4; ++s) {
      int kq = wv * 4 + s;
      ushort4 pk;
      unsigned short* pp = (unsigned short*)&pk;
#pragma unroll
      for (int j = 0; j < 4; ++j) {
        int k = kq * 4 + j;
        long row = rowbase + qlo + k;
        float v = xbc[row * XBCW + h * HD + lane] * dtsp[row * NH + h] * E2[k];
        pp[j] = f2bf(v);
      }
      *(ushort4*)&XdT[lane][kq * 4] = pk;
    }
    __syncthreads();
    float rs = kt ? __expf(ref - AcsS[qlo - 1]) : 1.f;
    if (ydw) {
      if (myqt >= kt) {
        if (kt)
#pragma unroll
          for (int i = 0; i < 4; ++i)
#pragma unroll
            for (int j = 0; j < 4; ++j) accY[i][j] *= rs;
#pragma unroll
        for (int ks = 0; ks < 2; ++ks) {
          s16x8 bfr[4];
#pragma unroll
          for (int j = 0; j < 4; ++j)
            bfr[j] = *(const s16x8*)&XdT[j * 16 + (lane & 15)][ks * 32 + (lane >> 4) * 8];
#pragma unroll
          for (int i = 0; i < 4; ++i) {
            s16x8 a = *(const s16x8*)&Gb[(long)(q0 + i * 16 + (lane & 15)) * 256 + qlo + ks * 32 + (lane >> 4) * 8];
#pragma unroll
            for (int j = 0; j < 4; ++j)
              accY[i][j] = __builtin_amdgcn_mfma_f32_16x16x32_bf16(a, bfr[j], accY[i][j], 0, 0, 0);
          }
        }
      }
    } else {
      if (kt)
#pragma unroll
        for (int i = 0; i < 4; ++i)
#pragma unroll
          for (int j = 0; j < 2; ++j) accS[i][j] *= rs;
#pragma unroll
      for (int ks = 0; ks < 2; ++ks) {
        s16x8 afx[4];
#pragma unroll
        for (int i = 0; i < 4; ++i)
          afx[i] = *(const s16x8*)&XdT[i * 16 + (lane & 15)][ks * 32 + (lane >> 4) * 8];
#pragma unroll
        for (int j2 = 0; j2 < 2; ++j2) {
          s16x8 bt = *(const s16x8*)&BTg[(long)(n0w + j2 * 16 + (lane & 15)) * 256 + qlo + ks * 32 + (lane >> 4) * 8];
#pragma unroll
          for (int i = 0; i < 4; ++i)
            accS[i][j2] = __builtin_amdgcn_mfma_f32_16x16x32_bf16(afx[i], bt, accS[i][j2], 0, 0, 0);
        }
      }
    }
  }
  const int cr = (lane >> 4) * 4, cc = lane & 15;
  if (ydw) {
#pragma unroll
    for (int i = 0; i < 4; ++i)
#pragma unroll
      for (int j = 0; j < 4; ++j) {
        int q = q0 + i * 16 + cr;
        int p = j * 16 + cc;
#pragma unroll
        for (int r = 0; r < 4; ++r)
          y[(rowbase + q + r) * DIN + h * HD + p] = accY[i][j][r] * E1f[q + r];
      }
  } else {
#pragma unroll
    for (int i = 0; i < 4; ++i)
#pragma unroll
      for (int j2 = 0; j2 < 2; ++j2) {
        int p = i * 16 + cr;
        int n = n0w + j2 * 16 + cc;
#pragma unroll
        for (int r = 0; r < 4; ++r)
          st[(long)bch * 8192 + (long)(p + r) * 128 + n] = accS[i][j2][r];
      }
  }
}

// ---------------- inter-chunk scan (in place; inner = p*128+n) ----------------
__global__ void scan_states(float* __restrict__ st, const float* __restrict__ acs)
{
  long idx = (long)blockIdx.x * 256 + threadIdx.x;
  if (idx >= (long)NB * NH * 8192) return;
  long inner = idx & 8191;
  int h = (int)((idx >> 13) & 7);
  int b = (int)(idx >> 16);
  float carry = 0.f;
  for (int c = 0; c < NCHUNK; ++c) {
    float dc = __expf(acs[(((long)b * NH + h) * NCHUNK + c) * QLEN + (QLEN - 1)]);
    long si = (((long)(b * NCHUNK + c) * NH + h) << 13) + inner;
    float s = st[si];
    st[si] = carry;
    carry = carry * dc + s;
  }
}

// ---------------- Yo via MFMA: y += exp(Acs[q]) * Cbf·prev^T + xh*D ----------------
__global__ __launch_bounds__(256) void yo_combine4(
    const float* __restrict__ xbc, const unsigned short* __restrict__ Cbf,
    const float* __restrict__ prev, const float* __restrict__ acs,
    const float* __restrict__ Dp, float* __restrict__ y)
{
  int bid = blockIdx.x;
  int xcd = bid & 7, i0 = bid >> 3;
  int bc = xcd * 8 + (i0 >> 3), h = i0 & 7;
  int c = bc & 3, b = bc >> 2;
  int bch = bc * 8 + h;
  __shared__ float EqA[QLEN];
  const int tid = threadIdx.x;
  const int lane = tid & 63, wv = tid >> 6;
  long rowbase = (long)b * LSEQ + c * QLEN;
  EqA[tid] = __expf(acs[(((long)b * NH + h) * NCHUNK + c) * QLEN + tid]);
  __syncthreads();
  const unsigned short* Cb = Cbf + rowbase * 128;
  const float* pv = prev + (long)bch * 8192;
  f32x4 acc[4][4];
#pragma unroll
  for (int i = 0; i < 4; ++i)
#pragma unroll
    for (int j = 0; j < 4; ++j) acc[i][j] = (f32x4){0.f, 0.f, 0.f, 0.f};
#pragma unroll
  for (int ks = 0; ks < 4; ++ks) {
    int n0 = ks * 32 + (lane >> 4) * 8;
    s16x8 bf[4];
#pragma unroll
    for (int j = 0; j < 4; ++j) {
      int p = j * 16 + (lane & 15);
      f32x4 v0 = *(const f32x4*)&pv[p * 128 + n0];
      f32x4 v1 = *(const f32x4*)&pv[p * 128 + n0 + 4];
#pragma unroll
      for (int t = 0; t < 4; ++t) {
        bf[j][t]     = (short)f2bf(v0[t]);
        bf[j][4 + t] = (short)f2bf(v1[t]);
      }
    }
#pragma unroll
    for (int i = 0; i < 4; ++i) {
      s16x8 af = *(const s16x8*)&Cb[(long)(wv * 64 + i * 16 + (lane & 15)) * 128 + n0];
#pragma unroll
      for (int j = 0; j < 4; ++j)
        acc[i][j] = __builtin_amdgcn_mfma_f32_16x16x32_bf16(af, bf[j], acc[i][j], 0, 0, 0);
    }
  }
  const int cr = (lane >> 4) * 4, cc = lane & 15;
  float Dh = Dp[h];
#pragma unroll
  for (int i = 0; i < 4; ++i)
#pragma unroll
    for (int j = 0; j < 4; ++j) {
      int q = wv * 64 + i * 16 + cr;
      int p = j * 16 + cc;
#pragma unroll
      for (int r = 0; r < 4; ++r) {
        long row = rowbase + q + r;
        float xh = xbc[row * XBCW + h * HD + p];
        y[row * DIN + h * HD + p] += acc[i][j][r] * EqA[q + r] + xh * Dh;
      }
    }
}

// ---------------- gated RMSNorm: bf16 z in, bf16 y out ----------------
__global__ __launch_bounds__(256) void gated_rms2(
    const float* __restrict__ y, const unsigned short* __restrict__ zxb,
    const float* __restrict__ rmsw, unsigned short* __restrict__ ybf)
{
  long row = blockIdx.x;
  int t = threadIdx.x;
  float z0 = bf2f(zxb[row * DPROJ + t]), z1 = bf2f(zxb[row * DPROJ + t + 256]);
  float v0 = y[row * DIN + t] * (z0 / (1.f + __expf(-z0)));
  float v1 = y[row * DIN + t + 256] * (z1 / (1.f + __expf(-z1)));
  float ss = v0 * v0 + v1 * v1;
#pragma unroll
  for (int off = 32; off; off >>= 1) ss += __shfl_down(ss, off);
  __shared__ float red[4];
  if ((t & 63) == 0) red[t >> 6] = ss;
  __syncthreads();
  float tot = red[0] + red[1] + red[2] + red[3];
  float scale = rsqrtf(tot * (1.f / DIN) + 1e-5f);
  ybf[row * DIN + t]       = f2bf(v0 * scale * rmsw[t]);
  ybf[row * DIN + t + 256] = f2bf(v1 * scale * rmsw[t + 256]);
}

// ---------------- LayerNorm in place over 256 ----------------
__global__ __launch_bounds__(256) void layernorm(
    float* __restrict__ y2, const float* __restrict__ g, const float* __restrict__ bb)
{
  long row = blockIdx.x;
  int t = threadIdx.x;
  float v = y2[row * DM + t];
  float s = v, q = v * v;
#pragma unroll
  for (int off = 32; off; off >>= 1) { s += __shfl_down(s, off); q += __shfl_down(q, off); }
  __shared__ float sA[4], sB[4];
  if ((t & 63) == 0) { sA[t >> 6] = s; sB[t >> 6] = q; }
  __syncthreads();
  float S = sA[0] + sA[1] + sA[2] + sA[3];
  float Qs = sB[0] + sB[1] + sB[2] + sB[3];
  float mu = S * (1.f / DM);
  float var = Qs * (1.f / DM) - mu * mu;
  y2[row * DM + t] = (v - mu) * rsqrtf(var + 1e-5f) * g[t] + bb[t];
}

// ---------------- classifier ----------------
__global__ void cls(const float* __restrict__ yn, const float* __restrict__ w,
                    const float* __restrict__ bias, float* __restrict__ out)
{
  long idx = (long)blockIdx.x * 256 + threadIdx.x;
  if (idx >= ROWS * NCLS) return;
  int j = (int)(idx % NCLS);
  long row = idx / NCLS;
  float acc = bias[j];
  for (int i = 0; i < DM; ++i) acc = fmaf(yn[row * DM + i], w[i * NCLS + j], acc);
  out[idx] = acc;
}

extern "C" void kernel_launch(void* const* d_in, const int* in_sizes, int n_in,
                              void* d_out, int out_size, void* d_ws, size_t ws_size,
                              hipStream_t stream)
{
  const float* x     = (const float*)d_in[0];
  const float* w_inp = (const float*)d_in[1];
  const float* b_inp = (const float*)d_in[2];
  const float* w_in  = (const float*)d_in[3];
  const float* convw = (const float*)d_in[4];
  const float* convb = (const float*)d_in[5];
  const float* dtb   = (const float*)d_in[6];
  const float* alog  = (const float*)d_in[7];
  const float* Dp    = (const float*)d_in[8];
  const float* rmsw  = (const float*)d_in[9];
  const float* wout  = (const float*)d_in[10];
  const float* lng   = (const float*)d_in[11];
  const float* lnb   = (const float*)d_in[12];
  const float* wcls  = (const float*)d_in[13];
  const float* bcls  = (const float*)d_in[14];
  float* out = (float*)d_out;
  float* ws  = (float*)d_ws;

  float* xbc  = ws + O_XBC;
  float* dtsp = ws + O_DT;
  float* acs  = ws + O_ACS;
  float* y    = ws + O_Y;
  float* st   = ws + O_ST;
  float* y2   = ws + O_Y2;
  float* Wdt  = ws + O_WDT;
  float* bdt  = Wdt + 1600;
  unsigned short* Gbf   = (unsigned short*)(ws + O_U);
  unsigned short* zxb   = (unsigned short*)(ws + O_ZX);
  unsigned short* u_bf  = (unsigned short*)(ws + O_UBF);
  unsigned short* w_inT = (unsigned short*)(ws + O_WINT);
  unsigned short* xp_bf = (unsigned short*)(ws + O_XPBF);
  unsigned short* w_inpT= (unsigned short*)(ws + O_WINPT);
  unsigned short* y_bf  = (unsigned short*)(ws + O_YBF);
  unsigned short* woutT = (unsigned short*)(ws + O_WOUTT);
  unsigned short* Bbf   = (unsigned short*)(ws + O_BBF);
  unsigned short* Cbf   = (unsigned short*)(ws + O_CBF);
  unsigned short* BbfT  = (unsigned short*)(ws + O_BT);

  cast_pad_x<<<(int)((ROWS * 56 + 255) / 256), 256, 0, stream>>>(x, xp_bf);
  tcast_pad_winp<<<224, 256, 0, stream>>>(w_inp, w_inpT);
  combine_wdt<<<7, 256, 0, stream>>>(w_inp, w_in, b_inp, Wdt, bdt);
  gemm_bf16<<<dim3(2, 128), 256, 0, stream>>>(xp_bf, w_inpT, nullptr, u_bf, b_inp, 16384, 256, 224);
  tcast<<<1288, 256, 0, stream>>>(w_in, w_inT, 8, DPROJ);
  gemm_bf16<<<dim3(11, 128), 256, 0, stream>>>(u_bf, w_inT, nullptr, zxb, nullptr, 16384, DPROJ, DM);
  conv_silu2<<<12288, 256, 0, stream>>>(zxb, convw, convb, xbc, Bbf, Cbf);
  dt_cumsum3<<<128, 256, 0, stream>>>(x, Wdt, bdt, dtb, alog, dtsp, acs);
  transB<<<dim3(2, 64), 256, 0, stream>>>(Bbf, BbfT);
  g_gemm_bf16<<<dim3(2, 2, 64), 256, 0, stream>>>(Cbf, Bbf, Gbf);
  yd_states5<<<1024, 256, 0, stream>>>(xbc, dtsp, acs, Gbf, BbfT, y, st);
  scan_states<<<4096, 256, 0, stream>>>(st, acs);
  yo_combine4<<<512, 256, 0, stream>>>(xbc, Cbf, st, acs, Dp, y);
  gated_rms2<<<16384, 256, 0, stream>>>(y, zxb, rmsw, y_bf);
  tcast<<<512, 256, 0, stream>>>(wout, woutT, 9, DM);
  gemm_bf16<<<dim3(2, 128), 256, 0, stream>>>(y_bf, woutT, y2, nullptr, nullptr, 16384, DM, DIN);
  layernorm<<<16384, 256, 0, stream>>>(y2, lng, lnb);
  cls<<<(int)((ROWS * NCLS + 255) / 256), 256, 0, stream>>>(y2, wcls, bcls, out);
}

// Round 7
// 314.695 us; speedup vs baseline: 3.9958x; 1.1016x over previous
//
#include <hip/hip_runtime.h>
#include <math.h>

#define ROWS   16384L
#define LSEQ   1024
#define NB     16
#define DM     256
#define DPROJ  1288
#define XBCW   768
#define DIN    512
#define DSTATE 128
#define NH     8
#define HD     64
#define QLEN   256
#define NCHUNK 4
#define NCLS   17

typedef __attribute__((ext_vector_type(8))) short s16x8;
typedef __attribute__((ext_vector_type(4))) float f32x4;

// ---- workspace map (float slots) ----
constexpr long O_GBF  = 0;                        // Gbf bf16 [64][256][256]
constexpr long O_ZX   = O_GBF + ROWS*DM;          // zxb bf16 [ROWS][1288]
constexpr long O_XBC  = O_ZX  + ROWS*DPROJ;       // region: Xbf/Bbf/Cbf/BbfT bf16
constexpr long O_DT   = O_XBC + ROWS*XBCW;
constexpr long O_ACS  = O_DT  + ROWS*NH;
constexpr long O_Y    = O_ACS + 131072;           // region: ybf bf16 + prep overlays
constexpr long O_ST   = O_Y   + ROWS*DIN;         // st f32 [512][64p][128n]
constexpr long O_Y2   = O_ST  + 4194304;          // y2 f32
// O_XBC region overlays (bf16):
constexpr long O_XBF  = O_XBC;                    // Xbf [ROWS][512]
constexpr long O_BBF  = O_XBC + 4200000;          // Bbf [ROWS][128]
constexpr long O_CBF  = O_XBC + 5300000;          // Cbf [ROWS][128]
constexpr long O_BT   = O_XBC + 6400000;          // BbfT [64][128][256]
// O_Y region overlays:
constexpr long O_YBF  = O_Y;                      // ybf [ROWS][512] bf16
constexpr long O_XPBF = O_Y + 4300000;            // xp_bf [ROWS][224] bf16
constexpr long O_WCT  = O_Y + 6200000;            // WcombT [1288][224] bf16
constexpr long O_WOUTT= O_Y + 6400000;            // woutT [256][512] bf16
constexpr long O_WDT  = O_Y + 6500000;            // Wdt[200][8]+bdt[8] f32
constexpr long O_BFULL= O_Y + 6520000;            // bfull [1288] f32

__device__ inline unsigned short f2bf(float f) {
  union { float f; unsigned u; } v; v.f = f;
  unsigned r = v.u + 0x7FFFu + ((v.u >> 16) & 1u);
  return (unsigned short)(r >> 16);
}
__device__ inline float bf2f(unsigned short s) {
  union { unsigned u; float f; } v; v.u = ((unsigned)s) << 16; return v.f;
}

// ---------------- prep: WcombT, bfull, Wdt/bdt, woutT ----------------
__global__ __launch_bounds__(256) void prep_w(
    const float* __restrict__ w_inp, const float* __restrict__ w_in,
    const float* __restrict__ b_inp, const float* __restrict__ wout,
    unsigned short* __restrict__ WcombT, float* __restrict__ bfull,
    float* __restrict__ Wdt, float* __restrict__ bdt,
    unsigned short* __restrict__ woutT)
{
  long e = (long)blockIdx.x * 256 + threadIdx.x;
  if (e < 288512) {                                  // WcombT[n][k]
    int n = (int)(e / 224), k = (int)(e % 224);
    unsigned short o = 0;
    if (k < 200) {
      float a = 0.f;
      for (int j = 0; j < 256; ++j)
        a += w_inp[(long)k * 256 + j] * w_in[(long)j * DPROJ + n];
      o = f2bf(a);
    }
    WcombT[e] = o;
  } else if (e < 289800) {                           // bfull[n]
    int n = (int)(e - 288512);
    float a = 0.f;
    for (int j = 0; j < 256; ++j) a += b_inp[j] * w_in[(long)j * DPROJ + n];
    bfull[n] = a;
  } else if (e < 291408) {                           // Wdt f32 (exact dt path)
    int i = (int)(e - 289800);
    if (i < 1600) {
      int k = i >> 3, h = i & 7;
      float a = 0.f;
      for (int j = 0; j < 256; ++j)
        a += w_inp[(long)k * 256 + j] * w_in[(long)j * DPROJ + 1280 + h];
      Wdt[i] = a;
    } else {
      int h = i - 1600;
      float a = 0.f;
      for (int j = 0; j < 256; ++j) a += b_inp[j] * w_in[(long)j * DPROJ + 1280 + h];
      bdt[h] = a;
    }
  } else if (e < 291408 + 131072) {                  // woutT[n][k]
    long i = e - 291408;
    int k = (int)(i & 511);
    long n = i >> 9;
    woutT[i] = f2bf(wout[(long)k * 256 + n]);
  }
}

// ---------------- pad+cast x: [ROWS][200] f32 -> [ROWS][224] bf16 ----------------
__global__ __launch_bounds__(256) void cast_pad_x(const float* __restrict__ x,
                                                  unsigned short* __restrict__ xp)
{
  long idx = (long)blockIdx.x * 256 + threadIdx.x;
  if (idx >= ROWS * 56) return;
  int q = (int)(idx % 56);
  long row = idx / 56;
  ushort4 o = {0, 0, 0, 0};
  if (q < 50) {
    float4 v = *(const float4*)&x[row * 200 + q * 4];
    o.x = f2bf(v.x); o.y = f2bf(v.y); o.z = f2bf(v.z); o.w = f2bf(v.w);
  }
  *(ushort4*)&xp[row * 224 + q * 4] = o;
}

// ---------------- bf16 MFMA GEMM: out = A[M,K] @ BT[N,K]^T (+bias) ----------------
__global__ __launch_bounds__(256) void gemm_bf16(
    const unsigned short* __restrict__ A, const unsigned short* __restrict__ BT,
    float* __restrict__ C, unsigned short* __restrict__ Cb,
    const float* __restrict__ bias, int M, int N, int K)
{
  __shared__ __align__(16) unsigned short As[128 * 32];
  __shared__ __align__(16) unsigned short Bs[128 * 32];
  const int tid = threadIdx.x;
  const int m0 = blockIdx.y * 128, n0 = blockIdx.x * 128;
  const int lane = tid & 63, wv = tid >> 6;
  const int wr = (wv >> 1) * 64, wc = (wv & 1) * 64;
  f32x4 acc[4][4];
#pragma unroll
  for (int i = 0; i < 4; ++i)
#pragma unroll
    for (int j = 0; j < 4; ++j) acc[i][j] = (f32x4){0.f, 0.f, 0.f, 0.f};

  for (int k0 = 0; k0 < K; k0 += 32) {
    __syncthreads();
#pragma unroll
    for (int s = 0; s < 2; ++s) {
      int idx = (tid + 256 * s) * 8;
      int r = idx >> 5, kk = idx & 31;
      *(s16x8*)&As[idx] = *(const s16x8*)&A[(long)(m0 + r) * K + k0 + kk];
    }
#pragma unroll
    for (int s = 0; s < 2; ++s) {
      int idx = (tid + 256 * s) * 8;
      int n = idx >> 5, kk = idx & 31;
      s16x8 vv = {};
      if (n0 + n < N) vv = *(const s16x8*)&BT[(long)(n0 + n) * K + k0 + kk];
      *(s16x8*)&Bs[idx] = vv;
    }
    __syncthreads();
    s16x8 af[4], bf[4];
#pragma unroll
    for (int i = 0; i < 4; ++i)
      af[i] = *(const s16x8*)&As[(wr + i * 16 + (lane & 15)) * 32 + (lane >> 4) * 8];
#pragma unroll
    for (int j = 0; j < 4; ++j)
      bf[j] = *(const s16x8*)&Bs[(wc + j * 16 + (lane & 15)) * 32 + (lane >> 4) * 8];
#pragma unroll
    for (int i = 0; i < 4; ++i)
#pragma unroll
      for (int j = 0; j < 4; ++j)
        acc[i][j] = __builtin_amdgcn_mfma_f32_16x16x32_bf16(af[i], bf[j], acc[i][j], 0, 0, 0);
  }
  const int cr = (lane >> 4) * 4, cc = lane & 15;
#pragma unroll
  for (int i = 0; i < 4; ++i)
#pragma unroll
    for (int j = 0; j < 4; ++j) {
      int col = n0 + wc + j * 16 + cc;
      if (col < N) {
        long rowb = (long)(m0 + wr + i * 16 + cr);
        float bv = bias ? bias[col] : 0.f;
#pragma unroll
        for (int r = 0; r < 4; ++r) {
          float v = acc[i][j][r] + bv;
          if (C)  C[(rowb + r) * N + col] = v;
          if (Cb) Cb[(rowb + r) * (long)N + col] = f2bf(v);
        }
      }
    }
}

// ---------------- G = C·B^T per (b,c) -> bf16 causal-masked ----------------
__global__ __launch_bounds__(256) void g_gemm_bf16(
    const unsigned short* __restrict__ Cbf, const unsigned short* __restrict__ Bbf,
    unsigned short* __restrict__ Gbf)
{
  int bc = blockIdx.z;
  unsigned short* Gout = Gbf + (long)bc * 65536;
  const int tid = threadIdx.x;
  const int m0 = blockIdx.y * 128, n0 = blockIdx.x * 128;
  if (blockIdx.x > blockIdx.y) {
    s16x8 z = {};
    for (int e = tid; e < 128 * 16; e += 256) {
      int r = e >> 4, seg = e & 15;
      *(s16x8*)&Gout[(long)(m0 + r) * 256 + n0 + seg * 8] = z;
    }
    return;
  }
  long rowbase = (long)(bc >> 2) * LSEQ + (bc & 3) * QLEN;
  const unsigned short* A  = Cbf + rowbase * 128;
  const unsigned short* BT = Bbf + rowbase * 128;
  __shared__ __align__(16) unsigned short As[128 * 32];
  __shared__ __align__(16) unsigned short Bs[128 * 32];
  const int lane = tid & 63, wv = tid >> 6;
  const int wr = (wv >> 1) * 64, wc = (wv & 1) * 64;
  f32x4 acc[4][4];
#pragma unroll
  for (int i = 0; i < 4; ++i)
#pragma unroll
    for (int j = 0; j < 4; ++j) acc[i][j] = (f32x4){0.f, 0.f, 0.f, 0.f};
  for (int k0 = 0; k0 < 128; k0 += 32) {
    __syncthreads();
#pragma unroll
    for (int s = 0; s < 2; ++s) {
      int idx = (tid + 256 * s) * 8;
      int r = idx >> 5, kk = idx & 31;
      *(s16x8*)&As[idx] = *(const s16x8*)&A[(long)(m0 + r) * 128 + k0 + kk];
      *(s16x8*)&Bs[idx] = *(const s16x8*)&BT[(long)(n0 + r) * 128 + k0 + kk];
    }
    __syncthreads();
    s16x8 af[4], bf[4];
#pragma unroll
    for (int i = 0; i < 4; ++i)
      af[i] = *(const s16x8*)&As[(wr + i * 16 + (lane & 15)) * 32 + (lane >> 4) * 8];
#pragma unroll
    for (int j = 0; j < 4; ++j)
      bf[j] = *(const s16x8*)&Bs[(wc + j * 16 + (lane & 15)) * 32 + (lane >> 4) * 8];
#pragma unroll
    for (int i = 0; i < 4; ++i)
#pragma unroll
      for (int j = 0; j < 4; ++j)
        acc[i][j] = __builtin_amdgcn_mfma_f32_16x16x32_bf16(af[i], bf[j], acc[i][j], 0, 0, 0);
  }
  const int cr = (lane >> 4) * 4, cc = lane & 15;
#pragma unroll
  for (int i = 0; i < 4; ++i)
#pragma unroll
    for (int j = 0; j < 4; ++j) {
      int col = n0 + wc + j * 16 + cc;
      int qb = m0 + wr + i * 16 + cr;
#pragma unroll
      for (int r = 0; r < 4; ++r)
        Gout[(long)(qb + r) * 256 + col] = (col <= qb + r) ? f2bf(acc[i][j][r]) : (unsigned short)0;
    }
}

// ---------------- conv1d (k=4, causal) + SiLU -> bf16 Xbf/Bbf/Cbf ----------------
__global__ __launch_bounds__(256) void conv_silu3(
    const unsigned short* __restrict__ zxb, const float* __restrict__ cw,
    const float* __restrict__ cb,
    unsigned short* __restrict__ Xbf, unsigned short* __restrict__ Bbf,
    unsigned short* __restrict__ Cbf)
{
  long idx = (long)blockIdx.x * 256 + threadIdx.x;
  if (idx >= ROWS * 192) return;
  int cq = (int)(idx % 192);
  long row = idx / 192;
  int t = (int)(row & 1023);
  int ch = cq * 4;
  float4 cbv = *(const float4*)&cb[ch];
  float a0 = cbv.x, a1 = cbv.y, a2 = cbv.z, a3 = cbv.w;
#pragma unroll
  for (int w = 0; w < 4; ++w) {
    int d = w - 3;
    if (t + d >= 0) {
      ushort4 zv = *(const ushort4*)&zxb[(row + d) * DPROJ + 512 + ch];
      float4 cwv = *(const float4*)&cw[w * XBCW + ch];
      a0 = fmaf(bf2f(zv.x), cwv.x, a0);
      a1 = fmaf(bf2f(zv.y), cwv.y, a1);
      a2 = fmaf(bf2f(zv.z), cwv.z, a2);
      a3 = fmaf(bf2f(zv.w), cwv.w, a3);
    }
  }
  ushort4 o;
  o.x = f2bf(a0 / (1.f + __expf(-a0)));
  o.y = f2bf(a1 / (1.f + __expf(-a1)));
  o.z = f2bf(a2 / (1.f + __expf(-a2)));
  o.w = f2bf(a3 / (1.f + __expf(-a3)));
  if (ch < 512)      *(ushort4*)&Xbf[row * DIN + ch] = o;
  else if (ch < 640) *(ushort4*)&Bbf[row * 128 + ch - 512] = o;
  else               *(ushort4*)&Cbf[row * 128 + ch - 640] = o;
}

// ---------------- dt from f32 x; softplus; wave-parallel cumsum ----------------
__global__ __launch_bounds__(256) void dt_cumsum3(
    const float* __restrict__ x, const float* __restrict__ Wdt,
    const float* __restrict__ bdt, const float* __restrict__ dtb,
    const float* __restrict__ alog,
    float* __restrict__ dtsp, float* __restrict__ acs)
{
  int g = ((int)blockIdx.x * 256 + (int)threadIdx.x) >> 6;
  int lane = threadIdx.x & 63;
  int c = g & 3, h = (g >> 2) & 7, b = g >> 5;
  float Ah = -__expf(alog[h]);
  float bias = dtb[h] + bdt[h];
  long rowbase = (long)b * LSEQ + c * QLEN;
  long abase = (((long)b * NH + h) * NCHUNK + c) * QLEN;
  float v[4];
#pragma unroll
  for (int j = 0; j < 4; ++j) {
    long row = rowbase + lane * 4 + j;
    const float4* x4 = (const float4*)&x[row * 200];
    float acc = bias;
    for (int i = 0; i < 50; ++i) {
      float4 xv = x4[i];
      acc += xv.x * Wdt[(i * 4 + 0) * 8 + h]
           + xv.y * Wdt[(i * 4 + 1) * 8 + h]
           + xv.z * Wdt[(i * 4 + 2) * 8 + h]
           + xv.w * Wdt[(i * 4 + 3) * 8 + h];
    }
    float sp = (acc > 20.f) ? acc : log1pf(__expf(acc));
    dtsp[row * NH + h] = sp;
    v[j] = sp * Ah;
  }
  v[1] += v[0]; v[2] += v[1]; v[3] += v[2];
  float tot = v[3];
  float run = tot;
#pragma unroll
  for (int d = 1; d < 64; d <<= 1) {
    float t = __shfl_up(run, d);
    if (lane >= d) run += t;
  }
  float excl = run - tot;
#pragma unroll
  for (int j = 0; j < 4; ++j) acs[abase + lane * 4 + j] = excl + v[j];
}

// ---------------- Bbf [ROWS][128] -> BbfT [bc][128][256] ----------------
__global__ __launch_bounds__(256) void transB(const unsigned short* __restrict__ Bbf,
                                              unsigned short* __restrict__ BbfT)
{
  __shared__ unsigned short T[128][130];
  int bc = blockIdx.y, kh = blockIdx.x;
  int tid = threadIdx.x;
  long rowbase = (long)(bc >> 2) * LSEQ + (bc & 3) * QLEN + kh * 128;
  for (int e = tid; e < 128 * 128; e += 256) {
    int r = e >> 7, n = e & 127;
    T[r][n] = Bbf[(rowbase + r) * 128 + n];
  }
  __syncthreads();
  for (int e = tid; e < 128 * 128; e += 256) {
    int n = e >> 7, k = e & 127;
    BbfT[((long)bc * 128 + n) * 256 + kh * 128 + k] = T[k][n];
  }
}

// ---------------- yd+states: full XdT staged once, pure-MFMA k loop ----------------
// grid 1024: (xcd, bc-local, h, half). Waves 0-1: Yd q0 = half*128+wv*64.
// Waves 2-3: statesT n range = half*64+(wv-2)*32.
__global__ __launch_bounds__(256) void yd_states6(
    const unsigned short* __restrict__ Xbf, const float* __restrict__ dtsp,
    const float* __restrict__ acs, const unsigned short* __restrict__ Gbf,
    const unsigned short* __restrict__ BbfT,
    unsigned short* __restrict__ ybf, float* __restrict__ st)
{
  int bid = blockIdx.x;
  int xcd = bid & 7, i0 = bid >> 3;
  int bc = xcd * 8 + (i0 >> 4);
  int rem = i0 & 15, h = rem >> 1, half = rem & 1;
  int c = bc & 3, b = bc >> 2;
  int bch = bc * 8 + h;

  __shared__ __align__(16) unsigned short XdT[64][264];  // [p][k], pad row=528B
  __shared__ float AcsS[256], E1f[256], E2f[256], dts[256];

  const int tid = threadIdx.x;
  const int lane = tid & 63, wv = tid >> 6;
  const bool ydw = wv < 2;
  const int q0 = half * 128 + wv * 64;
  const int myqt = half * 2 + wv;
  const int n0w = half * 64 + (wv - 2) * 32;
  long rowbase = (long)b * LSEQ + c * QLEN;
  const unsigned short* Gb  = Gbf + (long)bc * 65536;
  const unsigned short* BTg = BbfT + (long)bc * 32768;

  AcsS[tid] = acs[(((long)b * NH + h) * NCHUNK + c) * QLEN + tid];
  dts[tid]  = dtsp[(rowbase + tid) * NH + h];
  __syncthreads();
  E1f[tid] = __expf(AcsS[tid] - AcsS[tid | 63]);      // epilogue row scale (>=1)
  E2f[tid] = __expf(AcsS[tid | 63] - AcsS[tid]);      // Xd column scale (<=1)
  float rs_[4];
  rs_[0] = 1.f;
#pragma unroll
  for (int kt = 1; kt < 4; ++kt) rs_[kt] = __expf(AcsS[kt * 64 + 63] - AcsS[kt * 64 - 1]);
  __syncthreads();
  // stage XdT[p][k] for k in [wv*64, wv*64+64), p = lane
  {
    int kb = wv * 64;
#pragma unroll
    for (int s = 0; s < 16; ++s) {
      int k4 = kb + s * 4;
      ushort4 pk;
      unsigned short* pp = (unsigned short*)&pk;
#pragma unroll
      for (int j = 0; j < 4; ++j) {
        int k = k4 + j;
        float v = bf2f(Xbf[(rowbase + k) * DIN + h * HD + lane]) * dts[k] * E2f[k];
        pp[j] = f2bf(v);
      }
      *(ushort4*)&XdT[lane][k4] = pk;
    }
  }
  __syncthreads();

  f32x4 accY[4][4], accS[4][2];
#pragma unroll
  for (int i = 0; i < 4; ++i)
#pragma unroll
    for (int j = 0; j < 4; ++j) accY[i][j] = (f32x4){0.f, 0.f, 0.f, 0.f};
#pragma unroll
  for (int i = 0; i < 4; ++i)
#pragma unroll
    for (int j = 0; j < 2; ++j) accS[i][j] = (f32x4){0.f, 0.f, 0.f, 0.f};

  for (int kt = 0; kt < 4; ++kt) {
    int qlo = kt * 64;
    if (ydw) {
      if (myqt >= kt) {
        if (kt)
#pragma unroll
          for (int i = 0; i < 4; ++i)
#pragma unroll
            for (int j = 0; j < 4; ++j) accY[i][j] *= rs_[kt];
#pragma unroll
        for (int ks = 0; ks < 2; ++ks) {
          s16x8 bfr[4];
#pragma unroll
          for (int j = 0; j < 4; ++j)
            bfr[j] = *(const s16x8*)&XdT[j * 16 + (lane & 15)][qlo + ks * 32 + (lane >> 4) * 8];
#pragma unroll
          for (int i = 0; i < 4; ++i) {
            s16x8 a = *(const s16x8*)&Gb[(long)(q0 + i * 16 + (lane & 15)) * 256 + qlo + ks * 32 + (lane >> 4) * 8];
#pragma unroll
            for (int j = 0; j < 4; ++j)
              accY[i][j] = __builtin_amdgcn_mfma_f32_16x16x32_bf16(a, bfr[j], accY[i][j], 0, 0, 0);
          }
        }
      }
    } else {
      if (kt)
#pragma unroll
        for (int i = 0; i < 4; ++i)
#pragma unroll
          for (int j = 0; j < 2; ++j) accS[i][j] *= rs_[kt];
#pragma unroll
      for (int ks = 0; ks < 2; ++ks) {
        s16x8 afx[4];
#pragma unroll
        for (int i = 0; i < 4; ++i)
          afx[i] = *(const s16x8*)&XdT[i * 16 + (lane & 15)][qlo + ks * 32 + (lane >> 4) * 8];
#pragma unroll
        for (int j2 = 0; j2 < 2; ++j2) {
          s16x8 bt = *(const s16x8*)&BTg[(long)(n0w + j2 * 16 + (lane & 15)) * 256 + qlo + ks * 32 + (lane >> 4) * 8];
#pragma unroll
          for (int i = 0; i < 4; ++i)
            accS[i][j2] = __builtin_amdgcn_mfma_f32_16x16x32_bf16(afx[i], bt, accS[i][j2], 0, 0, 0);
        }
      }
    }
  }
  const int cr = (lane >> 4) * 4, cc = lane & 15;
  if (ydw) {
#pragma unroll
    for (int i = 0; i < 4; ++i)
#pragma unroll
      for (int j = 0; j < 4; ++j) {
        int q = q0 + i * 16 + cr;
        int p = j * 16 + cc;
#pragma unroll
        for (int r = 0; r < 4; ++r)
          ybf[(rowbase + q + r) * DIN + h * HD + p] = f2bf(accY[i][j][r] * E1f[q + r]);
      }
  } else {
#pragma unroll
    for (int i = 0; i < 4; ++i)
#pragma unroll
      for (int j2 = 0; j2 < 2; ++j2) {
        int p = i * 16 + cr;
        int n = n0w + j2 * 16 + cc;
#pragma unroll
        for (int r = 0; r < 4; ++r)
          st[(long)bch * 8192 + (long)(p + r) * 128 + n] = accS[i][j2][r];
      }
  }
}

// ---------------- inter-chunk scan (f32x4 vectorized, in place) ----------------
__global__ void scan_states(float* __restrict__ st, const float* __restrict__ acs)
{
  long idx = (long)blockIdx.x * 256 + threadIdx.x;       // f32x4 units
  if (idx >= (long)NB * NH * 2048) return;
  long inner = idx & 2047;
  int h = (int)((idx >> 11) & 7);
  int b = (int)(idx >> 14);
  f32x4 carry = {0.f, 0.f, 0.f, 0.f};
  for (int c = 0; c < NCHUNK; ++c) {
    float dc = __expf(acs[(((long)b * NH + h) * NCHUNK + c) * QLEN + (QLEN - 1)]);
    long si = (((long)(b * NCHUNK + c) * NH + h) << 13) + inner * 4;
    f32x4 s = *(f32x4*)&st[si];
    *(f32x4*)&st[si] = carry;
    carry = carry * dc + s;
  }
}

// ---------------- Yo via MFMA: ybf += exp(Acs[q]) * Cbf·prev^T + xh*D ----------------
__global__ __launch_bounds__(256) void yo_combine5(
    const unsigned short* __restrict__ Xbf, const unsigned short* __restrict__ Cbf,
    const float* __restrict__ prev, const float* __restrict__ acs,
    const float* __restrict__ Dp, unsigned short* __restrict__ ybf)
{
  int bid = blockIdx.x;
  int xcd = bid & 7, i0 = bid >> 3;
  int bc = xcd * 8 + (i0 >> 3), h = i0 & 7;
  int c = bc & 3, b = bc >> 2;
  int bch = bc * 8 + h;
  __shared__ float EqA[QLEN];
  const int tid = threadIdx.x;
  const int lane = tid & 63, wv = tid >> 6;
  long rowbase = (long)b * LSEQ + c * QLEN;
  EqA[tid] = __expf(acs[(((long)b * NH + h) * NCHUNK + c) * QLEN + tid]);
  __syncthreads();
  const unsigned short* Cb = Cbf + rowbase * 128;
  const float* pv = prev + (long)bch * 8192;
  f32x4 acc[4][4];
#pragma unroll
  for (int i = 0; i < 4; ++i)
#pragma unroll
    for (int j = 0; j < 4; ++j) acc[i][j] = (f32x4){0.f, 0.f, 0.f, 0.f};
#pragma unroll
  for (int ks = 0; ks < 4; ++ks) {
    int n0 = ks * 32 + (lane >> 4) * 8;
    s16x8 bf[4];
#pragma unroll
    for (int j = 0; j < 4; ++j) {
      int p = j * 16 + (lane & 15);
      f32x4 v0 = *(const f32x4*)&pv[p * 128 + n0];
      f32x4 v1 = *(const f32x4*)&pv[p * 128 + n0 + 4];
#pragma unroll
      for (int t = 0; t < 4; ++t) {
        bf[j][t]     = (short)f2bf(v0[t]);
        bf[j][4 + t] = (short)f2bf(v1[t]);
      }
    }
#pragma unroll
    for (int i = 0; i < 4; ++i) {
      s16x8 af = *(const s16x8*)&Cb[(long)(wv * 64 + i * 16 + (lane & 15)) * 128 + n0];
#pragma unroll
      for (int j = 0; j < 4; ++j)
        acc[i][j] = __builtin_amdgcn_mfma_f32_16x16x32_bf16(af, bf[j], acc[i][j], 0, 0, 0);
    }
  }
  const int cr = (lane >> 4) * 4, cc = lane & 15;
  float Dh = Dp[h];
#pragma unroll
  for (int i = 0; i < 4; ++i)
#pragma unroll
    for (int j = 0; j < 4; ++j) {
      int q = wv * 64 + i * 16 + cr;
      int p = j * 16 + cc;
#pragma unroll
      for (int r = 0; r < 4; ++r) {
        long row = rowbase + q + r;
        long yi = row * DIN + h * HD + p;
        float xh = bf2f(Xbf[yi]);
        float pr = bf2f(ybf[yi]);
        ybf[yi] = f2bf(pr + acc[i][j][r] * EqA[q + r] + xh * Dh);
      }
    }
}

// ---------------- gated RMSNorm in place on ybf (bf16) ----------------
__global__ __launch_bounds__(256) void gated_rms3(
    unsigned short* __restrict__ ybf, const unsigned short* __restrict__ zxb,
    const float* __restrict__ rmsw)
{
  long row = blockIdx.x;
  int t = threadIdx.x;
  ushort2 yv = *(const ushort2*)&ybf[row * DIN + 2 * t];
  ushort2 zv = *(const ushort2*)&zxb[row * DPROJ + 2 * t];
  float z0 = bf2f(zv.x), z1 = bf2f(zv.y);
  float v0 = bf2f(yv.x) * (z0 / (1.f + __expf(-z0)));
  float v1 = bf2f(yv.y) * (z1 / (1.f + __expf(-z1)));
  float ss = v0 * v0 + v1 * v1;
#pragma unroll
  for (int off = 32; off; off >>= 1) ss += __shfl_down(ss, off);
  __shared__ float red[4];
  if ((t & 63) == 0) red[t >> 6] = ss;
  __syncthreads();
  float tot = red[0] + red[1] + red[2] + red[3];
  float scale = rsqrtf(tot * (1.f / DIN) + 1e-5f);
  ushort2 o;
  o.x = f2bf(v0 * scale * rmsw[2 * t]);
  o.y = f2bf(v1 * scale * rmsw[2 * t + 1]);
  *(ushort2*)&ybf[row * DIN + 2 * t] = o;
}

// ---------------- fused LayerNorm + classifier ----------------
__global__ __launch_bounds__(256) void ln_cls(
    const float* __restrict__ y2, const float* __restrict__ g, const float* __restrict__ bb,
    const float* __restrict__ wcls, const float* __restrict__ bcls,
    float* __restrict__ out)
{
  __shared__ float sA[4], sB[4];
  __shared__ float ynS[256];
  __shared__ float ps[8][17];
  long row = blockIdx.x;
  int t = threadIdx.x;
  float v = y2[row * DM + t];
  float s = v, q = v * v;
#pragma unroll
  for (int off = 32; off; off >>= 1) { s += __shfl_down(s, off); q += __shfl_down(q, off); }
  if ((t & 63) == 0) { sA[t >> 6] = s; sB[t >> 6] = q; }
  __syncthreads();
  float S = sA[0] + sA[1] + sA[2] + sA[3];
  float Qs = sB[0] + sB[1] + sB[2] + sB[3];
  float mu = S * (1.f / DM);
  float var = Qs * (1.f / DM) - mu * mu;
  ynS[t] = (v - mu) * rsqrtf(var + 1e-5f) * g[t] + bb[t];
  __syncthreads();
  if (t < 136) {
    int j = t % 17, seg = t / 17;
    float a = 0.f;
    int i0 = seg * 32;
#pragma unroll 8
    for (int i = 0; i < 32; ++i) a = fmaf(ynS[i0 + i], wcls[(long)(i0 + i) * NCLS + j], a);
    ps[seg][j] = a;
  }
  __syncthreads();
  if (t < NCLS) {
    float a = bcls[t];
#pragma unroll
    for (int s2 = 0; s2 < 8; ++s2) a += ps[s2][t];
    out[row * NCLS + t] = a;
  }
}

extern "C" void kernel_launch(void* const* d_in, const int* in_sizes, int n_in,
                              void* d_out, int out_size, void* d_ws, size_t ws_size,
                              hipStream_t stream)
{
  const float* x     = (const float*)d_in[0];
  const float* w_inp = (const float*)d_in[1];
  const float* b_inp = (const float*)d_in[2];
  const float* w_in  = (const float*)d_in[3];
  const float* convw = (const float*)d_in[4];
  const float* convb = (const float*)d_in[5];
  const float* dtb   = (const float*)d_in[6];
  const float* alog  = (const float*)d_in[7];
  const float* Dp    = (const float*)d_in[8];
  const float* rmsw  = (const float*)d_in[9];
  const float* wout  = (const float*)d_in[10];
  const float* lng   = (const float*)d_in[11];
  const float* lnb   = (const float*)d_in[12];
  const float* wcls  = (const float*)d_in[13];
  const float* bcls  = (const float*)d_in[14];
  float* out = (float*)d_out;
  float* ws  = (float*)d_ws;

  float* dtsp = ws + O_DT;
  float* acs  = ws + O_ACS;
  float* st   = ws + O_ST;
  float* y2   = ws + O_Y2;
  float* Wdt  = ws + O_WDT;
  float* bdt  = Wdt + 1600;
  float* bfull= ws + O_BFULL;
  unsigned short* Gbf   = (unsigned short*)(ws + O_GBF);
  unsigned short* zxb   = (unsigned short*)(ws + O_ZX);
  unsigned short* Xbf   = (unsigned short*)(ws + O_XBF);
  unsigned short* Bbf   = (unsigned short*)(ws + O_BBF);
  unsigned short* Cbf   = (unsigned short*)(ws + O_CBF);
  unsigned short* BbfT  = (unsigned short*)(ws + O_BT);
  unsigned short* ybf   = (unsigned short*)(ws + O_YBF);
  unsigned short* xp_bf = (unsigned short*)(ws + O_XPBF);
  unsigned short* WcombT= (unsigned short*)(ws + O_WCT);
  unsigned short* woutT = (unsigned short*)(ws + O_WOUTT);

  prep_w<<<1651, 256, 0, stream>>>(w_inp, w_in, b_inp, wout, WcombT, bfull, Wdt, bdt, woutT);
  cast_pad_x<<<3584, 256, 0, stream>>>(x, xp_bf);
  // fused input_proj+in_proj: zxb = x @ (w_inp@w_in) + b_inp@w_in
  gemm_bf16<<<dim3(11, 128), 256, 0, stream>>>(xp_bf, WcombT, nullptr, zxb, bfull, 16384, DPROJ, 224);
  conv_silu3<<<12288, 256, 0, stream>>>(zxb, convw, convb, Xbf, Bbf, Cbf);
  dt_cumsum3<<<128, 256, 0, stream>>>(x, Wdt, bdt, dtb, alog, dtsp, acs);
  transB<<<dim3(2, 64), 256, 0, stream>>>(Bbf, BbfT);
  g_gemm_bf16<<<dim3(2, 2, 64), 256, 0, stream>>>(Cbf, Bbf, Gbf);
  yd_states6<<<1024, 256, 0, stream>>>(Xbf, dtsp, acs, Gbf, BbfT, ybf, st);
  scan_states<<<1024, 256, 0, stream>>>(st, acs);
  yo_combine5<<<512, 256, 0, stream>>>(Xbf, Cbf, st, acs, Dp, ybf);
  gated_rms3<<<16384, 256, 0, stream>>>(ybf, zxb, rmsw);
  gemm_bf16<<<dim3(2, 128), 256, 0, stream>>>(ybf, woutT, y2, nullptr, nullptr, 16384, DM, DIN);
  ln_cls<<<16384, 256, 0, stream>>>(y2, lng, lnb, wcls, bcls, out);
}

// Round 8
// 289.680 us; speedup vs baseline: 4.3409x; 1.0864x over previous
//
#include <hip/hip_runtime.h>
#include <math.h>

#define ROWS   16384L
#define LSEQ   1024
#define NB     16
#define DM     256
#define DPROJ  1288
#define XBCW   768
#define DIN    512
#define DSTATE 128
#define NH     8
#define HD     64
#define QLEN   256
#define NCHUNK 4
#define NCLS   17

typedef __attribute__((ext_vector_type(8))) short s16x8;
typedef __attribute__((ext_vector_type(4))) float f32x4;

// ---- workspace map (float slots) ----
constexpr long O_GBF  = 0;                        // Gbf bf16 [64][256][256]
constexpr long O_ZX   = O_GBF + ROWS*DM;          // zxb bf16 [ROWS][1288]
constexpr long O_XBC  = O_ZX  + ROWS*DPROJ;       // region: Xbf/Bbf/Cbf/BbfT bf16
constexpr long O_DT   = O_XBC + ROWS*XBCW;
constexpr long O_ACS  = O_DT  + ROWS*NH;
constexpr long O_Y    = O_ACS + 131072;           // region: ybf bf16 + prep overlays
constexpr long O_ST   = O_Y   + ROWS*DIN;         // st f32 [512][64p][128n]
constexpr long O_Y2   = O_ST  + 4194304;          // y2 f32
// O_XBC region overlays (bf16):
constexpr long O_XBF  = O_XBC;                    // Xbf [ROWS][512]
constexpr long O_BBF  = O_XBC + 4200000;          // Bbf [ROWS][128]
constexpr long O_CBF  = O_XBC + 5300000;          // Cbf [ROWS][128]
constexpr long O_BT   = O_XBC + 6400000;          // BbfT [64][128][256]
// O_Y region overlays:
constexpr long O_YBF  = O_Y;                      // ybf [ROWS][512] bf16
constexpr long O_XPBF = O_Y + 4300000;            // xp_bf [ROWS][224] bf16
constexpr long O_WCT  = O_Y + 6200000;            // WcombT [1288][224] bf16
constexpr long O_WOUTT= O_Y + 6400000;            // woutT [256][512] bf16
constexpr long O_WDT  = O_Y + 6500000;            // Wdt[200][8]+bdt[8] f32
constexpr long O_BFULL= O_Y + 6520000;            // bfull [1288] f32

__device__ inline unsigned short f2bf(float f) {
  union { float f; unsigned u; } v; v.f = f;
  unsigned r = v.u + 0x7FFFu + ((v.u >> 16) & 1u);
  return (unsigned short)(r >> 16);
}
__device__ inline float bf2f(unsigned short s) {
  union { unsigned u; float f; } v; v.u = ((unsigned)s) << 16; return v.f;
}

// ---------------- prep GEMM: Wcomb[k][n] = sum_j A[k][j]*w_in[j][n], A row 200 = b_inp
// Outputs: WcombT bf16 [n][224]; bfull f32 (k==200); Wdt f32 (n>=1280,k<200); bdt.
__global__ __launch_bounds__(256) void prep_gemm(
    const float* __restrict__ w_inp, const float* __restrict__ w_in,
    const float* __restrict__ b_inp,
    unsigned short* __restrict__ WcombT, float* __restrict__ bfull,
    float* __restrict__ Wdt, float* __restrict__ bdt)
{
  __shared__ float As[16][68];   // [j][k-local]
  __shared__ float Ws[16][68];   // [j][n-local]
  const int m0 = blockIdx.y * 64;      // k
  const int n0 = blockIdx.x * 64;      // n
  const int tid = threadIdx.x;
  const int tm = (tid >> 4) << 2, tn = (tid & 15) << 2;
  float acc[4][4] = {};
  for (int j0 = 0; j0 < 256; j0 += 16) {
#pragma unroll
    for (int i = 0; i < 4; ++i) {                 // A tile 64k x 16j
      int e = tid + i * 256;
      int m = m0 + (e >> 4), j = j0 + (e & 15);
      float v = 0.f;
      if (m < 200)       v = w_inp[(long)m * 256 + j];
      else if (m == 200) v = b_inp[j];
      As[e & 15][e >> 4] = v;
    }
#pragma unroll
    for (int i = 0; i < 4; ++i) {                 // W tile 16j x 64n
      int e = tid + i * 256;
      int j = e >> 6, n = n0 + (e & 63);
      Ws[j][e & 63] = (n < DPROJ) ? w_in[(long)(j0 + j) * DPROJ + n] : 0.f;
    }
    __syncthreads();
#pragma unroll
    for (int j = 0; j < 16; ++j) {
      float a[4], w[4];
#pragma unroll
      for (int i = 0; i < 4; ++i) a[i] = As[j][tm + i];
#pragma unroll
      for (int t = 0; t < 4; ++t) w[t] = Ws[j][tn + t];
#pragma unroll
      for (int i = 0; i < 4; ++i)
#pragma unroll
        for (int t = 0; t < 4; ++t) acc[i][t] = fmaf(a[i], w[t], acc[i][t]);
    }
    __syncthreads();
  }
#pragma unroll
  for (int i = 0; i < 4; ++i) {
    int k = m0 + tm + i;
#pragma unroll
    for (int t = 0; t < 4; ++t) {
      int n = n0 + tn + t;
      if (n >= DPROJ) continue;
      float v = acc[i][t];
      if (k < 224) WcombT[(long)n * 224 + k] = f2bf(v);
      if (k == 200) {
        bfull[n] = v;
        if (n >= 1280) bdt[n - 1280] = v;
      }
      if (k < 200 && n >= 1280) Wdt[k * 8 + (n - 1280)] = v;
    }
  }
}

// ---------------- transpose+cast: w[K,N] f32 -> wt[N,K] bf16 (K=1<<kbits) ------------
__global__ __launch_bounds__(256) void tcast(const float* __restrict__ w,
                                             unsigned short* __restrict__ wt,
                                             int kbits, int N)
{
  long i = (long)blockIdx.x * 256 + threadIdx.x;
  int K = 1 << kbits;
  if (i >= (long)K * N) return;
  int k = (int)(i & (K - 1));
  long n = i >> kbits;
  wt[i] = f2bf(w[(long)k * N + n]);
}

// ---------------- pad+cast x: [ROWS][200] f32 -> [ROWS][224] bf16 ----------------
__global__ __launch_bounds__(256) void cast_pad_x(const float* __restrict__ x,
                                                  unsigned short* __restrict__ xp)
{
  long idx = (long)blockIdx.x * 256 + threadIdx.x;
  if (idx >= ROWS * 56) return;
  int q = (int)(idx % 56);
  long row = idx / 56;
  ushort4 o = {0, 0, 0, 0};
  if (q < 50) {
    float4 v = *(const float4*)&x[row * 200 + q * 4];
    o.x = f2bf(v.x); o.y = f2bf(v.y); o.z = f2bf(v.z); o.w = f2bf(v.w);
  }
  *(ushort4*)&xp[row * 224 + q * 4] = o;
}

// ---------------- bf16 MFMA GEMM: out = A[M,K] @ BT[N,K]^T (+bias) ----------------
__global__ __launch_bounds__(256) void gemm_bf16(
    const unsigned short* __restrict__ A, const unsigned short* __restrict__ BT,
    float* __restrict__ C, unsigned short* __restrict__ Cb,
    const float* __restrict__ bias, int M, int N, int K)
{
  __shared__ __align__(16) unsigned short As[128 * 32];
  __shared__ __align__(16) unsigned short Bs[128 * 32];
  const int tid = threadIdx.x;
  const int m0 = blockIdx.y * 128, n0 = blockIdx.x * 128;
  const int lane = tid & 63, wv = tid >> 6;
  const int wr = (wv >> 1) * 64, wc = (wv & 1) * 64;
  f32x4 acc[4][4];
#pragma unroll
  for (int i = 0; i < 4; ++i)
#pragma unroll
    for (int j = 0; j < 4; ++j) acc[i][j] = (f32x4){0.f, 0.f, 0.f, 0.f};

  for (int k0 = 0; k0 < K; k0 += 32) {
    __syncthreads();
#pragma unroll
    for (int s = 0; s < 2; ++s) {
      int idx = (tid + 256 * s) * 8;
      int r = idx >> 5, kk = idx & 31;
      *(s16x8*)&As[idx] = *(const s16x8*)&A[(long)(m0 + r) * K + k0 + kk];
    }
#pragma unroll
    for (int s = 0; s < 2; ++s) {
      int idx = (tid + 256 * s) * 8;
      int n = idx >> 5, kk = idx & 31;
      s16x8 vv = {};
      if (n0 + n < N) vv = *(const s16x8*)&BT[(long)(n0 + n) * K + k0 + kk];
      *(s16x8*)&Bs[idx] = vv;
    }
    __syncthreads();
    s16x8 af[4], bf[4];
#pragma unroll
    for (int i = 0; i < 4; ++i)
      af[i] = *(const s16x8*)&As[(wr + i * 16 + (lane & 15)) * 32 + (lane >> 4) * 8];
#pragma unroll
    for (int j = 0; j < 4; ++j)
      bf[j] = *(const s16x8*)&Bs[(wc + j * 16 + (lane & 15)) * 32 + (lane >> 4) * 8];
#pragma unroll
    for (int i = 0; i < 4; ++i)
#pragma unroll
      for (int j = 0; j < 4; ++j)
        acc[i][j] = __builtin_amdgcn_mfma_f32_16x16x32_bf16(af[i], bf[j], acc[i][j], 0, 0, 0);
  }
  const int cr = (lane >> 4) * 4, cc = lane & 15;
#pragma unroll
  for (int i = 0; i < 4; ++i)
#pragma unroll
    for (int j = 0; j < 4; ++j) {
      int col = n0 + wc + j * 16 + cc;
      if (col < N) {
        long rowb = (long)(m0 + wr + i * 16 + cr);
        float bv = bias ? bias[col] : 0.f;
#pragma unroll
        for (int r = 0; r < 4; ++r) {
          float v = acc[i][j][r] + bv;
          if (C)  C[(rowb + r) * N + col] = v;
          if (Cb) Cb[(rowb + r) * (long)N + col] = f2bf(v);
        }
      }
    }
}

// ---------------- G = C·B^T per (b,c) -> bf16 causal-masked ----------------
__global__ __launch_bounds__(256) void g_gemm_bf16(
    const unsigned short* __restrict__ Cbf, const unsigned short* __restrict__ Bbf,
    unsigned short* __restrict__ Gbf)
{
  int bc = blockIdx.z;
  unsigned short* Gout = Gbf + (long)bc * 65536;
  const int tid = threadIdx.x;
  const int m0 = blockIdx.y * 128, n0 = blockIdx.x * 128;
  if (blockIdx.x > blockIdx.y) {
    s16x8 z = {};
    for (int e = tid; e < 128 * 16; e += 256) {
      int r = e >> 4, seg = e & 15;
      *(s16x8*)&Gout[(long)(m0 + r) * 256 + n0 + seg * 8] = z;
    }
    return;
  }
  long rowbase = (long)(bc >> 2) * LSEQ + (bc & 3) * QLEN;
  const unsigned short* A  = Cbf + rowbase * 128;
  const unsigned short* BT = Bbf + rowbase * 128;
  __shared__ __align__(16) unsigned short As[128 * 32];
  __shared__ __align__(16) unsigned short Bs[128 * 32];
  const int lane = tid & 63, wv = tid >> 6;
  const int wr = (wv >> 1) * 64, wc = (wv & 1) * 64;
  f32x4 acc[4][4];
#pragma unroll
  for (int i = 0; i < 4; ++i)
#pragma unroll
    for (int j = 0; j < 4; ++j) acc[i][j] = (f32x4){0.f, 0.f, 0.f, 0.f};
  for (int k0 = 0; k0 < 128; k0 += 32) {
    __syncthreads();
#pragma unroll
    for (int s = 0; s < 2; ++s) {
      int idx = (tid + 256 * s) * 8;
      int r = idx >> 5, kk = idx & 31;
      *(s16x8*)&As[idx] = *(const s16x8*)&A[(long)(m0 + r) * 128 + k0 + kk];
      *(s16x8*)&Bs[idx] = *(const s16x8*)&BT[(long)(n0 + r) * 128 + k0 + kk];
    }
    __syncthreads();
    s16x8 af[4], bf[4];
#pragma unroll
    for (int i = 0; i < 4; ++i)
      af[i] = *(const s16x8*)&As[(wr + i * 16 + (lane & 15)) * 32 + (lane >> 4) * 8];
#pragma unroll
    for (int j = 0; j < 4; ++j)
      bf[j] = *(const s16x8*)&Bs[(wc + j * 16 + (lane & 15)) * 32 + (lane >> 4) * 8];
#pragma unroll
    for (int i = 0; i < 4; ++i)
#pragma unroll
      for (int j = 0; j < 4; ++j)
        acc[i][j] = __builtin_amdgcn_mfma_f32_16x16x32_bf16(af[i], bf[j], acc[i][j], 0, 0, 0);
  }
  const int cr = (lane >> 4) * 4, cc = lane & 15;
#pragma unroll
  for (int i = 0; i < 4; ++i)
#pragma unroll
    for (int j = 0; j < 4; ++j) {
      int col = n0 + wc + j * 16 + cc;
      int qb = m0 + wr + i * 16 + cr;
#pragma unroll
      for (int r = 0; r < 4; ++r)
        Gout[(long)(qb + r) * 256 + col] = (col <= qb + r) ? f2bf(acc[i][j][r]) : (unsigned short)0;
    }
}

// ---------------- conv1d (k=4, causal) + SiLU -> bf16 Xbf/Bbf/Cbf ----------------
__global__ __launch_bounds__(256) void conv_silu3(
    const unsigned short* __restrict__ zxb, const float* __restrict__ cw,
    const float* __restrict__ cb,
    unsigned short* __restrict__ Xbf, unsigned short* __restrict__ Bbf,
    unsigned short* __restrict__ Cbf)
{
  long idx = (long)blockIdx.x * 256 + threadIdx.x;
  if (idx >= ROWS * 192) return;
  int cq = (int)(idx % 192);
  long row = idx / 192;
  int t = (int)(row & 1023);
  int ch = cq * 4;
  float4 cbv = *(const float4*)&cb[ch];
  float a0 = cbv.x, a1 = cbv.y, a2 = cbv.z, a3 = cbv.w;
#pragma unroll
  for (int w = 0; w < 4; ++w) {
    int d = w - 3;
    if (t + d >= 0) {
      ushort4 zv = *(const ushort4*)&zxb[(row + d) * DPROJ + 512 + ch];
      float4 cwv = *(const float4*)&cw[w * XBCW + ch];
      a0 = fmaf(bf2f(zv.x), cwv.x, a0);
      a1 = fmaf(bf2f(zv.y), cwv.y, a1);
      a2 = fmaf(bf2f(zv.z), cwv.z, a2);
      a3 = fmaf(bf2f(zv.w), cwv.w, a3);
    }
  }
  ushort4 o;
  o.x = f2bf(a0 / (1.f + __expf(-a0)));
  o.y = f2bf(a1 / (1.f + __expf(-a1)));
  o.z = f2bf(a2 / (1.f + __expf(-a2)));
  o.w = f2bf(a3 / (1.f + __expf(-a3)));
  if (ch < 512)      *(ushort4*)&Xbf[row * DIN + ch] = o;
  else if (ch < 640) *(ushort4*)&Bbf[row * 128 + ch - 512] = o;
  else               *(ushort4*)&Cbf[row * 128 + ch - 640] = o;
}

// ---------------- dt from f32 x; softplus; wave-parallel cumsum ----------------
__global__ __launch_bounds__(256) void dt_cumsum3(
    const float* __restrict__ x, const float* __restrict__ Wdt,
    const float* __restrict__ bdt, const float* __restrict__ dtb,
    const float* __restrict__ alog,
    float* __restrict__ dtsp, float* __restrict__ acs)
{
  int g = ((int)blockIdx.x * 256 + (int)threadIdx.x) >> 6;
  int lane = threadIdx.x & 63;
  int c = g & 3, h = (g >> 2) & 7, b = g >> 5;
  float Ah = -__expf(alog[h]);
  float bias = dtb[h] + bdt[h];
  long rowbase = (long)b * LSEQ + c * QLEN;
  long abase = (((long)b * NH + h) * NCHUNK + c) * QLEN;
  float v[4];
#pragma unroll
  for (int j = 0; j < 4; ++j) {
    long row = rowbase + lane * 4 + j;
    const float4* x4 = (const float4*)&x[row * 200];
    float acc = bias;
    for (int i = 0; i < 50; ++i) {
      float4 xv = x4[i];
      acc += xv.x * Wdt[(i * 4 + 0) * 8 + h]
           + xv.y * Wdt[(i * 4 + 1) * 8 + h]
           + xv.z * Wdt[(i * 4 + 2) * 8 + h]
           + xv.w * Wdt[(i * 4 + 3) * 8 + h];
    }
    float sp = (acc > 20.f) ? acc : log1pf(__expf(acc));
    dtsp[row * NH + h] = sp;
    v[j] = sp * Ah;
  }
  v[1] += v[0]; v[2] += v[1]; v[3] += v[2];
  float tot = v[3];
  float run = tot;
#pragma unroll
  for (int d = 1; d < 64; d <<= 1) {
    float t = __shfl_up(run, d);
    if (lane >= d) run += t;
  }
  float excl = run - tot;
#pragma unroll
  for (int j = 0; j < 4; ++j) acs[abase + lane * 4 + j] = excl + v[j];
}

// ---------------- Bbf [ROWS][128] -> BbfT [bc][128][256] ----------------
__global__ __launch_bounds__(256) void transB(const unsigned short* __restrict__ Bbf,
                                              unsigned short* __restrict__ BbfT)
{
  __shared__ unsigned short T[128][130];
  int bc = blockIdx.y, kh = blockIdx.x;
  int tid = threadIdx.x;
  long rowbase = (long)(bc >> 2) * LSEQ + (bc & 3) * QLEN + kh * 128;
  for (int e = tid; e < 128 * 128; e += 256) {
    int r = e >> 7, n = e & 127;
    T[r][n] = Bbf[(rowbase + r) * 128 + n];
  }
  __syncthreads();
  for (int e = tid; e < 128 * 128; e += 256) {
    int n = e >> 7, k = e & 127;
    BbfT[((long)bc * 128 + n) * 256 + kh * 128 + k] = T[k][n];
  }
}

// ---------------- yd+states: full XdT staged once, pure-MFMA k loop ----------------
__global__ __launch_bounds__(256) void yd_states6(
    const unsigned short* __restrict__ Xbf, const float* __restrict__ dtsp,
    const float* __restrict__ acs, const unsigned short* __restrict__ Gbf,
    const unsigned short* __restrict__ BbfT,
    unsigned short* __restrict__ ybf, float* __restrict__ st)
{
  int bid = blockIdx.x;
  int xcd = bid & 7, i0 = bid >> 3;
  int bc = xcd * 8 + (i0 >> 4);
  int rem = i0 & 15, h = rem >> 1, half = rem & 1;
  int c = bc & 3, b = bc >> 2;
  int bch = bc * 8 + h;

  __shared__ __align__(16) unsigned short XdT[64][264];
  __shared__ float AcsS[256], E1f[256], E2f[256], dts[256];

  const int tid = threadIdx.x;
  const int lane = tid & 63, wv = tid >> 6;
  const bool ydw = wv < 2;
  const int q0 = half * 128 + wv * 64;
  const int myqt = half * 2 + wv;
  const int n0w = half * 64 + (wv - 2) * 32;
  long rowbase = (long)b * LSEQ + c * QLEN;
  const unsigned short* Gb  = Gbf + (long)bc * 65536;
  const unsigned short* BTg = BbfT + (long)bc * 32768;

  AcsS[tid] = acs[(((long)b * NH + h) * NCHUNK + c) * QLEN + tid];
  dts[tid]  = dtsp[(rowbase + tid) * NH + h];
  __syncthreads();
  E1f[tid] = __expf(AcsS[tid] - AcsS[tid | 63]);
  E2f[tid] = __expf(AcsS[tid | 63] - AcsS[tid]);
  float rs_[4];
  rs_[0] = 1.f;
#pragma unroll
  for (int kt = 1; kt < 4; ++kt) rs_[kt] = __expf(AcsS[kt * 64 + 63] - AcsS[kt * 64 - 1]);
  __syncthreads();
  {
    int kb = wv * 64;
#pragma unroll
    for (int s = 0; s < 16; ++s) {
      int k4 = kb + s * 4;
      ushort4 pk;
      unsigned short* pp = (unsigned short*)&pk;
#pragma unroll
      for (int j = 0; j < 4; ++j) {
        int k = k4 + j;
        float v = bf2f(Xbf[(rowbase + k) * DIN + h * HD + lane]) * dts[k] * E2f[k];
        pp[j] = f2bf(v);
      }
      *(ushort4*)&XdT[lane][k4] = pk;
    }
  }
  __syncthreads();

  f32x4 accY[4][4], accS[4][2];
#pragma unroll
  for (int i = 0; i < 4; ++i)
#pragma unroll
    for (int j = 0; j < 4; ++j) accY[i][j] = (f32x4){0.f, 0.f, 0.f, 0.f};
#pragma unroll
  for (int i = 0; i < 4; ++i)
#pragma unroll
    for (int j = 0; j < 2; ++j) accS[i][j] = (f32x4){0.f, 0.f, 0.f, 0.f};

  for (int kt = 0; kt < 4; ++kt) {
    int qlo = kt * 64;
    if (ydw) {
      if (myqt >= kt) {
        if (kt)
#pragma unroll
          for (int i = 0; i < 4; ++i)
#pragma unroll
            for (int j = 0; j < 4; ++j) accY[i][j] *= rs_[kt];
#pragma unroll
        for (int ks = 0; ks < 2; ++ks) {
          s16x8 bfr[4];
#pragma unroll
          for (int j = 0; j < 4; ++j)
            bfr[j] = *(const s16x8*)&XdT[j * 16 + (lane & 15)][qlo + ks * 32 + (lane >> 4) * 8];
#pragma unroll
          for (int i = 0; i < 4; ++i) {
            s16x8 a = *(const s16x8*)&Gb[(long)(q0 + i * 16 + (lane & 15)) * 256 + qlo + ks * 32 + (lane >> 4) * 8];
#pragma unroll
            for (int j = 0; j < 4; ++j)
              accY[i][j] = __builtin_amdgcn_mfma_f32_16x16x32_bf16(a, bfr[j], accY[i][j], 0, 0, 0);
          }
        }
      }
    } else {
      if (kt)
#pragma unroll
        for (int i = 0; i < 4; ++i)
#pragma unroll
          for (int j = 0; j < 2; ++j) accS[i][j] *= rs_[kt];
#pragma unroll
      for (int ks = 0; ks < 2; ++ks) {
        s16x8 afx[4];
#pragma unroll
        for (int i = 0; i < 4; ++i)
          afx[i] = *(const s16x8*)&XdT[i * 16 + (lane & 15)][qlo + ks * 32 + (lane >> 4) * 8];
#pragma unroll
        for (int j2 = 0; j2 < 2; ++j2) {
          s16x8 bt = *(const s16x8*)&BTg[(long)(n0w + j2 * 16 + (lane & 15)) * 256 + qlo + ks * 32 + (lane >> 4) * 8];
#pragma unroll
          for (int i = 0; i < 4; ++i)
            accS[i][j2] = __builtin_amdgcn_mfma_f32_16x16x32_bf16(afx[i], bt, accS[i][j2], 0, 0, 0);
        }
      }
    }
  }
  const int cr = (lane >> 4) * 4, cc = lane & 15;
  if (ydw) {
#pragma unroll
    for (int i = 0; i < 4; ++i)
#pragma unroll
      for (int j = 0; j < 4; ++j) {
        int q = q0 + i * 16 + cr;
        int p = j * 16 + cc;
#pragma unroll
        for (int r = 0; r < 4; ++r)
          ybf[(rowbase + q + r) * DIN + h * HD + p] = f2bf(accY[i][j][r] * E1f[q + r]);
      }
  } else {
#pragma unroll
    for (int i = 0; i < 4; ++i)
#pragma unroll
      for (int j2 = 0; j2 < 2; ++j2) {
        int p = i * 16 + cr;
        int n = n0w + j2 * 16 + cc;
#pragma unroll
        for (int r = 0; r < 4; ++r)
          st[(long)bch * 8192 + (long)(p + r) * 128 + n] = accS[i][j2][r];
      }
  }
}

// ---------------- inter-chunk scan (f32x4 vectorized, in place) ----------------
__global__ void scan_states(float* __restrict__ st, const float* __restrict__ acs)
{
  long idx = (long)blockIdx.x * 256 + threadIdx.x;
  if (idx >= (long)NB * NH * 2048) return;
  long inner = idx & 2047;
  int h = (int)((idx >> 11) & 7);
  int b = (int)(idx >> 14);
  f32x4 carry = {0.f, 0.f, 0.f, 0.f};
  for (int c = 0; c < NCHUNK; ++c) {
    float dc = __expf(acs[(((long)b * NH + h) * NCHUNK + c) * QLEN + (QLEN - 1)]);
    long si = (((long)(b * NCHUNK + c) * NH + h) << 13) + inner * 4;
    f32x4 s = *(f32x4*)&st[si];
    *(f32x4*)&st[si] = carry;
    carry = carry * dc + s;
  }
}

// ---------------- Yo via MFMA: ybf += exp(Acs[q]) * Cbf·prev^T + xh*D ----------------
__global__ __launch_bounds__(256) void yo_combine5(
    const unsigned short* __restrict__ Xbf, const unsigned short* __restrict__ Cbf,
    const float* __restrict__ prev, const float* __restrict__ acs,
    const float* __restrict__ Dp, unsigned short* __restrict__ ybf)
{
  int bid = blockIdx.x;
  int xcd = bid & 7, i0 = bid >> 3;
  int bc = xcd * 8 + (i0 >> 3), h = i0 & 7;
  int c = bc & 3, b = bc >> 2;
  int bch = bc * 8 + h;
  __shared__ float EqA[QLEN];
  const int tid = threadIdx.x;
  const int lane = tid & 63, wv = tid >> 6;
  long rowbase = (long)b * LSEQ + c * QLEN;
  EqA[tid] = __expf(acs[(((long)b * NH + h) * NCHUNK + c) * QLEN + tid]);
  __syncthreads();
  const unsigned short* Cb = Cbf + rowbase * 128;
  const float* pv = prev + (long)bch * 8192;
  f32x4 acc[4][4];
#pragma unroll
  for (int i = 0; i < 4; ++i)
#pragma unroll
    for (int j = 0; j < 4; ++j) acc[i][j] = (f32x4){0.f, 0.f, 0.f, 0.f};
#pragma unroll
  for (int ks = 0; ks < 4; ++ks) {
    int n0 = ks * 32 + (lane >> 4) * 8;
    s16x8 bf[4];
#pragma unroll
    for (int j = 0; j < 4; ++j) {
      int p = j * 16 + (lane & 15);
      f32x4 v0 = *(const f32x4*)&pv[p * 128 + n0];
      f32x4 v1 = *(const f32x4*)&pv[p * 128 + n0 + 4];
#pragma unroll
      for (int t = 0; t < 4; ++t) {
        bf[j][t]     = (short)f2bf(v0[t]);
        bf[j][4 + t] = (short)f2bf(v1[t]);
      }
    }
#pragma unroll
    for (int i = 0; i < 4; ++i) {
      s16x8 af = *(const s16x8*)&Cb[(long)(wv * 64 + i * 16 + (lane & 15)) * 128 + n0];
#pragma unroll
      for (int j = 0; j < 4; ++j)
        acc[i][j] = __builtin_amdgcn_mfma_f32_16x16x32_bf16(af, bf[j], acc[i][j], 0, 0, 0);
    }
  }
  const int cr = (lane >> 4) * 4, cc = lane & 15;
  float Dh = Dp[h];
#pragma unroll
  for (int i = 0; i < 4; ++i)
#pragma unroll
    for (int j = 0; j < 4; ++j) {
      int q = wv * 64 + i * 16 + cr;
      int p = j * 16 + cc;
#pragma unroll
      for (int r = 0; r < 4; ++r) {
        long row = rowbase + q + r;
        long yi = row * DIN + h * HD + p;
        float xh = bf2f(Xbf[yi]);
        float pr = bf2f(ybf[yi]);
        ybf[yi] = f2bf(pr + acc[i][j][r] * EqA[q + r] + xh * Dh);
      }
    }
}

// ---------------- gated RMSNorm in place on ybf (bf16) ----------------
__global__ __launch_bounds__(256) void gated_rms3(
    unsigned short* __restrict__ ybf, const unsigned short* __restrict__ zxb,
    const float* __restrict__ rmsw)
{
  long row = blockIdx.x;
  int t = threadIdx.x;
  ushort2 yv = *(const ushort2*)&ybf[row * DIN + 2 * t];
  ushort2 zv = *(const ushort2*)&zxb[row * DPROJ + 2 * t];
  float z0 = bf2f(zv.x), z1 = bf2f(zv.y);
  float v0 = bf2f(yv.x) * (z0 / (1.f + __expf(-z0)));
  float v1 = bf2f(yv.y) * (z1 / (1.f + __expf(-z1)));
  float ss = v0 * v0 + v1 * v1;
#pragma unroll
  for (int off = 32; off; off >>= 1) ss += __shfl_down(ss, off);
  __shared__ float red[4];
  if ((t & 63) == 0) red[t >> 6] = ss;
  __syncthreads();
  float tot = red[0] + red[1] + red[2] + red[3];
  float scale = rsqrtf(tot * (1.f / DIN) + 1e-5f);
  ushort2 o;
  o.x = f2bf(v0 * scale * rmsw[2 * t]);
  o.y = f2bf(v1 * scale * rmsw[2 * t + 1]);
  *(ushort2*)&ybf[row * DIN + 2 * t] = o;
}

// ---------------- fused LayerNorm + classifier ----------------
__global__ __launch_bounds__(256) void ln_cls(
    const float* __restrict__ y2, const float* __restrict__ g, const float* __restrict__ bb,
    const float* __restrict__ wcls, const float* __restrict__ bcls,
    float* __restrict__ out)
{
  __shared__ float sA[4], sB[4];
  __shared__ float ynS[256];
  __shared__ float ps[8][17];
  long row = blockIdx.x;
  int t = threadIdx.x;
  float v = y2[row * DM + t];
  float s = v, q = v * v;
#pragma unroll
  for (int off = 32; off; off >>= 1) { s += __shfl_down(s, off); q += __shfl_down(q, off); }
  if ((t & 63) == 0) { sA[t >> 6] = s; sB[t >> 6] = q; }
  __syncthreads();
  float S = sA[0] + sA[1] + sA[2] + sA[3];
  float Qs = sB[0] + sB[1] + sB[2] + sB[3];
  float mu = S * (1.f / DM);
  float var = Qs * (1.f / DM) - mu * mu;
  ynS[t] = (v - mu) * rsqrtf(var + 1e-5f) * g[t] + bb[t];
  __syncthreads();
  if (t < 136) {
    int j = t % 17, seg = t / 17;
    float a = 0.f;
    int i0 = seg * 32;
#pragma unroll 8
    for (int i = 0; i < 32; ++i) a = fmaf(ynS[i0 + i], wcls[(long)(i0 + i) * NCLS + j], a);
    ps[seg][j] = a;
  }
  __syncthreads();
  if (t < NCLS) {
    float a = bcls[t];
#pragma unroll
    for (int s2 = 0; s2 < 8; ++s2) a += ps[s2][t];
    out[row * NCLS + t] = a;
  }
}

extern "C" void kernel_launch(void* const* d_in, const int* in_sizes, int n_in,
                              void* d_out, int out_size, void* d_ws, size_t ws_size,
                              hipStream_t stream)
{
  const float* x     = (const float*)d_in[0];
  const float* w_inp = (const float*)d_in[1];
  const float* b_inp = (const float*)d_in[2];
  const float* w_in  = (const float*)d_in[3];
  const float* convw = (const float*)d_in[4];
  const float* convb = (const float*)d_in[5];
  const float* dtb   = (const float*)d_in[6];
  const float* alog  = (const float*)d_in[7];
  const float* Dp    = (const float*)d_in[8];
  const float* rmsw  = (const float*)d_in[9];
  const float* wout  = (const float*)d_in[10];
  const float* lng   = (const float*)d_in[11];
  const float* lnb   = (const float*)d_in[12];
  const float* wcls  = (const float*)d_in[13];
  const float* bcls  = (const float*)d_in[14];
  float* out = (float*)d_out;
  float* ws  = (float*)d_ws;

  float* dtsp = ws + O_DT;
  float* acs  = ws + O_ACS;
  float* st   = ws + O_ST;
  float* y2   = ws + O_Y2;
  float* Wdt  = ws + O_WDT;
  float* bdt  = Wdt + 1600;
  float* bfull= ws + O_BFULL;
  unsigned short* Gbf   = (unsigned short*)(ws + O_GBF);
  unsigned short* zxb   = (unsigned short*)(ws + O_ZX);
  unsigned short* Xbf   = (unsigned short*)(ws + O_XBF);
  unsigned short* Bbf   = (unsigned short*)(ws + O_BBF);
  unsigned short* Cbf   = (unsigned short*)(ws + O_CBF);
  unsigned short* BbfT  = (unsigned short*)(ws + O_BT);
  unsigned short* ybf   = (unsigned short*)(ws + O_YBF);
  unsigned short* xp_bf = (unsigned short*)(ws + O_XPBF);
  unsigned short* WcombT= (unsigned short*)(ws + O_WCT);
  unsigned short* woutT = (unsigned short*)(ws + O_WOUTT);

  prep_gemm<<<dim3(21, 4), 256, 0, stream>>>(w_inp, w_in, b_inp, WcombT, bfull, Wdt, bdt);
  tcast<<<512, 256, 0, stream>>>(wout, woutT, 9, DM);
  cast_pad_x<<<3584, 256, 0, stream>>>(x, xp_bf);
  // fused input_proj+in_proj: zxb = x @ (w_inp@w_in) + b_inp@w_in
  gemm_bf16<<<dim3(11, 128), 256, 0, stream>>>(xp_bf, WcombT, nullptr, zxb, bfull, 16384, DPROJ, 224);
  conv_silu3<<<12288, 256, 0, stream>>>(zxb, convw, convb, Xbf, Bbf, Cbf);
  dt_cumsum3<<<128, 256, 0, stream>>>(x, Wdt, bdt, dtb, alog, dtsp, acs);
  transB<<<dim3(2, 64), 256, 0, stream>>>(Bbf, BbfT);
  g_gemm_bf16<<<dim3(2, 2, 64), 256, 0, stream>>>(Cbf, Bbf, Gbf);
  yd_states6<<<1024, 256, 0, stream>>>(Xbf, dtsp, acs, Gbf, BbfT, ybf, st);
  scan_states<<<1024, 256, 0, stream>>>(st, acs);
  yo_combine5<<<512, 256, 0, stream>>>(Xbf, Cbf, st, acs, Dp, ybf);
  gated_rms3<<<16384, 256, 0, stream>>>(ybf, zxb, rmsw);
  gemm_bf16<<<dim3(2, 128), 256, 0, stream>>>(ybf, woutT, y2, nullptr, nullptr, 16384, DM, DIN);
  ln_cls<<<16384, 256, 0, stream>>>(y2, lng, lnb, wcls, bcls, out);
}

// Round 9
// 268.047 us; speedup vs baseline: 4.6912x; 1.0807x over previous
//
#include <hip/hip_runtime.h>
#include <math.h>

#define ROWS   16384L
#define LSEQ   1024
#define NB     16
#define DM     256
#define DPROJ  1288
#define XBCW   768
#define DIN    512
#define DSTATE 128
#define NH     8
#define HD     64
#define QLEN   256
#define NCHUNK 4
#define NCLS   17

typedef __attribute__((ext_vector_type(8))) short s16x8;
typedef __attribute__((ext_vector_type(4))) float f32x4;

#define GLOAD_LDS16(gsrc, ldst) \
  __builtin_amdgcn_global_load_lds((const __attribute__((address_space(1))) void*)(gsrc), \
      (__attribute__((address_space(3))) void*)(ldst), 16, 0, 0)

// ---- workspace map (float slots) ----
constexpr long O_GBF  = 0;                        // Gbf bf16 [64][256][256]
constexpr long O_ZX   = O_GBF + ROWS*DM;          // zxb bf16 [ROWS][1288]
constexpr long O_XBC  = O_ZX  + ROWS*DPROJ;       // region: Xbf/Bbf/Cbf/BbfT bf16
constexpr long O_DT   = O_XBC + ROWS*XBCW;
constexpr long O_ACS  = O_DT  + ROWS*NH;
constexpr long O_Y    = O_ACS + 131072;           // region: ybf bf16 + prep overlays
constexpr long O_ST   = O_Y   + ROWS*DIN;         // st f32 [512][64p][128n]
constexpr long O_Y2   = O_ST  + 4194304;          // y2b bf16 (overlays Bbf/Cbf/BbfT, dead by then)
// O_XBC region overlays (bf16):
constexpr long O_XBF  = O_XBC;                    // Xbf [ROWS][512]
constexpr long O_BBF  = O_XBC + 4200000;          // Bbf [ROWS][128]
constexpr long O_CBF  = O_XBC + 5300000;          // Cbf [ROWS][128]
constexpr long O_BT   = O_XBC + 6400000;          // BbfT [64][128][256]
// O_Y region overlays:
constexpr long O_YBF  = O_Y;                      // ybf [ROWS][512] bf16
constexpr long O_XPBF = O_Y + 4300000;            // xp_bf [ROWS][224] bf16
constexpr long O_WCT  = O_Y + 6200000;            // WcombT [1288][224] bf16
constexpr long O_WOUTT= O_Y + 6400000;            // woutT [256][512] bf16
constexpr long O_WDT  = O_Y + 6500000;            // Wdt[200][8]+bdt[8] f32
constexpr long O_BFULL= O_Y + 6520000;            // bfull [1288] f32
constexpr long O_WCLST= O_Y + 6530000;            // wclsT [17][256] f32

__device__ inline unsigned short f2bf(float f) {
  union { float f; unsigned u; } v; v.f = f;
  unsigned r = v.u + 0x7FFFu + ((v.u >> 16) & 1u);
  return (unsigned short)(r >> 16);
}
__device__ inline float bf2f(unsigned short s) {
  union { unsigned u; float f; } v; v.u = ((unsigned)s) << 16; return v.f;
}

// ---------------- prep GEMM: Wcomb[k][n] = sum_j A[k][j]*w_in[j][n], A row 200 = b_inp
__global__ __launch_bounds__(256) void prep_gemm(
    const float* __restrict__ w_inp, const float* __restrict__ w_in,
    const float* __restrict__ b_inp,
    unsigned short* __restrict__ WcombT, float* __restrict__ bfull,
    float* __restrict__ Wdt, float* __restrict__ bdt)
{
  __shared__ float As[16][68];
  __shared__ float Ws[16][68];
  const int m0 = blockIdx.y * 64;
  const int n0 = blockIdx.x * 64;
  const int tid = threadIdx.x;
  const int tm = (tid >> 4) << 2, tn = (tid & 15) << 2;
  float acc[4][4] = {};
  for (int j0 = 0; j0 < 256; j0 += 16) {
#pragma unroll
    for (int i = 0; i < 4; ++i) {
      int e = tid + i * 256;
      int m = m0 + (e >> 4), j = j0 + (e & 15);
      float v = 0.f;
      if (m < 200)       v = w_inp[(long)m * 256 + j];
      else if (m == 200) v = b_inp[j];
      As[e & 15][e >> 4] = v;
    }
#pragma unroll
    for (int i = 0; i < 4; ++i) {
      int e = tid + i * 256;
      int j = e >> 6, n = n0 + (e & 63);
      Ws[j][e & 63] = (n < DPROJ) ? w_in[(long)(j0 + j) * DPROJ + n] : 0.f;
    }
    __syncthreads();
#pragma unroll
    for (int j = 0; j < 16; ++j) {
      float a[4], w[4];
#pragma unroll
      for (int i = 0; i < 4; ++i) a[i] = As[j][tm + i];
#pragma unroll
      for (int t = 0; t < 4; ++t) w[t] = Ws[j][tn + t];
#pragma unroll
      for (int i = 0; i < 4; ++i)
#pragma unroll
        for (int t = 0; t < 4; ++t) acc[i][t] = fmaf(a[i], w[t], acc[i][t]);
    }
    __syncthreads();
  }
#pragma unroll
  for (int i = 0; i < 4; ++i) {
    int k = m0 + tm + i;
#pragma unroll
    for (int t = 0; t < 4; ++t) {
      int n = n0 + tn + t;
      if (n >= DPROJ) continue;
      float v = acc[i][t];
      if (k < 224) WcombT[(long)n * 224 + k] = f2bf(v);
      if (k == 200) {
        bfull[n] = v;
        if (n >= 1280) bdt[n - 1280] = v;
      }
      if (k < 200 && n >= 1280) Wdt[k * 8 + (n - 1280)] = v;
    }
  }
}

// ---------------- transpose+cast: w[K,N] f32 -> wt[N,K] bf16 (K=1<<kbits) ------------
__global__ __launch_bounds__(256) void tcast(const float* __restrict__ w,
                                             unsigned short* __restrict__ wt,
                                             int kbits, int N)
{
  long i = (long)blockIdx.x * 256 + threadIdx.x;
  int K = 1 << kbits;
  if (i >= (long)K * N) return;
  int k = (int)(i & (K - 1));
  long n = i >> kbits;
  wt[i] = f2bf(w[(long)k * N + n]);
}

// ---------------- wcls [256][17] -> wclsT [17][256] f32 ----------------
__global__ __launch_bounds__(256) void tpose_wcls(const float* __restrict__ wcls,
                                                  float* __restrict__ wclsT)
{
  int i = blockIdx.x * 256 + threadIdx.x;
  if (i >= NCLS * 256) return;
  int j = i >> 8, k = i & 255;
  wclsT[i] = wcls[(long)k * NCLS + j];
}

// ---------------- pad+cast x: [ROWS][200] f32 -> [ROWS][224] bf16 ----------------
__global__ __launch_bounds__(256) void cast_pad_x(const float* __restrict__ x,
                                                  unsigned short* __restrict__ xp)
{
  long idx = (long)blockIdx.x * 256 + threadIdx.x;
  if (idx >= ROWS * 56) return;
  int q = (int)(idx % 56);
  long row = idx / 56;
  ushort4 o = {0, 0, 0, 0};
  if (q < 50) {
    float4 v = *(const float4*)&x[row * 200 + q * 4];
    o.x = f2bf(v.x); o.y = f2bf(v.y); o.z = f2bf(v.z); o.w = f2bf(v.w);
  }
  *(ushort4*)&xp[row * 224 + q * 4] = o;
}

// ---------------- bf16 MFMA GEMM (global_load_lds staging) ----------------
__global__ __launch_bounds__(256) void gemm_bf16(
    const unsigned short* __restrict__ A, const unsigned short* __restrict__ BT,
    float* __restrict__ C, unsigned short* __restrict__ Cb,
    const float* __restrict__ bias, int M, int N, int K)
{
  __shared__ __align__(16) unsigned short As[128 * 32];
  __shared__ __align__(16) unsigned short Bs[128 * 32];
  const int tid = threadIdx.x;
  const int m0 = blockIdx.y * 128, n0 = blockIdx.x * 128;
  const int lane = tid & 63, wv = tid >> 6;
  const int wr = (wv >> 1) * 64, wc = (wv & 1) * 64;
  f32x4 acc[4][4];
#pragma unroll
  for (int i = 0; i < 4; ++i)
#pragma unroll
    for (int j = 0; j < 4; ++j) acc[i][j] = (f32x4){0.f, 0.f, 0.f, 0.f};

  for (int k0 = 0; k0 < K; k0 += 32) {
    __syncthreads();
#pragma unroll
    for (int s = 0; s < 2; ++s) {
      int idx = (tid + 256 * s) * 8;
      int r = idx >> 5, kk = idx & 31;
      GLOAD_LDS16(&A[(long)(m0 + r) * K + k0 + kk], &As[idx]);
    }
#pragma unroll
    for (int s = 0; s < 2; ++s) {
      int idx = (tid + 256 * s) * 8;
      int n = idx >> 5, kk = idx & 31;
      int srcn = (n0 + n < N) ? (n0 + n) : 0;    // clamp; cols>=N discarded at write
      GLOAD_LDS16(&BT[(long)srcn * K + k0 + kk], &Bs[idx]);
    }
    __syncthreads();
    s16x8 af[4], bf[4];
#pragma unroll
    for (int i = 0; i < 4; ++i)
      af[i] = *(const s16x8*)&As[(wr + i * 16 + (lane & 15)) * 32 + (lane >> 4) * 8];
#pragma unroll
    for (int j = 0; j < 4; ++j)
      bf[j] = *(const s16x8*)&Bs[(wc + j * 16 + (lane & 15)) * 32 + (lane >> 4) * 8];
#pragma unroll
    for (int i = 0; i < 4; ++i)
#pragma unroll
      for (int j = 0; j < 4; ++j)
        acc[i][j] = __builtin_amdgcn_mfma_f32_16x16x32_bf16(af[i], bf[j], acc[i][j], 0, 0, 0);
  }
  const int cr = (lane >> 4) * 4, cc = lane & 15;
#pragma unroll
  for (int i = 0; i < 4; ++i)
#pragma unroll
    for (int j = 0; j < 4; ++j) {
      int col = n0 + wc + j * 16 + cc;
      if (col < N) {
        long rowb = (long)(m0 + wr + i * 16 + cr);
        float bv = bias ? bias[col] : 0.f;
#pragma unroll
        for (int r = 0; r < 4; ++r) {
          float v = acc[i][j][r] + bv;
          if (C)  C[(rowb + r) * N + col] = v;
          if (Cb) Cb[(rowb + r) * (long)N + col] = f2bf(v);
        }
      }
    }
}

// ---------------- G = C·B^T per (b,c) -> bf16 causal-masked ----------------
__global__ __launch_bounds__(256) void g_gemm_bf16(
    const unsigned short* __restrict__ Cbf, const unsigned short* __restrict__ Bbf,
    unsigned short* __restrict__ Gbf)
{
  int bc = blockIdx.z;
  unsigned short* Gout = Gbf + (long)bc * 65536;
  const int tid = threadIdx.x;
  const int m0 = blockIdx.y * 128, n0 = blockIdx.x * 128;
  if (blockIdx.x > blockIdx.y) {
    s16x8 z = {};
    for (int e = tid; e < 128 * 16; e += 256) {
      int r = e >> 4, seg = e & 15;
      *(s16x8*)&Gout[(long)(m0 + r) * 256 + n0 + seg * 8] = z;
    }
    return;
  }
  long rowbase = (long)(bc >> 2) * LSEQ + (bc & 3) * QLEN;
  const unsigned short* A  = Cbf + rowbase * 128;
  const unsigned short* BT = Bbf + rowbase * 128;
  __shared__ __align__(16) unsigned short As[128 * 32];
  __shared__ __align__(16) unsigned short Bs[128 * 32];
  const int lane = tid & 63, wv = tid >> 6;
  const int wr = (wv >> 1) * 64, wc = (wv & 1) * 64;
  f32x4 acc[4][4];
#pragma unroll
  for (int i = 0; i < 4; ++i)
#pragma unroll
    for (int j = 0; j < 4; ++j) acc[i][j] = (f32x4){0.f, 0.f, 0.f, 0.f};
  for (int k0 = 0; k0 < 128; k0 += 32) {
    __syncthreads();
#pragma unroll
    for (int s = 0; s < 2; ++s) {
      int idx = (tid + 256 * s) * 8;
      int r = idx >> 5, kk = idx & 31;
      GLOAD_LDS16(&A[(long)(m0 + r) * 128 + k0 + kk], &As[idx]);
      GLOAD_LDS16(&BT[(long)(n0 + r) * 128 + k0 + kk], &Bs[idx]);
    }
    __syncthreads();
    s16x8 af[4], bf[4];
#pragma unroll
    for (int i = 0; i < 4; ++i)
      af[i] = *(const s16x8*)&As[(wr + i * 16 + (lane & 15)) * 32 + (lane >> 4) * 8];
#pragma unroll
    for (int j = 0; j < 4; ++j)
      bf[j] = *(const s16x8*)&Bs[(wc + j * 16 + (lane & 15)) * 32 + (lane >> 4) * 8];
#pragma unroll
    for (int i = 0; i < 4; ++i)
#pragma unroll
      for (int j = 0; j < 4; ++j)
        acc[i][j] = __builtin_amdgcn_mfma_f32_16x16x32_bf16(af[i], bf[j], acc[i][j], 0, 0, 0);
  }
  const int cr = (lane >> 4) * 4, cc = lane & 15;
#pragma unroll
  for (int i = 0; i < 4; ++i)
#pragma unroll
    for (int j = 0; j < 4; ++j) {
      int col = n0 + wc + j * 16 + cc;
      int qb = m0 + wr + i * 16 + cr;
#pragma unroll
      for (int r = 0; r < 4; ++r)
        Gout[(long)(qb + r) * 256 + col] = (col <= qb + r) ? f2bf(acc[i][j][r]) : (unsigned short)0;
    }
}

// ---------------- conv1d (k=4, causal) + SiLU -> bf16 Xbf/Bbf/Cbf ----------------
__global__ __launch_bounds__(256) void conv_silu3(
    const unsigned short* __restrict__ zxb, const float* __restrict__ cw,
    const float* __restrict__ cb,
    unsigned short* __restrict__ Xbf, unsigned short* __restrict__ Bbf,
    unsigned short* __restrict__ Cbf)
{
  long idx = (long)blockIdx.x * 256 + threadIdx.x;
  if (idx >= ROWS * 192) return;
  int cq = (int)(idx % 192);
  long row = idx / 192;
  int t = (int)(row & 1023);
  int ch = cq * 4;
  float4 cbv = *(const float4*)&cb[ch];
  float a0 = cbv.x, a1 = cbv.y, a2 = cbv.z, a3 = cbv.w;
#pragma unroll
  for (int w = 0; w < 4; ++w) {
    int d = w - 3;
    if (t + d >= 0) {
      ushort4 zv = *(const ushort4*)&zxb[(row + d) * DPROJ + 512 + ch];
      float4 cwv = *(const float4*)&cw[w * XBCW + ch];
      a0 = fmaf(bf2f(zv.x), cwv.x, a0);
      a1 = fmaf(bf2f(zv.y), cwv.y, a1);
      a2 = fmaf(bf2f(zv.z), cwv.z, a2);
      a3 = fmaf(bf2f(zv.w), cwv.w, a3);
    }
  }
  ushort4 o;
  o.x = f2bf(a0 / (1.f + __expf(-a0)));
  o.y = f2bf(a1 / (1.f + __expf(-a1)));
  o.z = f2bf(a2 / (1.f + __expf(-a2)));
  o.w = f2bf(a3 / (1.f + __expf(-a3)));
  if (ch < 512)      *(ushort4*)&Xbf[row * DIN + ch] = o;
  else if (ch < 640) *(ushort4*)&Bbf[row * 128 + ch - 512] = o;
  else               *(ushort4*)&Cbf[row * 128 + ch - 640] = o;
}

// ---------------- dt from f32 x; softplus; wave-parallel cumsum ----------------
__global__ __launch_bounds__(256) void dt_cumsum3(
    const float* __restrict__ x, const float* __restrict__ Wdt,
    const float* __restrict__ bdt, const float* __restrict__ dtb,
    const float* __restrict__ alog,
    float* __restrict__ dtsp, float* __restrict__ acs)
{
  int g = ((int)blockIdx.x * 256 + (int)threadIdx.x) >> 6;
  int lane = threadIdx.x & 63;
  int c = g & 3, h = (g >> 2) & 7, b = g >> 5;
  float Ah = -__expf(alog[h]);
  float bias = dtb[h] + bdt[h];
  long rowbase = (long)b * LSEQ + c * QLEN;
  long abase = (((long)b * NH + h) * NCHUNK + c) * QLEN;
  float v[4];
#pragma unroll
  for (int j = 0; j < 4; ++j) {
    long row = rowbase + lane * 4 + j;
    const float4* x4 = (const float4*)&x[row * 200];
    float acc = bias;
    for (int i = 0; i < 50; ++i) {
      float4 xv = x4[i];
      acc += xv.x * Wdt[(i * 4 + 0) * 8 + h]
           + xv.y * Wdt[(i * 4 + 1) * 8 + h]
           + xv.z * Wdt[(i * 4 + 2) * 8 + h]
           + xv.w * Wdt[(i * 4 + 3) * 8 + h];
    }
    float sp = (acc > 20.f) ? acc : log1pf(__expf(acc));
    dtsp[row * NH + h] = sp;
    v[j] = sp * Ah;
  }
  v[1] += v[0]; v[2] += v[1]; v[3] += v[2];
  float tot = v[3];
  float run = tot;
#pragma unroll
  for (int d = 1; d < 64; d <<= 1) {
    float t = __shfl_up(run, d);
    if (lane >= d) run += t;
  }
  float excl = run - tot;
#pragma unroll
  for (int j = 0; j < 4; ++j) acs[abase + lane * 4 + j] = excl + v[j];
}

// ---------------- Bbf [ROWS][128] -> BbfT [bc][128][256] ----------------
__global__ __launch_bounds__(256) void transB(const unsigned short* __restrict__ Bbf,
                                              unsigned short* __restrict__ BbfT)
{
  __shared__ unsigned short T[128][130];
  int bc = blockIdx.y, kh = blockIdx.x;
  int tid = threadIdx.x;
  long rowbase = (long)(bc >> 2) * LSEQ + (bc & 3) * QLEN + kh * 128;
  for (int e = tid; e < 128 * 128; e += 256) {
    int r = e >> 7, n = e & 127;
    T[r][n] = Bbf[(rowbase + r) * 128 + n];
  }
  __syncthreads();
  for (int e = tid; e < 128 * 128; e += 256) {
    int n = e >> 7, k = e & 127;
    BbfT[((long)bc * 128 + n) * 256 + kh * 128 + k] = T[k][n];
  }
}

// ---------------- yd+states: full XdT staged once, pure-MFMA k loop ----------------
__global__ __launch_bounds__(256) void yd_states6(
    const unsigned short* __restrict__ Xbf, const float* __restrict__ dtsp,
    const float* __restrict__ acs, const unsigned short* __restrict__ Gbf,
    const unsigned short* __restrict__ BbfT,
    unsigned short* __restrict__ ybf, float* __restrict__ st)
{
  int bid = blockIdx.x;
  int xcd = bid & 7, i0 = bid >> 3;
  int bc = xcd * 8 + (i0 >> 4);
  int rem = i0 & 15, h = rem >> 1, half = rem & 1;
  int c = bc & 3, b = bc >> 2;
  int bch = bc * 8 + h;

  __shared__ __align__(16) unsigned short XdT[64][264];
  __shared__ float AcsS[256], E1f[256], E2f[256], dts[256];

  const int tid = threadIdx.x;
  const int lane = tid & 63, wv = tid >> 6;
  const bool ydw = wv < 2;
  const int q0 = half * 128 + wv * 64;
  const int myqt = half * 2 + wv;
  const int n0w = half * 64 + (wv - 2) * 32;
  long rowbase = (long)b * LSEQ + c * QLEN;
  const unsigned short* Gb  = Gbf + (long)bc * 65536;
  const unsigned short* BTg = BbfT + (long)bc * 32768;

  AcsS[tid] = acs[(((long)b * NH + h) * NCHUNK + c) * QLEN + tid];
  dts[tid]  = dtsp[(rowbase + tid) * NH + h];
  __syncthreads();
  E1f[tid] = __expf(AcsS[tid] - AcsS[tid | 63]);
  E2f[tid] = __expf(AcsS[tid | 63] - AcsS[tid]);
  float rs_[4];
  rs_[0] = 1.f;
#pragma unroll
  for (int kt = 1; kt < 4; ++kt) rs_[kt] = __expf(AcsS[kt * 64 + 63] - AcsS[kt * 64 - 1]);
  __syncthreads();
  {
    int kb = wv * 64;
#pragma unroll
    for (int s = 0; s < 16; ++s) {
      int k4 = kb + s * 4;
      ushort4 pk;
      unsigned short* pp = (unsigned short*)&pk;
#pragma unroll
      for (int j = 0; j < 4; ++j) {
        int k = k4 + j;
        float v = bf2f(Xbf[(rowbase + k) * DIN + h * HD + lane]) * dts[k] * E2f[k];
        pp[j] = f2bf(v);
      }
      *(ushort4*)&XdT[lane][k4] = pk;
    }
  }
  __syncthreads();

  f32x4 accY[4][4], accS[4][2];
#pragma unroll
  for (int i = 0; i < 4; ++i)
#pragma unroll
    for (int j = 0; j < 4; ++j) accY[i][j] = (f32x4){0.f, 0.f, 0.f, 0.f};
#pragma unroll
  for (int i = 0; i < 4; ++i)
#pragma unroll
    for (int j = 0; j < 2; ++j) accS[i][j] = (f32x4){0.f, 0.f, 0.f, 0.f};

  for (int kt = 0; kt < 4; ++kt) {
    int qlo = kt * 64;
    if (ydw) {
      if (myqt >= kt) {
        if (kt)
#pragma unroll
          for (int i = 0; i < 4; ++i)
#pragma unroll
            for (int j = 0; j < 4; ++j) accY[i][j] *= rs_[kt];
#pragma unroll
        for (int ks = 0; ks < 2; ++ks) {
          s16x8 bfr[4];
#pragma unroll
          for (int j = 0; j < 4; ++j)
            bfr[j] = *(const s16x8*)&XdT[j * 16 + (lane & 15)][qlo + ks * 32 + (lane >> 4) * 8];
#pragma unroll
          for (int i = 0; i < 4; ++i) {
            s16x8 a = *(const s16x8*)&Gb[(long)(q0 + i * 16 + (lane & 15)) * 256 + qlo + ks * 32 + (lane >> 4) * 8];
#pragma unroll
            for (int j = 0; j < 4; ++j)
              accY[i][j] = __builtin_amdgcn_mfma_f32_16x16x32_bf16(a, bfr[j], accY[i][j], 0, 0, 0);
          }
        }
      }
    } else {
      if (kt)
#pragma unroll
        for (int i = 0; i < 4; ++i)
#pragma unroll
          for (int j = 0; j < 2; ++j) accS[i][j] *= rs_[kt];
#pragma unroll
      for (int ks = 0; ks < 2; ++ks) {
        s16x8 afx[4];
#pragma unroll
        for (int i = 0; i < 4; ++i)
          afx[i] = *(const s16x8*)&XdT[i * 16 + (lane & 15)][qlo + ks * 32 + (lane >> 4) * 8];
#pragma unroll
        for (int j2 = 0; j2 < 2; ++j2) {
          s16x8 bt = *(const s16x8*)&BTg[(long)(n0w + j2 * 16 + (lane & 15)) * 256 + qlo + ks * 32 + (lane >> 4) * 8];
#pragma unroll
          for (int i = 0; i < 4; ++i)
            accS[i][j2] = __builtin_amdgcn_mfma_f32_16x16x32_bf16(afx[i], bt, accS[i][j2], 0, 0, 0);
        }
      }
    }
  }
  const int cr = (lane >> 4) * 4, cc = lane & 15;
  if (ydw) {
#pragma unroll
    for (int i = 0; i < 4; ++i)
#pragma unroll
      for (int j = 0; j < 4; ++j) {
        int q = q0 + i * 16 + cr;
        int p = j * 16 + cc;
#pragma unroll
        for (int r = 0; r < 4; ++r)
          ybf[(rowbase + q + r) * DIN + h * HD + p] = f2bf(accY[i][j][r] * E1f[q + r]);
      }
  } else {
#pragma unroll
    for (int i = 0; i < 4; ++i)
#pragma unroll
      for (int j2 = 0; j2 < 2; ++j2) {
        int p = i * 16 + cr;
        int n = n0w + j2 * 16 + cc;
#pragma unroll
        for (int r = 0; r < 4; ++r)
          st[(long)bch * 8192 + (long)(p + r) * 128 + n] = accS[i][j2][r];
      }
  }
}

// ---------------- inter-chunk scan (f32x4 vectorized, in place) ----------------
__global__ void scan_states(float* __restrict__ st, const float* __restrict__ acs)
{
  long idx = (long)blockIdx.x * 256 + threadIdx.x;
  if (idx >= (long)NB * NH * 2048) return;
  long inner = idx & 2047;
  int h = (int)((idx >> 11) & 7);
  int b = (int)(idx >> 14);
  f32x4 carry = {0.f, 0.f, 0.f, 0.f};
  for (int c = 0; c < NCHUNK; ++c) {
    float dc = __expf(acs[(((long)b * NH + h) * NCHUNK + c) * QLEN + (QLEN - 1)]);
    long si = (((long)(b * NCHUNK + c) * NH + h) << 13) + inner * 4;
    f32x4 s = *(f32x4*)&st[si];
    *(f32x4*)&st[si] = carry;
    carry = carry * dc + s;
  }
}

// ---------------- Yo via MFMA: ybf += exp(Acs[q]) * Cbf·prev^T + xh*D ----------------
__global__ __launch_bounds__(256) void yo_combine5(
    const unsigned short* __restrict__ Xbf, const unsigned short* __restrict__ Cbf,
    const float* __restrict__ prev, const float* __restrict__ acs,
    const float* __restrict__ Dp, unsigned short* __restrict__ ybf)
{
  int bid = blockIdx.x;
  int xcd = bid & 7, i0 = bid >> 3;
  int bc = xcd * 8 + (i0 >> 3), h = i0 & 7;
  int c = bc & 3, b = bc >> 2;
  int bch = bc * 8 + h;
  __shared__ float EqA[QLEN];
  const int tid = threadIdx.x;
  const int lane = tid & 63, wv = tid >> 6;
  long rowbase = (long)b * LSEQ + c * QLEN;
  EqA[tid] = __expf(acs[(((long)b * NH + h) * NCHUNK + c) * QLEN + tid]);
  __syncthreads();
  const unsigned short* Cb = Cbf + rowbase * 128;
  const float* pv = prev + (long)bch * 8192;
  f32x4 acc[4][4];
#pragma unroll
  for (int i = 0; i < 4; ++i)
#pragma unroll
    for (int j = 0; j < 4; ++j) acc[i][j] = (f32x4){0.f, 0.f, 0.f, 0.f};
#pragma unroll
  for (int ks = 0; ks < 4; ++ks) {
    int n0 = ks * 32 + (lane >> 4) * 8;
    s16x8 bf[4];
#pragma unroll
    for (int j = 0; j < 4; ++j) {
      int p = j * 16 + (lane & 15);
      f32x4 v0 = *(const f32x4*)&pv[p * 128 + n0];
      f32x4 v1 = *(const f32x4*)&pv[p * 128 + n0 + 4];
#pragma unroll
      for (int t = 0; t < 4; ++t) {
        bf[j][t]     = (short)f2bf(v0[t]);
        bf[j][4 + t] = (short)f2bf(v1[t]);
      }
    }
#pragma unroll
    for (int i = 0; i < 4; ++i) {
      s16x8 af = *(const s16x8*)&Cb[(long)(wv * 64 + i * 16 + (lane & 15)) * 128 + n0];
#pragma unroll
      for (int j = 0; j < 4; ++j)
        acc[i][j] = __builtin_amdgcn_mfma_f32_16x16x32_bf16(af, bf[j], acc[i][j], 0, 0, 0);
    }
  }
  const int cr = (lane >> 4) * 4, cc = lane & 15;
  float Dh = Dp[h];
#pragma unroll
  for (int i = 0; i < 4; ++i)
#pragma unroll
    for (int j = 0; j < 4; ++j) {
      int q = wv * 64 + i * 16 + cr;
      int p = j * 16 + cc;
#pragma unroll
      for (int r = 0; r < 4; ++r) {
        long row = rowbase + q + r;
        long yi = row * DIN + h * HD + p;
        float xh = bf2f(Xbf[yi]);
        float pr = bf2f(ybf[yi]);
        ybf[yi] = f2bf(pr + acc[i][j][r] * EqA[q + r] + xh * Dh);
      }
    }
}

// ---------------- gated RMSNorm in place on ybf (bf16) ----------------
__global__ __launch_bounds__(256) void gated_rms3(
    unsigned short* __restrict__ ybf, const unsigned short* __restrict__ zxb,
    const float* __restrict__ rmsw)
{
  long row = blockIdx.x;
  int t = threadIdx.x;
  ushort2 yv = *(const ushort2*)&ybf[row * DIN + 2 * t];
  ushort2 zv = *(const ushort2*)&zxb[row * DPROJ + 2 * t];
  float z0 = bf2f(zv.x), z1 = bf2f(zv.y);
  float v0 = bf2f(yv.x) * (z0 / (1.f + __expf(-z0)));
  float v1 = bf2f(yv.y) * (z1 / (1.f + __expf(-z1)));
  float ss = v0 * v0 + v1 * v1;
#pragma unroll
  for (int off = 32; off; off >>= 1) ss += __shfl_down(ss, off);
  __shared__ float red[4];
  if ((t & 63) == 0) red[t >> 6] = ss;
  __syncthreads();
  float tot = red[0] + red[1] + red[2] + red[3];
  float scale = rsqrtf(tot * (1.f / DIN) + 1e-5f);
  ushort2 o;
  o.x = f2bf(v0 * scale * rmsw[2 * t]);
  o.y = f2bf(v1 * scale * rmsw[2 * t + 1]);
  *(ushort2*)&ybf[row * DIN + 2 * t] = o;
}

// ---------------- LN + classifier: wave per row, no LDS ----------------
__global__ __launch_bounds__(256) void ln_cls2(
    const unsigned short* __restrict__ y2b, const float* __restrict__ g,
    const float* __restrict__ bb, const float* __restrict__ wclsT,
    const float* __restrict__ bcls, float* __restrict__ out)
{
  long row = (long)blockIdx.x * 4 + (threadIdx.x >> 6);
  int lane = threadIdx.x & 63;
  ushort4 yv = *(const ushort4*)&y2b[row * DM + lane * 4];
  float v0 = bf2f(yv.x), v1 = bf2f(yv.y), v2 = bf2f(yv.z), v3 = bf2f(yv.w);
  float s = v0 + v1 + v2 + v3;
  float q = v0 * v0 + v1 * v1 + v2 * v2 + v3 * v3;
#pragma unroll
  for (int off = 32; off; off >>= 1) {
    s += __shfl_xor(s, off);
    q += __shfl_xor(q, off);
  }
  float mu = s * (1.f / DM);
  float rstd = rsqrtf(q * (1.f / DM) - mu * mu + 1e-5f);
  float4 gv = *(const float4*)&g[lane * 4];
  float4 bv = *(const float4*)&bb[lane * 4];
  float y0 = (v0 - mu) * rstd * gv.x + bv.x;
  float y1 = (v1 - mu) * rstd * gv.y + bv.y;
  float y2_ = (v2 - mu) * rstd * gv.z + bv.z;
  float y3 = (v3 - mu) * rstd * gv.w + bv.w;
  float accs[NCLS];
#pragma unroll
  for (int j = 0; j < NCLS; ++j) {
    float4 wv = *(const float4*)&wclsT[j * 256 + lane * 4];
    accs[j] = y0 * wv.x + y1 * wv.y + y2_ * wv.z + y3 * wv.w;
  }
#pragma unroll
  for (int off = 32; off; off >>= 1)
#pragma unroll
    for (int j = 0; j < NCLS; ++j) accs[j] += __shfl_xor(accs[j], off);
  float o = accs[0] + bcls[0];
#pragma unroll
  for (int j = 1; j < NCLS; ++j)
    if (lane == j) o = accs[j] + bcls[j];
  if (lane < NCLS) out[row * NCLS + lane] = o;
}

extern "C" void kernel_launch(void* const* d_in, const int* in_sizes, int n_in,
                              void* d_out, int out_size, void* d_ws, size_t ws_size,
                              hipStream_t stream)
{
  const float* x     = (const float*)d_in[0];
  const float* w_inp = (const float*)d_in[1];
  const float* b_inp = (const float*)d_in[2];
  const float* w_in  = (const float*)d_in[3];
  const float* convw = (const float*)d_in[4];
  const float* convb = (const float*)d_in[5];
  const float* dtb   = (const float*)d_in[6];
  const float* alog  = (const float*)d_in[7];
  const float* Dp    = (const float*)d_in[8];
  const float* rmsw  = (const float*)d_in[9];
  const float* wout  = (const float*)d_in[10];
  const float* lng   = (const float*)d_in[11];
  const float* lnb   = (const float*)d_in[12];
  const float* wcls  = (const float*)d_in[13];
  const float* bcls  = (const float*)d_in[14];
  float* out = (float*)d_out;
  float* ws  = (float*)d_ws;

  float* dtsp = ws + O_DT;
  float* acs  = ws + O_ACS;
  float* st   = ws + O_ST;
  float* Wdt  = ws + O_WDT;
  float* bdt  = Wdt + 1600;
  float* bfull= ws + O_BFULL;
  float* wclsT= ws + O_WCLST;
  unsigned short* Gbf   = (unsigned short*)(ws + O_GBF);
  unsigned short* zxb   = (unsigned short*)(ws + O_ZX);
  unsigned short* Xbf   = (unsigned short*)(ws + O_XBF);
  unsigned short* Bbf   = (unsigned short*)(ws + O_BBF);
  unsigned short* Cbf   = (unsigned short*)(ws + O_CBF);
  unsigned short* BbfT  = (unsigned short*)(ws + O_BT);
  unsigned short* ybf   = (unsigned short*)(ws + O_YBF);
  unsigned short* xp_bf = (unsigned short*)(ws + O_XPBF);
  unsigned short* WcombT= (unsigned short*)(ws + O_WCT);
  unsigned short* woutT = (unsigned short*)(ws + O_WOUTT);
  unsigned short* y2b   = (unsigned short*)(ws + O_Y2);

  prep_gemm<<<dim3(21, 4), 256, 0, stream>>>(w_inp, w_in, b_inp, WcombT, bfull, Wdt, bdt);
  tcast<<<512, 256, 0, stream>>>(wout, woutT, 9, DM);
  tpose_wcls<<<17, 256, 0, stream>>>(wcls, wclsT);
  cast_pad_x<<<3584, 256, 0, stream>>>(x, xp_bf);
  gemm_bf16<<<dim3(11, 128), 256, 0, stream>>>(xp_bf, WcombT, nullptr, zxb, bfull, 16384, DPROJ, 224);
  conv_silu3<<<12288, 256, 0, stream>>>(zxb, convw, convb, Xbf, Bbf, Cbf);
  dt_cumsum3<<<128, 256, 0, stream>>>(x, Wdt, bdt, dtb, alog, dtsp, acs);
  transB<<<dim3(2, 64), 256, 0, stream>>>(Bbf, BbfT);
  g_gemm_bf16<<<dim3(2, 2, 64), 256, 0, stream>>>(Cbf, Bbf, Gbf);
  yd_states6<<<1024, 256, 0, stream>>>(Xbf, dtsp, acs, Gbf, BbfT, ybf, st);
  scan_states<<<1024, 256, 0, stream>>>(st, acs);
  yo_combine5<<<512, 256, 0, stream>>>(Xbf, Cbf, st, acs, Dp, ybf);
  gated_rms3<<<16384, 256, 0, stream>>>(ybf, zxb, rmsw);
  gemm_bf16<<<dim3(2, 128), 256, 0, stream>>>(ybf, woutT, nullptr, y2b, nullptr, 16384, DM, DIN);
  ln_cls2<<<4096, 256, 0, stream>>>(y2b, lng, lnb, wclsT, bcls, out);
}

// Round 10
// 253.409 us; speedup vs baseline: 4.9622x; 1.0578x over previous
//
#include <hip/hip_runtime.h>
#include <math.h>

#define ROWS   16384L
#define LSEQ   1024
#define NB     16
#define DM     256
#define DPROJ  1288
#define XBCW   768
#define DIN    512
#define DSTATE 128
#define NH     8
#define HD     64
#define QLEN   256
#define NCHUNK 4
#define NCLS   17

typedef __attribute__((ext_vector_type(8))) short s16x8;
typedef __attribute__((ext_vector_type(4))) float f32x4;

#define GLOAD_LDS16(gsrc, ldst) \
  __builtin_amdgcn_global_load_lds((const __attribute__((address_space(1))) void*)(gsrc), \
      (__attribute__((address_space(3))) void*)(ldst), 16, 0, 0)

// ---- workspace map (float slots) ----
constexpr long O_GBF  = 0;                        // Gbf bf16 [64][256][256]
constexpr long O_ZX   = O_GBF + ROWS*DM;          // zxb bf16 [ROWS][1288]
constexpr long O_XBC  = O_ZX  + ROWS*DPROJ;       // region: Xbf/Bbf/Cbf/BbfT bf16
constexpr long O_DT   = O_XBC + ROWS*XBCW;
constexpr long O_ACS  = O_DT  + ROWS*NH;
constexpr long O_Y    = O_ACS + 131072;           // region: ybf bf16 + prep overlays
constexpr long O_ST   = O_Y   + ROWS*DIN;         // st f32 [512][64p][128n]
constexpr long O_Y2   = O_ST  + 4194304;          // y2b bf16 (overlays dead by then)
// O_XBC region overlays (bf16):
constexpr long O_XBF  = O_XBC;                    // Xbf [ROWS][512]
constexpr long O_BBF  = O_XBC + 4200000;          // Bbf [ROWS][128]
constexpr long O_CBF  = O_XBC + 5300000;          // Cbf [ROWS][128]
constexpr long O_BT   = O_XBC + 6400000;          // BbfT [64][128][256]
// O_Y region overlays:
constexpr long O_YBF  = O_Y;                      // ybf [ROWS][512] bf16
constexpr long O_XPBF = O_Y + 4300000;            // xp_bf [ROWS][224] bf16
constexpr long O_WCT  = O_Y + 6200000;            // WcombT [1288][224] bf16
constexpr long O_WOUTT= O_Y + 6400000;            // woutT [256][512] bf16
constexpr long O_WDT  = O_Y + 6500000;            // Wdt[200][8]+bdt[8] f32
constexpr long O_BFULL= O_Y + 6520000;            // bfull [1288] f32
constexpr long O_WCLST= O_Y + 6530000;            // wclsT [17][256] f32

__device__ inline unsigned short f2bf(float f) {
  union { float f; unsigned u; } v; v.f = f;
  unsigned r = v.u + 0x7FFFu + ((v.u >> 16) & 1u);
  return (unsigned short)(r >> 16);
}
__device__ inline float bf2f(unsigned short s) {
  union { unsigned u; float f; } v; v.u = ((unsigned)s) << 16; return v.f;
}

// ---------------- one-shot prep GEMM: Wcomb[k][n] = sum_j A[k][j]*w_in[j][n] ----------
// A row 200 = b_inp. Entire K=256 staged in LDS; single barrier; no serial K tiles.
__global__ __launch_bounds__(256, 1) void prep_gemm2(
    const float* __restrict__ w_inp, const float* __restrict__ w_in,
    const float* __restrict__ b_inp,
    unsigned short* __restrict__ WcombT, float* __restrict__ bfull,
    float* __restrict__ Wdt, float* __restrict__ bdt)
{
  __shared__ float As[256][69];   // [j][k-local]  (stride 69: conflict-free writes)
  __shared__ float Ws[256][72];   // [j][n-local]  (stride 72: aligned float4 reads)
  const int m0 = blockIdx.y * 64;      // k
  const int n0 = blockIdx.x * 64;      // n
  const int tid = threadIdx.x;
  // stage A: thread tid holds j=tid, loops m; coalesced across tid
#pragma unroll 8
  for (int s = 0; s < 64; ++s) {
    int m = m0 + s;
    float v = 0.f;
    if (m < 200)       v = w_inp[(long)m * 256 + tid];
    else if (m == 200) v = b_inp[tid];
    As[tid][s] = v;
  }
  // stage W: e = j*64+n, n fast; coalesced
#pragma unroll 8
  for (int s = 0; s < 64; ++s) {
    int e = tid + s * 256;
    int j = e >> 6, n = n0 + (e & 63);
    Ws[j][e & 63] = (n < DPROJ) ? w_in[(long)j * DPROJ + n] : 0.f;
  }
  __syncthreads();
  const int tm = (tid >> 4) << 2, tn = (tid & 15) << 2;
  float acc[4][4] = {};
  for (int j = 0; j < 256; ++j) {
    float a0 = As[j][tm], a1 = As[j][tm + 1], a2 = As[j][tm + 2], a3 = As[j][tm + 3];
    float4 w4 = *(const float4*)&Ws[j][tn];
    acc[0][0] = fmaf(a0, w4.x, acc[0][0]); acc[0][1] = fmaf(a0, w4.y, acc[0][1]);
    acc[0][2] = fmaf(a0, w4.z, acc[0][2]); acc[0][3] = fmaf(a0, w4.w, acc[0][3]);
    acc[1][0] = fmaf(a1, w4.x, acc[1][0]); acc[1][1] = fmaf(a1, w4.y, acc[1][1]);
    acc[1][2] = fmaf(a1, w4.z, acc[1][2]); acc[1][3] = fmaf(a1, w4.w, acc[1][3]);
    acc[2][0] = fmaf(a2, w4.x, acc[2][0]); acc[2][1] = fmaf(a2, w4.y, acc[2][1]);
    acc[2][2] = fmaf(a2, w4.z, acc[2][2]); acc[2][3] = fmaf(a2, w4.w, acc[2][3]);
    acc[3][0] = fmaf(a3, w4.x, acc[3][0]); acc[3][1] = fmaf(a3, w4.y, acc[3][1]);
    acc[3][2] = fmaf(a3, w4.z, acc[3][2]); acc[3][3] = fmaf(a3, w4.w, acc[3][3]);
  }
#pragma unroll
  for (int i = 0; i < 4; ++i) {
    int k = m0 + tm + i;
#pragma unroll
    for (int t = 0; t < 4; ++t) {
      int n = n0 + tn + t;
      if (n >= DPROJ) continue;
      float v = acc[i][t];
      if (k < 224) WcombT[(long)n * 224 + k] = f2bf(v);
      if (k == 200) {
        bfull[n] = v;
        if (n >= 1280) bdt[n - 1280] = v;
      }
      if (k < 200 && n >= 1280) Wdt[k * 8 + (n - 1280)] = v;
    }
  }
}

// ---------------- transpose+cast: w[K,N] f32 -> wt[N,K] bf16 (K=1<<kbits) ------------
__global__ __launch_bounds__(256) void tcast(const float* __restrict__ w,
                                             unsigned short* __restrict__ wt,
                                             int kbits, int N)
{
  long i = (long)blockIdx.x * 256 + threadIdx.x;
  int K = 1 << kbits;
  if (i >= (long)K * N) return;
  int k = (int)(i & (K - 1));
  long n = i >> kbits;
  wt[i] = f2bf(w[(long)k * N + n]);
}

// ---------------- wcls [256][17] -> wclsT [17][256] f32 ----------------
__global__ __launch_bounds__(256) void tpose_wcls(const float* __restrict__ wcls,
                                                  float* __restrict__ wclsT)
{
  int i = blockIdx.x * 256 + threadIdx.x;
  if (i >= NCLS * 256) return;
  int j = i >> 8, k = i & 255;
  wclsT[i] = wcls[(long)k * NCLS + j];
}

// ---------------- pad+cast x: [ROWS][200] f32 -> [ROWS][224] bf16 ----------------
__global__ __launch_bounds__(256) void cast_pad_x(const float* __restrict__ x,
                                                  unsigned short* __restrict__ xp)
{
  long idx = (long)blockIdx.x * 256 + threadIdx.x;
  if (idx >= ROWS * 56) return;
  int q = (int)(idx % 56);
  long row = idx / 56;
  ushort4 o = {0, 0, 0, 0};
  if (q < 50) {
    float4 v = *(const float4*)&x[row * 200 + q * 4];
    o.x = f2bf(v.x); o.y = f2bf(v.y); o.z = f2bf(v.z); o.w = f2bf(v.w);
  }
  *(ushort4*)&xp[row * 224 + q * 4] = o;
}

// ---------------- bf16 MFMA GEMM (global_load_lds staging) ----------------
__global__ __launch_bounds__(256) void gemm_bf16(
    const unsigned short* __restrict__ A, const unsigned short* __restrict__ BT,
    float* __restrict__ C, unsigned short* __restrict__ Cb,
    const float* __restrict__ bias, int M, int N, int K)
{
  __shared__ __align__(16) unsigned short As[128 * 32];
  __shared__ __align__(16) unsigned short Bs[128 * 32];
  const int tid = threadIdx.x;
  const int m0 = blockIdx.y * 128, n0 = blockIdx.x * 128;
  const int lane = tid & 63, wv = tid >> 6;
  const int wr = (wv >> 1) * 64, wc = (wv & 1) * 64;
  f32x4 acc[4][4];
#pragma unroll
  for (int i = 0; i < 4; ++i)
#pragma unroll
    for (int j = 0; j < 4; ++j) acc[i][j] = (f32x4){0.f, 0.f, 0.f, 0.f};

  for (int k0 = 0; k0 < K; k0 += 32) {
    __syncthreads();
#pragma unroll
    for (int s = 0; s < 2; ++s) {
      int idx = (tid + 256 * s) * 8;
      int r = idx >> 5, kk = idx & 31;
      GLOAD_LDS16(&A[(long)(m0 + r) * K + k0 + kk], &As[idx]);
    }
#pragma unroll
    for (int s = 0; s < 2; ++s) {
      int idx = (tid + 256 * s) * 8;
      int n = idx >> 5, kk = idx & 31;
      int srcn = (n0 + n < N) ? (n0 + n) : 0;
      GLOAD_LDS16(&BT[(long)srcn * K + k0 + kk], &Bs[idx]);
    }
    __syncthreads();
    s16x8 af[4], bf[4];
#pragma unroll
    for (int i = 0; i < 4; ++i)
      af[i] = *(const s16x8*)&As[(wr + i * 16 + (lane & 15)) * 32 + (lane >> 4) * 8];
#pragma unroll
    for (int j = 0; j < 4; ++j)
      bf[j] = *(const s16x8*)&Bs[(wc + j * 16 + (lane & 15)) * 32 + (lane >> 4) * 8];
#pragma unroll
    for (int i = 0; i < 4; ++i)
#pragma unroll
      for (int j = 0; j < 4; ++j)
        acc[i][j] = __builtin_amdgcn_mfma_f32_16x16x32_bf16(af[i], bf[j], acc[i][j], 0, 0, 0);
  }
  const int cr = (lane >> 4) * 4, cc = lane & 15;
#pragma unroll
  for (int i = 0; i < 4; ++i)
#pragma unroll
    for (int j = 0; j < 4; ++j) {
      int col = n0 + wc + j * 16 + cc;
      if (col < N) {
        long rowb = (long)(m0 + wr + i * 16 + cr);
        float bv = bias ? bias[col] : 0.f;
#pragma unroll
        for (int r = 0; r < 4; ++r) {
          float v = acc[i][j][r] + bv;
          if (C)  C[(rowb + r) * N + col] = v;
          if (Cb) Cb[(rowb + r) * (long)N + col] = f2bf(v);
        }
      }
    }
}

// ---------------- G = C·B^T per (b,c) -> bf16 causal-masked ----------------
__global__ __launch_bounds__(256) void g_gemm_bf16(
    const unsigned short* __restrict__ Cbf, const unsigned short* __restrict__ Bbf,
    unsigned short* __restrict__ Gbf)
{
  int bc = blockIdx.z;
  unsigned short* Gout = Gbf + (long)bc * 65536;
  const int tid = threadIdx.x;
  const int m0 = blockIdx.y * 128, n0 = blockIdx.x * 128;
  if (blockIdx.x > blockIdx.y) {
    s16x8 z = {};
    for (int e = tid; e < 128 * 16; e += 256) {
      int r = e >> 4, seg = e & 15;
      *(s16x8*)&Gout[(long)(m0 + r) * 256 + n0 + seg * 8] = z;
    }
    return;
  }
  long rowbase = (long)(bc >> 2) * LSEQ + (bc & 3) * QLEN;
  const unsigned short* A  = Cbf + rowbase * 128;
  const unsigned short* BT = Bbf + rowbase * 128;
  __shared__ __align__(16) unsigned short As[128 * 32];
  __shared__ __align__(16) unsigned short Bs[128 * 32];
  const int lane = tid & 63, wv = tid >> 6;
  const int wr = (wv >> 1) * 64, wc = (wv & 1) * 64;
  f32x4 acc[4][4];
#pragma unroll
  for (int i = 0; i < 4; ++i)
#pragma unroll
    for (int j = 0; j < 4; ++j) acc[i][j] = (f32x4){0.f, 0.f, 0.f, 0.f};
  for (int k0 = 0; k0 < 128; k0 += 32) {
    __syncthreads();
#pragma unroll
    for (int s = 0; s < 2; ++s) {
      int idx = (tid + 256 * s) * 8;
      int r = idx >> 5, kk = idx & 31;
      GLOAD_LDS16(&A[(long)(m0 + r) * 128 + k0 + kk], &As[idx]);
      GLOAD_LDS16(&BT[(long)(n0 + r) * 128 + k0 + kk], &Bs[idx]);
    }
    __syncthreads();
    s16x8 af[4], bf[4];
#pragma unroll
    for (int i = 0; i < 4; ++i)
      af[i] = *(const s16x8*)&As[(wr + i * 16 + (lane & 15)) * 32 + (lane >> 4) * 8];
#pragma unroll
    for (int j = 0; j < 4; ++j)
      bf[j] = *(const s16x8*)&Bs[(wc + j * 16 + (lane & 15)) * 32 + (lane >> 4) * 8];
#pragma unroll
    for (int i = 0; i < 4; ++i)
#pragma unroll
      for (int j = 0; j < 4; ++j)
        acc[i][j] = __builtin_amdgcn_mfma_f32_16x16x32_bf16(af[i], bf[j], acc[i][j], 0, 0, 0);
  }
  const int cr = (lane >> 4) * 4, cc = lane & 15;
#pragma unroll
  for (int i = 0; i < 4; ++i)
#pragma unroll
    for (int j = 0; j < 4; ++j) {
      int col = n0 + wc + j * 16 + cc;
      int qb = m0 + wr + i * 16 + cr;
#pragma unroll
      for (int r = 0; r < 4; ++r)
        Gout[(long)(qb + r) * 256 + col] = (col <= qb + r) ? f2bf(acc[i][j][r]) : (unsigned short)0;
    }
}

// ---------------- conv1d (k=4, causal) + SiLU -> bf16 Xbf/Bbf/Cbf ----------------
__global__ __launch_bounds__(256) void conv_silu3(
    const unsigned short* __restrict__ zxb, const float* __restrict__ cw,
    const float* __restrict__ cb,
    unsigned short* __restrict__ Xbf, unsigned short* __restrict__ Bbf,
    unsigned short* __restrict__ Cbf)
{
  long idx = (long)blockIdx.x * 256 + threadIdx.x;
  if (idx >= ROWS * 192) return;
  int cq = (int)(idx % 192);
  long row = idx / 192;
  int t = (int)(row & 1023);
  int ch = cq * 4;
  float4 cbv = *(const float4*)&cb[ch];
  float a0 = cbv.x, a1 = cbv.y, a2 = cbv.z, a3 = cbv.w;
#pragma unroll
  for (int w = 0; w < 4; ++w) {
    int d = w - 3;
    if (t + d >= 0) {
      ushort4 zv = *(const ushort4*)&zxb[(row + d) * DPROJ + 512 + ch];
      float4 cwv = *(const float4*)&cw[w * XBCW + ch];
      a0 = fmaf(bf2f(zv.x), cwv.x, a0);
      a1 = fmaf(bf2f(zv.y), cwv.y, a1);
      a2 = fmaf(bf2f(zv.z), cwv.z, a2);
      a3 = fmaf(bf2f(zv.w), cwv.w, a3);
    }
  }
  ushort4 o;
  o.x = f2bf(a0 / (1.f + __expf(-a0)));
  o.y = f2bf(a1 / (1.f + __expf(-a1)));
  o.z = f2bf(a2 / (1.f + __expf(-a2)));
  o.w = f2bf(a3 / (1.f + __expf(-a3)));
  if (ch < 512)      *(ushort4*)&Xbf[row * DIN + ch] = o;
  else if (ch < 640) *(ushort4*)&Bbf[row * 128 + ch - 512] = o;
  else               *(ushort4*)&Cbf[row * 128 + ch - 640] = o;
}

// ---------------- dt logits: block = 32 rows, LDS-staged x and Wdt; f32-exact --------
__global__ __launch_bounds__(256) void dt_logits(
    const float* __restrict__ x, const float* __restrict__ Wdt,
    const float* __restrict__ bdt, const float* __restrict__ dtb,
    float* __restrict__ dtsp)
{
  __shared__ float xs[32][201];
  __shared__ float wdt_s[1600];
  long row0 = (long)blockIdx.x * 32;
  int tid = threadIdx.x;
#pragma unroll
  for (int s = 0; s < 25; ++s) {                    // 32*200 = 6400 = 25*256
    int e = tid + s * 256;
    int r = e / 200, c = e % 200;
    xs[r][c] = x[(row0 + r) * 200 + c];
  }
#pragma unroll
  for (int s = 0; s < 7; ++s) {                     // 1600 <= 7*256
    int e = tid + s * 256;
    if (e < 1600) wdt_s[e] = Wdt[e];
  }
  __syncthreads();
  int r = tid >> 3, h = tid & 7;
  float acc = dtb[h] + bdt[h];
  for (int i = 0; i < 200; ++i)
    acc = fmaf(xs[r][i], wdt_s[i * 8 + h], acc);
  float sp = (acc > 20.f) ? acc : log1pf(__expf(acc));
  dtsp[(row0 + r) * NH + h] = sp;
}

// ---------------- cumsum only: wave per (b,h,c) ----------------
__global__ __launch_bounds__(256) void dt_cumsum4(
    const float* __restrict__ dtsp, const float* __restrict__ alog,
    float* __restrict__ acs)
{
  int g = ((int)blockIdx.x * 256 + (int)threadIdx.x) >> 6;
  int lane = threadIdx.x & 63;
  int c = g & 3, h = (g >> 2) & 7, b = g >> 5;
  float Ah = -__expf(alog[h]);
  long rowbase = (long)b * LSEQ + c * QLEN;
  long abase = (((long)b * NH + h) * NCHUNK + c) * QLEN;
  float v[4];
#pragma unroll
  for (int j = 0; j < 4; ++j)
    v[j] = dtsp[(rowbase + lane * 4 + j) * NH + h] * Ah;
  v[1] += v[0]; v[2] += v[1]; v[3] += v[2];
  float tot = v[3];
  float run = tot;
#pragma unroll
  for (int d = 1; d < 64; d <<= 1) {
    float t = __shfl_up(run, d);
    if (lane >= d) run += t;
  }
  float excl = run - tot;
#pragma unroll
  for (int j = 0; j < 4; ++j) acs[abase + lane * 4 + j] = excl + v[j];
}

// ---------------- Bbf [ROWS][128] -> BbfT [bc][128][256] ----------------
__global__ __launch_bounds__(256) void transB(const unsigned short* __restrict__ Bbf,
                                              unsigned short* __restrict__ BbfT)
{
  __shared__ unsigned short T[128][130];
  int bc = blockIdx.y, kh = blockIdx.x;
  int tid = threadIdx.x;
  long rowbase = (long)(bc >> 2) * LSEQ + (bc & 3) * QLEN + kh * 128;
  for (int e = tid; e < 128 * 128; e += 256) {
    int r = e >> 7, n = e & 127;
    T[r][n] = Bbf[(rowbase + r) * 128 + n];
  }
  __syncthreads();
  for (int e = tid; e < 128 * 128; e += 256) {
    int n = e >> 7, k = e & 127;
    BbfT[((long)bc * 128 + n) * 256 + kh * 128 + k] = T[k][n];
  }
}

// ---------------- yd+states: full XdT staged once, pure-MFMA k loop ----------------
__global__ __launch_bounds__(256) void yd_states6(
    const unsigned short* __restrict__ Xbf, const float* __restrict__ dtsp,
    const float* __restrict__ acs, const unsigned short* __restrict__ Gbf,
    const unsigned short* __restrict__ BbfT,
    unsigned short* __restrict__ ybf, float* __restrict__ st)
{
  int bid = blockIdx.x;
  int xcd = bid & 7, i0 = bid >> 3;
  int bc = xcd * 8 + (i0 >> 4);
  int rem = i0 & 15, h = rem >> 1, half = rem & 1;
  int c = bc & 3, b = bc >> 2;
  int bch = bc * 8 + h;

  __shared__ __align__(16) unsigned short XdT[64][264];
  __shared__ float AcsS[256], E1f[256], E2f[256], dts[256];

  const int tid = threadIdx.x;
  const int lane = tid & 63, wv = tid >> 6;
  const bool ydw = wv < 2;
  const int q0 = half * 128 + wv * 64;
  const int myqt = half * 2 + wv;
  const int n0w = half * 64 + (wv - 2) * 32;
  long rowbase = (long)b * LSEQ + c * QLEN;
  const unsigned short* Gb  = Gbf + (long)bc * 65536;
  const unsigned short* BTg = BbfT + (long)bc * 32768;

  AcsS[tid] = acs[(((long)b * NH + h) * NCHUNK + c) * QLEN + tid];
  dts[tid]  = dtsp[(rowbase + tid) * NH + h];
  __syncthreads();
  E1f[tid] = __expf(AcsS[tid] - AcsS[tid | 63]);
  E2f[tid] = __expf(AcsS[tid | 63] - AcsS[tid]);
  float rs_[4];
  rs_[0] = 1.f;
#pragma unroll
  for (int kt = 1; kt < 4; ++kt) rs_[kt] = __expf(AcsS[kt * 64 + 63] - AcsS[kt * 64 - 1]);
  __syncthreads();
  {
    int kb = wv * 64;
#pragma unroll
    for (int s = 0; s < 16; ++s) {
      int k4 = kb + s * 4;
      ushort4 pk;
      unsigned short* pp = (unsigned short*)&pk;
#pragma unroll
      for (int j = 0; j < 4; ++j) {
        int k = k4 + j;
        float v = bf2f(Xbf[(rowbase + k) * DIN + h * HD + lane]) * dts[k] * E2f[k];
        pp[j] = f2bf(v);
      }
      *(ushort4*)&XdT[lane][k4] = pk;
    }
  }
  __syncthreads();

  f32x4 accY[4][4], accS[4][2];
#pragma unroll
  for (int i = 0; i < 4; ++i)
#pragma unroll
    for (int j = 0; j < 4; ++j) accY[i][j] = (f32x4){0.f, 0.f, 0.f, 0.f};
#pragma unroll
  for (int i = 0; i < 4; ++i)
#pragma unroll
    for (int j = 0; j < 2; ++j) accS[i][j] = (f32x4){0.f, 0.f, 0.f, 0.f};

  for (int kt = 0; kt < 4; ++kt) {
    int qlo = kt * 64;
    if (ydw) {
      if (myqt >= kt) {
        if (kt)
#pragma unroll
          for (int i = 0; i < 4; ++i)
#pragma unroll
            for (int j = 0; j < 4; ++j) accY[i][j] *= rs_[kt];
#pragma unroll
        for (int ks = 0; ks < 2; ++ks) {
          s16x8 bfr[4];
#pragma unroll
          for (int j = 0; j < 4; ++j)
            bfr[j] = *(const s16x8*)&XdT[j * 16 + (lane & 15)][qlo + ks * 32 + (lane >> 4) * 8];
#pragma unroll
          for (int i = 0; i < 4; ++i) {
            s16x8 a = *(const s16x8*)&Gb[(long)(q0 + i * 16 + (lane & 15)) * 256 + qlo + ks * 32 + (lane >> 4) * 8];
#pragma unroll
            for (int j = 0; j < 4; ++j)
              accY[i][j] = __builtin_amdgcn_mfma_f32_16x16x32_bf16(a, bfr[j], accY[i][j], 0, 0, 0);
          }
        }
      }
    } else {
      if (kt)
#pragma unroll
        for (int i = 0; i < 4; ++i)
#pragma unroll
          for (int j = 0; j < 2; ++j) accS[i][j] *= rs_[kt];
#pragma unroll
      for (int ks = 0; ks < 2; ++ks) {
        s16x8 afx[4];
#pragma unroll
        for (int i = 0; i < 4; ++i)
          afx[i] = *(const s16x8*)&XdT[i * 16 + (lane & 15)][qlo + ks * 32 + (lane >> 4) * 8];
#pragma unroll
        for (int j2 = 0; j2 < 2; ++j2) {
          s16x8 bt = *(const s16x8*)&BTg[(long)(n0w + j2 * 16 + (lane & 15)) * 256 + qlo + ks * 32 + (lane >> 4) * 8];
#pragma unroll
          for (int i = 0; i < 4; ++i)
            accS[i][j2] = __builtin_amdgcn_mfma_f32_16x16x32_bf16(afx[i], bt, accS[i][j2], 0, 0, 0);
        }
      }
    }
  }
  const int cr = (lane >> 4) * 4, cc = lane & 15;
  if (ydw) {
#pragma unroll
    for (int i = 0; i < 4; ++i)
#pragma unroll
      for (int j = 0; j < 4; ++j) {
        int q = q0 + i * 16 + cr;
        int p = j * 16 + cc;
#pragma unroll
        for (int r = 0; r < 4; ++r)
          ybf[(rowbase + q + r) * DIN + h * HD + p] = f2bf(accY[i][j][r] * E1f[q + r]);
      }
  } else {
#pragma unroll
    for (int i = 0; i < 4; ++i)
#pragma unroll
      for (int j2 = 0; j2 < 2; ++j2) {
        int p = i * 16 + cr;
        int n = n0w + j2 * 16 + cc;
#pragma unroll
        for (int r = 0; r < 4; ++r)
          st[(long)bch * 8192 + (long)(p + r) * 128 + n] = accS[i][j2][r];
      }
  }
}

// ---------------- inter-chunk scan (f32x4 vectorized, in place) ----------------
__global__ void scan_states(float* __restrict__ st, const float* __restrict__ acs)
{
  long idx = (long)blockIdx.x * 256 + threadIdx.x;
  if (idx >= (long)NB * NH * 2048) return;
  long inner = idx & 2047;
  int h = (int)((idx >> 11) & 7);
  int b = (int)(idx >> 14);
  f32x4 carry = {0.f, 0.f, 0.f, 0.f};
  for (int c = 0; c < NCHUNK; ++c) {
    float dc = __expf(acs[(((long)b * NH + h) * NCHUNK + c) * QLEN + (QLEN - 1)]);
    long si = (((long)(b * NCHUNK + c) * NH + h) << 13) + inner * 4;
    f32x4 s = *(f32x4*)&st[si];
    *(f32x4*)&st[si] = carry;
    carry = carry * dc + s;
  }
}

// ---------------- Yo via MFMA: ybf += exp(Acs[q]) * Cbf·prev^T + xh*D ----------------
__global__ __launch_bounds__(256) void yo_combine5(
    const unsigned short* __restrict__ Xbf, const unsigned short* __restrict__ Cbf,
    const float* __restrict__ prev, const float* __restrict__ acs,
    const float* __restrict__ Dp, unsigned short* __restrict__ ybf)
{
  int bid = blockIdx.x;
  int xcd = bid & 7, i0 = bid >> 3;
  int bc = xcd * 8 + (i0 >> 3), h = i0 & 7;
  int c = bc & 3, b = bc >> 2;
  int bch = bc * 8 + h;
  __shared__ float EqA[QLEN];
  const int tid = threadIdx.x;
  const int lane = tid & 63, wv = tid >> 6;
  long rowbase = (long)b * LSEQ + c * QLEN;
  EqA[tid] = __expf(acs[(((long)b * NH + h) * NCHUNK + c) * QLEN + tid]);
  __syncthreads();
  const unsigned short* Cb = Cbf + rowbase * 128;
  const float* pv = prev + (long)bch * 8192;
  f32x4 acc[4][4];
#pragma unroll
  for (int i = 0; i < 4; ++i)
#pragma unroll
    for (int j = 0; j < 4; ++j) acc[i][j] = (f32x4){0.f, 0.f, 0.f, 0.f};
#pragma unroll
  for (int ks = 0; ks < 4; ++ks) {
    int n0 = ks * 32 + (lane >> 4) * 8;
    s16x8 bf[4];
#pragma unroll
    for (int j = 0; j < 4; ++j) {
      int p = j * 16 + (lane & 15);
      f32x4 v0 = *(const f32x4*)&pv[p * 128 + n0];
      f32x4 v1 = *(const f32x4*)&pv[p * 128 + n0 + 4];
#pragma unroll
      for (int t = 0; t < 4; ++t) {
        bf[j][t]     = (short)f2bf(v0[t]);
        bf[j][4 + t] = (short)f2bf(v1[t]);
      }
    }
#pragma unroll
    for (int i = 0; i < 4; ++i) {
      s16x8 af = *(const s16x8*)&Cb[(long)(wv * 64 + i * 16 + (lane & 15)) * 128 + n0];
#pragma unroll
      for (int j = 0; j < 4; ++j)
        acc[i][j] = __builtin_amdgcn_mfma_f32_16x16x32_bf16(af, bf[j], acc[i][j], 0, 0, 0);
    }
  }
  const int cr = (lane >> 4) * 4, cc = lane & 15;
  float Dh = Dp[h];
#pragma unroll
  for (int i = 0; i < 4; ++i)
#pragma unroll
    for (int j = 0; j < 4; ++j) {
      int q = wv * 64 + i * 16 + cr;
      int p = j * 16 + cc;
#pragma unroll
      for (int r = 0; r < 4; ++r) {
        long row = rowbase + q + r;
        long yi = row * DIN + h * HD + p;
        float xh = bf2f(Xbf[yi]);
        float pr = bf2f(ybf[yi]);
        ybf[yi] = f2bf(pr + acc[i][j][r] * EqA[q + r] + xh * Dh);
      }
    }
}

// ---------------- gated RMSNorm in place on ybf (bf16) ----------------
__global__ __launch_bounds__(256) void gated_rms3(
    unsigned short* __restrict__ ybf, const unsigned short* __restrict__ zxb,
    const float* __restrict__ rmsw)
{
  long row = blockIdx.x;
  int t = threadIdx.x;
  ushort2 yv = *(const ushort2*)&ybf[row * DIN + 2 * t];
  ushort2 zv = *(const ushort2*)&zxb[row * DPROJ + 2 * t];
  float z0 = bf2f(zv.x), z1 = bf2f(zv.y);
  float v0 = bf2f(yv.x) * (z0 / (1.f + __expf(-z0)));
  float v1 = bf2f(yv.y) * (z1 / (1.f + __expf(-z1)));
  float ss = v0 * v0 + v1 * v1;
#pragma unroll
  for (int off = 32; off; off >>= 1) ss += __shfl_down(ss, off);
  __shared__ float red[4];
  if ((t & 63) == 0) red[t >> 6] = ss;
  __syncthreads();
  float tot = red[0] + red[1] + red[2] + red[3];
  float scale = rsqrtf(tot * (1.f / DIN) + 1e-5f);
  ushort2 o;
  o.x = f2bf(v0 * scale * rmsw[2 * t]);
  o.y = f2bf(v1 * scale * rmsw[2 * t + 1]);
  *(ushort2*)&ybf[row * DIN + 2 * t] = o;
}

// ---------------- LN + classifier: wave per row, no LDS ----------------
__global__ __launch_bounds__(256) void ln_cls2(
    const unsigned short* __restrict__ y2b, const float* __restrict__ g,
    const float* __restrict__ bb, const float* __restrict__ wclsT,
    const float* __restrict__ bcls, float* __restrict__ out)
{
  long row = (long)blockIdx.x * 4 + (threadIdx.x >> 6);
  int lane = threadIdx.x & 63;
  ushort4 yv = *(const ushort4*)&y2b[row * DM + lane * 4];
  float v0 = bf2f(yv.x), v1 = bf2f(yv.y), v2 = bf2f(yv.z), v3 = bf2f(yv.w);
  float s = v0 + v1 + v2 + v3;
  float q = v0 * v0 + v1 * v1 + v2 * v2 + v3 * v3;
#pragma unroll
  for (int off = 32; off; off >>= 1) {
    s += __shfl_xor(s, off);
    q += __shfl_xor(q, off);
  }
  float mu = s * (1.f / DM);
  float rstd = rsqrtf(q * (1.f / DM) - mu * mu + 1e-5f);
  float4 gv = *(const float4*)&g[lane * 4];
  float4 bv = *(const float4*)&bb[lane * 4];
  float y0 = (v0 - mu) * rstd * gv.x + bv.x;
  float y1 = (v1 - mu) * rstd * gv.y + bv.y;
  float y2_ = (v2 - mu) * rstd * gv.z + bv.z;
  float y3 = (v3 - mu) * rstd * gv.w + bv.w;
  float accs[NCLS];
#pragma unroll
  for (int j = 0; j < NCLS; ++j) {
    float4 wv = *(const float4*)&wclsT[j * 256 + lane * 4];
    accs[j] = y0 * wv.x + y1 * wv.y + y2_ * wv.z + y3 * wv.w;
  }
#pragma unroll
  for (int off = 32; off; off >>= 1)
#pragma unroll
    for (int j = 0; j < NCLS; ++j) accs[j] += __shfl_xor(accs[j], off);
  float o = accs[0] + bcls[0];
#pragma unroll
  for (int j = 1; j < NCLS; ++j)
    if (lane == j) o = accs[j] + bcls[j];
  if (lane < NCLS) out[row * NCLS + lane] = o;
}

extern "C" void kernel_launch(void* const* d_in, const int* in_sizes, int n_in,
                              void* d_out, int out_size, void* d_ws, size_t ws_size,
                              hipStream_t stream)
{
  const float* x     = (const float*)d_in[0];
  const float* w_inp = (const float*)d_in[1];
  const float* b_inp = (const float*)d_in[2];
  const float* w_in  = (const float*)d_in[3];
  const float* convw = (const float*)d_in[4];
  const float* convb = (const float*)d_in[5];
  const float* dtb   = (const float*)d_in[6];
  const float* alog  = (const float*)d_in[7];
  const float* Dp    = (const float*)d_in[8];
  const float* rmsw  = (const float*)d_in[9];
  const float* wout  = (const float*)d_in[10];
  const float* lng   = (const float*)d_in[11];
  const float* lnb   = (const float*)d_in[12];
  const float* wcls  = (const float*)d_in[13];
  const float* bcls  = (const float*)d_in[14];
  float* out = (float*)d_out;
  float* ws  = (float*)d_ws;

  float* dtsp = ws + O_DT;
  float* acs  = ws + O_ACS;
  float* st   = ws + O_ST;
  float* Wdt  = ws + O_WDT;
  float* bdt  = Wdt + 1600;
  float* bfull= ws + O_BFULL;
  float* wclsT= ws + O_WCLST;
  unsigned short* Gbf   = (unsigned short*)(ws + O_GBF);
  unsigned short* zxb   = (unsigned short*)(ws + O_ZX);
  unsigned short* Xbf   = (unsigned short*)(ws + O_XBF);
  unsigned short* Bbf   = (unsigned short*)(ws + O_BBF);
  unsigned short* Cbf   = (unsigned short*)(ws + O_CBF);
  unsigned short* BbfT  = (unsigned short*)(ws + O_BT);
  unsigned short* ybf   = (unsigned short*)(ws + O_YBF);
  unsigned short* xp_bf = (unsigned short*)(ws + O_XPBF);
  unsigned short* WcombT= (unsigned short*)(ws + O_WCT);
  unsigned short* woutT = (unsigned short*)(ws + O_WOUTT);
  unsigned short* y2b   = (unsigned short*)(ws + O_Y2);

  prep_gemm2<<<dim3(21, 4), 256, 0, stream>>>(w_inp, w_in, b_inp, WcombT, bfull, Wdt, bdt);
  tcast<<<512, 256, 0, stream>>>(wout, woutT, 9, DM);
  tpose_wcls<<<17, 256, 0, stream>>>(wcls, wclsT);
  cast_pad_x<<<3584, 256, 0, stream>>>(x, xp_bf);
  gemm_bf16<<<dim3(11, 128), 256, 0, stream>>>(xp_bf, WcombT, nullptr, zxb, bfull, 16384, DPROJ, 224);
  conv_silu3<<<12288, 256, 0, stream>>>(zxb, convw, convb, Xbf, Bbf, Cbf);
  dt_logits<<<512, 256, 0, stream>>>(x, Wdt, bdt, dtb, dtsp);
  dt_cumsum4<<<128, 256, 0, stream>>>(dtsp, alog, acs);
  transB<<<dim3(2, 64), 256, 0, stream>>>(Bbf, BbfT);
  g_gemm_bf16<<<dim3(2, 2, 64), 256, 0, stream>>>(Cbf, Bbf, Gbf);
  yd_states6<<<1024, 256, 0, stream>>>(Xbf, dtsp, acs, Gbf, BbfT, ybf, st);
  scan_states<<<1024, 256, 0, stream>>>(st, acs);
  yo_combine5<<<512, 256, 0, stream>>>(Xbf, Cbf, st, acs, Dp, ybf);
  gated_rms3<<<16384, 256, 0, stream>>>(ybf, zxb, rmsw);
  gemm_bf16<<<dim3(2, 128), 256, 0, stream>>>(ybf, woutT, nullptr, y2b, nullptr, 16384, DM, DIN);
  ln_cls2<<<4096, 256, 0, stream>>>(y2b, lng, lnb, wclsT, bcls, out);
}

// Round 11
// 228.204 us; speedup vs baseline: 5.5103x; 1.1104x over previous
//
#include <hip/hip_runtime.h>
#include <math.h>

#define ROWS   16384L
#define LSEQ   1024
#define NB     16
#define DM     256
#define DPROJ  1288
#define XBCW   768
#define DIN    512
#define DSTATE 128
#define NH     8
#define HD     64
#define QLEN   256
#define NCHUNK 4
#define NCLS   17

typedef __attribute__((ext_vector_type(8))) short s16x8;
typedef __attribute__((ext_vector_type(4))) float f32x4;

#define GLOAD_LDS16(gsrc, ldst) \
  __builtin_amdgcn_global_load_lds((const __attribute__((address_space(1))) void*)(gsrc), \
      (__attribute__((address_space(3))) void*)(ldst), 16, 0, 0)

// ---- workspace map (float slots) ----
constexpr long O_GBF  = 0;                        // Gbf bf16 [64][256][256]
constexpr long O_ZX   = O_GBF + ROWS*DM;          // zxb bf16 [ROWS][1288]
constexpr long O_XBC  = O_ZX  + ROWS*DPROJ;       // region: Xbf/Bbf/Cbf/BbfT bf16
constexpr long O_DT   = O_XBC + ROWS*XBCW;
constexpr long O_ACS  = O_DT  + ROWS*NH;
constexpr long O_Y    = O_ACS + 131072;           // region: ybf bf16 + prep overlays
constexpr long O_ST   = O_Y   + ROWS*DIN;         // st f32 [512][64p][128n]
constexpr long O_Y2   = O_ST  + 4194304;          // y2b bf16 (overlays dead by then)
// O_XBC region overlays (bf16):
constexpr long O_XBF  = O_XBC;                    // Xbf [ROWS][512]
constexpr long O_BBF  = O_XBC + 4200000;          // Bbf [ROWS][128]
constexpr long O_CBF  = O_XBC + 5300000;          // Cbf [ROWS][128]
constexpr long O_BT   = O_XBC + 6400000;          // BbfT [64][128][256]
// O_Y region overlays:
constexpr long O_YBF  = O_Y;                      // ybf [ROWS][512] bf16
constexpr long O_XPBF = O_Y + 4300000;            // xp_bf [ROWS][224] bf16
constexpr long O_WCT  = O_Y + 6200000;            // WcombT [1408][224] bf16 (157696 fl)
constexpr long O_WOUTT= O_Y + 6400000;            // woutT [256][512] bf16
constexpr long O_WDT  = O_Y + 6500000;            // Wdt[200][8]+bdt[8] f32
constexpr long O_WCLST= O_Y + 6530000;            // wclsT [17][256] f32
constexpr long O_WINT = O_Y + 6600000;            // w_inT [1408][256] bf16 (180224 fl)
constexpr long O_WIPE = O_Y + 6800000;            // w_inp_ext [224][256] bf16

__device__ inline unsigned short f2bf(float f) {
  union { float f; unsigned u; } v; v.f = f;
  unsigned r = v.u + 0x7FFFu + ((v.u >> 16) & 1u);
  return (unsigned short)(r >> 16);
}
__device__ inline float bf2f(unsigned short s) {
  union { unsigned u; float f; } v; v.u = ((unsigned)s) << 16; return v.f;
}

// ---------------- transpose+cast: w[K,N] f32 -> wt[N,K] bf16 (K=1<<kbits) ------------
__global__ __launch_bounds__(256) void tcast(const float* __restrict__ w,
                                             unsigned short* __restrict__ wt,
                                             int kbits, int N)
{
  long i = (long)blockIdx.x * 256 + threadIdx.x;
  int K = 1 << kbits;
  if (i >= (long)K * N) return;
  int k = (int)(i & (K - 1));
  long n = i >> kbits;
  wt[i] = f2bf(w[(long)k * N + n]);
}

// ---------------- w_inp_ext [224][256] bf16: rows<200 = w_inp, row200 = b_inp --------
__global__ __launch_bounds__(256) void cast_winp_ext(
    const float* __restrict__ w_inp, const float* __restrict__ b_inp,
    unsigned short* __restrict__ we)
{
  int i = blockIdx.x * 256 + threadIdx.x;          // 224*256 = 57344
  if (i >= 224 * 256) return;
  int k = i >> 8, j = i & 255;
  float v = 0.f;
  if (k < 200)       v = w_inp[(long)k * 256 + j];
  else if (k == 200) v = b_inp[j];
  we[i] = f2bf(v);
}

// ---------------- Wdt/bdt f32 (exact dt path): wave per k-row ----------------
__global__ __launch_bounds__(256) void wdt_small(
    const float* __restrict__ w_inp, const float* __restrict__ w_in,
    const float* __restrict__ b_inp,
    float* __restrict__ Wdt, float* __restrict__ bdt)
{
  int k = blockIdx.x * 4 + (threadIdx.x >> 6);
  if (k > 200) return;
  int lane = threadIdx.x & 63;
  int j0 = lane * 4;
  float4 xv = (k < 200) ? *(const float4*)&w_inp[(long)k * 256 + j0]
                        : *(const float4*)&b_inp[j0];
  float a0 = 0.f, a1 = 0.f, a2 = 0.f, a3 = 0.f, a4 = 0.f, a5 = 0.f, a6 = 0.f, a7 = 0.f;
  float xd[4] = {xv.x, xv.y, xv.z, xv.w};
#pragma unroll
  for (int d = 0; d < 4; ++d) {
    const float* wr = &w_in[(long)(j0 + d) * DPROJ + 1280];
    float4 wa = *(const float4*)wr;
    float4 wb = *(const float4*)(wr + 4);
    a0 = fmaf(xd[d], wa.x, a0); a1 = fmaf(xd[d], wa.y, a1);
    a2 = fmaf(xd[d], wa.z, a2); a3 = fmaf(xd[d], wa.w, a3);
    a4 = fmaf(xd[d], wb.x, a4); a5 = fmaf(xd[d], wb.y, a5);
    a6 = fmaf(xd[d], wb.z, a6); a7 = fmaf(xd[d], wb.w, a7);
  }
#pragma unroll
  for (int off = 32; off; off >>= 1) {
    a0 += __shfl_xor(a0, off); a1 += __shfl_xor(a1, off);
    a2 += __shfl_xor(a2, off); a3 += __shfl_xor(a3, off);
    a4 += __shfl_xor(a4, off); a5 += __shfl_xor(a5, off);
    a6 += __shfl_xor(a6, off); a7 += __shfl_xor(a7, off);
  }
  float o = a0;
  if (lane == 1) o = a1; if (lane == 2) o = a2; if (lane == 3) o = a3;
  if (lane == 4) o = a4; if (lane == 5) o = a5; if (lane == 6) o = a6;
  if (lane == 7) o = a7;
  if (lane < 8) {
    if (k < 200) Wdt[k * 8 + lane] = o;
    else         bdt[lane] = o;
  }
}

// ---------------- wcls [256][17] -> wclsT [17][256] f32 ----------------
__global__ __launch_bounds__(256) void tpose_wcls(const float* __restrict__ wcls,
                                                  float* __restrict__ wclsT)
{
  int i = blockIdx.x * 256 + threadIdx.x;
  if (i >= NCLS * 256) return;
  int j = i >> 8, k = i & 255;
  wclsT[i] = wcls[(long)k * NCLS + j];
}

// ---------------- pad+cast x: [ROWS][200] f32 -> [ROWS][224] bf16; col200 = 1.0 ------
__global__ __launch_bounds__(256) void cast_pad_x(const float* __restrict__ x,
                                                  unsigned short* __restrict__ xp)
{
  long idx = (long)blockIdx.x * 256 + threadIdx.x;
  if (idx >= ROWS * 56) return;
  int q = (int)(idx % 56);
  long row = idx / 56;
  ushort4 o = {0, 0, 0, 0};
  if (q < 50) {
    float4 v = *(const float4*)&x[row * 200 + q * 4];
    o.x = f2bf(v.x); o.y = f2bf(v.y); o.z = f2bf(v.z); o.w = f2bf(v.w);
  } else if (q == 50) {
    o.x = 0x3F80;                                  // 1.0 -> bias row multiplier
  }
  *(ushort4*)&xp[row * 224 + q * 4] = o;
}

// ---------------- bf16 MFMA GEMM (global_load_lds staging) ----------------
__global__ __launch_bounds__(256) void gemm_bf16(
    const unsigned short* __restrict__ A, const unsigned short* __restrict__ BT,
    float* __restrict__ C, unsigned short* __restrict__ Cb,
    const float* __restrict__ bias, int M, int N, int K)
{
  __shared__ __align__(16) unsigned short As[128 * 32];
  __shared__ __align__(16) unsigned short Bs[128 * 32];
  const int tid = threadIdx.x;
  const int m0 = blockIdx.y * 128, n0 = blockIdx.x * 128;
  const int lane = tid & 63, wv = tid >> 6;
  const int wr = (wv >> 1) * 64, wc = (wv & 1) * 64;
  f32x4 acc[4][4];
#pragma unroll
  for (int i = 0; i < 4; ++i)
#pragma unroll
    for (int j = 0; j < 4; ++j) acc[i][j] = (f32x4){0.f, 0.f, 0.f, 0.f};

  for (int k0 = 0; k0 < K; k0 += 32) {
    __syncthreads();
#pragma unroll
    for (int s = 0; s < 2; ++s) {
      int idx = (tid + 256 * s) * 8;
      int r = idx >> 5, kk = idx & 31;
      GLOAD_LDS16(&A[(long)(m0 + r) * K + k0 + kk], &As[idx]);
    }
#pragma unroll
    for (int s = 0; s < 2; ++s) {
      int idx = (tid + 256 * s) * 8;
      int n = idx >> 5, kk = idx & 31;
      int srcn = (n0 + n < N) ? (n0 + n) : 0;
      GLOAD_LDS16(&BT[(long)srcn * K + k0 + kk], &Bs[idx]);
    }
    __syncthreads();
    s16x8 af[4], bf[4];
#pragma unroll
    for (int i = 0; i < 4; ++i)
      af[i] = *(const s16x8*)&As[(wr + i * 16 + (lane & 15)) * 32 + (lane >> 4) * 8];
#pragma unroll
    for (int j = 0; j < 4; ++j)
      bf[j] = *(const s16x8*)&Bs[(wc + j * 16 + (lane & 15)) * 32 + (lane >> 4) * 8];
#pragma unroll
    for (int i = 0; i < 4; ++i)
#pragma unroll
      for (int j = 0; j < 4; ++j)
        acc[i][j] = __builtin_amdgcn_mfma_f32_16x16x32_bf16(af[i], bf[j], acc[i][j], 0, 0, 0);
  }
  const int cr = (lane >> 4) * 4, cc = lane & 15;
#pragma unroll
  for (int i = 0; i < 4; ++i)
#pragma unroll
    for (int j = 0; j < 4; ++j) {
      int col = n0 + wc + j * 16 + cc;
      if (col < N) {
        long rowb = (long)(m0 + wr + i * 16 + cr);
        float bv = bias ? bias[col] : 0.f;
#pragma unroll
        for (int r = 0; r < 4; ++r) {
          float v = acc[i][j][r] + bv;
          if (C)  C[(rowb + r) * N + col] = v;
          if (Cb) Cb[(rowb + r) * (long)N + col] = f2bf(v);
        }
      }
    }
}

// ---------------- G = C·B^T per (b,c) -> bf16 causal-masked ----------------
__global__ __launch_bounds__(256) void g_gemm_bf16(
    const unsigned short* __restrict__ Cbf, const unsigned short* __restrict__ Bbf,
    unsigned short* __restrict__ Gbf)
{
  int bc = blockIdx.z;
  unsigned short* Gout = Gbf + (long)bc * 65536;
  const int tid = threadIdx.x;
  const int m0 = blockIdx.y * 128, n0 = blockIdx.x * 128;
  if (blockIdx.x > blockIdx.y) {
    s16x8 z = {};
    for (int e = tid; e < 128 * 16; e += 256) {
      int r = e >> 4, seg = e & 15;
      *(s16x8*)&Gout[(long)(m0 + r) * 256 + n0 + seg * 8] = z;
    }
    return;
  }
  long rowbase = (long)(bc >> 2) * LSEQ + (bc & 3) * QLEN;
  const unsigned short* A  = Cbf + rowbase * 128;
  const unsigned short* BT = Bbf + rowbase * 128;
  __shared__ __align__(16) unsigned short As[128 * 32];
  __shared__ __align__(16) unsigned short Bs[128 * 32];
  const int lane = tid & 63, wv = tid >> 6;
  const int wr = (wv >> 1) * 64, wc = (wv & 1) * 64;
  f32x4 acc[4][4];
#pragma unroll
  for (int i = 0; i < 4; ++i)
#pragma unroll
    for (int j = 0; j < 4; ++j) acc[i][j] = (f32x4){0.f, 0.f, 0.f, 0.f};
  for (int k0 = 0; k0 < 128; k0 += 32) {
    __syncthreads();
#pragma unroll
    for (int s = 0; s < 2; ++s) {
      int idx = (tid + 256 * s) * 8;
      int r = idx >> 5, kk = idx & 31;
      GLOAD_LDS16(&A[(long)(m0 + r) * 128 + k0 + kk], &As[idx]);
      GLOAD_LDS16(&BT[(long)(n0 + r) * 128 + k0 + kk], &Bs[idx]);
    }
    __syncthreads();
    s16x8 af[4], bf[4];
#pragma unroll
    for (int i = 0; i < 4; ++i)
      af[i] = *(const s16x8*)&As[(wr + i * 16 + (lane & 15)) * 32 + (lane >> 4) * 8];
#pragma unroll
    for (int j = 0; j < 4; ++j)
      bf[j] = *(const s16x8*)&Bs[(wc + j * 16 + (lane & 15)) * 32 + (lane >> 4) * 8];
#pragma unroll
    for (int i = 0; i < 4; ++i)
#pragma unroll
      for (int j = 0; j < 4; ++j)
        acc[i][j] = __builtin_amdgcn_mfma_f32_16x16x32_bf16(af[i], bf[j], acc[i][j], 0, 0, 0);
  }
  const int cr = (lane >> 4) * 4, cc = lane & 15;
#pragma unroll
  for (int i = 0; i < 4; ++i)
#pragma unroll
    for (int j = 0; j < 4; ++j) {
      int col = n0 + wc + j * 16 + cc;
      int qb = m0 + wr + i * 16 + cr;
#pragma unroll
      for (int r = 0; r < 4; ++r)
        Gout[(long)(qb + r) * 256 + col] = (col <= qb + r) ? f2bf(acc[i][j][r]) : (unsigned short)0;
    }
}

// ---------------- conv1d (k=4, causal) + SiLU -> bf16 Xbf/Bbf/Cbf ----------------
__global__ __launch_bounds__(256) void conv_silu3(
    const unsigned short* __restrict__ zxb, const float* __restrict__ cw,
    const float* __restrict__ cb,
    unsigned short* __restrict__ Xbf, unsigned short* __restrict__ Bbf,
    unsigned short* __restrict__ Cbf)
{
  long idx = (long)blockIdx.x * 256 + threadIdx.x;
  if (idx >= ROWS * 192) return;
  int cq = (int)(idx % 192);
  long row = idx / 192;
  int t = (int)(row & 1023);
  int ch = cq * 4;
  float4 cbv = *(const float4*)&cb[ch];
  float a0 = cbv.x, a1 = cbv.y, a2 = cbv.z, a3 = cbv.w;
#pragma unroll
  for (int w = 0; w < 4; ++w) {
    int d = w - 3;
    if (t + d >= 0) {
      ushort4 zv = *(const ushort4*)&zxb[(row + d) * DPROJ + 512 + ch];
      float4 cwv = *(const float4*)&cw[w * XBCW + ch];
      a0 = fmaf(bf2f(zv.x), cwv.x, a0);
      a1 = fmaf(bf2f(zv.y), cwv.y, a1);
      a2 = fmaf(bf2f(zv.z), cwv.z, a2);
      a3 = fmaf(bf2f(zv.w), cwv.w, a3);
    }
  }
  ushort4 o;
  o.x = f2bf(a0 / (1.f + __expf(-a0)));
  o.y = f2bf(a1 / (1.f + __expf(-a1)));
  o.z = f2bf(a2 / (1.f + __expf(-a2)));
  o.w = f2bf(a3 / (1.f + __expf(-a3)));
  if (ch < 512)      *(ushort4*)&Xbf[row * DIN + ch] = o;
  else if (ch < 640) *(ushort4*)&Bbf[row * 128 + ch - 512] = o;
  else               *(ushort4*)&Cbf[row * 128 + ch - 640] = o;
}

// ---------------- dt logits: block = 32 rows, LDS-staged x and Wdt; f32-exact --------
__global__ __launch_bounds__(256) void dt_logits(
    const float* __restrict__ x, const float* __restrict__ Wdt,
    const float* __restrict__ bdt, const float* __restrict__ dtb,
    float* __restrict__ dtsp)
{
  __shared__ float xs[32][201];
  __shared__ float wdt_s[1600];
  long row0 = (long)blockIdx.x * 32;
  int tid = threadIdx.x;
#pragma unroll
  for (int s = 0; s < 25; ++s) {
    int e = tid + s * 256;
    int r = e / 200, c = e % 200;
    xs[r][c] = x[(row0 + r) * 200 + c];
  }
#pragma unroll
  for (int s = 0; s < 7; ++s) {
    int e = tid + s * 256;
    if (e < 1600) wdt_s[e] = Wdt[e];
  }
  __syncthreads();
  int r = tid >> 3, h = tid & 7;
  float acc = dtb[h] + bdt[h];
  for (int i = 0; i < 200; ++i)
    acc = fmaf(xs[r][i], wdt_s[i * 8 + h], acc);
  float sp = (acc > 20.f) ? acc : log1pf(__expf(acc));
  dtsp[(row0 + r) * NH + h] = sp;
}

// ---------------- cumsum only: wave per (b,h,c) ----------------
__global__ __launch_bounds__(256) void dt_cumsum4(
    const float* __restrict__ dtsp, const float* __restrict__ alog,
    float* __restrict__ acs)
{
  int g = ((int)blockIdx.x * 256 + (int)threadIdx.x) >> 6;
  int lane = threadIdx.x & 63;
  int c = g & 3, h = (g >> 2) & 7, b = g >> 5;
  float Ah = -__expf(alog[h]);
  long rowbase = (long)b * LSEQ + c * QLEN;
  long abase = (((long)b * NH + h) * NCHUNK + c) * QLEN;
  float v[4];
#pragma unroll
  for (int j = 0; j < 4; ++j)
    v[j] = dtsp[(rowbase + lane * 4 + j) * NH + h] * Ah;
  v[1] += v[0]; v[2] += v[1]; v[3] += v[2];
  float tot = v[3];
  float run = tot;
#pragma unroll
  for (int d = 1; d < 64; d <<= 1) {
    float t = __shfl_up(run, d);
    if (lane >= d) run += t;
  }
  float excl = run - tot;
#pragma unroll
  for (int j = 0; j < 4; ++j) acs[abase + lane * 4 + j] = excl + v[j];
}

// ---------------- Bbf [ROWS][128] -> BbfT [bc][128][256] ----------------
__global__ __launch_bounds__(256) void transB(const unsigned short* __restrict__ Bbf,
                                              unsigned short* __restrict__ BbfT)
{
  __shared__ unsigned short T[128][130];
  int bc = blockIdx.y, kh = blockIdx.x;
  int tid = threadIdx.x;
  long rowbase = (long)(bc >> 2) * LSEQ + (bc & 3) * QLEN + kh * 128;
  for (int e = tid; e < 128 * 128; e += 256) {
    int r = e >> 7, n = e & 127;
    T[r][n] = Bbf[(rowbase + r) * 128 + n];
  }
  __syncthreads();
  for (int e = tid; e < 128 * 128; e += 256) {
    int n = e >> 7, k = e & 127;
    BbfT[((long)bc * 128 + n) * 256 + kh * 128 + k] = T[k][n];
  }
}

// ---------------- yd+states: full XdT staged once, pure-MFMA k loop ----------------
__global__ __launch_bounds__(256) void yd_states6(
    const unsigned short* __restrict__ Xbf, const float* __restrict__ dtsp,
    const float* __restrict__ acs, const unsigned short* __restrict__ Gbf,
    const unsigned short* __restrict__ BbfT,
    unsigned short* __restrict__ ybf, float* __restrict__ st)
{
  int bid = blockIdx.x;
  int xcd = bid & 7, i0 = bid >> 3;
  int bc = xcd * 8 + (i0 >> 4);
  int rem = i0 & 15, h = rem >> 1, half = rem & 1;
  int c = bc & 3, b = bc >> 2;
  int bch = bc * 8 + h;

  __shared__ __align__(16) unsigned short XdT[64][264];
  __shared__ float AcsS[256], E1f[256], E2f[256], dts[256];

  const int tid = threadIdx.x;
  const int lane = tid & 63, wv = tid >> 6;
  const bool ydw = wv < 2;
  const int q0 = half * 128 + wv * 64;
  const int myqt = half * 2 + wv;
  const int n0w = half * 64 + (wv - 2) * 32;
  long rowbase = (long)b * LSEQ + c * QLEN;
  const unsigned short* Gb  = Gbf + (long)bc * 65536;
  const unsigned short* BTg = BbfT + (long)bc * 32768;

  AcsS[tid] = acs[(((long)b * NH + h) * NCHUNK + c) * QLEN + tid];
  dts[tid]  = dtsp[(rowbase + tid) * NH + h];
  __syncthreads();
  E1f[tid] = __expf(AcsS[tid] - AcsS[tid | 63]);
  E2f[tid] = __expf(AcsS[tid | 63] - AcsS[tid]);
  float rs_[4];
  rs_[0] = 1.f;
#pragma unroll
  for (int kt = 1; kt < 4; ++kt) rs_[kt] = __expf(AcsS[kt * 64 + 63] - AcsS[kt * 64 - 1]);
  __syncthreads();
  {
    int kb = wv * 64;
#pragma unroll
    for (int s = 0; s < 16; ++s) {
      int k4 = kb + s * 4;
      ushort4 pk;
      unsigned short* pp = (unsigned short*)&pk;
#pragma unroll
      for (int j = 0; j < 4; ++j) {
        int k = k4 + j;
        float v = bf2f(Xbf[(rowbase + k) * DIN + h * HD + lane]) * dts[k] * E2f[k];
        pp[j] = f2bf(v);
      }
      *(ushort4*)&XdT[lane][k4] = pk;
    }
  }
  __syncthreads();

  f32x4 accY[4][4], accS[4][2];
#pragma unroll
  for (int i = 0; i < 4; ++i)
#pragma unroll
    for (int j = 0; j < 4; ++j) accY[i][j] = (f32x4){0.f, 0.f, 0.f, 0.f};
#pragma unroll
  for (int i = 0; i < 4; ++i)
#pragma unroll
    for (int j = 0; j < 2; ++j) accS[i][j] = (f32x4){0.f, 0.f, 0.f, 0.f};

  for (int kt = 0; kt < 4; ++kt) {
    int qlo = kt * 64;
    if (ydw) {
      if (myqt >= kt) {
        if (kt)
#pragma unroll
          for (int i = 0; i < 4; ++i)
#pragma unroll
            for (int j = 0; j < 4; ++j) accY[i][j] *= rs_[kt];
#pragma unroll
        for (int ks = 0; ks < 2; ++ks) {
          s16x8 bfr[4];
#pragma unroll
          for (int j = 0; j < 4; ++j)
            bfr[j] = *(const s16x8*)&XdT[j * 16 + (lane & 15)][qlo + ks * 32 + (lane >> 4) * 8];
#pragma unroll
          for (int i = 0; i < 4; ++i) {
            s16x8 a = *(const s16x8*)&Gb[(long)(q0 + i * 16 + (lane & 15)) * 256 + qlo + ks * 32 + (lane >> 4) * 8];
#pragma unroll
            for (int j = 0; j < 4; ++j)
              accY[i][j] = __builtin_amdgcn_mfma_f32_16x16x32_bf16(a, bfr[j], accY[i][j], 0, 0, 0);
          }
        }
      }
    } else {
      if (kt)
#pragma unroll
        for (int i = 0; i < 4; ++i)
#pragma unroll
          for (int j = 0; j < 2; ++j) accS[i][j] *= rs_[kt];
#pragma unroll
      for (int ks = 0; ks < 2; ++ks) {
        s16x8 afx[4];
#pragma unroll
        for (int i = 0; i < 4; ++i)
          afx[i] = *(const s16x8*)&XdT[i * 16 + (lane & 15)][qlo + ks * 32 + (lane >> 4) * 8];
#pragma unroll
        for (int j2 = 0; j2 < 2; ++j2) {
          s16x8 bt = *(const s16x8*)&BTg[(long)(n0w + j2 * 16 + (lane & 15)) * 256 + qlo + ks * 32 + (lane >> 4) * 8];
#pragma unroll
          for (int i = 0; i < 4; ++i)
            accS[i][j2] = __builtin_amdgcn_mfma_f32_16x16x32_bf16(afx[i], bt, accS[i][j2], 0, 0, 0);
        }
      }
    }
  }
  const int cr = (lane >> 4) * 4, cc = lane & 15;
  if (ydw) {
#pragma unroll
    for (int i = 0; i < 4; ++i)
#pragma unroll
      for (int j = 0; j < 4; ++j) {
        int q = q0 + i * 16 + cr;
        int p = j * 16 + cc;
#pragma unroll
        for (int r = 0; r < 4; ++r)
          ybf[(rowbase + q + r) * DIN + h * HD + p] = f2bf(accY[i][j][r] * E1f[q + r]);
      }
  } else {
#pragma unroll
    for (int i = 0; i < 4; ++i)
#pragma unroll
      for (int j2 = 0; j2 < 2; ++j2) {
        int p = i * 16 + cr;
        int n = n0w + j2 * 16 + cc;
#pragma unroll
        for (int r = 0; r < 4; ++r)
          st[(long)bch * 8192 + (long)(p + r) * 128 + n] = accS[i][j2][r];
      }
  }
}

// ---------------- inter-chunk scan (f32x4 vectorized, in place) ----------------
__global__ void scan_states(float* __restrict__ st, const float* __restrict__ acs)
{
  long idx = (long)blockIdx.x * 256 + threadIdx.x;
  if (idx >= (long)NB * NH * 2048) return;
  long inner = idx & 2047;
  int h = (int)((idx >> 11) & 7);
  int b = (int)(idx >> 14);
  f32x4 carry = {0.f, 0.f, 0.f, 0.f};
  for (int c = 0; c < NCHUNK; ++c) {
    float dc = __expf(acs[(((long)b * NH + h) * NCHUNK + c) * QLEN + (QLEN - 1)]);
    long si = (((long)(b * NCHUNK + c) * NH + h) << 13) + inner * 4;
    f32x4 s = *(f32x4*)&st[si];
    *(f32x4*)&st[si] = carry;
    carry = carry * dc + s;
  }
}

// ---------------- Yo via MFMA: ybf += exp(Acs[q]) * Cbf·prev^T + xh*D ----------------
__global__ __launch_bounds__(256) void yo_combine5(
    const unsigned short* __restrict__ Xbf, const unsigned short* __restrict__ Cbf,
    const float* __restrict__ prev, const float* __restrict__ acs,
    const float* __restrict__ Dp, unsigned short* __restrict__ ybf)
{
  int bid = blockIdx.x;
  int xcd = bid & 7, i0 = bid >> 3;
  int bc = xcd * 8 + (i0 >> 3), h = i0 & 7;
  int c = bc & 3, b = bc >> 2;
  int bch = bc * 8 + h;
  __shared__ float EqA[QLEN];
  const int tid = threadIdx.x;
  const int lane = tid & 63, wv = tid >> 6;
  long rowbase = (long)b * LSEQ + c * QLEN;
  EqA[tid] = __expf(acs[(((long)b * NH + h) * NCHUNK + c) * QLEN + tid]);
  __syncthreads();
  const unsigned short* Cb = Cbf + rowbase * 128;
  const float* pv = prev + (long)bch * 8192;
  f32x4 acc[4][4];
#pragma unroll
  for (int i = 0; i < 4; ++i)
#pragma unroll
    for (int j = 0; j < 4; ++j) acc[i][j] = (f32x4){0.f, 0.f, 0.f, 0.f};
#pragma unroll
  for (int ks = 0; ks < 4; ++ks) {
    int n0 = ks * 32 + (lane >> 4) * 8;
    s16x8 bf[4];
#pragma unroll
    for (int j = 0; j < 4; ++j) {
      int p = j * 16 + (lane & 15);
      f32x4 v0 = *(const f32x4*)&pv[p * 128 + n0];
      f32x4 v1 = *(const f32x4*)&pv[p * 128 + n0 + 4];
#pragma unroll
      for (int t = 0; t < 4; ++t) {
        bf[j][t]     = (short)f2bf(v0[t]);
        bf[j][4 + t] = (short)f2bf(v1[t]);
      }
    }
#pragma unroll
    for (int i = 0; i < 4; ++i) {
      s16x8 af = *(const s16x8*)&Cb[(long)(wv * 64 + i * 16 + (lane & 15)) * 128 + n0];
#pragma unroll
      for (int j = 0; j < 4; ++j)
        acc[i][j] = __builtin_amdgcn_mfma_f32_16x16x32_bf16(af, bf[j], acc[i][j], 0, 0, 0);
    }
  }
  const int cr = (lane >> 4) * 4, cc = lane & 15;
  float Dh = Dp[h];
#pragma unroll
  for (int i = 0; i < 4; ++i)
#pragma unroll
    for (int j = 0; j < 4; ++j) {
      int q = wv * 64 + i * 16 + cr;
      int p = j * 16 + cc;
#pragma unroll
      for (int r = 0; r < 4; ++r) {
        long row = rowbase + q + r;
        long yi = row * DIN + h * HD + p;
        float xh = bf2f(Xbf[yi]);
        float pr = bf2f(ybf[yi]);
        ybf[yi] = f2bf(pr + acc[i][j][r] * EqA[q + r] + xh * Dh);
      }
    }
}

// ---------------- gated RMSNorm in place on ybf (bf16) ----------------
__global__ __launch_bounds__(256) void gated_rms3(
    unsigned short* __restrict__ ybf, const unsigned short* __restrict__ zxb,
    const float* __restrict__ rmsw)
{
  long row = blockIdx.x;
  int t = threadIdx.x;
  ushort2 yv = *(const ushort2*)&ybf[row * DIN + 2 * t];
  ushort2 zv = *(const ushort2*)&zxb[row * DPROJ + 2 * t];
  float z0 = bf2f(zv.x), z1 = bf2f(zv.y);
  float v0 = bf2f(yv.x) * (z0 / (1.f + __expf(-z0)));
  float v1 = bf2f(yv.y) * (z1 / (1.f + __expf(-z1)));
  float ss = v0 * v0 + v1 * v1;
#pragma unroll
  for (int off = 32; off; off >>= 1) ss += __shfl_down(ss, off);
  __shared__ float red[4];
  if ((t & 63) == 0) red[t >> 6] = ss;
  __syncthreads();
  float tot = red[0] + red[1] + red[2] + red[3];
  float scale = rsqrtf(tot * (1.f / DIN) + 1e-5f);
  ushort2 o;
  o.x = f2bf(v0 * scale * rmsw[2 * t]);
  o.y = f2bf(v1 * scale * rmsw[2 * t + 1]);
  *(ushort2*)&ybf[row * DIN + 2 * t] = o;
}

// ---------------- LN + classifier: wave per row, no LDS ----------------
__global__ __launch_bounds__(256) void ln_cls2(
    const unsigned short* __restrict__ y2b, const float* __restrict__ g,
    const float* __restrict__ bb, const float* __restrict__ wclsT,
    const float* __restrict__ bcls, float* __restrict__ out)
{
  long row = (long)blockIdx.x * 4 + (threadIdx.x >> 6);
  int lane = threadIdx.x & 63;
  ushort4 yv = *(const ushort4*)&y2b[row * DM + lane * 4];
  float v0 = bf2f(yv.x), v1 = bf2f(yv.y), v2 = bf2f(yv.z), v3 = bf2f(yv.w);
  float s = v0 + v1 + v2 + v3;
  float q = v0 * v0 + v1 * v1 + v2 * v2 + v3 * v3;
#pragma unroll
  for (int off = 32; off; off >>= 1) {
    s += __shfl_xor(s, off);
    q += __shfl_xor(q, off);
  }
  float mu = s * (1.f / DM);
  float rstd = rsqrtf(q * (1.f / DM) - mu * mu + 1e-5f);
  float4 gv = *(const float4*)&g[lane * 4];
  float4 bv = *(const float4*)&bb[lane * 4];
  float y0 = (v0 - mu) * rstd * gv.x + bv.x;
  float y1 = (v1 - mu) * rstd * gv.y + bv.y;
  float y2_ = (v2 - mu) * rstd * gv.z + bv.z;
  float y3 = (v3 - mu) * rstd * gv.w + bv.w;
  float accs[NCLS];
#pragma unroll
  for (int j = 0; j < NCLS; ++j) {
    float4 wv = *(const float4*)&wclsT[j * 256 + lane * 4];
    accs[j] = y0 * wv.x + y1 * wv.y + y2_ * wv.z + y3 * wv.w;
  }
#pragma unroll
  for (int off = 32; off; off >>= 1)
#pragma unroll
    for (int j = 0; j < NCLS; ++j) accs[j] += __shfl_xor(accs[j], off);
  float o = accs[0] + bcls[0];
#pragma unroll
  for (int j = 1; j < NCLS; ++j)
    if (lane == j) o = accs[j] + bcls[j];
  if (lane < NCLS) out[row * NCLS + lane] = o;
}

extern "C" void kernel_launch(void* const* d_in, const int* in_sizes, int n_in,
                              void* d_out, int out_size, void* d_ws, size_t ws_size,
                              hipStream_t stream)
{
  const float* x     = (const float*)d_in[0];
  const float* w_inp = (const float*)d_in[1];
  const float* b_inp = (const float*)d_in[2];
  const float* w_in  = (const float*)d_in[3];
  const float* convw = (const float*)d_in[4];
  const float* convb = (const float*)d_in[5];
  const float* dtb   = (const float*)d_in[6];
  const float* alog  = (const float*)d_in[7];
  const float* Dp    = (const float*)d_in[8];
  const float* rmsw  = (const float*)d_in[9];
  const float* wout  = (const float*)d_in[10];
  const float* lng   = (const float*)d_in[11];
  const float* lnb   = (const float*)d_in[12];
  const float* wcls  = (const float*)d_in[13];
  const float* bcls  = (const float*)d_in[14];
  float* out = (float*)d_out;
  float* ws  = (float*)d_ws;

  float* dtsp = ws + O_DT;
  float* acs  = ws + O_ACS;
  float* st   = ws + O_ST;
  float* Wdt  = ws + O_WDT;
  float* bdt  = Wdt + 1600;
  float* wclsT= ws + O_WCLST;
  unsigned short* Gbf    = (unsigned short*)(ws + O_GBF);
  unsigned short* zxb    = (unsigned short*)(ws + O_ZX);
  unsigned short* Xbf    = (unsigned short*)(ws + O_XBF);
  unsigned short* Bbf    = (unsigned short*)(ws + O_BBF);
  unsigned short* Cbf    = (unsigned short*)(ws + O_CBF);
  unsigned short* BbfT   = (unsigned short*)(ws + O_BT);
  unsigned short* ybf    = (unsigned short*)(ws + O_YBF);
  unsigned short* xp_bf  = (unsigned short*)(ws + O_XPBF);
  unsigned short* WcombT = (unsigned short*)(ws + O_WCT);
  unsigned short* woutT  = (unsigned short*)(ws + O_WOUTT);
  unsigned short* w_inT  = (unsigned short*)(ws + O_WINT);
  unsigned short* we_bf  = (unsigned short*)(ws + O_WIPE);
  unsigned short* y2b    = (unsigned short*)(ws + O_Y2);

  // ---- prep (all MFMA / tiny-wave; no bespoke f32 GEMM) ----
  tcast<<<1288, 256, 0, stream>>>(w_in, w_inT, 8, DPROJ);          // w_inT [1288(+pad)][256]
  cast_winp_ext<<<224, 256, 0, stream>>>(w_inp, b_inp, we_bf);     // [224][256]
  wdt_small<<<51, 256, 0, stream>>>(w_inp, w_in, b_inp, Wdt, bdt); // exact f32 dt weights
  gemm_bf16<<<dim3(2, 11), 256, 0, stream>>>(w_inT, we_bf, nullptr, WcombT, nullptr, 1408, 224, 256);
  tcast<<<512, 256, 0, stream>>>(wout, woutT, 9, DM);
  tpose_wcls<<<17, 256, 0, stream>>>(wcls, wclsT);
  cast_pad_x<<<3584, 256, 0, stream>>>(x, xp_bf);
  // ---- fused input_proj+in_proj (bias folded via x col 200 = 1.0) ----
  gemm_bf16<<<dim3(11, 128), 256, 0, stream>>>(xp_bf, WcombT, nullptr, zxb, nullptr, 16384, DPROJ, 224);
  conv_silu3<<<12288, 256, 0, stream>>>(zxb, convw, convb, Xbf, Bbf, Cbf);
  dt_logits<<<512, 256, 0, stream>>>(x, Wdt, bdt, dtb, dtsp);
  dt_cumsum4<<<128, 256, 0, stream>>>(dtsp, alog, acs);
  transB<<<dim3(2, 64), 256, 0, stream>>>(Bbf, BbfT);
  g_gemm_bf16<<<dim3(2, 2, 64), 256, 0, stream>>>(Cbf, Bbf, Gbf);
  yd_states6<<<1024, 256, 0, stream>>>(Xbf, dtsp, acs, Gbf, BbfT, ybf, st);
  scan_states<<<1024, 256, 0, stream>>>(st, acs);
  yo_combine5<<<512, 256, 0, stream>>>(Xbf, Cbf, st, acs, Dp, ybf);
  gated_rms3<<<16384, 256, 0, stream>>>(ybf, zxb, rmsw);
  gemm_bf16<<<dim3(2, 128), 256, 0, stream>>>(ybf, woutT, nullptr, y2b, nullptr, 16384, DM, DIN);
  ln_cls2<<<4096, 256, 0, stream>>>(y2b, lng, lnb, wclsT, bcls, out);
}

// Round 12
// 209.358 us; speedup vs baseline: 6.0063x; 1.0900x over previous
//
#include <hip/hip_runtime.h>
#include <math.h>

#define ROWS   16384L
#define LSEQ   1024
#define NB     16
#define DM     256
#define DPROJ  1288
#define XBCW   768
#define DIN    512
#define DSTATE 128
#define NH     8
#define HD     64
#define QLEN   256
#define NCHUNK 4
#define NCLS   17

typedef __attribute__((ext_vector_type(8))) short s16x8;
typedef __attribute__((ext_vector_type(4))) float f32x4;

#define GLOAD_LDS16(gsrc, ldst) \
  __builtin_amdgcn_global_load_lds((const __attribute__((address_space(1))) void*)(gsrc), \
      (__attribute__((address_space(3))) void*)(ldst), 16, 0, 0)

// ---- workspace map (float slots) ----
constexpr long O_GBF  = 0;                        // Gbf bf16 [64][256][256]
constexpr long O_ZX   = O_GBF + ROWS*DM;          // zxb bf16 [ROWS][1288]
constexpr long O_XBC  = O_ZX  + ROWS*DPROJ;       // region: Xbf/Bbf/Cbf/BbfT bf16
constexpr long O_DT   = O_XBC + ROWS*XBCW;
constexpr long O_ACS  = O_DT  + ROWS*NH;
constexpr long O_Y    = O_ACS + 131072;           // region: ybf bf16 + prep overlays
constexpr long O_ST   = O_Y   + ROWS*DIN;         // st bf16 [512][64p][128n]
constexpr long O_Y2   = O_ST  + 4194304;          // y2b bf16
// O_XBC region overlays (bf16):
constexpr long O_XBF  = O_XBC;                    // Xbf [ROWS][512]
constexpr long O_BBF  = O_XBC + 4200000;          // Bbf [ROWS][128]
constexpr long O_CBF  = O_XBC + 5300000;          // Cbf [ROWS][128]
constexpr long O_BT   = O_XBC + 6400000;          // BbfT [64][128][256]
// O_Y region overlays:
constexpr long O_YBF  = O_Y;                      // ybf [ROWS][512] bf16
constexpr long O_XPBF = O_Y + 4300000;            // xp_bf [ROWS][224] bf16
constexpr long O_WCT  = O_Y + 6200000;            // WcombT [1408][224] bf16
constexpr long O_WOUTT= O_Y + 6400000;            // woutT [256][512] bf16
constexpr long O_WDT  = O_Y + 6500000;            // Wdt[200][8]+bdt[8] f32
constexpr long O_WCLST= O_Y + 6530000;            // wclsT [17][256] f32
constexpr long O_WINT = O_Y + 6600000;            // w_inT [1408][256] bf16
constexpr long O_WIPE = O_Y + 6800000;            // w_inp_ext [224][256] bf16

__device__ inline unsigned short f2bf(float f) {
  union { float f; unsigned u; } v; v.f = f;
  unsigned r = v.u + 0x7FFFu + ((v.u >> 16) & 1u);
  return (unsigned short)(r >> 16);
}
__device__ inline float bf2f(unsigned short s) {
  union { unsigned u; float f; } v; v.u = ((unsigned)s) << 16; return v.f;
}

// ---------------- merged prep: block-range dispatch over 6 roles ----------------
// [0,3584): cast_pad_x | [3584,4872): tcast w_in | [4872,5384): tcast wout
// [5384,5608): cast_winp_ext | [5608,5659): wdt_small | [5659,5676): tpose_wcls
__global__ __launch_bounds__(256) void prep_misc(
    const float* __restrict__ x, unsigned short* __restrict__ xp,
    const float* __restrict__ w_in, unsigned short* __restrict__ w_inT,
    const float* __restrict__ wout, unsigned short* __restrict__ woutT,
    const float* __restrict__ w_inp, const float* __restrict__ b_inp,
    unsigned short* __restrict__ we,
    float* __restrict__ Wdt, float* __restrict__ bdt,
    const float* __restrict__ wcls, float* __restrict__ wclsT)
{
  int bid = blockIdx.x;
  int tid = threadIdx.x;
  if (bid < 3584) {                                      // cast_pad_x
    long idx = (long)bid * 256 + tid;
    int q = (int)(idx % 56);
    long row = idx / 56;
    ushort4 o = {0, 0, 0, 0};
    if (q < 50) {
      float4 v = *(const float4*)&x[row * 200 + q * 4];
      o.x = f2bf(v.x); o.y = f2bf(v.y); o.z = f2bf(v.z); o.w = f2bf(v.w);
    } else if (q == 50) {
      o.x = 0x3F80;                                      // 1.0 bias multiplier
    }
    *(ushort4*)&xp[row * 224 + q * 4] = o;
  } else if (bid < 4872) {                               // tcast w_in -> w_inT [n][256]
    long i = (long)(bid - 3584) * 256 + tid;
    int k = (int)(i & 255);
    long n = i >> 8;
    w_inT[i] = f2bf(w_in[(long)k * DPROJ + n]);
  } else if (bid < 5384) {                               // tcast wout -> woutT [n][512]
    long i = (long)(bid - 4872) * 256 + tid;
    int k = (int)(i & 511);
    long n = i >> 9;
    woutT[i] = f2bf(wout[(long)k * DM + n]);
  } else if (bid < 5608) {                               // cast_winp_ext [224][256]
    int i = (bid - 5384) * 256 + tid;
    int k = i >> 8, j = i & 255;
    float v = 0.f;
    if (k < 200)       v = w_inp[(long)k * 256 + j];
    else if (k == 200) v = b_inp[j];
    we[i] = f2bf(v);
  } else if (bid < 5659) {                               // wdt_small (exact f32 dt weights)
    int k = (bid - 5608) * 4 + (tid >> 6);
    if (k > 200) return;
    int lane = tid & 63;
    int j0 = lane * 4;
    float4 xv = (k < 200) ? *(const float4*)&w_inp[(long)k * 256 + j0]
                          : *(const float4*)&b_inp[j0];
    float a0 = 0.f, a1 = 0.f, a2 = 0.f, a3 = 0.f, a4 = 0.f, a5 = 0.f, a6 = 0.f, a7 = 0.f;
    float xd[4] = {xv.x, xv.y, xv.z, xv.w};
#pragma unroll
    for (int d = 0; d < 4; ++d) {
      const float* wr = &w_in[(long)(j0 + d) * DPROJ + 1280];
      float4 wa = *(const float4*)wr;
      float4 wb = *(const float4*)(wr + 4);
      a0 = fmaf(xd[d], wa.x, a0); a1 = fmaf(xd[d], wa.y, a1);
      a2 = fmaf(xd[d], wa.z, a2); a3 = fmaf(xd[d], wa.w, a3);
      a4 = fmaf(xd[d], wb.x, a4); a5 = fmaf(xd[d], wb.y, a5);
      a6 = fmaf(xd[d], wb.z, a6); a7 = fmaf(xd[d], wb.w, a7);
    }
#pragma unroll
    for (int off = 32; off; off >>= 1) {
      a0 += __shfl_xor(a0, off); a1 += __shfl_xor(a1, off);
      a2 += __shfl_xor(a2, off); a3 += __shfl_xor(a3, off);
      a4 += __shfl_xor(a4, off); a5 += __shfl_xor(a5, off);
      a6 += __shfl_xor(a6, off); a7 += __shfl_xor(a7, off);
    }
    float o = a0;
    if (lane == 1) o = a1; if (lane == 2) o = a2; if (lane == 3) o = a3;
    if (lane == 4) o = a4; if (lane == 5) o = a5; if (lane == 6) o = a6;
    if (lane == 7) o = a7;
    if (lane < 8) {
      if (k < 200) Wdt[k * 8 + lane] = o;
      else         bdt[lane] = o;
    }
  } else {                                               // tpose_wcls
    int i = (bid - 5659) * 256 + tid;
    if (i < NCLS * 256) {
      int j = i >> 8, k = i & 255;
      wclsT[i] = wcls[(long)k * NCLS + j];
    }
  }
}

// ---------------- bf16 MFMA GEMM (global_load_lds staging) ----------------
__global__ __launch_bounds__(256) void gemm_bf16(
    const unsigned short* __restrict__ A, const unsigned short* __restrict__ BT,
    float* __restrict__ C, unsigned short* __restrict__ Cb,
    const float* __restrict__ bias, int M, int N, int K)
{
  __shared__ __align__(16) unsigned short As[128 * 32];
  __shared__ __align__(16) unsigned short Bs[128 * 32];
  const int tid = threadIdx.x;
  const int m0 = blockIdx.y * 128, n0 = blockIdx.x * 128;
  const int lane = tid & 63, wv = tid >> 6;
  const int wr = (wv >> 1) * 64, wc = (wv & 1) * 64;
  f32x4 acc[4][4];
#pragma unroll
  for (int i = 0; i < 4; ++i)
#pragma unroll
    for (int j = 0; j < 4; ++j) acc[i][j] = (f32x4){0.f, 0.f, 0.f, 0.f};

  for (int k0 = 0; k0 < K; k0 += 32) {
    __syncthreads();
#pragma unroll
    for (int s = 0; s < 2; ++s) {
      int idx = (tid + 256 * s) * 8;
      int r = idx >> 5, kk = idx & 31;
      GLOAD_LDS16(&A[(long)(m0 + r) * K + k0 + kk], &As[idx]);
    }
#pragma unroll
    for (int s = 0; s < 2; ++s) {
      int idx = (tid + 256 * s) * 8;
      int n = idx >> 5, kk = idx & 31;
      int srcn = (n0 + n < N) ? (n0 + n) : 0;
      GLOAD_LDS16(&BT[(long)srcn * K + k0 + kk], &Bs[idx]);
    }
    __syncthreads();
    s16x8 af[4], bf[4];
#pragma unroll
    for (int i = 0; i < 4; ++i)
      af[i] = *(const s16x8*)&As[(wr + i * 16 + (lane & 15)) * 32 + (lane >> 4) * 8];
#pragma unroll
    for (int j = 0; j < 4; ++j)
      bf[j] = *(const s16x8*)&Bs[(wc + j * 16 + (lane & 15)) * 32 + (lane >> 4) * 8];
#pragma unroll
    for (int i = 0; i < 4; ++i)
#pragma unroll
      for (int j = 0; j < 4; ++j)
        acc[i][j] = __builtin_amdgcn_mfma_f32_16x16x32_bf16(af[i], bf[j], acc[i][j], 0, 0, 0);
  }
  const int cr = (lane >> 4) * 4, cc = lane & 15;
#pragma unroll
  for (int i = 0; i < 4; ++i)
#pragma unroll
    for (int j = 0; j < 4; ++j) {
      int col = n0 + wc + j * 16 + cc;
      if (col < N) {
        long rowb = (long)(m0 + wr + i * 16 + cr);
        float bv = bias ? bias[col] : 0.f;
#pragma unroll
        for (int r = 0; r < 4; ++r) {
          float v = acc[i][j][r] + bv;
          if (C)  C[(rowb + r) * N + col] = v;
          if (Cb) Cb[(rowb + r) * (long)N + col] = f2bf(v);
        }
      }
    }
}

// ---------------- G = C·B^T per (b,c) -> bf16 causal-masked ----------------
__global__ __launch_bounds__(256) void g_gemm_bf16(
    const unsigned short* __restrict__ Cbf, const unsigned short* __restrict__ Bbf,
    unsigned short* __restrict__ Gbf)
{
  int bc = blockIdx.z;
  unsigned short* Gout = Gbf + (long)bc * 65536;
  const int tid = threadIdx.x;
  const int m0 = blockIdx.y * 128, n0 = blockIdx.x * 128;
  if (blockIdx.x > blockIdx.y) {
    s16x8 z = {};
    for (int e = tid; e < 128 * 16; e += 256) {
      int r = e >> 4, seg = e & 15;
      *(s16x8*)&Gout[(long)(m0 + r) * 256 + n0 + seg * 8] = z;
    }
    return;
  }
  long rowbase = (long)(bc >> 2) * LSEQ + (bc & 3) * QLEN;
  const unsigned short* A  = Cbf + rowbase * 128;
  const unsigned short* BT = Bbf + rowbase * 128;
  __shared__ __align__(16) unsigned short As[128 * 32];
  __shared__ __align__(16) unsigned short Bs[128 * 32];
  const int lane = tid & 63, wv = tid >> 6;
  const int wr = (wv >> 1) * 64, wc = (wv & 1) * 64;
  f32x4 acc[4][4];
#pragma unroll
  for (int i = 0; i < 4; ++i)
#pragma unroll
    for (int j = 0; j < 4; ++j) acc[i][j] = (f32x4){0.f, 0.f, 0.f, 0.f};
  for (int k0 = 0; k0 < 128; k0 += 32) {
    __syncthreads();
#pragma unroll
    for (int s = 0; s < 2; ++s) {
      int idx = (tid + 256 * s) * 8;
      int r = idx >> 5, kk = idx & 31;
      GLOAD_LDS16(&A[(long)(m0 + r) * 128 + k0 + kk], &As[idx]);
      GLOAD_LDS16(&BT[(long)(n0 + r) * 128 + k0 + kk], &Bs[idx]);
    }
    __syncthreads();
    s16x8 af[4], bf[4];
#pragma unroll
    for (int i = 0; i < 4; ++i)
      af[i] = *(const s16x8*)&As[(wr + i * 16 + (lane & 15)) * 32 + (lane >> 4) * 8];
#pragma unroll
    for (int j = 0; j < 4; ++j)
      bf[j] = *(const s16x8*)&Bs[(wc + j * 16 + (lane & 15)) * 32 + (lane >> 4) * 8];
#pragma unroll
    for (int i = 0; i < 4; ++i)
#pragma unroll
      for (int j = 0; j < 4; ++j)
        acc[i][j] = __builtin_amdgcn_mfma_f32_16x16x32_bf16(af[i], bf[j], acc[i][j], 0, 0, 0);
  }
  const int cr = (lane >> 4) * 4, cc = lane & 15;
#pragma unroll
  for (int i = 0; i < 4; ++i)
#pragma unroll
    for (int j = 0; j < 4; ++j) {
      int col = n0 + wc + j * 16 + cc;
      int qb = m0 + wr + i * 16 + cr;
#pragma unroll
      for (int r = 0; r < 4; ++r)
        Gout[(long)(qb + r) * 256 + col] = (col <= qb + r) ? f2bf(acc[i][j][r]) : (unsigned short)0;
    }
}

// ---------------- conv1d (k=4, causal) + SiLU -> bf16 Xbf/Bbf/Cbf ----------------
__global__ __launch_bounds__(256) void conv_silu3(
    const unsigned short* __restrict__ zxb, const float* __restrict__ cw,
    const float* __restrict__ cb,
    unsigned short* __restrict__ Xbf, unsigned short* __restrict__ Bbf,
    unsigned short* __restrict__ Cbf)
{
  long idx = (long)blockIdx.x * 256 + threadIdx.x;
  if (idx >= ROWS * 192) return;
  int cq = (int)(idx % 192);
  long row = idx / 192;
  int t = (int)(row & 1023);
  int ch = cq * 4;
  float4 cbv = *(const float4*)&cb[ch];
  float a0 = cbv.x, a1 = cbv.y, a2 = cbv.z, a3 = cbv.w;
#pragma unroll
  for (int w = 0; w < 4; ++w) {
    int d = w - 3;
    if (t + d >= 0) {
      ushort4 zv = *(const ushort4*)&zxb[(row + d) * DPROJ + 512 + ch];
      float4 cwv = *(const float4*)&cw[w * XBCW + ch];
      a0 = fmaf(bf2f(zv.x), cwv.x, a0);
      a1 = fmaf(bf2f(zv.y), cwv.y, a1);
      a2 = fmaf(bf2f(zv.z), cwv.z, a2);
      a3 = fmaf(bf2f(zv.w), cwv.w, a3);
    }
  }
  ushort4 o;
  o.x = f2bf(a0 / (1.f + __expf(-a0)));
  o.y = f2bf(a1 / (1.f + __expf(-a1)));
  o.z = f2bf(a2 / (1.f + __expf(-a2)));
  o.w = f2bf(a3 / (1.f + __expf(-a3)));
  if (ch < 512)      *(ushort4*)&Xbf[row * DIN + ch] = o;
  else if (ch < 640) *(ushort4*)&Bbf[row * 128 + ch - 512] = o;
  else               *(ushort4*)&Cbf[row * 128 + ch - 640] = o;
}

// ---------------- dt logits: block = 32 rows, LDS-staged x and Wdt; f32-exact --------
__global__ __launch_bounds__(256) void dt_logits(
    const float* __restrict__ x, const float* __restrict__ Wdt,
    const float* __restrict__ bdt, const float* __restrict__ dtb,
    float* __restrict__ dtsp)
{
  __shared__ float xs[32][201];
  __shared__ float wdt_s[1600];
  long row0 = (long)blockIdx.x * 32;
  int tid = threadIdx.x;
#pragma unroll
  for (int s = 0; s < 25; ++s) {
    int e = tid + s * 256;
    int r = e / 200, c = e % 200;
    xs[r][c] = x[(row0 + r) * 200 + c];
  }
#pragma unroll
  for (int s = 0; s < 7; ++s) {
    int e = tid + s * 256;
    if (e < 1600) wdt_s[e] = Wdt[e];
  }
  __syncthreads();
  int r = tid >> 3, h = tid & 7;
  float acc = dtb[h] + bdt[h];
  for (int i = 0; i < 200; ++i)
    acc = fmaf(xs[r][i], wdt_s[i * 8 + h], acc);
  float sp = (acc > 20.f) ? acc : log1pf(__expf(acc));
  dtsp[(row0 + r) * NH + h] = sp;
}

// ---------------- cumsum only: wave per (b,h,c) ----------------
__global__ __launch_bounds__(256) void dt_cumsum4(
    const float* __restrict__ dtsp, const float* __restrict__ alog,
    float* __restrict__ acs)
{
  int g = ((int)blockIdx.x * 256 + (int)threadIdx.x) >> 6;
  int lane = threadIdx.x & 63;
  int c = g & 3, h = (g >> 2) & 7, b = g >> 5;
  float Ah = -__expf(alog[h]);
  long rowbase = (long)b * LSEQ + c * QLEN;
  long abase = (((long)b * NH + h) * NCHUNK + c) * QLEN;
  float v[4];
#pragma unroll
  for (int j = 0; j < 4; ++j)
    v[j] = dtsp[(rowbase + lane * 4 + j) * NH + h] * Ah;
  v[1] += v[0]; v[2] += v[1]; v[3] += v[2];
  float tot = v[3];
  float run = tot;
#pragma unroll
  for (int d = 1; d < 64; d <<= 1) {
    float t = __shfl_up(run, d);
    if (lane >= d) run += t;
  }
  float excl = run - tot;
#pragma unroll
  for (int j = 0; j < 4; ++j) acs[abase + lane * 4 + j] = excl + v[j];
}

// ---------------- Bbf [ROWS][128] -> BbfT [bc][128][256] ----------------
__global__ __launch_bounds__(256) void transB(const unsigned short* __restrict__ Bbf,
                                              unsigned short* __restrict__ BbfT)
{
  __shared__ unsigned short T[128][130];
  int bc = blockIdx.y, kh = blockIdx.x;
  int tid = threadIdx.x;
  long rowbase = (long)(bc >> 2) * LSEQ + (bc & 3) * QLEN + kh * 128;
  for (int e = tid; e < 128 * 128; e += 256) {
    int r = e >> 7, n = e & 127;
    T[r][n] = Bbf[(rowbase + r) * 128 + n];
  }
  __syncthreads();
  for (int e = tid; e < 128 * 128; e += 256) {
    int n = e >> 7, k = e & 127;
    BbfT[((long)bc * 128 + n) * 256 + kh * 128 + k] = T[k][n];
  }
}

// ---------------- yd+states: balanced q-block split {0,3}/{1,2}; bf16 st -------------
__global__ __launch_bounds__(256) void yd_states7(
    const unsigned short* __restrict__ Xbf, const float* __restrict__ dtsp,
    const float* __restrict__ acs, const unsigned short* __restrict__ Gbf,
    const unsigned short* __restrict__ BbfT,
    unsigned short* __restrict__ ybf, unsigned short* __restrict__ st)
{
  int bid = blockIdx.x;
  int xcd = bid & 7, i0 = bid >> 3;
  int bc = xcd * 8 + (i0 >> 4);
  int rem = i0 & 15, h = rem >> 1, half = rem & 1;
  int c = bc & 3, b = bc >> 2;
  int bch = bc * 8 + h;

  __shared__ __align__(16) unsigned short XdT[64][264];
  __shared__ float AcsS[256], E1f[256], E2f[256], dts[256];

  const int tid = threadIdx.x;
  const int lane = tid & 63, wv = tid >> 6;
  const bool ydw = wv < 2;
  // balanced triangle split: half0 -> q-blocks {0,3}; half1 -> {1,2}
  const int qb = half == 0 ? (wv == 0 ? 0 : 3) : (wv == 0 ? 1 : 2);
  const int q0 = qb * 64;
  const int n0w = half * 64 + (wv - 2) * 32;
  long rowbase = (long)b * LSEQ + c * QLEN;
  const unsigned short* Gb  = Gbf + (long)bc * 65536;
  const unsigned short* BTg = BbfT + (long)bc * 32768;

  AcsS[tid] = acs[(((long)b * NH + h) * NCHUNK + c) * QLEN + tid];
  dts[tid]  = dtsp[(rowbase + tid) * NH + h];
  __syncthreads();
  E1f[tid] = __expf(AcsS[tid] - AcsS[tid | 63]);
  E2f[tid] = __expf(AcsS[tid | 63] - AcsS[tid]);
  float rs_[4];
  rs_[0] = 1.f;
#pragma unroll
  for (int kt = 1; kt < 4; ++kt) rs_[kt] = __expf(AcsS[kt * 64 + 63] - AcsS[kt * 64 - 1]);
  __syncthreads();
  {
    int kb = wv * 64;
#pragma unroll
    for (int s = 0; s < 16; ++s) {
      int k4 = kb + s * 4;
      ushort4 pk;
      unsigned short* pp = (unsigned short*)&pk;
#pragma unroll
      for (int j = 0; j < 4; ++j) {
        int k = k4 + j;
        float v = bf2f(Xbf[(rowbase + k) * DIN + h * HD + lane]) * dts[k] * E2f[k];
        pp[j] = f2bf(v);
      }
      *(ushort4*)&XdT[lane][k4] = pk;
    }
  }
  __syncthreads();

  f32x4 accY[4][4], accS[4][2];
#pragma unroll
  for (int i = 0; i < 4; ++i)
#pragma unroll
    for (int j = 0; j < 4; ++j) accY[i][j] = (f32x4){0.f, 0.f, 0.f, 0.f};
#pragma unroll
  for (int i = 0; i < 4; ++i)
#pragma unroll
    for (int j = 0; j < 2; ++j) accS[i][j] = (f32x4){0.f, 0.f, 0.f, 0.f};

  for (int kt = 0; kt < 4; ++kt) {
    int qlo = kt * 64;
    if (ydw) {
      if (qb >= kt) {
        if (kt)
#pragma unroll
          for (int i = 0; i < 4; ++i)
#pragma unroll
            for (int j = 0; j < 4; ++j) accY[i][j] *= rs_[kt];
#pragma unroll
        for (int ks = 0; ks < 2; ++ks) {
          s16x8 bfr[4];
#pragma unroll
          for (int j = 0; j < 4; ++j)
            bfr[j] = *(const s16x8*)&XdT[j * 16 + (lane & 15)][qlo + ks * 32 + (lane >> 4) * 8];
#pragma unroll
          for (int i = 0; i < 4; ++i) {
            s16x8 a = *(const s16x8*)&Gb[(long)(q0 + i * 16 + (lane & 15)) * 256 + qlo + ks * 32 + (lane >> 4) * 8];
#pragma unroll
            for (int j = 0; j < 4; ++j)
              accY[i][j] = __builtin_amdgcn_mfma_f32_16x16x32_bf16(a, bfr[j], accY[i][j], 0, 0, 0);
          }
        }
      }
    } else {
      if (kt)
#pragma unroll
        for (int i = 0; i < 4; ++i)
#pragma unroll
          for (int j = 0; j < 2; ++j) accS[i][j] *= rs_[kt];
#pragma unroll
      for (int ks = 0; ks < 2; ++ks) {
        s16x8 afx[4];
#pragma unroll
        for (int i = 0; i < 4; ++i)
          afx[i] = *(const s16x8*)&XdT[i * 16 + (lane & 15)][qlo + ks * 32 + (lane >> 4) * 8];
#pragma unroll
        for (int j2 = 0; j2 < 2; ++j2) {
          s16x8 bt = *(const s16x8*)&BTg[(long)(n0w + j2 * 16 + (lane & 15)) * 256 + qlo + ks * 32 + (lane >> 4) * 8];
#pragma unroll
          for (int i = 0; i < 4; ++i)
            accS[i][j2] = __builtin_amdgcn_mfma_f32_16x16x32_bf16(afx[i], bt, accS[i][j2], 0, 0, 0);
        }
      }
    }
  }
  const int cr = (lane >> 4) * 4, cc = lane & 15;
  if (ydw) {
#pragma unroll
    for (int i = 0; i < 4; ++i)
#pragma unroll
      for (int j = 0; j < 4; ++j) {
        int q = q0 + i * 16 + cr;
        int p = j * 16 + cc;
#pragma unroll
        for (int r = 0; r < 4; ++r)
          ybf[(rowbase + q + r) * DIN + h * HD + p] = f2bf(accY[i][j][r] * E1f[q + r]);
      }
  } else {
#pragma unroll
    for (int i = 0; i < 4; ++i)
#pragma unroll
      for (int j2 = 0; j2 < 2; ++j2) {
        int p = i * 16 + cr;
        int n = n0w + j2 * 16 + cc;
#pragma unroll
        for (int r = 0; r < 4; ++r)
          st[(long)bch * 8192 + (long)(p + r) * 128 + n] = f2bf(accS[i][j2][r]);
      }
  }
}

// ---------------- inter-chunk scan (bf16 storage, f32 carry) ----------------
__global__ void scan_states(unsigned short* __restrict__ st, const float* __restrict__ acs)
{
  long idx = (long)blockIdx.x * 256 + threadIdx.x;       // ushort4 units
  if (idx >= (long)NB * NH * 2048) return;
  long inner = idx & 2047;
  int h = (int)((idx >> 11) & 7);
  int b = (int)(idx >> 14);
  f32x4 carry = {0.f, 0.f, 0.f, 0.f};
  for (int c = 0; c < NCHUNK; ++c) {
    float dc = __expf(acs[(((long)b * NH + h) * NCHUNK + c) * QLEN + (QLEN - 1)]);
    long si = (((long)(b * NCHUNK + c) * NH + h) << 13) + inner * 4;
    ushort4 s4 = *(ushort4*)&st[si];
    f32x4 s = {bf2f(s4.x), bf2f(s4.y), bf2f(s4.z), bf2f(s4.w)};
    ushort4 o = {f2bf(carry[0]), f2bf(carry[1]), f2bf(carry[2]), f2bf(carry[3])};
    *(ushort4*)&st[si] = o;
    carry = carry * dc + s;
  }
}

// ---------------- Yo via MFMA: prev bf16 (direct operand load) ----------------
__global__ __launch_bounds__(256) void yo_combine6(
    const unsigned short* __restrict__ Xbf, const unsigned short* __restrict__ Cbf,
    const unsigned short* __restrict__ prev, const float* __restrict__ acs,
    const float* __restrict__ Dp, unsigned short* __restrict__ ybf)
{
  int bid = blockIdx.x;
  int xcd = bid & 7, i0 = bid >> 3;
  int bc = xcd * 8 + (i0 >> 3), h = i0 & 7;
  int c = bc & 3, b = bc >> 2;
  int bch = bc * 8 + h;
  __shared__ float EqA[QLEN];
  const int tid = threadIdx.x;
  const int lane = tid & 63, wv = tid >> 6;
  long rowbase = (long)b * LSEQ + c * QLEN;
  EqA[tid] = __expf(acs[(((long)b * NH + h) * NCHUNK + c) * QLEN + tid]);
  __syncthreads();
  const unsigned short* Cb = Cbf + rowbase * 128;
  const unsigned short* pv = prev + (long)bch * 8192;
  f32x4 acc[4][4];
#pragma unroll
  for (int i = 0; i < 4; ++i)
#pragma unroll
    for (int j = 0; j < 4; ++j) acc[i][j] = (f32x4){0.f, 0.f, 0.f, 0.f};
#pragma unroll
  for (int ks = 0; ks < 4; ++ks) {
    int n0 = ks * 32 + (lane >> 4) * 8;
    s16x8 bf[4];
#pragma unroll
    for (int j = 0; j < 4; ++j) {
      int p = j * 16 + (lane & 15);
      bf[j] = *(const s16x8*)&pv[p * 128 + n0];
    }
#pragma unroll
    for (int i = 0; i < 4; ++i) {
      s16x8 af = *(const s16x8*)&Cb[(long)(wv * 64 + i * 16 + (lane & 15)) * 128 + n0];
#pragma unroll
      for (int j = 0; j < 4; ++j)
        acc[i][j] = __builtin_amdgcn_mfma_f32_16x16x32_bf16(af, bf[j], acc[i][j], 0, 0, 0);
    }
  }
  const int cr = (lane >> 4) * 4, cc = lane & 15;
  float Dh = Dp[h];
#pragma unroll
  for (int i = 0; i < 4; ++i)
#pragma unroll
    for (int j = 0; j < 4; ++j) {
      int q = wv * 64 + i * 16 + cr;
      int p = j * 16 + cc;
#pragma unroll
      for (int r = 0; r < 4; ++r) {
        long row = rowbase + q + r;
        long yi = row * DIN + h * HD + p;
        float xh = bf2f(Xbf[yi]);
        float pr = bf2f(ybf[yi]);
        ybf[yi] = f2bf(pr + acc[i][j][r] * EqA[q + r] + xh * Dh);
      }
    }
}

// ---------------- gated RMSNorm in place on ybf (bf16) ----------------
__global__ __launch_bounds__(256) void gated_rms3(
    unsigned short* __restrict__ ybf, const unsigned short* __restrict__ zxb,
    const float* __restrict__ rmsw)
{
  long row = blockIdx.x;
  int t = threadIdx.x;
  ushort2 yv = *(const ushort2*)&ybf[row * DIN + 2 * t];
  ushort2 zv = *(const ushort2*)&zxb[row * DPROJ + 2 * t];
  float z0 = bf2f(zv.x), z1 = bf2f(zv.y);
  float v0 = bf2f(yv.x) * (z0 / (1.f + __expf(-z0)));
  float v1 = bf2f(yv.y) * (z1 / (1.f + __expf(-z1)));
  float ss = v0 * v0 + v1 * v1;
#pragma unroll
  for (int off = 32; off; off >>= 1) ss += __shfl_down(ss, off);
  __shared__ float red[4];
  if ((t & 63) == 0) red[t >> 6] = ss;
  __syncthreads();
  float tot = red[0] + red[1] + red[2] + red[3];
  float scale = rsqrtf(tot * (1.f / DIN) + 1e-5f);
  ushort2 o;
  o.x = f2bf(v0 * scale * rmsw[2 * t]);
  o.y = f2bf(v1 * scale * rmsw[2 * t + 1]);
  *(ushort2*)&ybf[row * DIN + 2 * t] = o;
}

// ---------------- LN + classifier: wave per row, no LDS ----------------
__global__ __launch_bounds__(256) void ln_cls2(
    const unsigned short* __restrict__ y2b, const float* __restrict__ g,
    const float* __restrict__ bb, const float* __restrict__ wclsT,
    const float* __restrict__ bcls, float* __restrict__ out)
{
  long row = (long)blockIdx.x * 4 + (threadIdx.x >> 6);
  int lane = threadIdx.x & 63;
  ushort4 yv = *(const ushort4*)&y2b[row * DM + lane * 4];
  float v0 = bf2f(yv.x), v1 = bf2f(yv.y), v2 = bf2f(yv.z), v3 = bf2f(yv.w);
  float s = v0 + v1 + v2 + v3;
  float q = v0 * v0 + v1 * v1 + v2 * v2 + v3 * v3;
#pragma unroll
  for (int off = 32; off; off >>= 1) {
    s += __shfl_xor(s, off);
    q += __shfl_xor(q, off);
  }
  float mu = s * (1.f / DM);
  float rstd = rsqrtf(q * (1.f / DM) - mu * mu + 1e-5f);
  float4 gv = *(const float4*)&g[lane * 4];
  float4 bv = *(const float4*)&bb[lane * 4];
  float y0 = (v0 - mu) * rstd * gv.x + bv.x;
  float y1 = (v1 - mu) * rstd * gv.y + bv.y;
  float y2_ = (v2 - mu) * rstd * gv.z + bv.z;
  float y3 = (v3 - mu) * rstd * gv.w + bv.w;
  float accs[NCLS];
#pragma unroll
  for (int j = 0; j < NCLS; ++j) {
    float4 wv = *(const float4*)&wclsT[j * 256 + lane * 4];
    accs[j] = y0 * wv.x + y1 * wv.y + y2_ * wv.z + y3 * wv.w;
  }
#pragma unroll
  for (int off = 32; off; off >>= 1)
#pragma unroll
    for (int j = 0; j < NCLS; ++j) accs[j] += __shfl_xor(accs[j], off);
  float o = accs[0] + bcls[0];
#pragma unroll
  for (int j = 1; j < NCLS; ++j)
    if (lane == j) o = accs[j] + bcls[j];
  if (lane < NCLS) out[row * NCLS + lane] = o;
}

extern "C" void kernel_launch(void* const* d_in, const int* in_sizes, int n_in,
                              void* d_out, int out_size, void* d_ws, size_t ws_size,
                              hipStream_t stream)
{
  const float* x     = (const float*)d_in[0];
  const float* w_inp = (const float*)d_in[1];
  const float* b_inp = (const float*)d_in[2];
  const float* w_in  = (const float*)d_in[3];
  const float* convw = (const float*)d_in[4];
  const float* convb = (const float*)d_in[5];
  const float* dtb   = (const float*)d_in[6];
  const float* alog  = (const float*)d_in[7];
  const float* Dp    = (const float*)d_in[8];
  const float* rmsw  = (const float*)d_in[9];
  const float* wout  = (const float*)d_in[10];
  const float* lng   = (const float*)d_in[11];
  const float* lnb   = (const float*)d_in[12];
  const float* wcls  = (const float*)d_in[13];
  const float* bcls  = (const float*)d_in[14];
  float* out = (float*)d_out;
  float* ws  = (float*)d_ws;

  float* dtsp = ws + O_DT;
  float* acs  = ws + O_ACS;
  float* Wdt  = ws + O_WDT;
  float* bdt  = Wdt + 1600;
  float* wclsT= ws + O_WCLST;
  unsigned short* Gbf    = (unsigned short*)(ws + O_GBF);
  unsigned short* zxb    = (unsigned short*)(ws + O_ZX);
  unsigned short* Xbf    = (unsigned short*)(ws + O_XBF);
  unsigned short* Bbf    = (unsigned short*)(ws + O_BBF);
  unsigned short* Cbf    = (unsigned short*)(ws + O_CBF);
  unsigned short* BbfT   = (unsigned short*)(ws + O_BT);
  unsigned short* ybf    = (unsigned short*)(ws + O_YBF);
  unsigned short* xp_bf  = (unsigned short*)(ws + O_XPBF);
  unsigned short* WcombT = (unsigned short*)(ws + O_WCT);
  unsigned short* woutT  = (unsigned short*)(ws + O_WOUTT);
  unsigned short* w_inT  = (unsigned short*)(ws + O_WINT);
  unsigned short* we_bf  = (unsigned short*)(ws + O_WIPE);
  unsigned short* st     = (unsigned short*)(ws + O_ST);
  unsigned short* y2b    = (unsigned short*)(ws + O_Y2);

  prep_misc<<<5676, 256, 0, stream>>>(x, xp_bf, w_in, w_inT, wout, woutT,
                                      w_inp, b_inp, we_bf, Wdt, bdt, wcls, wclsT);
  gemm_bf16<<<dim3(2, 11), 256, 0, stream>>>(w_inT, we_bf, nullptr, WcombT, nullptr, 1408, 224, 256);
  gemm_bf16<<<dim3(11, 128), 256, 0, stream>>>(xp_bf, WcombT, nullptr, zxb, nullptr, 16384, DPROJ, 224);
  conv_silu3<<<12288, 256, 0, stream>>>(zxb, convw, convb, Xbf, Bbf, Cbf);
  dt_logits<<<512, 256, 0, stream>>>(x, Wdt, bdt, dtb, dtsp);
  dt_cumsum4<<<128, 256, 0, stream>>>(dtsp, alog, acs);
  transB<<<dim3(2, 64), 256, 0, stream>>>(Bbf, BbfT);
  g_gemm_bf16<<<dim3(2, 2, 64), 256, 0, stream>>>(Cbf, Bbf, Gbf);
  yd_states7<<<1024, 256, 0, stream>>>(Xbf, dtsp, acs, Gbf, BbfT, ybf, st);
  scan_states<<<1024, 256, 0, stream>>>(st, acs);
  yo_combine6<<<512, 256, 0, stream>>>(Xbf, Cbf, st, acs, Dp, ybf);
  gated_rms3<<<16384, 256, 0, stream>>>(ybf, zxb, rmsw);
  gemm_bf16<<<dim3(2, 128), 256, 0, stream>>>(ybf, woutT, nullptr, y2b, nullptr, 16384, DM, DIN);
  ln_cls2<<<4096, 256, 0, stream>>>(y2b, lng, lnb, wclsT, bcls, out);
}

// Round 14
// 190.384 us; speedup vs baseline: 6.6049x; 1.0997x over previous
//
#include <hip/hip_runtime.h>
#include <math.h>

#define ROWS   16384L
#define LSEQ   1024
#define NB     16
#define DM     256
#define DPROJ  1288
#define ZXW    1280          // zxb leading dim (dt cols dropped)
#define XBCW   768
#define DIN    512
#define DSTATE 128
#define NH     8
#define HD     64
#define QLEN   256
#define NCHUNK 4
#define NCLS   17

typedef __attribute__((ext_vector_type(8))) short s16x8;
typedef __attribute__((ext_vector_type(8))) unsigned short u16x8;
typedef __attribute__((ext_vector_type(4))) float f32x4;

#define GLOAD_LDS16(gsrc, ldst) \
  __builtin_amdgcn_global_load_lds((const __attribute__((address_space(1))) void*)(gsrc), \
      (__attribute__((address_space(3))) void*)(ldst), 16, 0, 0)

// ---- workspace map (float slots) ----
constexpr long O_GBF  = 0;
constexpr long O_ZX   = O_GBF + ROWS*DM;          // zxb bf16 [ROWS][1280]
constexpr long O_XBC  = O_ZX  + ROWS*DPROJ;
constexpr long O_DT   = O_XBC + ROWS*XBCW;
constexpr long O_ACS  = O_DT  + ROWS*NH;
constexpr long O_Y    = O_ACS + 131072;
constexpr long O_ST   = O_Y   + ROWS*DIN;         // st bf16 [512][64p][128n]
constexpr long O_Y2   = O_ST  + 4194304;
constexpr long O_XBF  = O_XBC;
constexpr long O_BBF  = O_XBC + 4200000;
constexpr long O_CBF  = O_XBC + 5300000;
constexpr long O_BT   = O_XBC + 6400000;
constexpr long O_YBF  = O_Y;
constexpr long O_XPBF = O_Y + 4300000;
constexpr long O_WCT  = O_Y + 6200000;
constexpr long O_WOUTT= O_Y + 6400000;
constexpr long O_WDT  = O_Y + 6500000;
constexpr long O_WCLST= O_Y + 6530000;
constexpr long O_WINT = O_Y + 6600000;
constexpr long O_WIPE = O_Y + 6800000;

__device__ inline unsigned short f2bf(float f) {
  union { float f; unsigned u; } v; v.f = f;
  unsigned r = v.u + 0x7FFFu + ((v.u >> 16) & 1u);
  return (unsigned short)(r >> 16);
}
__device__ inline float bf2f(unsigned short s) {
  union { unsigned u; float f; } v; v.u = ((unsigned)s) << 16; return v.f;
}

// bijective XCD-chunked swizzle (m204)
__device__ inline void xcd_swizzle(int gx, int& bx, int& by) {
  int nwg = gx * (int)gridDim.y;
  int lid = (int)blockIdx.y * gx + (int)blockIdx.x;
  int q = nwg >> 3, r = nwg & 7;
  int xcd = lid & 7, idx = lid >> 3;
  int base = xcd < r ? xcd * (q + 1) : r * (q + 1) + (xcd - r) * q;
  int w = base + idx;
  bx = w % gx; by = w / gx;
}

// ---------------- merged prep: block-range dispatch over 6 roles ----------------
__global__ __launch_bounds__(256) void prep_misc(
    const float* __restrict__ x, unsigned short* __restrict__ xp,
    const float* __restrict__ w_in, unsigned short* __restrict__ w_inT,
    const float* __restrict__ wout, unsigned short* __restrict__ woutT,
    const float* __restrict__ w_inp, const float* __restrict__ b_inp,
    unsigned short* __restrict__ we,
    float* __restrict__ Wdt, float* __restrict__ bdt,
    const float* __restrict__ wcls, float* __restrict__ wclsT)
{
  int bid = blockIdx.x;
  int tid = threadIdx.x;
  if (bid < 3584) {                                      // cast_pad_x (col 200 = 1.0)
    long idx = (long)bid * 256 + tid;
    int q = (int)(idx % 56);
    long row = idx / 56;
    ushort4 o = {0, 0, 0, 0};
    if (q < 50) {
      float4 v = *(const float4*)&x[row * 200 + q * 4];
      o.x = f2bf(v.x); o.y = f2bf(v.y); o.z = f2bf(v.z); o.w = f2bf(v.w);
    } else if (q == 50) {
      o.x = 0x3F80;
    }
    *(ushort4*)&xp[row * 224 + q * 4] = o;
  } else if (bid < 4872) {                               // tcast w_in -> w_inT [n][256]
    long i = (long)(bid - 3584) * 256 + tid;
    int k = (int)(i & 255);
    long n = i >> 8;
    w_inT[i] = f2bf(w_in[(long)k * DPROJ + n]);
  } else if (bid < 5384) {                               // tcast wout -> woutT [n][512]
    long i = (long)(bid - 4872) * 256 + tid;
    int k = (int)(i & 511);
    long n = i >> 9;
    woutT[i] = f2bf(wout[(long)k * DM + n]);
  } else if (bid < 5608) {                               // cast_winp_ext [224][256]
    int i = (bid - 5384) * 256 + tid;
    int k = i >> 8, j = i & 255;
    float v = 0.f;
    if (k < 200)       v = w_inp[(long)k * 256 + j];
    else if (k == 200) v = b_inp[j];
    we[i] = f2bf(v);
  } else if (bid < 5659) {                               // wdt_small (exact f32 dt weights)
    int k = (bid - 5608) * 4 + (tid >> 6);
    if (k > 200) return;
    int lane = tid & 63;
    int j0 = lane * 4;
    float4 xv = (k < 200) ? *(const float4*)&w_inp[(long)k * 256 + j0]
                          : *(const float4*)&b_inp[j0];
    float a0 = 0.f, a1 = 0.f, a2 = 0.f, a3 = 0.f, a4 = 0.f, a5 = 0.f, a6 = 0.f, a7 = 0.f;
    float xd[4] = {xv.x, xv.y, xv.z, xv.w};
#pragma unroll
    for (int d = 0; d < 4; ++d) {
      const float* wr = &w_in[(long)(j0 + d) * DPROJ + 1280];
      float4 wa = *(const float4*)wr;
      float4 wb = *(const float4*)(wr + 4);
      a0 = fmaf(xd[d], wa.x, a0); a1 = fmaf(xd[d], wa.y, a1);
      a2 = fmaf(xd[d], wa.z, a2); a3 = fmaf(xd[d], wa.w, a3);
      a4 = fmaf(xd[d], wb.x, a4); a5 = fmaf(xd[d], wb.y, a5);
      a6 = fmaf(xd[d], wb.z, a6); a7 = fmaf(xd[d], wb.w, a7);
    }
#pragma unroll
    for (int off = 32; off; off >>= 1) {
      a0 += __shfl_xor(a0, off); a1 += __shfl_xor(a1, off);
      a2 += __shfl_xor(a2, off); a3 += __shfl_xor(a3, off);
      a4 += __shfl_xor(a4, off); a5 += __shfl_xor(a5, off);
      a6 += __shfl_xor(a6, off); a7 += __shfl_xor(a7, off);
    }
    float o = a0;
    if (lane == 1) o = a1; if (lane == 2) o = a2; if (lane == 3) o = a3;
    if (lane == 4) o = a4; if (lane == 5) o = a5; if (lane == 6) o = a6;
    if (lane == 7) o = a7;
    if (lane < 8) {
      if (k < 200) Wdt[k * 8 + lane] = o;
      else         bdt[lane] = o;
    }
  } else {                                               // tpose_wcls
    int i = (bid - 5659) * 256 + tid;
    if (i < NCLS * 256) {
      int j = i >> 8, k = i & 255;
      wclsT[i] = wcls[(long)k * NCLS + j];
    }
  }
}

// ---------------- bf16 MFMA GEMM (global_load_lds staging + XCD swizzle) -------------
__global__ __launch_bounds__(256) void gemm_bf16(
    const unsigned short* __restrict__ A, const unsigned short* __restrict__ BT,
    float* __restrict__ C, unsigned short* __restrict__ Cb,
    const float* __restrict__ bias, int M, int N, int K)
{
  int bx, by;
  xcd_swizzle(gridDim.x, bx, by);
  __shared__ __align__(16) unsigned short As[128 * 32];
  __shared__ __align__(16) unsigned short Bs[128 * 32];
  const int tid = threadIdx.x;
  const int m0 = by * 128, n0 = bx * 128;
  const int lane = tid & 63, wv = tid >> 6;
  const int wr = (wv >> 1) * 64, wc = (wv & 1) * 64;
  f32x4 acc[4][4];
#pragma unroll
  for (int i = 0; i < 4; ++i)
#pragma unroll
    for (int j = 0; j < 4; ++j) acc[i][j] = (f32x4){0.f, 0.f, 0.f, 0.f};

  for (int k0 = 0; k0 < K; k0 += 32) {
    __syncthreads();
#pragma unroll
    for (int s = 0; s < 2; ++s) {
      int idx = (tid + 256 * s) * 8;
      int r = idx >> 5, kk = idx & 31;
      GLOAD_LDS16(&A[(long)(m0 + r) * K + k0 + kk], &As[idx]);
    }
#pragma unroll
    for (int s = 0; s < 2; ++s) {
      int idx = (tid + 256 * s) * 8;
      int n = idx >> 5, kk = idx & 31;
      int srcn = (n0 + n < N) ? (n0 + n) : 0;
      GLOAD_LDS16(&BT[(long)srcn * K + k0 + kk], &Bs[idx]);
    }
    __syncthreads();
    s16x8 af[4], bf[4];
#pragma unroll
    for (int i = 0; i < 4; ++i)
      af[i] = *(const s16x8*)&As[(wr + i * 16 + (lane & 15)) * 32 + (lane >> 4) * 8];
#pragma unroll
    for (int j = 0; j < 4; ++j)
      bf[j] = *(const s16x8*)&Bs[(wc + j * 16 + (lane & 15)) * 32 + (lane >> 4) * 8];
#pragma unroll
    for (int i = 0; i < 4; ++i)
#pragma unroll
      for (int j = 0; j < 4; ++j)
        acc[i][j] = __builtin_amdgcn_mfma_f32_16x16x32_bf16(af[i], bf[j], acc[i][j], 0, 0, 0);
  }
  const int cr = (lane >> 4) * 4, cc = lane & 15;
#pragma unroll
  for (int i = 0; i < 4; ++i)
#pragma unroll
    for (int j = 0; j < 4; ++j) {
      int col = n0 + wc + j * 16 + cc;
      if (col < N) {
        long rowb = (long)(m0 + wr + i * 16 + cr);
        float bv = bias ? bias[col] : 0.f;
#pragma unroll
        for (int r = 0; r < 4; ++r) {
          float v = acc[i][j][r] + bv;
          if (C)  C[(rowb + r) * N + col] = v;
          if (Cb) Cb[(rowb + r) * (long)N + col] = f2bf(v);
        }
      }
    }
}

// ---------------- merged transB + G-GEMM (block-range dispatch) ----------------
__global__ __launch_bounds__(256) void trans_g(
    const unsigned short* __restrict__ Bbf, unsigned short* __restrict__ BbfT,
    const unsigned short* __restrict__ Cbf, unsigned short* __restrict__ Gbf)
{
  const int bid = blockIdx.x;
  const int tid = threadIdx.x;
  if (bid < 128) {                                   // ---- transB ----
    __shared__ unsigned short T[128][130];
    int bc = bid >> 1, kh = bid & 1;
    long rowbase = (long)(bc >> 2) * LSEQ + (bc & 3) * QLEN + kh * 128;
    for (int e = tid; e < 128 * 128; e += 256) {
      int r = e >> 7, n = e & 127;
      T[r][n] = Bbf[(rowbase + r) * 128 + n];
    }
    __syncthreads();
    for (int e = tid; e < 128 * 128; e += 256) {
      int n = e >> 7, k = e & 127;
      BbfT[((long)bc * 128 + n) * 256 + kh * 128 + k] = T[k][n];
    }
    return;
  }
  if (bid >= 320) {                                  // ---- zero upper tile (m0=0,n0=128) ----
    int bc = bid - 320;
    unsigned short* Gout = Gbf + (long)bc * 65536;
    s16x8 z = {};
    for (int e = tid; e < 128 * 16; e += 256) {
      int r = e >> 4, seg = e & 15;
      *(s16x8*)&Gout[(long)r * 256 + 128 + seg * 8] = z;
    }
    return;
  }
  int bid2 = bid - 128;
  int t = bid2 % 3, bc = bid2 / 3;
  int m0 = (t == 0) ? 0 : 128;
  int n0 = (t == 2) ? 128 : 0;
  unsigned short* Gout = Gbf + (long)bc * 65536;
  long rowbase = (long)(bc >> 2) * LSEQ + (bc & 3) * QLEN;
  const unsigned short* A  = Cbf + rowbase * 128;
  const unsigned short* BT = Bbf + rowbase * 128;
  __shared__ __align__(16) unsigned short As[128 * 32];
  __shared__ __align__(16) unsigned short Bs[128 * 32];
  const int lane = tid & 63, wv = tid >> 6;
  const int wr = (wv >> 1) * 64, wc = (wv & 1) * 64;
  f32x4 acc[4][4];
#pragma unroll
  for (int i = 0; i < 4; ++i)
#pragma unroll
    for (int j = 0; j < 4; ++j) acc[i][j] = (f32x4){0.f, 0.f, 0.f, 0.f};
  for (int k0 = 0; k0 < 128; k0 += 32) {
    __syncthreads();
#pragma unroll
    for (int s = 0; s < 2; ++s) {
      int idx = (tid + 256 * s) * 8;
      int r = idx >> 5, kk = idx & 31;
      GLOAD_LDS16(&A[(long)(m0 + r) * 128 + k0 + kk], &As[idx]);
      GLOAD_LDS16(&BT[(long)(n0 + r) * 128 + k0 + kk], &Bs[idx]);
    }
    __syncthreads();
    s16x8 af[4], bf[4];
#pragma unroll
    for (int i = 0; i < 4; ++i)
      af[i] = *(const s16x8*)&As[(wr + i * 16 + (lane & 15)) * 32 + (lane >> 4) * 8];
#pragma unroll
    for (int j = 0; j < 4; ++j)
      bf[j] = *(const s16x8*)&Bs[(wc + j * 16 + (lane & 15)) * 32 + (lane >> 4) * 8];
#pragma unroll
    for (int i = 0; i < 4; ++i)
#pragma unroll
      for (int j = 0; j < 4; ++j)
        acc[i][j] = __builtin_amdgcn_mfma_f32_16x16x32_bf16(af[i], bf[j], acc[i][j], 0, 0, 0);
  }
  const int cr = (lane >> 4) * 4, cc = lane & 15;
#pragma unroll
  for (int i = 0; i < 4; ++i)
#pragma unroll
    for (int j = 0; j < 4; ++j) {
      int col = n0 + wc + j * 16 + cc;
      int qb = m0 + wr + i * 16 + cr;
#pragma unroll
      for (int r = 0; r < 4; ++r)
        Gout[(long)(qb + r) * 256 + col] = (col <= qb + r) ? f2bf(acc[i][j][r]) : (unsigned short)0;
    }
}

// ---------------- conv1d (k=4, causal) + SiLU, ushort8; zxb stride ZXW -----------------
__global__ __launch_bounds__(256) void conv_silu4(
    const unsigned short* __restrict__ zxb, const float* __restrict__ cw,
    const float* __restrict__ cb,
    unsigned short* __restrict__ Xbf, unsigned short* __restrict__ Bbf,
    unsigned short* __restrict__ Cbf)
{
  long idx = (long)blockIdx.x * 256 + threadIdx.x;
  if (idx >= ROWS * 96) return;
  int co = (int)(idx % 96);
  long row = idx / 96;
  int t = (int)(row & 1023);
  int ch = co * 8;
  float a[8];
  {
    float4 cb0 = *(const float4*)&cb[ch];
    float4 cb1 = *(const float4*)&cb[ch + 4];
    a[0] = cb0.x; a[1] = cb0.y; a[2] = cb0.z; a[3] = cb0.w;
    a[4] = cb1.x; a[5] = cb1.y; a[6] = cb1.z; a[7] = cb1.w;
  }
#pragma unroll
  for (int w = 0; w < 4; ++w) {
    int d = w - 3;
    if (t + d >= 0) {
      u16x8 zv = *(const u16x8*)&zxb[(row + d) * ZXW + 512 + ch];
      float4 cw0 = *(const float4*)&cw[w * XBCW + ch];
      float4 cw1 = *(const float4*)&cw[w * XBCW + ch + 4];
      a[0] = fmaf(bf2f(zv[0]), cw0.x, a[0]);
      a[1] = fmaf(bf2f(zv[1]), cw0.y, a[1]);
      a[2] = fmaf(bf2f(zv[2]), cw0.z, a[2]);
      a[3] = fmaf(bf2f(zv[3]), cw0.w, a[3]);
      a[4] = fmaf(bf2f(zv[4]), cw1.x, a[4]);
      a[5] = fmaf(bf2f(zv[5]), cw1.y, a[5]);
      a[6] = fmaf(bf2f(zv[6]), cw1.z, a[6]);
      a[7] = fmaf(bf2f(zv[7]), cw1.w, a[7]);
    }
  }
  u16x8 o;
#pragma unroll
  for (int i = 0; i < 8; ++i)
    o[i] = f2bf(a[i] / (1.f + __expf(-a[i])));
  if (ch < 512)      *(u16x8*)&Xbf[row * DIN + ch] = o;
  else if (ch < 640) *(u16x8*)&Bbf[row * 128 + ch - 512] = o;
  else               *(u16x8*)&Cbf[row * 128 + ch - 640] = o;
}

// ---------------- dt logits: block = 32 rows, LDS-staged x and Wdt; f32-exact --------
__global__ __launch_bounds__(256) void dt_logits(
    const float* __restrict__ x, const float* __restrict__ Wdt,
    const float* __restrict__ bdt, const float* __restrict__ dtb,
    float* __restrict__ dtsp)
{
  __shared__ float xs[32][201];
  __shared__ float wdt_s[1600];
  long row0 = (long)blockIdx.x * 32;
  int tid = threadIdx.x;
#pragma unroll
  for (int s = 0; s < 25; ++s) {
    int e = tid + s * 256;
    int r = e / 200, c = e % 200;
    xs[r][c] = x[(row0 + r) * 200 + c];
  }
#pragma unroll
  for (int s = 0; s < 7; ++s) {
    int e = tid + s * 256;
    if (e < 1600) wdt_s[e] = Wdt[e];
  }
  __syncthreads();
  int r = tid >> 3, h = tid & 7;
  float acc = dtb[h] + bdt[h];
  for (int i = 0; i < 200; ++i)
    acc = fmaf(xs[r][i], wdt_s[i * 8 + h], acc);
  float sp = (acc > 20.f) ? acc : log1pf(__expf(acc));
  dtsp[(row0 + r) * NH + h] = sp;
}

// ---------------- cumsum only: wave per (b,h,c) ----------------
__global__ __launch_bounds__(256) void dt_cumsum4(
    const float* __restrict__ dtsp, const float* __restrict__ alog,
    float* __restrict__ acs)
{
  int g = ((int)blockIdx.x * 256 + (int)threadIdx.x) >> 6;
  int lane = threadIdx.x & 63;
  int c = g & 3, h = (g >> 2) & 7, b = g >> 5;
  float Ah = -__expf(alog[h]);
  long rowbase = (long)b * LSEQ + c * QLEN;
  long abase = (((long)b * NH + h) * NCHUNK + c) * QLEN;
  float v[4];
#pragma unroll
  for (int j = 0; j < 4; ++j)
    v[j] = dtsp[(rowbase + lane * 4 + j) * NH + h] * Ah;
  v[1] += v[0]; v[2] += v[1]; v[3] += v[2];
  float tot = v[3];
  float run = tot;
#pragma unroll
  for (int d = 1; d < 64; d <<= 1) {
    float t = __shfl_up(run, d);
    if (lane >= d) run += t;
  }
  float excl = run - tot;
#pragma unroll
  for (int j = 0; j < 4; ++j) acs[abase + lane * 4 + j] = excl + v[j];
}

// ---------------- yd+states: balanced q-block split {0,3}/{1,2}; bf16 st -------------
__global__ __launch_bounds__(256) void yd_states7(
    const unsigned short* __restrict__ Xbf, const float* __restrict__ dtsp,
    const float* __restrict__ acs, const unsigned short* __restrict__ Gbf,
    const unsigned short* __restrict__ BbfT,
    unsigned short* __restrict__ ybf, unsigned short* __restrict__ st)
{
  int bid = blockIdx.x;
  int xcd = bid & 7, i0 = bid >> 3;
  int bc = xcd * 8 + (i0 >> 4);
  int rem = i0 & 15, h = rem >> 1, half = rem & 1;
  int c = bc & 3, b = bc >> 2;
  int bch = bc * 8 + h;

  __shared__ __align__(16) unsigned short XdT[64][264];
  __shared__ float AcsS[256], E1f[256], E2f[256], dts[256];

  const int tid = threadIdx.x;
  const int lane = tid & 63, wv = tid >> 6;
  const bool ydw = wv < 2;
  const int qb = half == 0 ? (wv == 0 ? 0 : 3) : (wv == 0 ? 1 : 2);
  const int q0 = qb * 64;
  const int n0w = half * 64 + (wv - 2) * 32;
  long rowbase = (long)b * LSEQ + c * QLEN;
  const unsigned short* Gb  = Gbf + (long)bc * 65536;
  const unsigned short* BTg = BbfT + (long)bc * 32768;

  AcsS[tid] = acs[(((long)b * NH + h) * NCHUNK + c) * QLEN + tid];
  dts[tid]  = dtsp[(rowbase + tid) * NH + h];
  __syncthreads();
  E1f[tid] = __expf(AcsS[tid] - AcsS[tid | 63]);
  E2f[tid] = __expf(AcsS[tid | 63] - AcsS[tid]);
  float rs_[4];
  rs_[0] = 1.f;
#pragma unroll
  for (int kt = 1; kt < 4; ++kt) rs_[kt] = __expf(AcsS[kt * 64 + 63] - AcsS[kt * 64 - 1]);
  __syncthreads();
  {
    int kb = wv * 64;
#pragma unroll
    for (int s = 0; s < 16; ++s) {
      int k4 = kb + s * 4;
      ushort4 pk;
      unsigned short* pp = (unsigned short*)&pk;
#pragma unroll
      for (int j = 0; j < 4; ++j) {
        int k = k4 + j;
        float v = bf2f(Xbf[(rowbase + k) * DIN + h * HD + lane]) * dts[k] * E2f[k];
        pp[j] = f2bf(v);
      }
      *(ushort4*)&XdT[lane][k4] = pk;
    }
  }
  __syncthreads();

  f32x4 accY[4][4], accS[4][2];
#pragma unroll
  for (int i = 0; i < 4; ++i)
#pragma unroll
    for (int j = 0; j < 4; ++j) accY[i][j] = (f32x4){0.f, 0.f, 0.f, 0.f};
#pragma unroll
  for (int i = 0; i < 4; ++i)
#pragma unroll
    for (int j = 0; j < 2; ++j) accS[i][j] = (f32x4){0.f, 0.f, 0.f, 0.f};

  for (int kt = 0; kt < 4; ++kt) {
    int qlo = kt * 64;
    if (ydw) {
      if (qb >= kt) {
        if (kt)
#pragma unroll
          for (int i = 0; i < 4; ++i)
#pragma unroll
            for (int j = 0; j < 4; ++j) accY[i][j] *= rs_[kt];
#pragma unroll
        for (int ks = 0; ks < 2; ++ks) {
          s16x8 bfr[4];
#pragma unroll
          for (int j = 0; j < 4; ++j)
            bfr[j] = *(const s16x8*)&XdT[j * 16 + (lane & 15)][qlo + ks * 32 + (lane >> 4) * 8];
#pragma unroll
          for (int i = 0; i < 4; ++i) {
            s16x8 a = *(const s16x8*)&Gb[(long)(q0 + i * 16 + (lane & 15)) * 256 + qlo + ks * 32 + (lane >> 4) * 8];
#pragma unroll
            for (int j = 0; j < 4; ++j)
              accY[i][j] = __builtin_amdgcn_mfma_f32_16x16x32_bf16(a, bfr[j], accY[i][j], 0, 0, 0);
          }
        }
      }
    } else {
      if (kt)
#pragma unroll
        for (int i = 0; i < 4; ++i)
#pragma unroll
          for (int j = 0; j < 2; ++j) accS[i][j] *= rs_[kt];
#pragma unroll
      for (int ks = 0; ks < 2; ++ks) {
        s16x8 afx[4];
#pragma unroll
        for (int i = 0; i < 4; ++i)
          afx[i] = *(const s16x8*)&XdT[i * 16 + (lane & 15)][qlo + ks * 32 + (lane >> 4) * 8];
#pragma unroll
        for (int j2 = 0; j2 < 2; ++j2) {
          s16x8 bt = *(const s16x8*)&BTg[(long)(n0w + j2 * 16 + (lane & 15)) * 256 + qlo + ks * 32 + (lane >> 4) * 8];
#pragma unroll
          for (int i = 0; i < 4; ++i)
            accS[i][j2] = __builtin_amdgcn_mfma_f32_16x16x32_bf16(afx[i], bt, accS[i][j2], 0, 0, 0);
        }
      }
    }
  }
  const int cr = (lane >> 4) * 4, cc = lane & 15;
  if (ydw) {
#pragma unroll
    for (int i = 0; i < 4; ++i)
#pragma unroll
      for (int j = 0; j < 4; ++j) {
        int q = q0 + i * 16 + cr;
        int p = j * 16 + cc;
#pragma unroll
        for (int r = 0; r < 4; ++r)
          ybf[(rowbase + q + r) * DIN + h * HD + p] = f2bf(accY[i][j][r] * E1f[q + r]);
      }
  } else {
#pragma unroll
    for (int i = 0; i < 4; ++i)
#pragma unroll
      for (int j2 = 0; j2 < 2; ++j2) {
        int p = i * 16 + cr;
        int n = n0w + j2 * 16 + cc;
#pragma unroll
        for (int r = 0; r < 4; ++r)
          st[(long)bch * 8192 + (long)(p + r) * 128 + n] = f2bf(accS[i][j2][r]);
      }
  }
}

// ---------------- inter-chunk scan (bf16 storage, f32 carry) ----------------
__global__ void scan_states(unsigned short* __restrict__ st, const float* __restrict__ acs)
{
  long idx = (long)blockIdx.x * 256 + threadIdx.x;
  if (idx >= (long)NB * NH * 2048) return;
  long inner = idx & 2047;
  int h = (int)((idx >> 11) & 7);
  int b = (int)(idx >> 14);
  f32x4 carry = {0.f, 0.f, 0.f, 0.f};
  for (int c = 0; c < NCHUNK; ++c) {
    float dc = __expf(acs[(((long)b * NH + h) * NCHUNK + c) * QLEN + (QLEN - 1)]);
    long si = (((long)(b * NCHUNK + c) * NH + h) << 13) + inner * 4;
    ushort4 s4 = *(ushort4*)&st[si];
    f32x4 s = {bf2f(s4.x), bf2f(s4.y), bf2f(s4.z), bf2f(s4.w)};
    ushort4 o = {f2bf(carry[0]), f2bf(carry[1]), f2bf(carry[2]), f2bf(carry[3])};
    *(ushort4*)&st[si] = o;
    carry = carry * dc + s;
  }
}

// ---------------- Yo via MFMA: prev bf16 direct operand ----------------
__global__ __launch_bounds__(256) void yo_combine6(
    const unsigned short* __restrict__ Xbf, const unsigned short* __restrict__ Cbf,
    const unsigned short* __restrict__ prev, const float* __restrict__ acs,
    const float* __restrict__ Dp, unsigned short* __restrict__ ybf)
{
  int bid = blockIdx.x;
  int xcd = bid & 7, i0 = bid >> 3;
  int bc = xcd * 8 + (i0 >> 3), h = i0 & 7;
  int c = bc & 3, b = bc >> 2;
  int bch = bc * 8 + h;
  __shared__ float EqA[QLEN];
  const int tid = threadIdx.x;
  const int lane = tid & 63, wv = tid >> 6;
  long rowbase = (long)b * LSEQ + c * QLEN;
  EqA[tid] = __expf(acs[(((long)b * NH + h) * NCHUNK + c) * QLEN + tid]);
  __syncthreads();
  const unsigned short* Cb = Cbf + rowbase * 128;
  const unsigned short* pv = prev + (long)bch * 8192;
  f32x4 acc[4][4];
#pragma unroll
  for (int i = 0; i < 4; ++i)
#pragma unroll
    for (int j = 0; j < 4; ++j) acc[i][j] = (f32x4){0.f, 0.f, 0.f, 0.f};
#pragma unroll
  for (int ks = 0; ks < 4; ++ks) {
    int n0 = ks * 32 + (lane >> 4) * 8;
    s16x8 bf[4];
#pragma unroll
    for (int j = 0; j < 4; ++j) {
      int p = j * 16 + (lane & 15);
      bf[j] = *(const s16x8*)&pv[p * 128 + n0];
    }
#pragma unroll
    for (int i = 0; i < 4; ++i) {
      s16x8 af = *(const s16x8*)&Cb[(long)(wv * 64 + i * 16 + (lane & 15)) * 128 + n0];
#pragma unroll
      for (int j = 0; j < 4; ++j)
        acc[i][j] = __builtin_amdgcn_mfma_f32_16x16x32_bf16(af, bf[j], acc[i][j], 0, 0, 0);
    }
  }
  const int cr = (lane >> 4) * 4, cc = lane & 15;
  float Dh = Dp[h];
#pragma unroll
  for (int i = 0; i < 4; ++i)
#pragma unroll
    for (int j = 0; j < 4; ++j) {
      int q = wv * 64 + i * 16 + cr;
      int p = j * 16 + cc;
#pragma unroll
      for (int r = 0; r < 4; ++r) {
        long row = rowbase + q + r;
        long yi = row * DIN + h * HD + p;
        float xh = bf2f(Xbf[yi]);
        float pr = bf2f(ybf[yi]);
        ybf[yi] = f2bf(pr + acc[i][j][r] * EqA[q + r] + xh * Dh);
      }
    }
}

// ---------------- gated RMSNorm: wave per row, ushort8; zxb stride ZXW ---------------
__global__ __launch_bounds__(256) void gated_rms4(
    unsigned short* __restrict__ ybf, const unsigned short* __restrict__ zxb,
    const float* __restrict__ rmsw)
{
  long row = (long)blockIdx.x * 4 + (threadIdx.x >> 6);
  int lane = threadIdx.x & 63;
  u16x8 yv = *(const u16x8*)&ybf[row * DIN + lane * 8];
  u16x8 zv = *(const u16x8*)&zxb[row * ZXW + lane * 8];
  float v[8];
  float ss = 0.f;
#pragma unroll
  for (int i = 0; i < 8; ++i) {
    float z = bf2f(zv[i]);
    v[i] = bf2f(yv[i]) * (z / (1.f + __expf(-z)));
    ss = fmaf(v[i], v[i], ss);
  }
#pragma unroll
  for (int off = 32; off; off >>= 1) ss += __shfl_xor(ss, off);
  float scale = rsqrtf(ss * (1.f / DIN) + 1e-5f);
  u16x8 o;
#pragma unroll
  for (int i = 0; i < 8; ++i) {
    float w = rmsw[lane * 8 + i];
    o[i] = f2bf(v[i] * scale * w);
  }
  *(u16x8*)&ybf[row * DIN + lane * 8] = o;
}

// ---------------- LN + classifier: wave per row, no LDS ----------------
__global__ __launch_bounds__(256) void ln_cls2(
    const unsigned short* __restrict__ y2b, const float* __restrict__ g,
    const float* __restrict__ bb, const float* __restrict__ wclsT,
    const float* __restrict__ bcls, float* __restrict__ out)
{
  long row = (long)blockIdx.x * 4 + (threadIdx.x >> 6);
  int lane = threadIdx.x & 63;
  ushort4 yv = *(const ushort4*)&y2b[row * DM + lane * 4];
  float v0 = bf2f(yv.x), v1 = bf2f(yv.y), v2 = bf2f(yv.z), v3 = bf2f(yv.w);
  float s = v0 + v1 + v2 + v3;
  float q = v0 * v0 + v1 * v1 + v2 * v2 + v3 * v3;
#pragma unroll
  for (int off = 32; off; off >>= 1) {
    s += __shfl_xor(s, off);
    q += __shfl_xor(q, off);
  }
  float mu = s * (1.f / DM);
  float rstd = rsqrtf(q * (1.f / DM) - mu * mu + 1e-5f);
  float4 gv = *(const float4*)&g[lane * 4];
  float4 bv = *(const float4*)&bb[lane * 4];
  float y0 = (v0 - mu) * rstd * gv.x + bv.x;
  float y1 = (v1 - mu) * rstd * gv.y + bv.y;
  float y2_ = (v2 - mu) * rstd * gv.z + bv.z;
  float y3 = (v3 - mu) * rstd * gv.w + bv.w;
  float accs[NCLS];
#pragma unroll
  for (int j = 0; j < NCLS; ++j) {
    float4 wv = *(const float4*)&wclsT[j * 256 + lane * 4];
    accs[j] = y0 * wv.x + y1 * wv.y + y2_ * wv.z + y3 * wv.w;
  }
#pragma unroll
  for (int off = 32; off; off >>= 1)
#pragma unroll
    for (int j = 0; j < NCLS; ++j) accs[j] += __shfl_xor(accs[j], off);
  float o = accs[0] + bcls[0];
#pragma unroll
  for (int j = 1; j < NCLS; ++j)
    if (lane == j) o = accs[j] + bcls[j];
  if (lane < NCLS) out[row * NCLS + lane] = o;
}

extern "C" void kernel_launch(void* const* d_in, const int* in_sizes, int n_in,
                              void* d_out, int out_size, void* d_ws, size_t ws_size,
                              hipStream_t stream)
{
  const float* x     = (const float*)d_in[0];
  const float* w_inp = (const float*)d_in[1];
  const float* b_inp = (const float*)d_in[2];
  const float* w_in  = (const float*)d_in[3];
  const float* convw = (const float*)d_in[4];
  const float* convb = (const float*)d_in[5];
  const float* dtb   = (const float*)d_in[6];
  const float* alog  = (const float*)d_in[7];
  const float* Dp    = (const float*)d_in[8];
  const float* rmsw  = (const float*)d_in[9];
  const float* wout  = (const float*)d_in[10];
  const float* lng   = (const float*)d_in[11];
  const float* lnb   = (const float*)d_in[12];
  const float* wcls  = (const float*)d_in[13];
  const float* bcls  = (const float*)d_in[14];
  float* out = (float*)d_out;
  float* ws  = (float*)d_ws;

  float* dtsp = ws + O_DT;
  float* acs  = ws + O_ACS;
  float* Wdt  = ws + O_WDT;
  float* bdt  = Wdt + 1600;
  float* wclsT= ws + O_WCLST;
  unsigned short* Gbf    = (unsigned short*)(ws + O_GBF);
  unsigned short* zxb    = (unsigned short*)(ws + O_ZX);
  unsigned short* Xbf    = (unsigned short*)(ws + O_XBF);
  unsigned short* Bbf    = (unsigned short*)(ws + O_BBF);
  unsigned short* Cbf    = (unsigned short*)(ws + O_CBF);
  unsigned short* BbfT   = (unsigned short*)(ws + O_BT);
  unsigned short* ybf    = (unsigned short*)(ws + O_YBF);
  unsigned short* xp_bf  = (unsigned short*)(ws + O_XPBF);
  unsigned short* WcombT = (unsigned short*)(ws + O_WCT);
  unsigned short* woutT  = (unsigned short*)(ws + O_WOUTT);
  unsigned short* w_inT  = (unsigned short*)(ws + O_WINT);
  unsigned short* we_bf  = (unsigned short*)(ws + O_WIPE);
  unsigned short* st     = (unsigned short*)(ws + O_ST);
  unsigned short* y2b    = (unsigned short*)(ws + O_Y2);

  prep_misc<<<5676, 256, 0, stream>>>(x, xp_bf, w_in, w_inT, wout, woutT,
                                      w_inp, b_inp, we_bf, Wdt, bdt, wcls, wclsT);
  gemm_bf16<<<dim3(2, 11), 256, 0, stream>>>(w_inT, we_bf, nullptr, WcombT, nullptr, 1408, 224, 256);
  // fused input_proj+in_proj, dt cols dropped; zxb row-stride = ZXW = 1280
  gemm_bf16<<<dim3(10, 128), 256, 0, stream>>>(xp_bf, WcombT, nullptr, zxb, nullptr, 16384, ZXW, 224);
  conv_silu4<<<6144, 256, 0, stream>>>(zxb, convw, convb, Xbf, Bbf, Cbf);
  dt_logits<<<512, 256, 0, stream>>>(x, Wdt, bdt, dtb, dtsp);
  dt_cumsum4<<<128, 256, 0, stream>>>(dtsp, alog, acs);
  trans_g<<<384, 256, 0, stream>>>(Bbf, BbfT, Cbf, Gbf);
  yd_states7<<<1024, 256, 0, stream>>>(Xbf, dtsp, acs, Gbf, BbfT, ybf, st);
  scan_states<<<1024, 256, 0, stream>>>(st, acs);
  yo_combine6<<<512, 256, 0, stream>>>(Xbf, Cbf, st, acs, Dp, ybf);
  gated_rms4<<<4096, 256, 0, stream>>>(ybf, zxb, rmsw);
  gemm_bf16<<<dim3(2, 128), 256, 0, stream>>>(ybf, woutT, nullptr, y2b, nullptr, 16384, DM, DIN);
  ln_cls2<<<4096, 256, 0, stream>>>(y2b, lng, lnb, wclsT, bcls, out);
}

// Round 15
// 184.442 us; speedup vs baseline: 6.8177x; 1.0322x over previous
//
#include <hip/hip_runtime.h>
#include <math.h>

#define ROWS   16384L
#define LSEQ   1024
#define NB     16
#define DM     256
#define DPROJ  1288
#define ZXW    1280          // zxb leading dim (dt cols dropped)
#define XBCW   768
#define DIN    512
#define DSTATE 128
#define NH     8
#define HD     64
#define QLEN   256
#define NCHUNK 4
#define NCLS   17

typedef __attribute__((ext_vector_type(8))) short s16x8;
typedef __attribute__((ext_vector_type(8))) unsigned short u16x8;
typedef __attribute__((ext_vector_type(4))) float f32x4;

#define GLOAD_LDS16(gsrc, ldst) \
  __builtin_amdgcn_global_load_lds((const __attribute__((address_space(1))) void*)(gsrc), \
      (__attribute__((address_space(3))) void*)(ldst), 16, 0, 0)

// ---- workspace map (float slots) ----
constexpr long O_GBF  = 0;
constexpr long O_ZX   = O_GBF + ROWS*DM;          // zxb bf16 [ROWS][1280]
constexpr long O_XBC  = O_ZX  + ROWS*DPROJ;
constexpr long O_DT   = O_XBC + ROWS*XBCW;
constexpr long O_ACS  = O_DT  + ROWS*NH;
constexpr long O_Y    = O_ACS + 131072;
constexpr long O_ST   = O_Y   + ROWS*DIN;         // st bf16 [512][64p][128n]
constexpr long O_Y2   = O_ST  + 4194304;
constexpr long O_XBF  = O_XBC;
constexpr long O_BBF  = O_XBC + 4200000;
constexpr long O_CBF  = O_XBC + 5300000;
constexpr long O_BT   = O_XBC + 6400000;
constexpr long O_YBF  = O_Y;
constexpr long O_XPBF = O_Y + 4300000;
constexpr long O_WCT  = O_Y + 6200000;
constexpr long O_WOUTT= O_Y + 6400000;
constexpr long O_WDT  = O_Y + 6500000;
constexpr long O_WCLST= O_Y + 6530000;
constexpr long O_WINT = O_Y + 6600000;
constexpr long O_WIPE = O_Y + 6800000;

__device__ inline unsigned short f2bf(float f) {
  union { float f; unsigned u; } v; v.f = f;
  unsigned r = v.u + 0x7FFFu + ((v.u >> 16) & 1u);
  return (unsigned short)(r >> 16);
}
__device__ inline float bf2f(unsigned short s) {
  union { unsigned u; float f; } v; v.u = ((unsigned)s) << 16; return v.f;
}

// bijective XCD-chunked swizzle (m204)
__device__ inline void xcd_swizzle(int gx, int& bx, int& by) {
  int nwg = gx * (int)gridDim.y;
  int lid = (int)blockIdx.y * gx + (int)blockIdx.x;
  int q = nwg >> 3, r = nwg & 7;
  int xcd = lid & 7, idx = lid >> 3;
  int base = xcd < r ? xcd * (q + 1) : r * (q + 1) + (xcd - r) * q;
  int w = base + idx;
  bx = w % gx; by = w / gx;
}

// ---------------- merged prep: block-range dispatch over 6 roles ----------------
__global__ __launch_bounds__(256) void prep_misc(
    const float* __restrict__ x, unsigned short* __restrict__ xp,
    const float* __restrict__ w_in, unsigned short* __restrict__ w_inT,
    const float* __restrict__ wout, unsigned short* __restrict__ woutT,
    const float* __restrict__ w_inp, const float* __restrict__ b_inp,
    unsigned short* __restrict__ we,
    float* __restrict__ Wdt, float* __restrict__ bdt,
    const float* __restrict__ wcls, float* __restrict__ wclsT)
{
  int bid = blockIdx.x;
  int tid = threadIdx.x;
  if (bid < 3584) {                                      // cast_pad_x (col 200 = 1.0)
    long idx = (long)bid * 256 + tid;
    int q = (int)(idx % 56);
    long row = idx / 56;
    ushort4 o = {0, 0, 0, 0};
    if (q < 50) {
      float4 v = *(const float4*)&x[row * 200 + q * 4];
      o.x = f2bf(v.x); o.y = f2bf(v.y); o.z = f2bf(v.z); o.w = f2bf(v.w);
    } else if (q == 50) {
      o.x = 0x3F80;
    }
    *(ushort4*)&xp[row * 224 + q * 4] = o;
  } else if (bid < 4872) {                               // tcast w_in -> w_inT [n][256]
    long i = (long)(bid - 3584) * 256 + tid;
    int k = (int)(i & 255);
    long n = i >> 8;
    w_inT[i] = f2bf(w_in[(long)k * DPROJ + n]);
  } else if (bid < 5384) {                               // tcast wout -> woutT [n][512]
    long i = (long)(bid - 4872) * 256 + tid;
    int k = (int)(i & 511);
    long n = i >> 9;
    woutT[i] = f2bf(wout[(long)k * DM + n]);
  } else if (bid < 5608) {                               // cast_winp_ext [224][256]
    int i = (bid - 5384) * 256 + tid;
    int k = i >> 8, j = i & 255;
    float v = 0.f;
    if (k < 200)       v = w_inp[(long)k * 256 + j];
    else if (k == 200) v = b_inp[j];
    we[i] = f2bf(v);
  } else if (bid < 5659) {                               // wdt_small (exact f32 dt weights)
    int k = (bid - 5608) * 4 + (tid >> 6);
    if (k > 200) return;
    int lane = tid & 63;
    int j0 = lane * 4;
    float4 xv = (k < 200) ? *(const float4*)&w_inp[(long)k * 256 + j0]
                          : *(const float4*)&b_inp[j0];
    float a0 = 0.f, a1 = 0.f, a2 = 0.f, a3 = 0.f, a4 = 0.f, a5 = 0.f, a6 = 0.f, a7 = 0.f;
    float xd[4] = {xv.x, xv.y, xv.z, xv.w};
#pragma unroll
    for (int d = 0; d < 4; ++d) {
      const float* wr = &w_in[(long)(j0 + d) * DPROJ + 1280];
      float4 wa = *(const float4*)wr;
      float4 wb = *(const float4*)(wr + 4);
      a0 = fmaf(xd[d], wa.x, a0); a1 = fmaf(xd[d], wa.y, a1);
      a2 = fmaf(xd[d], wa.z, a2); a3 = fmaf(xd[d], wa.w, a3);
      a4 = fmaf(xd[d], wb.x, a4); a5 = fmaf(xd[d], wb.y, a5);
      a6 = fmaf(xd[d], wb.z, a6); a7 = fmaf(xd[d], wb.w, a7);
    }
#pragma unroll
    for (int off = 32; off; off >>= 1) {
      a0 += __shfl_xor(a0, off); a1 += __shfl_xor(a1, off);
      a2 += __shfl_xor(a2, off); a3 += __shfl_xor(a3, off);
      a4 += __shfl_xor(a4, off); a5 += __shfl_xor(a5, off);
      a6 += __shfl_xor(a6, off); a7 += __shfl_xor(a7, off);
    }
    float o = a0;
    if (lane == 1) o = a1; if (lane == 2) o = a2; if (lane == 3) o = a3;
    if (lane == 4) o = a4; if (lane == 5) o = a5; if (lane == 6) o = a6;
    if (lane == 7) o = a7;
    if (lane < 8) {
      if (k < 200) Wdt[k * 8 + lane] = o;
      else         bdt[lane] = o;
    }
  } else {                                               // tpose_wcls
    int i = (bid - 5659) * 256 + tid;
    if (i < NCLS * 256) {
      int j = i >> 8, k = i & 255;
      wclsT[i] = wcls[(long)k * NCLS + j];
    }
  }
}

// ---------------- bf16 MFMA GEMM (global_load_lds staging + XCD swizzle) -------------
__global__ __launch_bounds__(256) void gemm_bf16(
    const unsigned short* __restrict__ A, const unsigned short* __restrict__ BT,
    float* __restrict__ C, unsigned short* __restrict__ Cb,
    const float* __restrict__ bias, int M, int N, int K)
{
  int bx, by;
  xcd_swizzle(gridDim.x, bx, by);
  __shared__ __align__(16) unsigned short As[128 * 32];
  __shared__ __align__(16) unsigned short Bs[128 * 32];
  const int tid = threadIdx.x;
  const int m0 = by * 128, n0 = bx * 128;
  const int lane = tid & 63, wv = tid >> 6;
  const int wr = (wv >> 1) * 64, wc = (wv & 1) * 64;
  f32x4 acc[4][4];
#pragma unroll
  for (int i = 0; i < 4; ++i)
#pragma unroll
    for (int j = 0; j < 4; ++j) acc[i][j] = (f32x4){0.f, 0.f, 0.f, 0.f};

  for (int k0 = 0; k0 < K; k0 += 32) {
    __syncthreads();
#pragma unroll
    for (int s = 0; s < 2; ++s) {
      int idx = (tid + 256 * s) * 8;
      int r = idx >> 5, kk = idx & 31;
      GLOAD_LDS16(&A[(long)(m0 + r) * K + k0 + kk], &As[idx]);
    }
#pragma unroll
    for (int s = 0; s < 2; ++s) {
      int idx = (tid + 256 * s) * 8;
      int n = idx >> 5, kk = idx & 31;
      int srcn = (n0 + n < N) ? (n0 + n) : 0;
      GLOAD_LDS16(&BT[(long)srcn * K + k0 + kk], &Bs[idx]);
    }
    __syncthreads();
    s16x8 af[4], bf[4];
#pragma unroll
    for (int i = 0; i < 4; ++i)
      af[i] = *(const s16x8*)&As[(wr + i * 16 + (lane & 15)) * 32 + (lane >> 4) * 8];
#pragma unroll
    for (int j = 0; j < 4; ++j)
      bf[j] = *(const s16x8*)&Bs[(wc + j * 16 + (lane & 15)) * 32 + (lane >> 4) * 8];
    __builtin_amdgcn_s_setprio(1);
#pragma unroll
    for (int i = 0; i < 4; ++i)
#pragma unroll
      for (int j = 0; j < 4; ++j)
        acc[i][j] = __builtin_amdgcn_mfma_f32_16x16x32_bf16(af[i], bf[j], acc[i][j], 0, 0, 0);
    __builtin_amdgcn_s_setprio(0);
  }
  const int cr = (lane >> 4) * 4, cc = lane & 15;
#pragma unroll
  for (int i = 0; i < 4; ++i)
#pragma unroll
    for (int j = 0; j < 4; ++j) {
      int col = n0 + wc + j * 16 + cc;
      if (col < N) {
        long rowb = (long)(m0 + wr + i * 16 + cr);
        float bv = bias ? bias[col] : 0.f;
#pragma unroll
        for (int r = 0; r < 4; ++r) {
          float v = acc[i][j][r] + bv;
          if (C)  C[(rowb + r) * N + col] = v;
          if (Cb) Cb[(rowb + r) * (long)N + col] = f2bf(v);
        }
      }
    }
}

// ---------------- merged transB + G-GEMM (block-range dispatch) ----------------
__global__ __launch_bounds__(256) void trans_g(
    const unsigned short* __restrict__ Bbf, unsigned short* __restrict__ BbfT,
    const unsigned short* __restrict__ Cbf, unsigned short* __restrict__ Gbf)
{
  const int bid = blockIdx.x;
  const int tid = threadIdx.x;
  if (bid < 128) {                                   // ---- transB ----
    __shared__ unsigned short T[128][130];
    int bc = bid >> 1, kh = bid & 1;
    long rowbase = (long)(bc >> 2) * LSEQ + (bc & 3) * QLEN + kh * 128;
    for (int e = tid; e < 128 * 128; e += 256) {
      int r = e >> 7, n = e & 127;
      T[r][n] = Bbf[(rowbase + r) * 128 + n];
    }
    __syncthreads();
    for (int e = tid; e < 128 * 128; e += 256) {
      int n = e >> 7, k = e & 127;
      BbfT[((long)bc * 128 + n) * 256 + kh * 128 + k] = T[k][n];
    }
    return;
  }
  if (bid >= 320) {                                  // ---- zero upper tile (m0=0,n0=128) ----
    int bc = bid - 320;
    unsigned short* Gout = Gbf + (long)bc * 65536;
    s16x8 z = {};
    for (int e = tid; e < 128 * 16; e += 256) {
      int r = e >> 4, seg = e & 15;
      *(s16x8*)&Gout[(long)r * 256 + 128 + seg * 8] = z;
    }
    return;
  }
  int bid2 = bid - 128;
  int t = bid2 % 3, bc = bid2 / 3;
  int m0 = (t == 0) ? 0 : 128;
  int n0 = (t == 2) ? 128 : 0;
  unsigned short* Gout = Gbf + (long)bc * 65536;
  long rowbase = (long)(bc >> 2) * LSEQ + (bc & 3) * QLEN;
  const unsigned short* A  = Cbf + rowbase * 128;
  const unsigned short* BT = Bbf + rowbase * 128;
  __shared__ __align__(16) unsigned short As[128 * 32];
  __shared__ __align__(16) unsigned short Bs[128 * 32];
  const int lane = tid & 63, wv = tid >> 6;
  const int wr = (wv >> 1) * 64, wc = (wv & 1) * 64;
  f32x4 acc[4][4];
#pragma unroll
  for (int i = 0; i < 4; ++i)
#pragma unroll
    for (int j = 0; j < 4; ++j) acc[i][j] = (f32x4){0.f, 0.f, 0.f, 0.f};
  for (int k0 = 0; k0 < 128; k0 += 32) {
    __syncthreads();
#pragma unroll
    for (int s = 0; s < 2; ++s) {
      int idx = (tid + 256 * s) * 8;
      int r = idx >> 5, kk = idx & 31;
      GLOAD_LDS16(&A[(long)(m0 + r) * 128 + k0 + kk], &As[idx]);
      GLOAD_LDS16(&BT[(long)(n0 + r) * 128 + k0 + kk], &Bs[idx]);
    }
    __syncthreads();
    s16x8 af[4], bf[4];
#pragma unroll
    for (int i = 0; i < 4; ++i)
      af[i] = *(const s16x8*)&As[(wr + i * 16 + (lane & 15)) * 32 + (lane >> 4) * 8];
#pragma unroll
    for (int j = 0; j < 4; ++j)
      bf[j] = *(const s16x8*)&Bs[(wc + j * 16 + (lane & 15)) * 32 + (lane >> 4) * 8];
    __builtin_amdgcn_s_setprio(1);
#pragma unroll
    for (int i = 0; i < 4; ++i)
#pragma unroll
      for (int j = 0; j < 4; ++j)
        acc[i][j] = __builtin_amdgcn_mfma_f32_16x16x32_bf16(af[i], bf[j], acc[i][j], 0, 0, 0);
    __builtin_amdgcn_s_setprio(0);
  }
  const int cr = (lane >> 4) * 4, cc = lane & 15;
#pragma unroll
  for (int i = 0; i < 4; ++i)
#pragma unroll
    for (int j = 0; j < 4; ++j) {
      int col = n0 + wc + j * 16 + cc;
      int qb = m0 + wr + i * 16 + cr;
#pragma unroll
      for (int r = 0; r < 4; ++r)
        Gout[(long)(qb + r) * 256 + col] = (col <= qb + r) ? f2bf(acc[i][j][r]) : (unsigned short)0;
    }
}

// ---------------- conv1d (k=4, causal) + SiLU: 4-timestep x 8-channel tiles ----------
__global__ __launch_bounds__(256) void conv_silu5(
    const unsigned short* __restrict__ zxb, const float* __restrict__ cw,
    const float* __restrict__ cb,
    unsigned short* __restrict__ Xbf, unsigned short* __restrict__ Bbf,
    unsigned short* __restrict__ Cbf)
{
  long idx = (long)blockIdx.x * 256 + threadIdx.x;     // (b, tq, ch-oct)
  if (idx >= (ROWS / 4) * 96) return;
  int co = (int)(idx % 96);
  long tmp = idx / 96;
  int tq = (int)(tmp & 255);
  int b = (int)(tmp >> 8);
  int ch = co * 8;
  long row0 = (long)b * LSEQ + tq * 4;
  // 7 input rows (t offsets -3..+3 of row0); zero the causal out-of-range taps
  u16x8 zv[7];
#pragma unroll
  for (int j = 0; j < 7; ++j) {
    if (j >= 3 || tq > 0)
      zv[j] = *(const u16x8*)&zxb[(row0 + j - 3) * ZXW + 512 + ch];
    else
      zv[j] = (u16x8){0, 0, 0, 0, 0, 0, 0, 0};
  }
  float cwv[4][8], cbv[8];
  {
    float4 b0 = *(const float4*)&cb[ch];
    float4 b1 = *(const float4*)&cb[ch + 4];
    cbv[0] = b0.x; cbv[1] = b0.y; cbv[2] = b0.z; cbv[3] = b0.w;
    cbv[4] = b1.x; cbv[5] = b1.y; cbv[6] = b1.z; cbv[7] = b1.w;
  }
#pragma unroll
  for (int w = 0; w < 4; ++w) {
    float4 c0 = *(const float4*)&cw[w * XBCW + ch];
    float4 c1 = *(const float4*)&cw[w * XBCW + ch + 4];
    cwv[w][0] = c0.x; cwv[w][1] = c0.y; cwv[w][2] = c0.z; cwv[w][3] = c0.w;
    cwv[w][4] = c1.x; cwv[w][5] = c1.y; cwv[w][6] = c1.z; cwv[w][7] = c1.w;
  }
#pragma unroll
  for (int i = 0; i < 4; ++i) {
    float a[8];
#pragma unroll
    for (int k = 0; k < 8; ++k) a[k] = cbv[k];
#pragma unroll
    for (int w = 0; w < 4; ++w) {
#pragma unroll
      for (int k = 0; k < 8; ++k)
        a[k] = fmaf(bf2f(zv[i + w][k]), cwv[w][k], a[k]);
    }
    u16x8 o;
#pragma unroll
    for (int k = 0; k < 8; ++k)
      o[k] = f2bf(a[k] / (1.f + __expf(-a[k])));
    long row = row0 + i;
    if (ch < 512)      *(u16x8*)&Xbf[row * DIN + ch] = o;
    else if (ch < 640) *(u16x8*)&Bbf[row * 128 + ch - 512] = o;
    else               *(u16x8*)&Cbf[row * 128 + ch - 640] = o;
  }
}

// ---------------- dt logits: block = 32 rows, LDS-staged x and Wdt; f32-exact --------
__global__ __launch_bounds__(256) void dt_logits(
    const float* __restrict__ x, const float* __restrict__ Wdt,
    const float* __restrict__ bdt, const float* __restrict__ dtb,
    float* __restrict__ dtsp)
{
  __shared__ float xs[32][201];
  __shared__ float wdt_s[1600];
  long row0 = (long)blockIdx.x * 32;
  int tid = threadIdx.x;
#pragma unroll
  for (int s = 0; s < 25; ++s) {
    int e = tid + s * 256;
    int r = e / 200, c = e % 200;
    xs[r][c] = x[(row0 + r) * 200 + c];
  }
#pragma unroll
  for (int s = 0; s < 7; ++s) {
    int e = tid + s * 256;
    if (e < 1600) wdt_s[e] = Wdt[e];
  }
  __syncthreads();
  int r = tid >> 3, h = tid & 7;
  float acc = dtb[h] + bdt[h];
  for (int i = 0; i < 200; ++i)
    acc = fmaf(xs[r][i], wdt_s[i * 8 + h], acc);
  float sp = (acc > 20.f) ? acc : log1pf(__expf(acc));
  dtsp[(row0 + r) * NH + h] = sp;
}

// ---------------- cumsum only: wave per (b,h,c) ----------------
__global__ __launch_bounds__(256) void dt_cumsum4(
    const float* __restrict__ dtsp, const float* __restrict__ alog,
    float* __restrict__ acs)
{
  int g = ((int)blockIdx.x * 256 + (int)threadIdx.x) >> 6;
  int lane = threadIdx.x & 63;
  int c = g & 3, h = (g >> 2) & 7, b = g >> 5;
  float Ah = -__expf(alog[h]);
  long rowbase = (long)b * LSEQ + c * QLEN;
  long abase = (((long)b * NH + h) * NCHUNK + c) * QLEN;
  float v[4];
#pragma unroll
  for (int j = 0; j < 4; ++j)
    v[j] = dtsp[(rowbase + lane * 4 + j) * NH + h] * Ah;
  v[1] += v[0]; v[2] += v[1]; v[3] += v[2];
  float tot = v[3];
  float run = tot;
#pragma unroll
  for (int d = 1; d < 64; d <<= 1) {
    float t = __shfl_up(run, d);
    if (lane >= d) run += t;
  }
  float excl = run - tot;
#pragma unroll
  for (int j = 0; j < 4; ++j) acs[abase + lane * 4 + j] = excl + v[j];
}

// ---------------- yd+states: balanced q-block split {0,3}/{1,2}; bf16 st -------------
__global__ __launch_bounds__(256) void yd_states7(
    const unsigned short* __restrict__ Xbf, const float* __restrict__ dtsp,
    const float* __restrict__ acs, const unsigned short* __restrict__ Gbf,
    const unsigned short* __restrict__ BbfT,
    unsigned short* __restrict__ ybf, unsigned short* __restrict__ st)
{
  int bid = blockIdx.x;
  int xcd = bid & 7, i0 = bid >> 3;
  int bc = xcd * 8 + (i0 >> 4);
  int rem = i0 & 15, h = rem >> 1, half = rem & 1;
  int c = bc & 3, b = bc >> 2;
  int bch = bc * 8 + h;

  __shared__ __align__(16) unsigned short XdT[64][264];
  __shared__ float AcsS[256], E1f[256], E2f[256], dts[256];

  const int tid = threadIdx.x;
  const int lane = tid & 63, wv = tid >> 6;
  const bool ydw = wv < 2;
  const int qb = half == 0 ? (wv == 0 ? 0 : 3) : (wv == 0 ? 1 : 2);
  const int q0 = qb * 64;
  const int n0w = half * 64 + (wv - 2) * 32;
  long rowbase = (long)b * LSEQ + c * QLEN;
  const unsigned short* Gb  = Gbf + (long)bc * 65536;
  const unsigned short* BTg = BbfT + (long)bc * 32768;

  AcsS[tid] = acs[(((long)b * NH + h) * NCHUNK + c) * QLEN + tid];
  dts[tid]  = dtsp[(rowbase + tid) * NH + h];
  __syncthreads();
  E1f[tid] = __expf(AcsS[tid] - AcsS[tid | 63]);
  E2f[tid] = __expf(AcsS[tid | 63] - AcsS[tid]);
  float rs_[4];
  rs_[0] = 1.f;
#pragma unroll
  for (int kt = 1; kt < 4; ++kt) rs_[kt] = __expf(AcsS[kt * 64 + 63] - AcsS[kt * 64 - 1]);
  __syncthreads();
  {
    int kb = wv * 64;
#pragma unroll
    for (int s = 0; s < 16; ++s) {
      int k4 = kb + s * 4;
      ushort4 pk;
      unsigned short* pp = (unsigned short*)&pk;
#pragma unroll
      for (int j = 0; j < 4; ++j) {
        int k = k4 + j;
        float v = bf2f(Xbf[(rowbase + k) * DIN + h * HD + lane]) * dts[k] * E2f[k];
        pp[j] = f2bf(v);
      }
      *(ushort4*)&XdT[lane][k4] = pk;
    }
  }
  __syncthreads();

  f32x4 accY[4][4], accS[4][2];
#pragma unroll
  for (int i = 0; i < 4; ++i)
#pragma unroll
    for (int j = 0; j < 4; ++j) accY[i][j] = (f32x4){0.f, 0.f, 0.f, 0.f};
#pragma unroll
  for (int i = 0; i < 4; ++i)
#pragma unroll
    for (int j = 0; j < 2; ++j) accS[i][j] = (f32x4){0.f, 0.f, 0.f, 0.f};

  for (int kt = 0; kt < 4; ++kt) {
    int qlo = kt * 64;
    if (ydw) {
      if (qb >= kt) {
        if (kt)
#pragma unroll
          for (int i = 0; i < 4; ++i)
#pragma unroll
            for (int j = 0; j < 4; ++j) accY[i][j] *= rs_[kt];
#pragma unroll
        for (int ks = 0; ks < 2; ++ks) {
          s16x8 bfr[4];
#pragma unroll
          for (int j = 0; j < 4; ++j)
            bfr[j] = *(const s16x8*)&XdT[j * 16 + (lane & 15)][qlo + ks * 32 + (lane >> 4) * 8];
          __builtin_amdgcn_s_setprio(1);
#pragma unroll
          for (int i = 0; i < 4; ++i) {
            s16x8 a = *(const s16x8*)&Gb[(long)(q0 + i * 16 + (lane & 15)) * 256 + qlo + ks * 32 + (lane >> 4) * 8];
#pragma unroll
            for (int j = 0; j < 4; ++j)
              accY[i][j] = __builtin_amdgcn_mfma_f32_16x16x32_bf16(a, bfr[j], accY[i][j], 0, 0, 0);
          }
          __builtin_amdgcn_s_setprio(0);
        }
      }
    } else {
      if (kt)
#pragma unroll
        for (int i = 0; i < 4; ++i)
#pragma unroll
          for (int j = 0; j < 2; ++j) accS[i][j] *= rs_[kt];
#pragma unroll
      for (int ks = 0; ks < 2; ++ks) {
        s16x8 afx[4];
#pragma unroll
        for (int i = 0; i < 4; ++i)
          afx[i] = *(const s16x8*)&XdT[i * 16 + (lane & 15)][qlo + ks * 32 + (lane >> 4) * 8];
        __builtin_amdgcn_s_setprio(1);
#pragma unroll
        for (int j2 = 0; j2 < 2; ++j2) {
          s16x8 bt = *(const s16x8*)&BTg[(long)(n0w + j2 * 16 + (lane & 15)) * 256 + qlo + ks * 32 + (lane >> 4) * 8];
#pragma unroll
          for (int i = 0; i < 4; ++i)
            accS[i][j2] = __builtin_amdgcn_mfma_f32_16x16x32_bf16(afx[i], bt, accS[i][j2], 0, 0, 0);
        }
        __builtin_amdgcn_s_setprio(0);
      }
    }
  }
  const int cr = (lane >> 4) * 4, cc = lane & 15;
  if (ydw) {
#pragma unroll
    for (int i = 0; i < 4; ++i)
#pragma unroll
      for (int j = 0; j < 4; ++j) {
        int q = q0 + i * 16 + cr;
        int p = j * 16 + cc;
#pragma unroll
        for (int r = 0; r < 4; ++r)
          ybf[(rowbase + q + r) * DIN + h * HD + p] = f2bf(accY[i][j][r] * E1f[q + r]);
      }
  } else {
#pragma unroll
    for (int i = 0; i < 4; ++i)
#pragma unroll
      for (int j2 = 0; j2 < 2; ++j2) {
        int p = i * 16 + cr;
        int n = n0w + j2 * 16 + cc;
#pragma unroll
        for (int r = 0; r < 4; ++r)
          st[(long)bch * 8192 + (long)(p + r) * 128 + n] = f2bf(accS[i][j2][r]);
      }
  }
}

// ---------------- inter-chunk scan (bf16 storage, f32 carry) ----------------
__global__ void scan_states(unsigned short* __restrict__ st, const float* __restrict__ acs)
{
  long idx = (long)blockIdx.x * 256 + threadIdx.x;
  if (idx >= (long)NB * NH * 2048) return;
  long inner = idx & 2047;
  int h = (int)((idx >> 11) & 7);
  int b = (int)(idx >> 14);
  f32x4 carry = {0.f, 0.f, 0.f, 0.f};
  for (int c = 0; c < NCHUNK; ++c) {
    float dc = __expf(acs[(((long)b * NH + h) * NCHUNK + c) * QLEN + (QLEN - 1)]);
    long si = (((long)(b * NCHUNK + c) * NH + h) << 13) + inner * 4;
    ushort4 s4 = *(ushort4*)&st[si];
    f32x4 s = {bf2f(s4.x), bf2f(s4.y), bf2f(s4.z), bf2f(s4.w)};
    ushort4 o = {f2bf(carry[0]), f2bf(carry[1]), f2bf(carry[2]), f2bf(carry[3])};
    *(ushort4*)&st[si] = o;
    carry = carry * dc + s;
  }
}

// ---------------- Yo via MFMA: prev bf16 direct operand ----------------
__global__ __launch_bounds__(256) void yo_combine6(
    const unsigned short* __restrict__ Xbf, const unsigned short* __restrict__ Cbf,
    const unsigned short* __restrict__ prev, const float* __restrict__ acs,
    const float* __restrict__ Dp, unsigned short* __restrict__ ybf)
{
  int bid = blockIdx.x;
  int xcd = bid & 7, i0 = bid >> 3;
  int bc = xcd * 8 + (i0 >> 3), h = i0 & 7;
  int c = bc & 3, b = bc >> 2;
  int bch = bc * 8 + h;
  __shared__ float EqA[QLEN];
  const int tid = threadIdx.x;
  const int lane = tid & 63, wv = tid >> 6;
  long rowbase = (long)b * LSEQ + c * QLEN;
  EqA[tid] = __expf(acs[(((long)b * NH + h) * NCHUNK + c) * QLEN + tid]);
  __syncthreads();
  const unsigned short* Cb = Cbf + rowbase * 128;
  const unsigned short* pv = prev + (long)bch * 8192;
  f32x4 acc[4][4];
#pragma unroll
  for (int i = 0; i < 4; ++i)
#pragma unroll
    for (int j = 0; j < 4; ++j) acc[i][j] = (f32x4){0.f, 0.f, 0.f, 0.f};
#pragma unroll
  for (int ks = 0; ks < 4; ++ks) {
    int n0 = ks * 32 + (lane >> 4) * 8;
    s16x8 bf[4];
#pragma unroll
    for (int j = 0; j < 4; ++j) {
      int p = j * 16 + (lane & 15);
      bf[j] = *(const s16x8*)&pv[p * 128 + n0];
    }
    __builtin_amdgcn_s_setprio(1);
#pragma unroll
    for (int i = 0; i < 4; ++i) {
      s16x8 af = *(const s16x8*)&Cb[(long)(wv * 64 + i * 16 + (lane & 15)) * 128 + n0];
#pragma unroll
      for (int j = 0; j < 4; ++j)
        acc[i][j] = __builtin_amdgcn_mfma_f32_16x16x32_bf16(af, bf[j], acc[i][j], 0, 0, 0);
    }
    __builtin_amdgcn_s_setprio(0);
  }
  const int cr = (lane >> 4) * 4, cc = lane & 15;
  float Dh = Dp[h];
#pragma unroll
  for (int i = 0; i < 4; ++i)
#pragma unroll
    for (int j = 0; j < 4; ++j) {
      int q = wv * 64 + i * 16 + cr;
      int p = j * 16 + cc;
#pragma unroll
      for (int r = 0; r < 4; ++r) {
        long row = rowbase + q + r;
        long yi = row * DIN + h * HD + p;
        float xh = bf2f(Xbf[yi]);
        float pr = bf2f(ybf[yi]);
        ybf[yi] = f2bf(pr + acc[i][j][r] * EqA[q + r] + xh * Dh);
      }
    }
}

// ---------------- gated RMSNorm: wave per row, ushort8; zxb stride ZXW ---------------
__global__ __launch_bounds__(256) void gated_rms4(
    unsigned short* __restrict__ ybf, const unsigned short* __restrict__ zxb,
    const float* __restrict__ rmsw)
{
  long row = (long)blockIdx.x * 4 + (threadIdx.x >> 6);
  int lane = threadIdx.x & 63;
  u16x8 yv = *(const u16x8*)&ybf[row * DIN + lane * 8];
  u16x8 zv = *(const u16x8*)&zxb[row * ZXW + lane * 8];
  float v[8];
  float ss = 0.f;
#pragma unroll
  for (int i = 0; i < 8; ++i) {
    float z = bf2f(zv[i]);
    v[i] = bf2f(yv[i]) * (z / (1.f + __expf(-z)));
    ss = fmaf(v[i], v[i], ss);
  }
#pragma unroll
  for (int off = 32; off; off >>= 1) ss += __shfl_xor(ss, off);
  float scale = rsqrtf(ss * (1.f / DIN) + 1e-5f);
  u16x8 o;
#pragma unroll
  for (int i = 0; i < 8; ++i) {
    float w = rmsw[lane * 8 + i];
    o[i] = f2bf(v[i] * scale * w);
  }
  *(u16x8*)&ybf[row * DIN + lane * 8] = o;
}

// ---------------- LN + classifier: wave per row, no LDS ----------------
__global__ __launch_bounds__(256) void ln_cls2(
    const unsigned short* __restrict__ y2b, const float* __restrict__ g,
    const float* __restrict__ bb, const float* __restrict__ wclsT,
    const float* __restrict__ bcls, float* __restrict__ out)
{
  long row = (long)blockIdx.x * 4 + (threadIdx.x >> 6);
  int lane = threadIdx.x & 63;
  ushort4 yv = *(const ushort4*)&y2b[row * DM + lane * 4];
  float v0 = bf2f(yv.x), v1 = bf2f(yv.y), v2 = bf2f(yv.z), v3 = bf2f(yv.w);
  float s = v0 + v1 + v2 + v3;
  float q = v0 * v0 + v1 * v1 + v2 * v2 + v3 * v3;
#pragma unroll
  for (int off = 32; off; off >>= 1) {
    s += __shfl_xor(s, off);
    q += __shfl_xor(q, off);
  }
  float mu = s * (1.f / DM);
  float rstd = rsqrtf(q * (1.f / DM) - mu * mu + 1e-5f);
  float4 gv = *(const float4*)&g[lane * 4];
  float4 bv = *(const float4*)&bb[lane * 4];
  float y0 = (v0 - mu) * rstd * gv.x + bv.x;
  float y1 = (v1 - mu) * rstd * gv.y + bv.y;
  float y2_ = (v2 - mu) * rstd * gv.z + bv.z;
  float y3 = (v3 - mu) * rstd * gv.w + bv.w;
  float accs[NCLS];
#pragma unroll
  for (int j = 0; j < NCLS; ++j) {
    float4 wv = *(const float4*)&wclsT[j * 256 + lane * 4];
    accs[j] = y0 * wv.x + y1 * wv.y + y2_ * wv.z + y3 * wv.w;
  }
#pragma unroll
  for (int off = 32; off; off >>= 1)
#pragma unroll
    for (int j = 0; j < NCLS; ++j) accs[j] += __shfl_xor(accs[j], off);
  float o = accs[0] + bcls[0];
#pragma unroll
  for (int j = 1; j < NCLS; ++j)
    if (lane == j) o = accs[j] + bcls[j];
  if (lane < NCLS) out[row * NCLS + lane] = o;
}

extern "C" void kernel_launch(void* const* d_in, const int* in_sizes, int n_in,
                              void* d_out, int out_size, void* d_ws, size_t ws_size,
                              hipStream_t stream)
{
  const float* x     = (const float*)d_in[0];
  const float* w_inp = (const float*)d_in[1];
  const float* b_inp = (const float*)d_in[2];
  const float* w_in  = (const float*)d_in[3];
  const float* convw = (const float*)d_in[4];
  const float* convb = (const float*)d_in[5];
  const float* dtb   = (const float*)d_in[6];
  const float* alog  = (const float*)d_in[7];
  const float* Dp    = (const float*)d_in[8];
  const float* rmsw  = (const float*)d_in[9];
  const float* wout  = (const float*)d_in[10];
  const float* lng   = (const float*)d_in[11];
  const float* lnb   = (const float*)d_in[12];
  const float* wcls  = (const float*)d_in[13];
  const float* bcls  = (const float*)d_in[14];
  float* out = (float*)d_out;
  float* ws  = (float*)d_ws;

  float* dtsp = ws + O_DT;
  float* acs  = ws + O_ACS;
  float* Wdt  = ws + O_WDT;
  float* bdt  = Wdt + 1600;
  float* wclsT= ws + O_WCLST;
  unsigned short* Gbf    = (unsigned short*)(ws + O_GBF);
  unsigned short* zxb    = (unsigned short*)(ws + O_ZX);
  unsigned short* Xbf    = (unsigned short*)(ws + O_XBF);
  unsigned short* Bbf    = (unsigned short*)(ws + O_BBF);
  unsigned short* Cbf    = (unsigned short*)(ws + O_CBF);
  unsigned short* BbfT   = (unsigned short*)(ws + O_BT);
  unsigned short* ybf    = (unsigned short*)(ws + O_YBF);
  unsigned short* xp_bf  = (unsigned short*)(ws + O_XPBF);
  unsigned short* WcombT = (unsigned short*)(ws + O_WCT);
  unsigned short* woutT  = (unsigned short*)(ws + O_WOUTT);
  unsigned short* w_inT  = (unsigned short*)(ws + O_WINT);
  unsigned short* we_bf  = (unsigned short*)(ws + O_WIPE);
  unsigned short* st     = (unsigned short*)(ws + O_ST);
  unsigned short* y2b    = (unsigned short*)(ws + O_Y2);

  prep_misc<<<5676, 256, 0, stream>>>(x, xp_bf, w_in, w_inT, wout, woutT,
                                      w_inp, b_inp, we_bf, Wdt, bdt, wcls, wclsT);
  gemm_bf16<<<dim3(2, 11), 256, 0, stream>>>(w_inT, we_bf, nullptr, WcombT, nullptr, 1408, 224, 256);
  gemm_bf16<<<dim3(10, 128), 256, 0, stream>>>(xp_bf, WcombT, nullptr, zxb, nullptr, 16384, ZXW, 224);
  conv_silu5<<<1536, 256, 0, stream>>>(zxb, convw, convb, Xbf, Bbf, Cbf);
  dt_logits<<<512, 256, 0, stream>>>(x, Wdt, bdt, dtb, dtsp);
  dt_cumsum4<<<128, 256, 0, stream>>>(dtsp, alog, acs);
  trans_g<<<384, 256, 0, stream>>>(Bbf, BbfT, Cbf, Gbf);
  yd_states7<<<1024, 256, 0, stream>>>(Xbf, dtsp, acs, Gbf, BbfT, ybf, st);
  scan_states<<<1024, 256, 0, stream>>>(st, acs);
  yo_combine6<<<512, 256, 0, stream>>>(Xbf, Cbf, st, acs, Dp, ybf);
  gated_rms4<<<4096, 256, 0, stream>>>(ybf, zxb, rmsw);
  gemm_bf16<<<dim3(2, 128), 256, 0, stream>>>(ybf, woutT, nullptr, y2b, nullptr, 16384, DM, DIN);
  ln_cls2<<<4096, 256, 0, stream>>>(y2b, lng, lnb, wclsT, bcls, out);
}